// Round 3
// baseline (9007.042 us; speedup 1.0000x reference)
//
#include <hip/hip_runtime.h>
#include <hip/hip_bf16.h>

// TorchMD_GN_Ext R3: MFMA-ized edge/node GEMMs (mfma_f32_16x16x32_bf16).
// 64-row x 128-col tiles, 256 threads (4 waves, one 16-row band each).
// Weights pre-packed into B-fragment order; attr recomputed in-kernel.
// Dtype probe (bf16 vs f32 inputs) retained from R2; MFMA kernels read
// pre-converted ws copies only. Workspace ~46MB (same envelope as R2).

#define NATOMS 10000
#define NEDGES 320000
#define HC 128
#define RBF 50
#define NLAY 6
#define MAXZ_ 100
#define NCHUNK 4
#define CA (NATOMS / NCHUNK)        // 2500 atoms/chunk
#define MAXCE 96000                 // max edges/chunk (mean 80000)
#define EGRID (MAXCE / 64)          // 1500 blocks of 64 edges
#define AGRID ((CA + 63) / 64)      // 40
#define YGRID ((NATOMS + 63) / 64)  // 157

typedef __hip_bfloat16 bf16;
typedef __attribute__((ext_vector_type(8))) short bf8v;   // 8 bf16 (4 VGPRs)
typedef __attribute__((ext_vector_type(4))) float f4v;    // 4 fp32 acc

__device__ __forceinline__ float b2f(bf16 v) { return __bfloat162float(v); }
__device__ __forceinline__ bf16  f2b(float v) { return __float2bfloat16(v); }

template<int ISF>
__device__ __forceinline__ float LD(const void* p, size_t i) {
    if (ISF) return ((const float*)p)[i];
    return b2f(((const bf16*)p)[i]);
}

// ---------------- dtype probe ----------------
__global__ void probe_k(const void* pos, int nelem, int* flag) {
    int i = blockIdx.x * 256 + threadIdx.x;
    float v = 0.0f;
    if (i < nelem) {
        v = fabsf(b2f(((const bf16*)pos)[i]));
        if (v != v) v = 1e30f;
    }
    atomicMax(flag, __float_as_int(v));
}
__global__ void setflag_k(int* flag) {
    if (threadIdx.x == 0) flag[1] = (__int_as_float(flag[0]) > 1.0e4f) ? 1 : 0;
}

// ---------------- CSR build ----------------
__global__ void zero_k(int* p, int n) {
    int i = blockIdx.x * 256 + threadIdx.x;
    if (i < n) p[i] = 0;
}
__device__ __forceinline__ int clampN(int v) {
    return v < 0 ? 0 : (v >= NATOMS ? NATOMS - 1 : v);
}
__global__ void hist_k(const int* __restrict__ dst, int* __restrict__ counts) {
    int e = blockIdx.x * 256 + threadIdx.x;
    if (e < NEDGES) atomicAdd(&counts[clampN(dst[e])], 1);
}
__global__ void scan_k(const int* __restrict__ counts, int* __restrict__ rowptr) {
    __shared__ int lds[1024];
    __shared__ int carry;
    int tid = threadIdx.x;
    if (tid == 0) { carry = 0; rowptr[0] = 0; }
    __syncthreads();
    for (int base = 0; base < NATOMS; base += 1024) {
        int i = base + tid;
        int v = (i < NATOMS) ? counts[i] : 0;
        lds[tid] = v;
        __syncthreads();
        for (int off = 1; off < 1024; off <<= 1) {
            int t = (tid >= off) ? lds[tid - off] : 0;
            __syncthreads();
            lds[tid] += t;
            __syncthreads();
        }
        if (i < NATOMS) rowptr[i + 1] = lds[tid] + carry;
        __syncthreads();
        if (tid == 0) carry += lds[1023];
        __syncthreads();
    }
}
__global__ void copy_k(const int* __restrict__ a, int* __restrict__ b, int n) {
    int i = blockIdx.x * 256 + threadIdx.x;
    if (i < n) b[i] = a[i];
}
__global__ void perm_k(const int* __restrict__ dst, int* __restrict__ cursor,
                       int* __restrict__ perm) {
    int e = blockIdx.x * 256 + threadIdx.x;
    if (e < NEDGES) {
        int p = atomicAdd(&cursor[clampN(dst[e])], 1);
        perm[p] = e;
    }
}

// ---------------- geometry ----------------
template<int ISF>
__device__ void geom_body(const int* __restrict__ ei, const void* __restrict__ pos,
                          const int* __restrict__ perm,
                          float* __restrict__ C_s, float* __restrict__ Cm_s,
                          float* __restrict__ ed_s, int* __restrict__ src_s) {
    int i = blockIdx.x * 256 + threadIdx.x;
    if (i >= NEDGES) return;
    int e = perm[i];
    int s = clampN(ei[e]);
    int t = clampN(ei[NEDGES + e]);
    float dx = LD<ISF>(pos, (size_t)s * 3 + 0) - LD<ISF>(pos, (size_t)t * 3 + 0);
    float dy = LD<ISF>(pos, (size_t)s * 3 + 1) - LD<ISF>(pos, (size_t)t * 3 + 1);
    float dz = LD<ISF>(pos, (size_t)s * 3 + 2) - LD<ISF>(pos, (size_t)t * 3 + 2);
    float d = sqrtf(dx * dx + dy * dy + dz * dz + 1e-12f);
    if (d != d) d = 1e30f;
    float C = (d < 5.0f) ? 0.5f * (__cosf(d * 0.6283185307f) + 1.0f) : 0.0f;
    C_s[i] = C;
    Cm_s[i] = (s != t) ? C : 0.0f;
    ed_s[i] = __expf(-d);
    src_s[i] = s;
}
__global__ void geom_k(const int* ei, const void* pos, const int* perm, const int* flagp,
                       float* C_s, float* Cm_s, float* ed_s, int* src_s) {
    if (flagp[1]) geom_body<1>(ei, pos, perm, C_s, Cm_s, ed_s, src_s);
    else          geom_body<0>(ei, pos, perm, C_s, Cm_s, ed_s, src_s);
}

// ---------------- weight pack/convert ----------------
// Pack K x 128 row-major weight into B-fragment order:
// dst[l][((nt*ksteps+ks)*64+lane)*8 + j] = W[l][k=ks*32+(lane>>4)*8+j][n=nt*16+(lane&15)]
template<int ISF>
__device__ void packB_body(const void* src, int K, int ksteps, size_t perLsrc,
                           size_t perLdst, int L, bf16* dst) {
    int t = blockIdx.x * 256 + threadIdx.x;
    int total = L * 8 * ksteps * 64;
    if (t >= total) return;
    int lane = t & 63;
    int t2 = t >> 6;
    int ks = t2 % ksteps;
    int t3 = t2 / ksteps;
    int nt = t3 & 7;
    int l  = t3 >> 3;
    int quad = lane >> 4, lc = lane & 15;
    int col = nt * 16 + lc;
    for (int j = 0; j < 8; j++) {
        int k = ks * 32 + quad * 8 + j;
        float v = (k < K) ? LD<ISF>(src, (size_t)l * perLsrc + (size_t)k * 128 + col) : 0.0f;
        dst[(size_t)l * perLdst + ((size_t)((nt * ksteps + ks) * 64 + lane)) * 8 + j] = f2b(v);
    }
}
__global__ void packB_k(const void* src, int K, int ksteps, size_t perLsrc,
                        size_t perLdst, int L, const int* flagp, bf16* dst) {
    if (flagp[1]) packB_body<1>(src, K, ksteps, perLsrc, perLdst, L, dst);
    else          packB_body<0>(src, K, ksteps, perLsrc, perLdst, L, dst);
}
template<int ISF>
__device__ void cvt_body(const void* src, int n, float* dst) {
    int i = blockIdx.x * 256 + threadIdx.x;
    if (i < n) dst[i] = LD<ISF>(src, i);
}
__global__ void cvt_k(const void* src, int n, const int* flagp, float* dst) {
    if (flagp[1]) cvt_body<1>(src, n, dst);
    else          cvt_body<0>(src, n, dst);
}

// ---------------- MFMA helpers ----------------
#define MFMA(a, b, c) __builtin_amdgcn_mfma_f32_16x16x32_bf16((a), (b), (c), 0, 0, 0)

// attr tile compute: 64 edges x 64 k (50 real + 14 pad) into LDS bf16 [64][72]
__device__ __forceinline__ void attr_tile(bf16 (*attr)[72], int i0, int e1,
                                          const float* __restrict__ C_s,
                                          const float* __restrict__ ed_s,
                                          const float* __restrict__ meanscv,
                                          const float* __restrict__ betascv,
                                          int tid) {
    int m = tid >> 2, rg = (tid & 3) * 16;
    int i = i0 + m;
    float Ci = 0.0f, edi = 0.0f;
    if (i < e1) { Ci = C_s[i]; edi = ed_s[i]; }
    #pragma unroll
    for (int rr = 0; rr < 16; rr++) {
        int r = rg + rr;
        float v = 0.0f;
        if (r < RBF) {
            float u = edi - meanscv[r];
            v = Ci * __expf(-betascv[r] * u * u);
        }
        attr[m][r] = f2b(v);
    }
}

// ---------------- neighbor-embedding edge kernel (MFMA, GEMM1 only) -------
__global__ __launch_bounds__(256)
void nbr_mfma_k(const int* __restrict__ rowptr, int a0, int a1,
                const float* __restrict__ ed_s, const float* __restrict__ C_s,
                const float* __restrict__ Cm_s, const int* __restrict__ src_s,
                const int* __restrict__ z, const float* __restrict__ nbrembcv,
                const bf16* __restrict__ wpp, const float* __restrict__ bpcv,
                const float* __restrict__ meanscv, const float* __restrict__ betascv,
                bf16* __restrict__ medge) {
    __shared__ bf16 attr[64][72];
    int e0 = rowptr[a0], e1 = rowptr[a1];
    int i0 = e0 + blockIdx.x * 64;
    if (i0 >= e1) return;
    int tid = threadIdx.x;
    attr_tile(attr, i0, e1, C_s, ed_s, meanscv, betascv, tid);
    __syncthreads();

    int wave = tid >> 6, lane = tid & 63, quad = lane >> 4, lc = lane & 15;
    bf8v af[2];
    #pragma unroll
    for (int ks = 0; ks < 2; ks++)
        af[ks] = *(const bf8v*)&attr[wave * 16 + lc][ks * 32 + quad * 8];
    f4v zero = {0.f, 0.f, 0.f, 0.f};
    f4v acc[8];
    #pragma unroll
    for (int nt = 0; nt < 8; nt++) acc[nt] = zero;
    #pragma unroll
    for (int nt = 0; nt < 8; nt++)
        #pragma unroll
        for (int ks = 0; ks < 2; ks++) {
            bf8v b = *(const bf8v*)(wpp + ((nt * 2 + ks) * 64 + lane) * 8);
            acc[nt] = MFMA(af[ks], b, acc[nt]);
        }
    // epilogue: (acc + bp[n]) * Cm * nbr_emb[z[src]][n]
    float Cr[4]; int zr[4]; int ir[4]; bool val[4];
    #pragma unroll
    for (int r = 0; r < 4; r++) {
        int m = wave * 16 + quad * 4 + r;
        int i = i0 + m;
        ir[r] = i; val[r] = (i < e1);
        Cr[r] = 0.0f; zr[r] = 0;
        if (val[r]) {
            Cr[r] = Cm_s[i];
            int zz = z[src_s[i]];
            zr[r] = (zz < 0) ? 0 : (zz >= MAXZ_ ? MAXZ_ - 1 : zz);
        }
    }
    #pragma unroll
    for (int nt = 0; nt < 8; nt++) {
        int n = nt * 16 + lc;
        float bb = bpcv[n];
        #pragma unroll
        for (int r = 0; r < 4; r++) {
            if (val[r]) {
                float v = (acc[nt][r] + bb) * Cr[r] * nbrembcv[(size_t)zr[r] * HC + n];
                medge[(size_t)(ir[r] - e0) * HC + n] = f2b(v);
            }
        }
    }
}

__global__ void nbr_aggr_k(const int* __restrict__ rowptr, int a0,
                           const bf16* __restrict__ medge, float* __restrict__ msg) {
    int n = a0 + blockIdx.x, f = threadIdx.x;
    int e0 = rowptr[a0];
    float acc = 0.0f;
    int i1 = rowptr[n + 1];
    for (int i = rowptr[n]; i < i1; i++) acc += b2f(medge[(size_t)(i - e0) * HC + f]);
    msg[(size_t)n * HC + f] = acc;
}

template<int ISF>
__device__ void combine_body(const int* __restrict__ z, const void* __restrict__ emb,
                             const float* __restrict__ msg, const void* __restrict__ Wc,
                             const void* __restrict__ bc, float* __restrict__ x,
                             bf16* __restrict__ xb) {
    __shared__ float row[2 * HC];
    int n = blockIdx.x, j = threadIdx.x;
    int zz = z[n]; zz = zz < 0 ? 0 : (zz >= MAXZ_ ? MAXZ_ - 1 : zz);
    row[j] = LD<ISF>(emb, (size_t)zz * HC + j);
    row[HC + j] = msg[(size_t)n * HC + j];
    __syncthreads();
    float acc = LD<ISF>(bc, j);
    for (int h = 0; h < 2 * HC; h++) acc += row[h] * LD<ISF>(Wc, (size_t)h * HC + j);
    x[(size_t)n * HC + j] = acc;
    xb[(size_t)n * HC + j] = f2b(acc);
}
__global__ void combine_k(const int* z, const void* emb, const float* msg,
                          const void* Wc, const void* bc, const int* flagp,
                          float* x, bf16* xb) {
    if (flagp[1]) combine_body<1>(z, emb, msg, Wc, bc, x, xb);
    else          combine_body<0>(z, emb, msg, Wc, bc, x, xb);
}

// ---------------- ygemm: y = x @ cW1[l] (MFMA, A direct from global) -------
__global__ __launch_bounds__(256)
void ygemm_mfma_k(const bf16* __restrict__ xb, const bf16* __restrict__ cw1p,
                  int l, bf16* __restrict__ ybf) {
    int tid = threadIdx.x;
    int wave = tid >> 6, lane = tid & 63, quad = lane >> 4, lc = lane & 15;
    int m0 = blockIdx.x * 64;
    bf8v azero = {0, 0, 0, 0, 0, 0, 0, 0};
    bf8v af[4];
    int arow = m0 + wave * 16 + lc;
    #pragma unroll
    for (int ks = 0; ks < 4; ks++) {
        if (arow < NATOMS)
            af[ks] = *(const bf8v*)(xb + (size_t)arow * HC + ks * 32 + quad * 8);
        else af[ks] = azero;
    }
    f4v zero = {0.f, 0.f, 0.f, 0.f};
    f4v acc[8];
    #pragma unroll
    for (int nt = 0; nt < 8; nt++) acc[nt] = zero;
    const bf16* base = cw1p + (size_t)l * 16384;
    #pragma unroll
    for (int nt = 0; nt < 8; nt++)
        #pragma unroll
        for (int ks = 0; ks < 4; ks++) {
            bf8v b = *(const bf8v*)(base + ((nt * 4 + ks) * 64 + lane) * 8);
            acc[nt] = MFMA(af[ks], b, acc[nt]);
        }
    #pragma unroll
    for (int nt = 0; nt < 8; nt++) {
        int n = nt * 16 + lc;
        #pragma unroll
        for (int r = 0; r < 4; r++) {
            int row = m0 + wave * 16 + quad * 4 + r;
            if (row < NATOMS) ybf[(size_t)row * HC + n] = f2b(acc[nt][r]);
        }
    }
}

// ---------------- filter MLP + gather + product (MFMA) ---------------------
__global__ __launch_bounds__(256)
void filt_mfma_k(const int* __restrict__ rowptr, int a0, int a1, int l,
                 const float* __restrict__ ed_s, const float* __restrict__ C_s,
                 const int* __restrict__ src_s, const bf16* __restrict__ ybf,
                 const bf16* __restrict__ w1p, const bf16* __restrict__ w2p,
                 const float* __restrict__ b1cv, const float* __restrict__ b2cv,
                 const float* __restrict__ meanscv, const float* __restrict__ betascv,
                 bf16* __restrict__ medge) {
    __shared__ bf16 attr[64][72];
    __shared__ bf16 hid[64][136];
    int e0 = rowptr[a0], e1 = rowptr[a1];
    int i0 = e0 + blockIdx.x * 64;
    if (i0 >= e1) return;
    int tid = threadIdx.x;
    attr_tile(attr, i0, e1, C_s, ed_s, meanscv, betascv, tid);
    __syncthreads();

    int wave = tid >> 6, lane = tid & 63, quad = lane >> 4, lc = lane & 15;
    // GEMM1: attr(64x64) @ W1p -> hid
    bf8v af[2];
    #pragma unroll
    for (int ks = 0; ks < 2; ks++)
        af[ks] = *(const bf8v*)&attr[wave * 16 + lc][ks * 32 + quad * 8];
    f4v zero = {0.f, 0.f, 0.f, 0.f};
    f4v acc[8];
    #pragma unroll
    for (int nt = 0; nt < 8; nt++) acc[nt] = zero;
    const bf16* w1b = w1p + (size_t)l * 8192;
    #pragma unroll
    for (int nt = 0; nt < 8; nt++)
        #pragma unroll
        for (int ks = 0; ks < 2; ks++) {
            bf8v b = *(const bf8v*)(w1b + ((nt * 2 + ks) * 64 + lane) * 8);
            acc[nt] = MFMA(af[ks], b, acc[nt]);
        }
    // bias + silu -> hid (C-layout scalar stores within own row band)
    #pragma unroll
    for (int nt = 0; nt < 8; nt++) {
        int n = nt * 16 + lc;
        float bb = b1cv[l * HC + n];
        #pragma unroll
        for (int r = 0; r < 4; r++) {
            float v = acc[nt][r] + bb;
            v = v / (1.0f + __expf(-v));
            hid[wave * 16 + quad * 4 + r][n] = f2b(v);
        }
    }
    __syncthreads();
    // GEMM2: hid(64x128) @ W2p
    bf8v a2[4];
    #pragma unroll
    for (int ks = 0; ks < 4; ks++)
        a2[ks] = *(const bf8v*)&hid[wave * 16 + lc][ks * 32 + quad * 8];
    f4v acc2[8];
    #pragma unroll
    for (int nt = 0; nt < 8; nt++) acc2[nt] = zero;
    const bf16* w2b = w2p + (size_t)l * 16384;
    #pragma unroll
    for (int nt = 0; nt < 8; nt++)
        #pragma unroll
        for (int ks = 0; ks < 4; ks++) {
            bf8v b = *(const bf8v*)(w2b + ((nt * 4 + ks) * 64 + lane) * 8);
            acc2[nt] = MFMA(a2[ks], b, acc2[nt]);
        }
    // epilogue: Wf = (acc2+b2)*C; m = Wf * y[src]; store medge
    float Cr[4]; int sr[4]; int ir[4]; bool val[4];
    #pragma unroll
    for (int r = 0; r < 4; r++) {
        int m = wave * 16 + quad * 4 + r;
        int i = i0 + m;
        ir[r] = i; val[r] = (i < e1);
        Cr[r] = 0.0f; sr[r] = 0;
        if (val[r]) { Cr[r] = C_s[i]; sr[r] = src_s[i]; }
    }
    #pragma unroll
    for (int nt = 0; nt < 8; nt++) {
        int n = nt * 16 + lc;
        float bb = b2cv[l * HC + n];
        #pragma unroll
        for (int r = 0; r < 4; r++) {
            if (val[r]) {
                float wf = (acc2[nt][r] + bb) * Cr[r];
                float mv = wf * b2f(ybf[(size_t)sr[r] * HC + n]);
                medge[(size_t)(ir[r] - e0) * HC + n] = f2b(mv);
            }
        }
    }
}

// ---------------- aggregate + conv lin2 + silu + final lin + residual ------
__global__ __launch_bounds__(256)
void aggr_mfma_k(const int* __restrict__ rowptr, int a0, int a1, int l,
                 const bf16* __restrict__ medge,
                 const bf16* __restrict__ cw2p, const float* __restrict__ cb2cv,
                 const bf16* __restrict__ lwp, const float* __restrict__ lbcv,
                 float* __restrict__ x, bf16* __restrict__ xb) {
    __shared__ bf16 mrow[64][136];
    int e0 = rowptr[a0];
    int na0 = a0 + blockIdx.x * 64;
    int tid = threadIdx.x;
    // segment-sum phase: 2 atom-groups x 128 cols (coalesced 256B per edge row)
    int g = tid >> 7, col = tid & 127;
    for (int a = g; a < 64; a += 2) {
        int n0 = na0 + a;
        float s = 0.0f;
        if (n0 < a1) {
            int ib = rowptr[n0], ie = rowptr[n0 + 1];
            for (int i = ib; i < ie; i++)
                s += b2f(medge[(size_t)(i - e0) * HC + col]);
        }
        mrow[a][col] = f2b(s);
    }
    __syncthreads();
    int wave = tid >> 6, lane = tid & 63, quad = lane >> 4, lc = lane & 15;
    // GEMM1: mrow @ cW2p
    bf8v af[4];
    #pragma unroll
    for (int ks = 0; ks < 4; ks++)
        af[ks] = *(const bf8v*)&mrow[wave * 16 + lc][ks * 32 + quad * 8];
    f4v zero = {0.f, 0.f, 0.f, 0.f};
    f4v acc[8];
    #pragma unroll
    for (int nt = 0; nt < 8; nt++) acc[nt] = zero;
    const bf16* c2b = cw2p + (size_t)l * 16384;
    #pragma unroll
    for (int nt = 0; nt < 8; nt++)
        #pragma unroll
        for (int ks = 0; ks < 4; ks++) {
            bf8v b = *(const bf8v*)(c2b + ((nt * 4 + ks) * 64 + lane) * 8);
            acc[nt] = MFMA(af[ks], b, acc[nt]);
        }
    __syncthreads();
    // bias + silu, write back into mrow (own row band)
    #pragma unroll
    for (int nt = 0; nt < 8; nt++) {
        int n = nt * 16 + lc;
        float bb = cb2cv[l * HC + n];
        #pragma unroll
        for (int r = 0; r < 4; r++) {
            float v = acc[nt][r] + bb;
            v = v / (1.0f + __expf(-v));
            mrow[wave * 16 + quad * 4 + r][n] = f2b(v);
        }
    }
    __syncthreads();
    // GEMM2: silu-out @ lW
    bf8v a2[4];
    #pragma unroll
    for (int ks = 0; ks < 4; ks++)
        a2[ks] = *(const bf8v*)&mrow[wave * 16 + lc][ks * 32 + quad * 8];
    f4v acc2[8];
    #pragma unroll
    for (int nt = 0; nt < 8; nt++) acc2[nt] = zero;
    const bf16* lwb = lwp + (size_t)l * 16384;
    #pragma unroll
    for (int nt = 0; nt < 8; nt++)
        #pragma unroll
        for (int ks = 0; ks < 4; ks++) {
            bf8v b = *(const bf8v*)(lwb + ((nt * 4 + ks) * 64 + lane) * 8);
            acc2[nt] = MFMA(a2[ks], b, acc2[nt]);
        }
    // epilogue: x += val + lb; xb = bf16(x)
    #pragma unroll
    for (int nt = 0; nt < 8; nt++) {
        int n = nt * 16 + lc;
        float bb = lbcv[l * HC + n];
        #pragma unroll
        for (int r = 0; r < 4; r++) {
            int row = na0 + wave * 16 + quad * 4 + r;
            if (row < a1) {
                size_t o = (size_t)row * HC + n;
                float nv = x[o] + acc2[nt][r] + bb;
                x[o] = nv;
                xb[o] = f2b(nv);
            }
        }
    }
}

__global__ void out_k(const float* __restrict__ x, void* out, const int* flagp) {
    int i = blockIdx.x * 256 + threadIdx.x;
    if (i >= NATOMS * HC) return;
    if (flagp[1]) ((float*)out)[i] = x[i];
    else          ((bf16*)out)[i] = f2b(x[i]);
}

// ---------------- launch ----------------
extern "C" void kernel_launch(void* const* d_in, const int* in_sizes, int n_in,
                              void* d_out, int out_size, void* d_ws, size_t ws_size,
                              hipStream_t stream) {
    const int*  z      = (const int*) d_in[0];
    const void* pos    = d_in[1];
    const int*  ei     = (const int*) d_in[3];
    const void* emb    = d_in[4];
    const void* nbremb = d_in[5];
    const void* Wp     = d_in[6];
    const void* bp     = d_in[7];
    const void* Wc     = d_in[8];
    const void* bc     = d_in[9];
    const void* means  = d_in[10];
    const void* betas  = d_in[11];
    const void* W1     = d_in[12];
    const void* b1     = d_in[13];
    const void* W2     = d_in[14];
    const void* b2     = d_in[15];
    const void* cW1    = d_in[16];
    const void* cW2    = d_in[17];
    const void* cb2    = d_in[18];
    const void* lW     = d_in[19];
    const void* lb     = d_in[20];

    char* p = (char*)d_ws;
    auto alloc = [&](size_t bytes) { char* r = p; p += (bytes + 255) / 256 * 256; return r; };
    int*   flag    = (int*)  alloc(256);
    int*   counts  = (int*)  alloc((size_t)NATOMS * 4);
    int*   rowptr  = (int*)  alloc((size_t)(NATOMS + 1) * 4);
    int*   cursor  = (int*)  alloc((size_t)NATOMS * 4);
    int*   perm    = (int*)  alloc((size_t)NEDGES * 4);
    int*   src_s   = (int*)  alloc((size_t)NEDGES * 4);
    float* C_s     = (float*)alloc((size_t)NEDGES * 4);
    float* Cm_s    = (float*)alloc((size_t)NEDGES * 4);
    float* ed_s    = (float*)alloc((size_t)NEDGES * 4);
    float* x       = (float*)alloc((size_t)NATOMS * HC * 4);
    bf16*  xb      = (bf16*) alloc((size_t)NATOMS * HC * 2);
    bf16*  ybf     = (bf16*) alloc((size_t)NATOMS * HC * 2);
    float* msg     = (float*)alloc((size_t)NATOMS * HC * 4);
    bf16*  medge   = (bf16*) alloc((size_t)MAXCE * HC * 2);   // 24.6 MB
    // packed weights (B-fragment order)
    bf16*  wpp     = (bf16*) alloc((size_t)8192 * 2);
    bf16*  w1p     = (bf16*) alloc((size_t)NLAY * 8192 * 2);
    bf16*  w2p     = (bf16*) alloc((size_t)NLAY * 16384 * 2);
    bf16*  cw1p    = (bf16*) alloc((size_t)NLAY * 16384 * 2);
    bf16*  cw2p    = (bf16*) alloc((size_t)NLAY * 16384 * 2);
    bf16*  lwp     = (bf16*) alloc((size_t)NLAY * 16384 * 2);
    // converted fp32 params
    float* nbrembcv= (float*)alloc((size_t)MAXZ_ * HC * 4);
    float* bpcv    = (float*)alloc((size_t)HC * 4);
    float* b1cv    = (float*)alloc((size_t)NLAY * HC * 4);
    float* b2cv    = (float*)alloc((size_t)NLAY * HC * 4);
    float* cb2cv   = (float*)alloc((size_t)NLAY * HC * 4);
    float* lbcv    = (float*)alloc((size_t)NLAY * HC * 4);
    float* meanscv = (float*)alloc((size_t)RBF * 4);
    float* betascv = (float*)alloc((size_t)RBF * 4);

    const int EG = (NEDGES + 255) / 256;
    const int NG = (NATOMS + 255) / 256;

    zero_k<<<1, 64, 0, stream>>>(flag, 2);
    zero_k<<<NG, 256, 0, stream>>>(counts, NATOMS);
    probe_k<<<(NATOMS * 3 + 255) / 256, 256, 0, stream>>>(pos, NATOMS * 3, flag);
    setflag_k<<<1, 64, 0, stream>>>(flag);

    hist_k<<<EG, 256, 0, stream>>>(ei + NEDGES, counts);
    scan_k<<<1, 1024, 0, stream>>>(counts, rowptr);
    copy_k<<<NG, 256, 0, stream>>>(rowptr, cursor, NATOMS);
    perm_k<<<EG, 256, 0, stream>>>(ei + NEDGES, cursor, perm);
    geom_k<<<EG, 256, 0, stream>>>(ei, pos, perm, flag, C_s, Cm_s, ed_s, src_s);

    // pack weights + convert params
    packB_k<<<4,  256, 0, stream>>>(Wp,  RBF, 2, 6400, 8192, 1, flag, wpp);
    packB_k<<<24, 256, 0, stream>>>(W1,  RBF, 2, 6400, 8192, NLAY, flag, w1p);
    packB_k<<<48, 256, 0, stream>>>(W2,  HC, 4, 16384, 16384, NLAY, flag, w2p);
    packB_k<<<48, 256, 0, stream>>>(cW1, HC, 4, 16384, 16384, NLAY, flag, cw1p);
    packB_k<<<48, 256, 0, stream>>>(cW2, HC, 4, 16384, 16384, NLAY, flag, cw2p);
    packB_k<<<48, 256, 0, stream>>>(lW,  HC, 4, 16384, 16384, NLAY, flag, lwp);
    cvt_k<<<(MAXZ_ * HC + 255) / 256, 256, 0, stream>>>(nbremb, MAXZ_ * HC, flag, nbrembcv);
    cvt_k<<<1, 256, 0, stream>>>(bp, HC, flag, bpcv);
    cvt_k<<<3, 256, 0, stream>>>(b1, NLAY * HC, flag, b1cv);
    cvt_k<<<3, 256, 0, stream>>>(b2, NLAY * HC, flag, b2cv);
    cvt_k<<<3, 256, 0, stream>>>(cb2, NLAY * HC, flag, cb2cv);
    cvt_k<<<3, 256, 0, stream>>>(lb, NLAY * HC, flag, lbcv);
    cvt_k<<<1, 64, 0, stream>>>(means, RBF, flag, meanscv);
    cvt_k<<<1, 64, 0, stream>>>(betas, RBF, flag, betascv);

    // neighbor embedding
    for (int c = 0; c < NCHUNK; c++) {
        int a0 = c * CA, a1 = a0 + CA;
        nbr_mfma_k<<<EGRID, 256, 0, stream>>>(rowptr, a0, a1, ed_s, C_s, Cm_s, src_s,
                                              z, nbrembcv, wpp, bpcv, meanscv, betascv, medge);
        nbr_aggr_k<<<CA, 128, 0, stream>>>(rowptr, a0, medge, msg);
    }
    combine_k<<<NATOMS, 128, 0, stream>>>(z, emb, msg, Wc, bc, flag, x, xb);

    // interaction layers
    for (int l = 0; l < NLAY; l++) {
        ygemm_mfma_k<<<YGRID, 256, 0, stream>>>(xb, cw1p, l, ybf);
        for (int c = 0; c < NCHUNK; c++) {
            int a0 = c * CA, a1 = a0 + CA;
            filt_mfma_k<<<EGRID, 256, 0, stream>>>(rowptr, a0, a1, l, ed_s, C_s, src_s,
                                                   ybf, w1p, w2p, b1cv, b2cv,
                                                   meanscv, betascv, medge);
            aggr_mfma_k<<<AGRID, 256, 0, stream>>>(rowptr, a0, a1, l, medge,
                                                   cw2p, cb2cv, lwp, lbcv, x, xb);
        }
    }
    out_k<<<(NATOMS * HC + 255) / 256, 256, 0, stream>>>(x, d_out, flag);
}

// Round 4
// 1817.968 us; speedup vs baseline: 4.9545x; 4.9545x over previous
//
#include <hip/hip_runtime.h>
#include <hip/hip_bf16.h>

// TorchMD_GN_Ext R4: R3's MFMA GEMMs kept, but aggregation UN-fused from the
// node update. R3's aggr_mfma_k fused serial segment-sum into a 40-block MFMA
// kernel -> 1.65% occupancy, 336us x24 = 90% of runtime. R4: aggr_sum_k
// (2500 blocks/chunk, coalesced row sums -> msum) + upd_mfma_k (157 blocks,
// per layer over ALL atoms: msum@cW2+silu -> @lW + residual).

#define NATOMS 10000
#define NEDGES 320000
#define HC 128
#define RBF 50
#define NLAY 6
#define MAXZ_ 100
#define NCHUNK 4
#define CA (NATOMS / NCHUNK)        // 2500 atoms/chunk
#define MAXCE 96000                 // max edges/chunk (mean 80000)
#define EGRID (MAXCE / 64)          // 1500 blocks of 64 edges
#define YGRID ((NATOMS + 63) / 64)  // 157

typedef __hip_bfloat16 bf16;
typedef __attribute__((ext_vector_type(8))) short bf8v;   // 8 bf16 (4 VGPRs)
typedef __attribute__((ext_vector_type(4))) float f4v;    // 4 fp32 acc

__device__ __forceinline__ float b2f(bf16 v) { return __bfloat162float(v); }
__device__ __forceinline__ bf16  f2b(float v) { return __float2bfloat16(v); }

template<int ISF>
__device__ __forceinline__ float LD(const void* p, size_t i) {
    if (ISF) return ((const float*)p)[i];
    return b2f(((const bf16*)p)[i]);
}

// ---------------- dtype probe ----------------
__global__ void probe_k(const void* pos, int nelem, int* flag) {
    int i = blockIdx.x * 256 + threadIdx.x;
    float v = 0.0f;
    if (i < nelem) {
        v = fabsf(b2f(((const bf16*)pos)[i]));
        if (v != v) v = 1e30f;
    }
    atomicMax(flag, __float_as_int(v));
}
__global__ void setflag_k(int* flag) {
    if (threadIdx.x == 0) flag[1] = (__int_as_float(flag[0]) > 1.0e4f) ? 1 : 0;
}

// ---------------- CSR build ----------------
__global__ void zero_k(int* p, int n) {
    int i = blockIdx.x * 256 + threadIdx.x;
    if (i < n) p[i] = 0;
}
__device__ __forceinline__ int clampN(int v) {
    return v < 0 ? 0 : (v >= NATOMS ? NATOMS - 1 : v);
}
__global__ void hist_k(const int* __restrict__ dst, int* __restrict__ counts) {
    int e = blockIdx.x * 256 + threadIdx.x;
    if (e < NEDGES) atomicAdd(&counts[clampN(dst[e])], 1);
}
__global__ void scan_k(const int* __restrict__ counts, int* __restrict__ rowptr) {
    __shared__ int lds[1024];
    __shared__ int carry;
    int tid = threadIdx.x;
    if (tid == 0) { carry = 0; rowptr[0] = 0; }
    __syncthreads();
    for (int base = 0; base < NATOMS; base += 1024) {
        int i = base + tid;
        int v = (i < NATOMS) ? counts[i] : 0;
        lds[tid] = v;
        __syncthreads();
        for (int off = 1; off < 1024; off <<= 1) {
            int t = (tid >= off) ? lds[tid - off] : 0;
            __syncthreads();
            lds[tid] += t;
            __syncthreads();
        }
        if (i < NATOMS) rowptr[i + 1] = lds[tid] + carry;
        __syncthreads();
        if (tid == 0) carry += lds[1023];
        __syncthreads();
    }
}
__global__ void copy_k(const int* __restrict__ a, int* __restrict__ b, int n) {
    int i = blockIdx.x * 256 + threadIdx.x;
    if (i < n) b[i] = a[i];
}
__global__ void perm_k(const int* __restrict__ dst, int* __restrict__ cursor,
                       int* __restrict__ perm) {
    int e = blockIdx.x * 256 + threadIdx.x;
    if (e < NEDGES) {
        int p = atomicAdd(&cursor[clampN(dst[e])], 1);
        perm[p] = e;
    }
}

// ---------------- geometry ----------------
template<int ISF>
__device__ void geom_body(const int* __restrict__ ei, const void* __restrict__ pos,
                          const int* __restrict__ perm,
                          float* __restrict__ C_s, float* __restrict__ Cm_s,
                          float* __restrict__ ed_s, int* __restrict__ src_s) {
    int i = blockIdx.x * 256 + threadIdx.x;
    if (i >= NEDGES) return;
    int e = perm[i];
    int s = clampN(ei[e]);
    int t = clampN(ei[NEDGES + e]);
    float dx = LD<ISF>(pos, (size_t)s * 3 + 0) - LD<ISF>(pos, (size_t)t * 3 + 0);
    float dy = LD<ISF>(pos, (size_t)s * 3 + 1) - LD<ISF>(pos, (size_t)t * 3 + 1);
    float dz = LD<ISF>(pos, (size_t)s * 3 + 2) - LD<ISF>(pos, (size_t)t * 3 + 2);
    float d = sqrtf(dx * dx + dy * dy + dz * dz + 1e-12f);
    if (d != d) d = 1e30f;
    float C = (d < 5.0f) ? 0.5f * (__cosf(d * 0.6283185307f) + 1.0f) : 0.0f;
    C_s[i] = C;
    Cm_s[i] = (s != t) ? C : 0.0f;
    ed_s[i] = __expf(-d);
    src_s[i] = s;
}
__global__ void geom_k(const int* ei, const void* pos, const int* perm, const int* flagp,
                       float* C_s, float* Cm_s, float* ed_s, int* src_s) {
    if (flagp[1]) geom_body<1>(ei, pos, perm, C_s, Cm_s, ed_s, src_s);
    else          geom_body<0>(ei, pos, perm, C_s, Cm_s, ed_s, src_s);
}

// ---------------- weight pack/convert ----------------
template<int ISF>
__device__ void packB_body(const void* src, int K, int ksteps, size_t perLsrc,
                           size_t perLdst, int L, bf16* dst) {
    int t = blockIdx.x * 256 + threadIdx.x;
    int total = L * 8 * ksteps * 64;
    if (t >= total) return;
    int lane = t & 63;
    int t2 = t >> 6;
    int ks = t2 % ksteps;
    int t3 = t2 / ksteps;
    int nt = t3 & 7;
    int l  = t3 >> 3;
    int quad = lane >> 4, lc = lane & 15;
    int col = nt * 16 + lc;
    for (int j = 0; j < 8; j++) {
        int k = ks * 32 + quad * 8 + j;
        float v = (k < K) ? LD<ISF>(src, (size_t)l * perLsrc + (size_t)k * 128 + col) : 0.0f;
        dst[(size_t)l * perLdst + ((size_t)((nt * ksteps + ks) * 64 + lane)) * 8 + j] = f2b(v);
    }
}
__global__ void packB_k(const void* src, int K, int ksteps, size_t perLsrc,
                        size_t perLdst, int L, const int* flagp, bf16* dst) {
    if (flagp[1]) packB_body<1>(src, K, ksteps, perLsrc, perLdst, L, dst);
    else          packB_body<0>(src, K, ksteps, perLsrc, perLdst, L, dst);
}
template<int ISF>
__device__ void cvt_body(const void* src, int n, float* dst) {
    int i = blockIdx.x * 256 + threadIdx.x;
    if (i < n) dst[i] = LD<ISF>(src, i);
}
__global__ void cvt_k(const void* src, int n, const int* flagp, float* dst) {
    if (flagp[1]) cvt_body<1>(src, n, dst);
    else          cvt_body<0>(src, n, dst);
}

// ---------------- MFMA helpers ----------------
#define MFMA(a, b, c) __builtin_amdgcn_mfma_f32_16x16x32_bf16((a), (b), (c), 0, 0, 0)

__device__ __forceinline__ void attr_tile(bf16 (*attr)[72], int i0, int e1,
                                          const float* __restrict__ C_s,
                                          const float* __restrict__ ed_s,
                                          const float* __restrict__ meanscv,
                                          const float* __restrict__ betascv,
                                          int tid) {
    int m = tid >> 2, rg = (tid & 3) * 16;
    int i = i0 + m;
    float Ci = 0.0f, edi = 0.0f;
    if (i < e1) { Ci = C_s[i]; edi = ed_s[i]; }
    #pragma unroll
    for (int rr = 0; rr < 16; rr++) {
        int r = rg + rr;
        float v = 0.0f;
        if (r < RBF) {
            float u = edi - meanscv[r];
            v = Ci * __expf(-betascv[r] * u * u);
        }
        attr[m][r] = f2b(v);
    }
}

// ---------------- neighbor-embedding edge kernel ----------------
__global__ __launch_bounds__(256)
void nbr_mfma_k(const int* __restrict__ rowptr, int a0, int a1,
                const float* __restrict__ ed_s, const float* __restrict__ C_s,
                const float* __restrict__ Cm_s, const int* __restrict__ src_s,
                const int* __restrict__ z, const float* __restrict__ nbrembcv,
                const bf16* __restrict__ wpp, const float* __restrict__ bpcv,
                const float* __restrict__ meanscv, const float* __restrict__ betascv,
                bf16* __restrict__ medge) {
    __shared__ bf16 attr[64][72];
    int e0 = rowptr[a0], e1 = rowptr[a1];
    int i0 = e0 + blockIdx.x * 64;
    if (i0 >= e1) return;
    int tid = threadIdx.x;
    attr_tile(attr, i0, e1, C_s, ed_s, meanscv, betascv, tid);
    __syncthreads();

    int wave = tid >> 6, lane = tid & 63, quad = lane >> 4, lc = lane & 15;
    bf8v af[2];
    #pragma unroll
    for (int ks = 0; ks < 2; ks++)
        af[ks] = *(const bf8v*)&attr[wave * 16 + lc][ks * 32 + quad * 8];
    f4v zero = {0.f, 0.f, 0.f, 0.f};
    f4v acc[8];
    #pragma unroll
    for (int nt = 0; nt < 8; nt++) acc[nt] = zero;
    #pragma unroll
    for (int nt = 0; nt < 8; nt++)
        #pragma unroll
        for (int ks = 0; ks < 2; ks++) {
            bf8v b = *(const bf8v*)(wpp + ((nt * 2 + ks) * 64 + lane) * 8);
            acc[nt] = MFMA(af[ks], b, acc[nt]);
        }
    float Cr[4]; int zr[4]; int ir[4]; bool val[4];
    #pragma unroll
    for (int r = 0; r < 4; r++) {
        int m = wave * 16 + quad * 4 + r;
        int i = i0 + m;
        ir[r] = i; val[r] = (i < e1);
        Cr[r] = 0.0f; zr[r] = 0;
        if (val[r]) {
            Cr[r] = Cm_s[i];
            int zz = z[src_s[i]];
            zr[r] = (zz < 0) ? 0 : (zz >= MAXZ_ ? MAXZ_ - 1 : zz);
        }
    }
    #pragma unroll
    for (int nt = 0; nt < 8; nt++) {
        int n = nt * 16 + lc;
        float bb = bpcv[n];
        #pragma unroll
        for (int r = 0; r < 4; r++) {
            if (val[r]) {
                float v = (acc[nt][r] + bb) * Cr[r] * nbrembcv[(size_t)zr[r] * HC + n];
                medge[(size_t)(ir[r] - e0) * HC + n] = f2b(v);
            }
        }
    }
}

__global__ void nbr_aggr_k(const int* __restrict__ rowptr, int a0,
                           const bf16* __restrict__ medge, float* __restrict__ msg) {
    int n = a0 + blockIdx.x, f = threadIdx.x;
    int e0 = rowptr[a0];
    float acc = 0.0f;
    int i1 = rowptr[n + 1];
    for (int i = rowptr[n]; i < i1; i++) acc += b2f(medge[(size_t)(i - e0) * HC + f]);
    msg[(size_t)n * HC + f] = acc;
}

template<int ISF>
__device__ void combine_body(const int* __restrict__ z, const void* __restrict__ emb,
                             const float* __restrict__ msg, const void* __restrict__ Wc,
                             const void* __restrict__ bc, float* __restrict__ x,
                             bf16* __restrict__ xb) {
    __shared__ float row[2 * HC];
    int n = blockIdx.x, j = threadIdx.x;
    int zz = z[n]; zz = zz < 0 ? 0 : (zz >= MAXZ_ ? MAXZ_ - 1 : zz);
    row[j] = LD<ISF>(emb, (size_t)zz * HC + j);
    row[HC + j] = msg[(size_t)n * HC + j];
    __syncthreads();
    float acc = LD<ISF>(bc, j);
    for (int h = 0; h < 2 * HC; h++) acc += row[h] * LD<ISF>(Wc, (size_t)h * HC + j);
    x[(size_t)n * HC + j] = acc;
    xb[(size_t)n * HC + j] = f2b(acc);
}
__global__ void combine_k(const int* z, const void* emb, const float* msg,
                          const void* Wc, const void* bc, const int* flagp,
                          float* x, bf16* xb) {
    if (flagp[1]) combine_body<1>(z, emb, msg, Wc, bc, x, xb);
    else          combine_body<0>(z, emb, msg, Wc, bc, x, xb);
}

// ---------------- ygemm: y = x @ cW1[l] ----------------
__global__ __launch_bounds__(256)
void ygemm_mfma_k(const bf16* __restrict__ xb, const bf16* __restrict__ cw1p,
                  int l, bf16* __restrict__ ybf) {
    int tid = threadIdx.x;
    int wave = tid >> 6, lane = tid & 63, quad = lane >> 4, lc = lane & 15;
    int m0 = blockIdx.x * 64;
    bf8v azero = {0, 0, 0, 0, 0, 0, 0, 0};
    bf8v af[4];
    int arow = m0 + wave * 16 + lc;
    #pragma unroll
    for (int ks = 0; ks < 4; ks++) {
        if (arow < NATOMS)
            af[ks] = *(const bf8v*)(xb + (size_t)arow * HC + ks * 32 + quad * 8);
        else af[ks] = azero;
    }
    f4v zero = {0.f, 0.f, 0.f, 0.f};
    f4v acc[8];
    #pragma unroll
    for (int nt = 0; nt < 8; nt++) acc[nt] = zero;
    const bf16* base = cw1p + (size_t)l * 16384;
    #pragma unroll
    for (int nt = 0; nt < 8; nt++)
        #pragma unroll
        for (int ks = 0; ks < 4; ks++) {
            bf8v b = *(const bf8v*)(base + ((nt * 4 + ks) * 64 + lane) * 8);
            acc[nt] = MFMA(af[ks], b, acc[nt]);
        }
    #pragma unroll
    for (int nt = 0; nt < 8; nt++) {
        int n = nt * 16 + lc;
        #pragma unroll
        for (int r = 0; r < 4; r++) {
            int row = m0 + wave * 16 + quad * 4 + r;
            if (row < NATOMS) ybf[(size_t)row * HC + n] = f2b(acc[nt][r]);
        }
    }
}

// ---------------- filter MLP + gather + product ----------------
__global__ __launch_bounds__(256)
void filt_mfma_k(const int* __restrict__ rowptr, int a0, int a1, int l,
                 const float* __restrict__ ed_s, const float* __restrict__ C_s,
                 const int* __restrict__ src_s, const bf16* __restrict__ ybf,
                 const bf16* __restrict__ w1p, const bf16* __restrict__ w2p,
                 const float* __restrict__ b1cv, const float* __restrict__ b2cv,
                 const float* __restrict__ meanscv, const float* __restrict__ betascv,
                 bf16* __restrict__ medge) {
    __shared__ bf16 attr[64][72];
    __shared__ bf16 hid[64][136];
    int e0 = rowptr[a0], e1 = rowptr[a1];
    int i0 = e0 + blockIdx.x * 64;
    if (i0 >= e1) return;
    int tid = threadIdx.x;
    attr_tile(attr, i0, e1, C_s, ed_s, meanscv, betascv, tid);
    __syncthreads();

    int wave = tid >> 6, lane = tid & 63, quad = lane >> 4, lc = lane & 15;
    bf8v af[2];
    #pragma unroll
    for (int ks = 0; ks < 2; ks++)
        af[ks] = *(const bf8v*)&attr[wave * 16 + lc][ks * 32 + quad * 8];
    f4v zero = {0.f, 0.f, 0.f, 0.f};
    f4v acc[8];
    #pragma unroll
    for (int nt = 0; nt < 8; nt++) acc[nt] = zero;
    const bf16* w1b = w1p + (size_t)l * 8192;
    #pragma unroll
    for (int nt = 0; nt < 8; nt++)
        #pragma unroll
        for (int ks = 0; ks < 2; ks++) {
            bf8v b = *(const bf8v*)(w1b + ((nt * 2 + ks) * 64 + lane) * 8);
            acc[nt] = MFMA(af[ks], b, acc[nt]);
        }
    #pragma unroll
    for (int nt = 0; nt < 8; nt++) {
        int n = nt * 16 + lc;
        float bb = b1cv[l * HC + n];
        #pragma unroll
        for (int r = 0; r < 4; r++) {
            float v = acc[nt][r] + bb;
            v = v / (1.0f + __expf(-v));
            hid[wave * 16 + quad * 4 + r][n] = f2b(v);
        }
    }
    __syncthreads();
    bf8v a2[4];
    #pragma unroll
    for (int ks = 0; ks < 4; ks++)
        a2[ks] = *(const bf8v*)&hid[wave * 16 + lc][ks * 32 + quad * 8];
    f4v acc2[8];
    #pragma unroll
    for (int nt = 0; nt < 8; nt++) acc2[nt] = zero;
    const bf16* w2b = w2p + (size_t)l * 16384;
    #pragma unroll
    for (int nt = 0; nt < 8; nt++)
        #pragma unroll
        for (int ks = 0; ks < 4; ks++) {
            bf8v b = *(const bf8v*)(w2b + ((nt * 4 + ks) * 64 + lane) * 8);
            acc2[nt] = MFMA(a2[ks], b, acc2[nt]);
        }
    float Cr[4]; int sr[4]; int ir[4]; bool val[4];
    #pragma unroll
    for (int r = 0; r < 4; r++) {
        int m = wave * 16 + quad * 4 + r;
        int i = i0 + m;
        ir[r] = i; val[r] = (i < e1);
        Cr[r] = 0.0f; sr[r] = 0;
        if (val[r]) { Cr[r] = C_s[i]; sr[r] = src_s[i]; }
    }
    #pragma unroll
    for (int nt = 0; nt < 8; nt++) {
        int n = nt * 16 + lc;
        float bb = b2cv[l * HC + n];
        #pragma unroll
        for (int r = 0; r < 4; r++) {
            if (val[r]) {
                float wf = (acc2[nt][r] + bb) * Cr[r];
                float mv = wf * b2f(ybf[(size_t)sr[r] * HC + n]);
                medge[(size_t)(ir[r] - e0) * HC + n] = f2b(mv);
            }
        }
    }
}

// ---------------- segment-sum (per chunk, 1 block/atom) ----------------
__global__ void aggr_sum_k(const int* __restrict__ rowptr, int a0,
                           const bf16* __restrict__ medge, bf16* __restrict__ msum) {
    int n = a0 + blockIdx.x, f = threadIdx.x;
    int e0 = rowptr[a0];
    float acc = 0.0f;
    int i1 = rowptr[n + 1];
    for (int i = rowptr[n]; i < i1; i++) acc += b2f(medge[(size_t)(i - e0) * HC + f]);
    msum[(size_t)n * HC + f] = f2b(acc);
}

// ---------------- node update: msum@cW2+cb2 -> silu -> @lW+lb -> x+= -------
__global__ __launch_bounds__(256)
void upd_mfma_k(const bf16* __restrict__ msum, int l,
                const bf16* __restrict__ cw2p, const float* __restrict__ cb2cv,
                const bf16* __restrict__ lwp, const float* __restrict__ lbcv,
                float* __restrict__ x, bf16* __restrict__ xb) {
    __shared__ bf16 srow[64][136];
    int tid = threadIdx.x;
    int wave = tid >> 6, lane = tid & 63, quad = lane >> 4, lc = lane & 15;
    int m0 = blockIdx.x * 64;
    bf8v azero = {0, 0, 0, 0, 0, 0, 0, 0};
    bf8v af[4];
    int arow = m0 + wave * 16 + lc;
    #pragma unroll
    for (int ks = 0; ks < 4; ks++) {
        if (arow < NATOMS)
            af[ks] = *(const bf8v*)(msum + (size_t)arow * HC + ks * 32 + quad * 8);
        else af[ks] = azero;
    }
    f4v zero = {0.f, 0.f, 0.f, 0.f};
    f4v acc[8];
    #pragma unroll
    for (int nt = 0; nt < 8; nt++) acc[nt] = zero;
    const bf16* c2b = cw2p + (size_t)l * 16384;
    #pragma unroll
    for (int nt = 0; nt < 8; nt++)
        #pragma unroll
        for (int ks = 0; ks < 4; ks++) {
            bf8v b = *(const bf8v*)(c2b + ((nt * 4 + ks) * 64 + lane) * 8);
            acc[nt] = MFMA(af[ks], b, acc[nt]);
        }
    // bias + silu -> srow (A-layout round-trip through LDS)
    #pragma unroll
    for (int nt = 0; nt < 8; nt++) {
        int n = nt * 16 + lc;
        float bb = cb2cv[l * HC + n];
        #pragma unroll
        for (int r = 0; r < 4; r++) {
            float v = acc[nt][r] + bb;
            v = v / (1.0f + __expf(-v));
            srow[wave * 16 + quad * 4 + r][n] = f2b(v);
        }
    }
    __syncthreads();
    bf8v a2[4];
    #pragma unroll
    for (int ks = 0; ks < 4; ks++)
        a2[ks] = *(const bf8v*)&srow[wave * 16 + lc][ks * 32 + quad * 8];
    f4v acc2[8];
    #pragma unroll
    for (int nt = 0; nt < 8; nt++) acc2[nt] = zero;
    const bf16* lwb = lwp + (size_t)l * 16384;
    #pragma unroll
    for (int nt = 0; nt < 8; nt++)
        #pragma unroll
        for (int ks = 0; ks < 4; ks++) {
            bf8v b = *(const bf8v*)(lwb + ((nt * 4 + ks) * 64 + lane) * 8);
            acc2[nt] = MFMA(a2[ks], b, acc2[nt]);
        }
    #pragma unroll
    for (int nt = 0; nt < 8; nt++) {
        int n = nt * 16 + lc;
        float bb = lbcv[l * HC + n];
        #pragma unroll
        for (int r = 0; r < 4; r++) {
            int row = m0 + wave * 16 + quad * 4 + r;
            if (row < NATOMS) {
                size_t o = (size_t)row * HC + n;
                float nv = x[o] + acc2[nt][r] + bb;
                x[o] = nv;
                xb[o] = f2b(nv);
            }
        }
    }
}

__global__ void out_k(const float* __restrict__ x, void* out, const int* flagp) {
    int i = blockIdx.x * 256 + threadIdx.x;
    if (i >= NATOMS * HC) return;
    if (flagp[1]) ((float*)out)[i] = x[i];
    else          ((bf16*)out)[i] = f2b(x[i]);
}

// ---------------- launch ----------------
extern "C" void kernel_launch(void* const* d_in, const int* in_sizes, int n_in,
                              void* d_out, int out_size, void* d_ws, size_t ws_size,
                              hipStream_t stream) {
    const int*  z      = (const int*) d_in[0];
    const void* pos    = d_in[1];
    const int*  ei     = (const int*) d_in[3];
    const void* emb    = d_in[4];
    const void* nbremb = d_in[5];
    const void* Wp     = d_in[6];
    const void* bp     = d_in[7];
    const void* Wc     = d_in[8];
    const void* bc     = d_in[9];
    const void* means  = d_in[10];
    const void* betas  = d_in[11];
    const void* W1     = d_in[12];
    const void* b1     = d_in[13];
    const void* W2     = d_in[14];
    const void* b2     = d_in[15];
    const void* cW1    = d_in[16];
    const void* cW2    = d_in[17];
    const void* cb2    = d_in[18];
    const void* lW     = d_in[19];
    const void* lb     = d_in[20];

    char* p = (char*)d_ws;
    auto alloc = [&](size_t bytes) { char* r = p; p += (bytes + 255) / 256 * 256; return r; };
    int*   flag    = (int*)  alloc(256);
    int*   counts  = (int*)  alloc((size_t)NATOMS * 4);
    int*   rowptr  = (int*)  alloc((size_t)(NATOMS + 1) * 4);
    int*   cursor  = (int*)  alloc((size_t)NATOMS * 4);
    int*   perm    = (int*)  alloc((size_t)NEDGES * 4);
    int*   src_s   = (int*)  alloc((size_t)NEDGES * 4);
    float* C_s     = (float*)alloc((size_t)NEDGES * 4);
    float* Cm_s    = (float*)alloc((size_t)NEDGES * 4);
    float* ed_s    = (float*)alloc((size_t)NEDGES * 4);
    float* x       = (float*)alloc((size_t)NATOMS * HC * 4);
    bf16*  xb      = (bf16*) alloc((size_t)NATOMS * HC * 2);
    bf16*  ybf     = (bf16*) alloc((size_t)NATOMS * HC * 2);
    bf16*  msum    = (bf16*) alloc((size_t)NATOMS * HC * 2);
    float* msg     = (float*)alloc((size_t)NATOMS * HC * 4);
    bf16*  medge   = (bf16*) alloc((size_t)MAXCE * HC * 2);   // 24.6 MB
    bf16*  wpp     = (bf16*) alloc((size_t)8192 * 2);
    bf16*  w1p     = (bf16*) alloc((size_t)NLAY * 8192 * 2);
    bf16*  w2p     = (bf16*) alloc((size_t)NLAY * 16384 * 2);
    bf16*  cw1p    = (bf16*) alloc((size_t)NLAY * 16384 * 2);
    bf16*  cw2p    = (bf16*) alloc((size_t)NLAY * 16384 * 2);
    bf16*  lwp     = (bf16*) alloc((size_t)NLAY * 16384 * 2);
    float* nbrembcv= (float*)alloc((size_t)MAXZ_ * HC * 4);
    float* bpcv    = (float*)alloc((size_t)HC * 4);
    float* b1cv    = (float*)alloc((size_t)NLAY * HC * 4);
    float* b2cv    = (float*)alloc((size_t)NLAY * HC * 4);
    float* cb2cv   = (float*)alloc((size_t)NLAY * HC * 4);
    float* lbcv    = (float*)alloc((size_t)NLAY * HC * 4);
    float* meanscv = (float*)alloc((size_t)RBF * 4);
    float* betascv = (float*)alloc((size_t)RBF * 4);

    const int EG = (NEDGES + 255) / 256;
    const int NG = (NATOMS + 255) / 256;

    zero_k<<<1, 64, 0, stream>>>(flag, 2);
    zero_k<<<NG, 256, 0, stream>>>(counts, NATOMS);
    probe_k<<<(NATOMS * 3 + 255) / 256, 256, 0, stream>>>(pos, NATOMS * 3, flag);
    setflag_k<<<1, 64, 0, stream>>>(flag);

    hist_k<<<EG, 256, 0, stream>>>(ei + NEDGES, counts);
    scan_k<<<1, 1024, 0, stream>>>(counts, rowptr);
    copy_k<<<NG, 256, 0, stream>>>(rowptr, cursor, NATOMS);
    perm_k<<<EG, 256, 0, stream>>>(ei + NEDGES, cursor, perm);
    geom_k<<<EG, 256, 0, stream>>>(ei, pos, perm, flag, C_s, Cm_s, ed_s, src_s);

    packB_k<<<4,  256, 0, stream>>>(Wp,  RBF, 2, 6400, 8192, 1, flag, wpp);
    packB_k<<<24, 256, 0, stream>>>(W1,  RBF, 2, 6400, 8192, NLAY, flag, w1p);
    packB_k<<<48, 256, 0, stream>>>(W2,  HC, 4, 16384, 16384, NLAY, flag, w2p);
    packB_k<<<48, 256, 0, stream>>>(cW1, HC, 4, 16384, 16384, NLAY, flag, cw1p);
    packB_k<<<48, 256, 0, stream>>>(cW2, HC, 4, 16384, 16384, NLAY, flag, cw2p);
    packB_k<<<48, 256, 0, stream>>>(lW,  HC, 4, 16384, 16384, NLAY, flag, lwp);
    cvt_k<<<(MAXZ_ * HC + 255) / 256, 256, 0, stream>>>(nbremb, MAXZ_ * HC, flag, nbrembcv);
    cvt_k<<<1, 256, 0, stream>>>(bp, HC, flag, bpcv);
    cvt_k<<<3, 256, 0, stream>>>(b1, NLAY * HC, flag, b1cv);
    cvt_k<<<3, 256, 0, stream>>>(b2, NLAY * HC, flag, b2cv);
    cvt_k<<<3, 256, 0, stream>>>(cb2, NLAY * HC, flag, cb2cv);
    cvt_k<<<3, 256, 0, stream>>>(lb, NLAY * HC, flag, lbcv);
    cvt_k<<<1, 64, 0, stream>>>(means, RBF, flag, meanscv);
    cvt_k<<<1, 64, 0, stream>>>(betas, RBF, flag, betascv);

    for (int c = 0; c < NCHUNK; c++) {
        int a0 = c * CA, a1 = a0 + CA;
        nbr_mfma_k<<<EGRID, 256, 0, stream>>>(rowptr, a0, a1, ed_s, C_s, Cm_s, src_s,
                                              z, nbrembcv, wpp, bpcv, meanscv, betascv, medge);
        nbr_aggr_k<<<CA, 128, 0, stream>>>(rowptr, a0, medge, msg);
    }
    combine_k<<<NATOMS, 128, 0, stream>>>(z, emb, msg, Wc, bc, flag, x, xb);

    for (int l = 0; l < NLAY; l++) {
        ygemm_mfma_k<<<YGRID, 256, 0, stream>>>(xb, cw1p, l, ybf);
        for (int c = 0; c < NCHUNK; c++) {
            int a0 = c * CA, a1 = a0 + CA;
            filt_mfma_k<<<EGRID, 256, 0, stream>>>(rowptr, a0, a1, l, ed_s, C_s, src_s,
                                                   ybf, w1p, w2p, b1cv, b2cv,
                                                   meanscv, betascv, medge);
            aggr_sum_k<<<CA, 128, 0, stream>>>(rowptr, a0, medge, msum);
        }
        upd_mfma_k<<<YGRID, 256, 0, stream>>>(msum, l, cw2p, cb2cv, lwp, lbcv, x, xb);
    }
    out_k<<<(NATOMS * HC + 255) / 256, 256, 0, stream>>>(x, d_out, flag);
}

// Round 5
// 939.839 us; speedup vs baseline: 9.5836x; 1.9343x over previous
//
#include <hip/hip_runtime.h>
#include <hip/hip_bf16.h>

// TorchMD_GN_Ext R5:
//  - combine MFMA-ized (was 47us scalar GEMM -> ~6us: acomb=[emb[z]|msg] @ packed Wc)
//  - segment-sum FUSED into edge kernels via LDS + boundary atomics
//    (eliminates medge 82MB/layer round-trip, aggr_sum_k/nbr_aggr_k, chunking)
//  - E = 320000 = 5000*64 exactly: full blocks, no tail checks.

#define NATOMS 10000
#define NEDGES 320000
#define HC 128
#define RBF 50
#define NLAY 6
#define MAXZ_ 100
#define EGRID (NEDGES / 64)         // 5000
#define YGRID ((NATOMS + 63) / 64)  // 157

typedef __hip_bfloat16 bf16;
typedef __attribute__((ext_vector_type(8))) short bf8v;
typedef __attribute__((ext_vector_type(4))) float f4v;

__device__ __forceinline__ float b2f(bf16 v) { return __bfloat162float(v); }
__device__ __forceinline__ bf16  f2b(float v) { return __float2bfloat16(v); }
__device__ __forceinline__ short f2s(float v) { bf16 h = f2b(v); return *(short*)&h; }

template<int ISF>
__device__ __forceinline__ float LD(const void* p, size_t i) {
    if (ISF) return ((const float*)p)[i];
    return b2f(((const bf16*)p)[i]);
}

// ---------------- dtype probe ----------------
__global__ void probe_k(const void* pos, int nelem, int* flag) {
    int i = blockIdx.x * 256 + threadIdx.x;
    float v = 0.0f;
    if (i < nelem) {
        v = fabsf(b2f(((const bf16*)pos)[i]));
        if (v != v) v = 1e30f;
    }
    atomicMax(flag, __float_as_int(v));
}
__global__ void setflag_k(int* flag) {
    if (threadIdx.x == 0) flag[1] = (__int_as_float(flag[0]) > 1.0e4f) ? 1 : 0;
}

// ---------------- CSR build ----------------
__global__ void zero_k(int* p, int n) {
    int i = blockIdx.x * 256 + threadIdx.x;
    if (i < n) p[i] = 0;
}
__device__ __forceinline__ int clampN(int v) {
    return v < 0 ? 0 : (v >= NATOMS ? NATOMS - 1 : v);
}
__global__ void hist_k(const int* __restrict__ dst, int* __restrict__ counts) {
    int e = blockIdx.x * 256 + threadIdx.x;
    if (e < NEDGES) atomicAdd(&counts[clampN(dst[e])], 1);
}
__global__ void scan_k(const int* __restrict__ counts, int* __restrict__ rowptr) {
    __shared__ int lds[1024];
    __shared__ int carry;
    int tid = threadIdx.x;
    if (tid == 0) { carry = 0; rowptr[0] = 0; }
    __syncthreads();
    for (int base = 0; base < NATOMS; base += 1024) {
        int i = base + tid;
        int v = (i < NATOMS) ? counts[i] : 0;
        lds[tid] = v;
        __syncthreads();
        for (int off = 1; off < 1024; off <<= 1) {
            int t = (tid >= off) ? lds[tid - off] : 0;
            __syncthreads();
            lds[tid] += t;
            __syncthreads();
        }
        if (i < NATOMS) rowptr[i + 1] = lds[tid] + carry;
        __syncthreads();
        if (tid == 0) carry += lds[1023];
        __syncthreads();
    }
}
__global__ void copy_k(const int* __restrict__ a, int* __restrict__ b, int n) {
    int i = blockIdx.x * 256 + threadIdx.x;
    if (i < n) b[i] = a[i];
}
__global__ void perm_k(const int* __restrict__ dst, int* __restrict__ cursor,
                       int* __restrict__ perm) {
    int e = blockIdx.x * 256 + threadIdx.x;
    if (e < NEDGES) {
        int p = atomicAdd(&cursor[clampN(dst[e])], 1);
        perm[p] = e;
    }
}

// ---------------- geometry ----------------
template<int ISF>
__device__ void geom_body(const int* __restrict__ ei, const void* __restrict__ pos,
                          const int* __restrict__ perm,
                          float* __restrict__ C_s, float* __restrict__ Cm_s,
                          float* __restrict__ ed_s, int* __restrict__ src_s,
                          int* __restrict__ dst_s) {
    int i = blockIdx.x * 256 + threadIdx.x;
    if (i >= NEDGES) return;
    int e = perm[i];
    int s = clampN(ei[e]);
    int t = clampN(ei[NEDGES + e]);
    float dx = LD<ISF>(pos, (size_t)s * 3 + 0) - LD<ISF>(pos, (size_t)t * 3 + 0);
    float dy = LD<ISF>(pos, (size_t)s * 3 + 1) - LD<ISF>(pos, (size_t)t * 3 + 1);
    float dz = LD<ISF>(pos, (size_t)s * 3 + 2) - LD<ISF>(pos, (size_t)t * 3 + 2);
    float d = sqrtf(dx * dx + dy * dy + dz * dz + 1e-12f);
    if (d != d) d = 1e30f;
    float C = (d < 5.0f) ? 0.5f * (__cosf(d * 0.6283185307f) + 1.0f) : 0.0f;
    C_s[i] = C;
    Cm_s[i] = (s != t) ? C : 0.0f;
    ed_s[i] = __expf(-d);
    src_s[i] = s;
    dst_s[i] = t;
}
__global__ void geom_k(const int* ei, const void* pos, const int* perm, const int* flagp,
                       float* C_s, float* Cm_s, float* ed_s, int* src_s, int* dst_s) {
    if (flagp[1]) geom_body<1>(ei, pos, perm, C_s, Cm_s, ed_s, src_s, dst_s);
    else          geom_body<0>(ei, pos, perm, C_s, Cm_s, ed_s, src_s, dst_s);
}

// ---------------- weight pack/convert ----------------
template<int ISF>
__device__ void packB_body(const void* src, int K, int ksteps, size_t perLsrc,
                           size_t perLdst, int L, bf16* dst) {
    int t = blockIdx.x * 256 + threadIdx.x;
    int total = L * 8 * ksteps * 64;
    if (t >= total) return;
    int lane = t & 63;
    int t2 = t >> 6;
    int ks = t2 % ksteps;
    int t3 = t2 / ksteps;
    int nt = t3 & 7;
    int l  = t3 >> 3;
    int quad = lane >> 4, lc = lane & 15;
    int col = nt * 16 + lc;
    for (int j = 0; j < 8; j++) {
        int k = ks * 32 + quad * 8 + j;
        float v = (k < K) ? LD<ISF>(src, (size_t)l * perLsrc + (size_t)k * 128 + col) : 0.0f;
        dst[(size_t)l * perLdst + ((size_t)((nt * ksteps + ks) * 64 + lane)) * 8 + j] = f2b(v);
    }
}
__global__ void packB_k(const void* src, int K, int ksteps, size_t perLsrc,
                        size_t perLdst, int L, const int* flagp, bf16* dst) {
    if (flagp[1]) packB_body<1>(src, K, ksteps, perLsrc, perLdst, L, dst);
    else          packB_body<0>(src, K, ksteps, perLsrc, perLdst, L, dst);
}
template<int ISF>
__device__ void cvt_body(const void* src, int n, float* dst) {
    int i = blockIdx.x * 256 + threadIdx.x;
    if (i < n) dst[i] = LD<ISF>(src, i);
}
__global__ void cvt_k(const void* src, int n, const int* flagp, float* dst) {
    if (flagp[1]) cvt_body<1>(src, n, dst);
    else          cvt_body<0>(src, n, dst);
}

// ---------------- MFMA helpers ----------------
#define MFMA(a, b, c) __builtin_amdgcn_mfma_f32_16x16x32_bf16((a), (b), (c), 0, 0, 0)

__device__ __forceinline__ void attr_tile(bf16 (*attr)[72], int i0,
                                          const float* __restrict__ C_s,
                                          const float* __restrict__ ed_s,
                                          const float* __restrict__ meanscv,
                                          const float* __restrict__ betascv,
                                          int tid) {
    int m = tid >> 2, rg = (tid & 3) * 16;
    int i = i0 + m;
    float Ci = C_s[i], edi = ed_s[i];
    #pragma unroll
    for (int rr = 0; rr < 16; rr++) {
        int r = rg + rr;
        float v = 0.0f;
        if (r < RBF) {
            float u = edi - meanscv[r];
            v = Ci * __expf(-betascv[r] * u * u);
        }
        attr[m][r] = f2b(v);
    }
}

// segmented column sum over 64 LDS rows -> out (fp32), boundary rows atomic.
__device__ __forceinline__ void seg_sum(const bf16 (*mv)[136], const int* ddst,
                                        float* __restrict__ out, int tid) {
    if (tid < 128) {
        int col = tid;
        int cur = ddst[0]; float s = 0.0f; int segstart = 0;
        for (int e = 0; e < 64; e++) {
            int dn = ddst[e];
            if (dn != cur) {
                if (segstart == 0) atomicAdd(&out[(size_t)cur * HC + col], s);
                else out[(size_t)cur * HC + col] = s;   // interior: complete sum
                cur = dn; s = 0.0f; segstart = e;
            }
            s += b2f(mv[e][col]);
        }
        atomicAdd(&out[(size_t)cur * HC + col], s);     // last segment: boundary
    }
}

// ---------------- neighbor-embedding edge kernel (fused sum) ---------------
__global__ __launch_bounds__(256)
void nbr_mfma_k(const float* __restrict__ ed_s, const float* __restrict__ C_s,
                const float* __restrict__ Cm_s, const int* __restrict__ src_s,
                const int* __restrict__ dst_s,
                const int* __restrict__ z, const float* __restrict__ nbrembcv,
                const bf16* __restrict__ wpp, const float* __restrict__ bpcv,
                const float* __restrict__ meanscv, const float* __restrict__ betascv,
                float* __restrict__ msg) {
    __shared__ bf16 attr[64][72];
    __shared__ bf16 mv[64][136];
    __shared__ int ddst[64];
    int i0 = blockIdx.x * 64;
    int tid = threadIdx.x;
    if (tid < 64) ddst[tid] = dst_s[i0 + tid];
    attr_tile(attr, i0, C_s, ed_s, meanscv, betascv, tid);
    __syncthreads();

    int wave = tid >> 6, lane = tid & 63, quad = lane >> 4, lc = lane & 15;
    bf8v af[2];
    #pragma unroll
    for (int ks = 0; ks < 2; ks++)
        af[ks] = *(const bf8v*)&attr[wave * 16 + lc][ks * 32 + quad * 8];
    f4v zero = {0.f, 0.f, 0.f, 0.f};
    f4v acc[8];
    #pragma unroll
    for (int nt = 0; nt < 8; nt++) acc[nt] = zero;
    #pragma unroll
    for (int nt = 0; nt < 8; nt++)
        #pragma unroll
        for (int ks = 0; ks < 2; ks++) {
            bf8v b = *(const bf8v*)(wpp + ((nt * 2 + ks) * 64 + lane) * 8);
            acc[nt] = MFMA(af[ks], b, acc[nt]);
        }
    float Cr[4]; int zr[4];
    #pragma unroll
    for (int r = 0; r < 4; r++) {
        int i = i0 + wave * 16 + quad * 4 + r;
        Cr[r] = Cm_s[i];
        int zz = z[src_s[i]];
        zr[r] = (zz < 0) ? 0 : (zz >= MAXZ_ ? MAXZ_ - 1 : zz);
    }
    #pragma unroll
    for (int nt = 0; nt < 8; nt++) {
        int n = nt * 16 + lc;
        float bb = bpcv[n];
        #pragma unroll
        for (int r = 0; r < 4; r++) {
            float v = (acc[nt][r] + bb) * Cr[r] * nbrembcv[(size_t)zr[r] * HC + n];
            mv[wave * 16 + quad * 4 + r][n] = f2b(v);
        }
    }
    __syncthreads();
    seg_sum(mv, ddst, msg, tid);
}

// ---------------- acomb prep: [emb[z[n]] | msg[n]] bf16 ----------------
template<int ISF>
__device__ void prep_body(const int* __restrict__ z, const void* __restrict__ emb,
                          const float* __restrict__ msg, bf16* __restrict__ acomb) {
    int n = blockIdx.x, j = threadIdx.x;
    int zz = z[n]; zz = zz < 0 ? 0 : (zz >= MAXZ_ ? MAXZ_ - 1 : zz);
    float v = (j < HC) ? LD<ISF>(emb, (size_t)zz * HC + j)
                       : msg[(size_t)n * HC + (j - HC)];
    acomb[(size_t)n * 256 + j] = f2b(v);
}
__global__ void prep_k(const int* z, const void* emb, const float* msg,
                       const int* flagp, bf16* acomb) {
    if (flagp[1]) prep_body<1>(z, emb, msg, acomb);
    else          prep_body<0>(z, emb, msg, acomb);
}

// ---------------- combine: x = acomb @ Wc + bc (MFMA, K=256) ----------------
__global__ __launch_bounds__(256)
void combine_mfma_k(const bf16* __restrict__ acomb, const bf16* __restrict__ wcp,
                    const float* __restrict__ bccv, float* __restrict__ x,
                    bf16* __restrict__ xb) {
    int tid = threadIdx.x;
    int wave = tid >> 6, lane = tid & 63, quad = lane >> 4, lc = lane & 15;
    int m0 = blockIdx.x * 64;
    bf8v azero = {0, 0, 0, 0, 0, 0, 0, 0};
    bf8v af[8];
    int arow = m0 + wave * 16 + lc;
    #pragma unroll
    for (int ks = 0; ks < 8; ks++) {
        if (arow < NATOMS)
            af[ks] = *(const bf8v*)(acomb + (size_t)arow * 256 + ks * 32 + quad * 8);
        else af[ks] = azero;
    }
    f4v zero = {0.f, 0.f, 0.f, 0.f};
    f4v acc[8];
    #pragma unroll
    for (int nt = 0; nt < 8; nt++) acc[nt] = zero;
    #pragma unroll
    for (int nt = 0; nt < 8; nt++)
        #pragma unroll
        for (int ks = 0; ks < 8; ks++) {
            bf8v b = *(const bf8v*)(wcp + ((nt * 8 + ks) * 64 + lane) * 8);
            acc[nt] = MFMA(af[ks], b, acc[nt]);
        }
    #pragma unroll
    for (int nt = 0; nt < 8; nt++) {
        int n = nt * 16 + lc;
        float bb = bccv[n];
        #pragma unroll
        for (int r = 0; r < 4; r++) {
            int row = m0 + wave * 16 + quad * 4 + r;
            if (row < NATOMS) {
                float v = acc[nt][r] + bb;
                x[(size_t)row * HC + n] = v;
                xb[(size_t)row * HC + n] = f2b(v);
            }
        }
    }
}

// ---------------- ygemm: y = x @ cW1[l] ----------------
__global__ __launch_bounds__(256)
void ygemm_mfma_k(const bf16* __restrict__ xb, const bf16* __restrict__ cw1p,
                  int l, bf16* __restrict__ ybf) {
    int tid = threadIdx.x;
    int wave = tid >> 6, lane = tid & 63, quad = lane >> 4, lc = lane & 15;
    int m0 = blockIdx.x * 64;
    bf8v azero = {0, 0, 0, 0, 0, 0, 0, 0};
    bf8v af[4];
    int arow = m0 + wave * 16 + lc;
    #pragma unroll
    for (int ks = 0; ks < 4; ks++) {
        if (arow < NATOMS)
            af[ks] = *(const bf8v*)(xb + (size_t)arow * HC + ks * 32 + quad * 8);
        else af[ks] = azero;
    }
    f4v zero = {0.f, 0.f, 0.f, 0.f};
    f4v acc[8];
    #pragma unroll
    for (int nt = 0; nt < 8; nt++) acc[nt] = zero;
    const bf16* base = cw1p + (size_t)l * 16384;
    #pragma unroll
    for (int nt = 0; nt < 8; nt++)
        #pragma unroll
        for (int ks = 0; ks < 4; ks++) {
            bf8v b = *(const bf8v*)(base + ((nt * 4 + ks) * 64 + lane) * 8);
            acc[nt] = MFMA(af[ks], b, acc[nt]);
        }
    #pragma unroll
    for (int nt = 0; nt < 8; nt++) {
        int n = nt * 16 + lc;
        #pragma unroll
        for (int r = 0; r < 4; r++) {
            int row = m0 + wave * 16 + quad * 4 + r;
            if (row < NATOMS) ybf[(size_t)row * HC + n] = f2b(acc[nt][r]);
        }
    }
}

// ---------------- filter MLP + gather + product + fused sum ----------------
__global__ __launch_bounds__(256)
void filt_mfma_k(int l,
                 const float* __restrict__ ed_s, const float* __restrict__ C_s,
                 const int* __restrict__ src_s, const int* __restrict__ dst_s,
                 const bf16* __restrict__ ybf,
                 const bf16* __restrict__ w1p, const bf16* __restrict__ w2p,
                 const float* __restrict__ b1cv, const float* __restrict__ b2cv,
                 const float* __restrict__ meanscv, const float* __restrict__ betascv,
                 float* __restrict__ msum) {
    __shared__ bf16 attr[64][72];
    __shared__ bf16 hid[64][136];
    __shared__ int ddst[64];
    int i0 = blockIdx.x * 64;
    int tid = threadIdx.x;
    if (tid < 64) ddst[tid] = dst_s[i0 + tid];
    attr_tile(attr, i0, C_s, ed_s, meanscv, betascv, tid);
    __syncthreads();

    int wave = tid >> 6, lane = tid & 63, quad = lane >> 4, lc = lane & 15;
    bf8v af[2];
    #pragma unroll
    for (int ks = 0; ks < 2; ks++)
        af[ks] = *(const bf8v*)&attr[wave * 16 + lc][ks * 32 + quad * 8];
    f4v zero = {0.f, 0.f, 0.f, 0.f};
    f4v acc[8];
    #pragma unroll
    for (int nt = 0; nt < 8; nt++) acc[nt] = zero;
    const bf16* w1b = w1p + (size_t)l * 8192;
    #pragma unroll
    for (int nt = 0; nt < 8; nt++)
        #pragma unroll
        for (int ks = 0; ks < 2; ks++) {
            bf8v b = *(const bf8v*)(w1b + ((nt * 2 + ks) * 64 + lane) * 8);
            acc[nt] = MFMA(af[ks], b, acc[nt]);
        }
    #pragma unroll
    for (int nt = 0; nt < 8; nt++) {
        int n = nt * 16 + lc;
        float bb = b1cv[l * HC + n];
        #pragma unroll
        for (int r = 0; r < 4; r++) {
            float v = acc[nt][r] + bb;
            v = v / (1.0f + __expf(-v));
            hid[wave * 16 + quad * 4 + r][n] = f2b(v);
        }
    }
    __syncthreads();
    bf8v a2[4];
    #pragma unroll
    for (int ks = 0; ks < 4; ks++)
        a2[ks] = *(const bf8v*)&hid[wave * 16 + lc][ks * 32 + quad * 8];
    __syncthreads();   // all a2 loads done before hid is overwritten with mv
    f4v acc2[8];
    #pragma unroll
    for (int nt = 0; nt < 8; nt++) acc2[nt] = zero;
    const bf16* w2b = w2p + (size_t)l * 16384;
    #pragma unroll
    for (int nt = 0; nt < 8; nt++)
        #pragma unroll
        for (int ks = 0; ks < 4; ks++) {
            bf8v b = *(const bf8v*)(w2b + ((nt * 4 + ks) * 64 + lane) * 8);
            acc2[nt] = MFMA(a2[ks], b, acc2[nt]);
        }
    float Cr[4]; int sr[4];
    #pragma unroll
    for (int r = 0; r < 4; r++) {
        int i = i0 + wave * 16 + quad * 4 + r;
        Cr[r] = C_s[i];
        sr[r] = src_s[i];
    }
    #pragma unroll
    for (int nt = 0; nt < 8; nt++) {
        int n = nt * 16 + lc;
        float bb = b2cv[l * HC + n];
        #pragma unroll
        for (int r = 0; r < 4; r++) {
            float wf = (acc2[nt][r] + bb) * Cr[r];
            float mv = wf * b2f(ybf[(size_t)sr[r] * HC + n]);
            hid[wave * 16 + quad * 4 + r][n] = f2b(mv);
        }
    }
    __syncthreads();
    seg_sum(hid, ddst, msum, tid);
}

// ---------------- node update: msum@cW2+cb2 -> silu -> @lW+lb -> x+= -------
__global__ __launch_bounds__(256)
void upd_mfma_k(const float* __restrict__ msum, int l,
                const bf16* __restrict__ cw2p, const float* __restrict__ cb2cv,
                const bf16* __restrict__ lwp, const float* __restrict__ lbcv,
                float* __restrict__ x, bf16* __restrict__ xb) {
    __shared__ bf16 srow[64][136];
    int tid = threadIdx.x;
    int wave = tid >> 6, lane = tid & 63, quad = lane >> 4, lc = lane & 15;
    int m0 = blockIdx.x * 64;
    bf8v azero = {0, 0, 0, 0, 0, 0, 0, 0};
    bf8v af[4];
    int arow = m0 + wave * 16 + lc;
    #pragma unroll
    for (int ks = 0; ks < 4; ks++) {
        if (arow < NATOMS) {
            const float* p = msum + (size_t)arow * HC + ks * 32 + quad * 8;
            bf8v f;
            #pragma unroll
            for (int j = 0; j < 8; j++) f[j] = f2s(p[j]);
            af[ks] = f;
        } else af[ks] = azero;
    }
    f4v zero = {0.f, 0.f, 0.f, 0.f};
    f4v acc[8];
    #pragma unroll
    for (int nt = 0; nt < 8; nt++) acc[nt] = zero;
    const bf16* c2b = cw2p + (size_t)l * 16384;
    #pragma unroll
    for (int nt = 0; nt < 8; nt++)
        #pragma unroll
        for (int ks = 0; ks < 4; ks++) {
            bf8v b = *(const bf8v*)(c2b + ((nt * 4 + ks) * 64 + lane) * 8);
            acc[nt] = MFMA(af[ks], b, acc[nt]);
        }
    #pragma unroll
    for (int nt = 0; nt < 8; nt++) {
        int n = nt * 16 + lc;
        float bb = cb2cv[l * HC + n];
        #pragma unroll
        for (int r = 0; r < 4; r++) {
            float v = acc[nt][r] + bb;
            v = v / (1.0f + __expf(-v));
            srow[wave * 16 + quad * 4 + r][n] = f2b(v);
        }
    }
    __syncthreads();
    bf8v a2[4];
    #pragma unroll
    for (int ks = 0; ks < 4; ks++)
        a2[ks] = *(const bf8v*)&srow[wave * 16 + lc][ks * 32 + quad * 8];
    f4v acc2[8];
    #pragma unroll
    for (int nt = 0; nt < 8; nt++) acc2[nt] = zero;
    const bf16* lwb = lwp + (size_t)l * 16384;
    #pragma unroll
    for (int nt = 0; nt < 8; nt++)
        #pragma unroll
        for (int ks = 0; ks < 4; ks++) {
            bf8v b = *(const bf8v*)(lwb + ((nt * 4 + ks) * 64 + lane) * 8);
            acc2[nt] = MFMA(a2[ks], b, acc2[nt]);
        }
    #pragma unroll
    for (int nt = 0; nt < 8; nt++) {
        int n = nt * 16 + lc;
        float bb = lbcv[l * HC + n];
        #pragma unroll
        for (int r = 0; r < 4; r++) {
            int row = m0 + wave * 16 + quad * 4 + r;
            if (row < NATOMS) {
                size_t o = (size_t)row * HC + n;
                float nv = x[o] + acc2[nt][r] + bb;
                x[o] = nv;
                xb[o] = f2b(nv);
            }
        }
    }
}

__global__ void out_k(const float* __restrict__ x, void* out, const int* flagp) {
    int i = blockIdx.x * 256 + threadIdx.x;
    if (i >= NATOMS * HC) return;
    if (flagp[1]) ((float*)out)[i] = x[i];
    else          ((bf16*)out)[i] = f2b(x[i]);
}

// ---------------- launch ----------------
extern "C" void kernel_launch(void* const* d_in, const int* in_sizes, int n_in,
                              void* d_out, int out_size, void* d_ws, size_t ws_size,
                              hipStream_t stream) {
    const int*  z      = (const int*) d_in[0];
    const void* pos    = d_in[1];
    const int*  ei     = (const int*) d_in[3];
    const void* emb    = d_in[4];
    const void* nbremb = d_in[5];
    const void* Wp     = d_in[6];
    const void* bp     = d_in[7];
    const void* Wc     = d_in[8];
    const void* bc     = d_in[9];
    const void* means  = d_in[10];
    const void* betas  = d_in[11];
    const void* W1     = d_in[12];
    const void* b1     = d_in[13];
    const void* W2     = d_in[14];
    const void* b2     = d_in[15];
    const void* cW1    = d_in[16];
    const void* cW2    = d_in[17];
    const void* cb2    = d_in[18];
    const void* lW     = d_in[19];
    const void* lb     = d_in[20];

    char* p = (char*)d_ws;
    auto alloc = [&](size_t bytes) { char* r = p; p += (bytes + 255) / 256 * 256; return r; };
    int*   flag    = (int*)  alloc(256);
    int*   counts  = (int*)  alloc((size_t)NATOMS * 4);
    int*   rowptr  = (int*)  alloc((size_t)(NATOMS + 1) * 4);
    int*   cursor  = (int*)  alloc((size_t)NATOMS * 4);
    int*   perm    = (int*)  alloc((size_t)NEDGES * 4);
    int*   src_s   = (int*)  alloc((size_t)NEDGES * 4);
    int*   dst_s   = (int*)  alloc((size_t)NEDGES * 4);
    float* C_s     = (float*)alloc((size_t)NEDGES * 4);
    float* Cm_s    = (float*)alloc((size_t)NEDGES * 4);
    float* ed_s    = (float*)alloc((size_t)NEDGES * 4);
    float* x       = (float*)alloc((size_t)NATOMS * HC * 4);
    bf16*  xb      = (bf16*) alloc((size_t)NATOMS * HC * 2);
    bf16*  ybf     = (bf16*) alloc((size_t)NATOMS * HC * 2);
    float* msum    = (float*)alloc((size_t)NATOMS * HC * 4);
    float* msg     = (float*)alloc((size_t)NATOMS * HC * 4);
    bf16*  acomb   = (bf16*) alloc((size_t)NATOMS * 256 * 2);
    bf16*  wpp     = (bf16*) alloc((size_t)8192 * 2);
    bf16*  wcp     = (bf16*) alloc((size_t)32768 * 2);
    bf16*  w1p     = (bf16*) alloc((size_t)NLAY * 8192 * 2);
    bf16*  w2p     = (bf16*) alloc((size_t)NLAY * 16384 * 2);
    bf16*  cw1p    = (bf16*) alloc((size_t)NLAY * 16384 * 2);
    bf16*  cw2p    = (bf16*) alloc((size_t)NLAY * 16384 * 2);
    bf16*  lwp     = (bf16*) alloc((size_t)NLAY * 16384 * 2);
    float* nbrembcv= (float*)alloc((size_t)MAXZ_ * HC * 4);
    float* bpcv    = (float*)alloc((size_t)HC * 4);
    float* bccv    = (float*)alloc((size_t)HC * 4);
    float* b1cv    = (float*)alloc((size_t)NLAY * HC * 4);
    float* b2cv    = (float*)alloc((size_t)NLAY * HC * 4);
    float* cb2cv   = (float*)alloc((size_t)NLAY * HC * 4);
    float* lbcv    = (float*)alloc((size_t)NLAY * HC * 4);
    float* meanscv = (float*)alloc((size_t)RBF * 4);
    float* betascv = (float*)alloc((size_t)RBF * 4);

    const int EG = (NEDGES + 255) / 256;
    const int NG = (NATOMS + 255) / 256;

    zero_k<<<1, 64, 0, stream>>>(flag, 2);
    zero_k<<<NG, 256, 0, stream>>>(counts, NATOMS);
    probe_k<<<(NATOMS * 3 + 255) / 256, 256, 0, stream>>>(pos, NATOMS * 3, flag);
    setflag_k<<<1, 64, 0, stream>>>(flag);

    hist_k<<<EG, 256, 0, stream>>>(ei + NEDGES, counts);
    scan_k<<<1, 1024, 0, stream>>>(counts, rowptr);
    copy_k<<<NG, 256, 0, stream>>>(rowptr, cursor, NATOMS);
    perm_k<<<EG, 256, 0, stream>>>(ei + NEDGES, cursor, perm);
    geom_k<<<EG, 256, 0, stream>>>(ei, pos, perm, flag, C_s, Cm_s, ed_s, src_s, dst_s);

    packB_k<<<4,  256, 0, stream>>>(Wp,  RBF, 2, 6400, 8192, 1, flag, wpp);
    packB_k<<<16, 256, 0, stream>>>(Wc,  256, 8, 32768, 32768, 1, flag, wcp);
    packB_k<<<24, 256, 0, stream>>>(W1,  RBF, 2, 6400, 8192, NLAY, flag, w1p);
    packB_k<<<48, 256, 0, stream>>>(W2,  HC, 4, 16384, 16384, NLAY, flag, w2p);
    packB_k<<<48, 256, 0, stream>>>(cW1, HC, 4, 16384, 16384, NLAY, flag, cw1p);
    packB_k<<<48, 256, 0, stream>>>(cW2, HC, 4, 16384, 16384, NLAY, flag, cw2p);
    packB_k<<<48, 256, 0, stream>>>(lW,  HC, 4, 16384, 16384, NLAY, flag, lwp);
    cvt_k<<<(MAXZ_ * HC + 255) / 256, 256, 0, stream>>>(nbremb, MAXZ_ * HC, flag, nbrembcv);
    cvt_k<<<1, 256, 0, stream>>>(bp, HC, flag, bpcv);
    cvt_k<<<1, 256, 0, stream>>>(bc, HC, flag, bccv);
    cvt_k<<<3, 256, 0, stream>>>(b1, NLAY * HC, flag, b1cv);
    cvt_k<<<3, 256, 0, stream>>>(b2, NLAY * HC, flag, b2cv);
    cvt_k<<<3, 256, 0, stream>>>(cb2, NLAY * HC, flag, cb2cv);
    cvt_k<<<3, 256, 0, stream>>>(lb, NLAY * HC, flag, lbcv);
    cvt_k<<<1, 64, 0, stream>>>(means, RBF, flag, meanscv);
    cvt_k<<<1, 64, 0, stream>>>(betas, RBF, flag, betascv);

    // neighbor embedding (fused sum -> msg)
    hipMemsetAsync(msg, 0, (size_t)NATOMS * HC * 4, stream);
    nbr_mfma_k<<<EGRID, 256, 0, stream>>>(ed_s, C_s, Cm_s, src_s, dst_s, z, nbrembcv,
                                          wpp, bpcv, meanscv, betascv, msg);
    prep_k<<<NATOMS, 256, 0, stream>>>(z, emb, msg, flag, acomb);
    combine_mfma_k<<<YGRID, 256, 0, stream>>>(acomb, wcp, bccv, x, xb);

    for (int l = 0; l < NLAY; l++) {
        ygemm_mfma_k<<<YGRID, 256, 0, stream>>>(xb, cw1p, l, ybf);
        hipMemsetAsync(msum, 0, (size_t)NATOMS * HC * 4, stream);
        filt_mfma_k<<<EGRID, 256, 0, stream>>>(l, ed_s, C_s, src_s, dst_s, ybf,
                                               w1p, w2p, b1cv, b2cv,
                                               meanscv, betascv, msum);
        upd_mfma_k<<<YGRID, 256, 0, stream>>>(msum, l, cw2p, cb2cv, lwp, lbcv, x, xb);
    }
    out_k<<<(NATOMS * HC + 255) / 256, 256, 0, stream>>>(x, d_out, flag);
}

// Round 6
// 812.668 us; speedup vs baseline: 11.0833x; 1.1565x over previous
//
#include <hip/hip_runtime.h>
#include <hip/hip_bf16.h>

// TorchMD_GN_Ext R6:
//  - attr RBF computed directly in A-fragment registers (no attr LDS round trip)
//  - seg_sum parallel over all 256 threads (2 halves x 32 rows), boundary atomics
//  - y[src] / nbr-emb rows cooperatively staged into LDS (coalesced 16B loads)
//  - ygemm fused into combine/upd epilogue (GEMM3 with cW1[l+1])
//  - shuffle-based scan, merged pack/cvt launches (~38 dispatches total)

#define NATOMS 10000
#define NEDGES 320000
#define HC 128
#define RBF 50
#define NLAY 6
#define MAXZ_ 100
#define EGRID (NEDGES / 64)         // 5000
#define YGRID ((NATOMS + 63) / 64)  // 157

typedef __hip_bfloat16 bf16;
typedef __attribute__((ext_vector_type(8))) short bf8v;
typedef __attribute__((ext_vector_type(4))) float f4v;

__device__ __forceinline__ float b2f(bf16 v) { return __bfloat162float(v); }
__device__ __forceinline__ bf16  f2b(float v) { return __float2bfloat16(v); }
__device__ __forceinline__ short f2s(float v) { bf16 h = f2b(v); return *(short*)&h; }

template<int ISF>
__device__ __forceinline__ float LD(const void* p, size_t i) {
    if (ISF) return ((const float*)p)[i];
    return b2f(((const bf16*)p)[i]);
}

// ---------------- dtype probe ----------------
__global__ void probe_k(const void* pos, int nelem, int* flag) {
    int i = blockIdx.x * 256 + threadIdx.x;
    float v = 0.0f;
    if (i < nelem) {
        v = fabsf(b2f(((const bf16*)pos)[i]));
        if (v != v) v = 1e30f;
    }
    atomicMax(flag, __float_as_int(v));
}
__global__ void setflag_k(int* flag) {
    if (threadIdx.x == 0) flag[1] = (__int_as_float(flag[0]) > 1.0e4f) ? 1 : 0;
}

// ---------------- CSR build ----------------
__global__ void zero_k(int* p, int n) {
    int i = blockIdx.x * 256 + threadIdx.x;
    if (i < n) p[i] = 0;
}
__device__ __forceinline__ int clampN(int v) {
    return v < 0 ? 0 : (v >= NATOMS ? NATOMS - 1 : v);
}
__global__ void hist_k(const int* __restrict__ dst, int* __restrict__ counts) {
    int e = blockIdx.x * 256 + threadIdx.x;
    if (e < NEDGES) atomicAdd(&counts[clampN(dst[e])], 1);
}
// shuffle-based single-block scan: 1024 threads, 4 barriers per 1024-chunk
__global__ void scan_k(const int* __restrict__ counts, int* __restrict__ rowptr) {
    __shared__ int wsum[16];
    __shared__ int carry_s;
    __shared__ int chunktot;
    int tid = threadIdx.x, lane = tid & 63, w = tid >> 6;
    if (tid == 0) { carry_s = 0; rowptr[0] = 0; }
    __syncthreads();
    for (int base = 0; base < NATOMS; base += 1024) {
        int i = base + tid;
        int s = (i < NATOMS) ? counts[i] : 0;
        #pragma unroll
        for (int off = 1; off < 64; off <<= 1) {
            int t = __shfl_up(s, off, 64);
            if (lane >= off) s += t;
        }
        if (lane == 63) wsum[w] = s;
        __syncthreads();
        if (w == 0 && lane < 16) {
            int t = wsum[lane];
            int si = t;
            #pragma unroll
            for (int off = 1; off < 16; off <<= 1) {
                int u = __shfl_up(si, off, 64);
                if (lane >= off) si += u;
            }
            wsum[lane] = si - t;
            if (lane == 15) chunktot = si;
        }
        __syncthreads();
        int carry = carry_s;
        if (i < NATOMS) rowptr[i + 1] = carry + wsum[w] + s;
        __syncthreads();
        if (tid == 0) carry_s += chunktot;
        __syncthreads();
    }
}
__global__ void copy_k(const int* __restrict__ a, int* __restrict__ b, int n) {
    int i = blockIdx.x * 256 + threadIdx.x;
    if (i < n) b[i] = a[i];
}
__global__ void perm_k(const int* __restrict__ dst, int* __restrict__ cursor,
                       int* __restrict__ perm) {
    int e = blockIdx.x * 256 + threadIdx.x;
    if (e < NEDGES) {
        int p = atomicAdd(&cursor[clampN(dst[e])], 1);
        perm[p] = e;
    }
}

// ---------------- geometry ----------------
template<int ISF>
__device__ void geom_body(const int* __restrict__ ei, const void* __restrict__ pos,
                          const int* __restrict__ perm,
                          float* __restrict__ C_s, float* __restrict__ Cm_s,
                          float* __restrict__ ed_s, int* __restrict__ src_s,
                          int* __restrict__ dst_s) {
    int i = blockIdx.x * 256 + threadIdx.x;
    if (i >= NEDGES) return;
    int e = perm[i];
    int s = clampN(ei[e]);
    int t = clampN(ei[NEDGES + e]);
    float dx = LD<ISF>(pos, (size_t)s * 3 + 0) - LD<ISF>(pos, (size_t)t * 3 + 0);
    float dy = LD<ISF>(pos, (size_t)s * 3 + 1) - LD<ISF>(pos, (size_t)t * 3 + 1);
    float dz = LD<ISF>(pos, (size_t)s * 3 + 2) - LD<ISF>(pos, (size_t)t * 3 + 2);
    float d = sqrtf(dx * dx + dy * dy + dz * dz + 1e-12f);
    if (d != d) d = 1e30f;
    float C = (d < 5.0f) ? 0.5f * (__cosf(d * 0.6283185307f) + 1.0f) : 0.0f;
    C_s[i] = C;
    Cm_s[i] = (s != t) ? C : 0.0f;
    ed_s[i] = __expf(-d);
    src_s[i] = s;
    dst_s[i] = t;
}
__global__ void geom_k(const int* ei, const void* pos, const int* perm, const int* flagp,
                       float* C_s, float* Cm_s, float* ed_s, int* src_s, int* dst_s) {
    if (flagp[1]) geom_body<1>(ei, pos, perm, C_s, Cm_s, ed_s, src_s, dst_s);
    else          geom_body<0>(ei, pos, perm, C_s, Cm_s, ed_s, src_s, dst_s);
}

// ---------------- weight pack / convert ----------------
template<int ISF>
__device__ void packB_body(const void* src, int K, int ksteps, size_t perLsrc,
                           size_t perLdst, int L, bf16* dst) {
    int t = blockIdx.x * 256 + threadIdx.x;
    int total = L * 8 * ksteps * 64;
    if (t >= total) return;
    int lane = t & 63;
    int t2 = t >> 6;
    int ks = t2 % ksteps;
    int t3 = t2 / ksteps;
    int nt = t3 & 7;
    int l  = t3 >> 3;
    int quad = lane >> 4, lc = lane & 15;
    int col = nt * 16 + lc;
    for (int j = 0; j < 8; j++) {
        int k = ks * 32 + quad * 8 + j;
        float v = (k < K) ? LD<ISF>(src, (size_t)l * perLsrc + (size_t)k * 128 + col) : 0.0f;
        dst[(size_t)l * perLdst + ((size_t)((nt * ksteps + ks) * 64 + lane)) * 8 + j] = f2b(v);
    }
}
__global__ void packB_k(const void* src, int K, int ksteps, size_t perLsrc,
                        size_t perLdst, int L, const int* flagp, bf16* dst) {
    if (flagp[1]) packB_body<1>(src, K, ksteps, perLsrc, perLdst, L, dst);
    else          packB_body<0>(src, K, ksteps, perLsrc, perLdst, L, dst);
}
// merged pack of the 24 K=128 square weights (W2,cW1,cW2,lW x 6 layers)
template<int ISF>
__device__ void packB24_body(const void* w2, const void* cw1, const void* cw2,
                             const void* lw, bf16* w2p, bf16* cw1p, bf16* cw2p,
                             bf16* lwp) {
    int t = blockIdx.x * 256 + threadIdx.x;
    if (t >= 24 * 8 * 4 * 64) return;
    int lane = t & 63;
    int t2 = t >> 6;
    int ks = t2 & 3;
    int t3 = t2 >> 2;
    int nt = t3 & 7;
    int m  = t3 >> 3;            // 0..23
    int which = m / NLAY, li = m % NLAY;
    const void* src = which == 0 ? w2 : which == 1 ? cw1 : which == 2 ? cw2 : lw;
    bf16* dst = which == 0 ? w2p : which == 1 ? cw1p : which == 2 ? cw2p : lwp;
    int quad = lane >> 4, lc = lane & 15;
    int col = nt * 16 + lc;
    #pragma unroll
    for (int j = 0; j < 8; j++) {
        int k = ks * 32 + quad * 8 + j;
        float v = LD<ISF>(src, (size_t)li * 16384 + (size_t)k * 128 + col);
        dst[(size_t)li * 16384 + ((size_t)((nt * 4 + ks) * 64 + lane)) * 8 + j] = f2b(v);
    }
}
__global__ void packB24_k(const void* w2, const void* cw1, const void* cw2,
                          const void* lw, const int* flagp,
                          bf16* w2p, bf16* cw1p, bf16* cw2p, bf16* lwp) {
    if (flagp[1]) packB24_body<1>(w2, cw1, cw2, lw, w2p, cw1p, cw2p, lwp);
    else          packB24_body<0>(w2, cw1, cw2, lw, w2p, cw1p, cw2p, lwp);
}
// merged small-vector converts (means, betas, bp, bc, b1, b2, cb2, lb)
template<int ISF>
__device__ void cvts_body(const void* means, const void* betas, const void* bp,
                          const void* bc, const void* b1, const void* b2,
                          const void* cb2, const void* lb,
                          float* meanscv, float* betascv, float* bpcv, float* bccv,
                          float* b1cv, float* b2cv, float* cb2cv, float* lbcv) {
    int i = blockIdx.x * 256 + threadIdx.x;
    if      (i < 50)   meanscv[i]        = LD<ISF>(means, i);
    else if (i < 100)  betascv[i - 50]   = LD<ISF>(betas, i - 50);
    else if (i < 228)  bpcv[i - 100]     = LD<ISF>(bp, i - 100);
    else if (i < 356)  bccv[i - 228]     = LD<ISF>(bc, i - 228);
    else if (i < 1124) b1cv[i - 356]     = LD<ISF>(b1, i - 356);
    else if (i < 1892) b2cv[i - 1124]    = LD<ISF>(b2, i - 1124);
    else if (i < 2660) cb2cv[i - 1892]   = LD<ISF>(cb2, i - 1892);
    else if (i < 3428) lbcv[i - 2660]    = LD<ISF>(lb, i - 2660);
}
__global__ void cvts_k(const void* means, const void* betas, const void* bp,
                       const void* bc, const void* b1, const void* b2,
                       const void* cb2, const void* lb, const int* flagp,
                       float* meanscv, float* betascv, float* bpcv, float* bccv,
                       float* b1cv, float* b2cv, float* cb2cv, float* lbcv) {
    if (flagp[1]) cvts_body<1>(means, betas, bp, bc, b1, b2, cb2, lb,
                               meanscv, betascv, bpcv, bccv, b1cv, b2cv, cb2cv, lbcv);
    else          cvts_body<0>(means, betas, bp, bc, b1, b2, cb2, lb,
                               meanscv, betascv, bpcv, bccv, b1cv, b2cv, cb2cv, lbcv);
}
// bf16 copy of neighbor-embedding table
template<int ISF>
__device__ void cvtb_body(const void* src, int n, bf16* dst) {
    int i = blockIdx.x * 256 + threadIdx.x;
    if (i < n) dst[i] = f2b(LD<ISF>(src, i));
}
__global__ void cvtb_k(const void* src, int n, const int* flagp, bf16* dst) {
    if (flagp[1]) cvtb_body<1>(src, n, dst);
    else          cvtb_body<0>(src, n, dst);
}

// ---------------- MFMA helpers ----------------
#define MFMA(a, b, c) __builtin_amdgcn_mfma_f32_16x16x32_bf16((a), (b), (c), 0, 0, 0)

// parallel segmented column-sum: 256 threads, 2 halves x 32 rows; interior
// segments direct-store, boundary segments atomicAdd (out zero-initialized).
__device__ __forceinline__ void seg_sum2(const bf16 (*mv)[136], const int* ddst,
                                         float* __restrict__ out, int tid) {
    int col = tid & 127;
    int base = (tid >> 7) * 32;
    int cur = ddst[base];
    float s = 0.0f;
    bool first = true;
    for (int e = base; e < base + 32; e++) {
        int dn = ddst[e];
        if (dn != cur) {
            if (first) atomicAdd(&out[(size_t)cur * HC + col], s);
            else out[(size_t)cur * HC + col] = s;
            first = false; cur = dn; s = 0.0f;
        }
        s += b2f(mv[e][col]);
    }
    atomicAdd(&out[(size_t)cur * HC + col], s);
}

// ---------------- neighbor-embedding edge kernel ----------------
__global__ __launch_bounds__(256)
void nbr_mfma_k(const float* __restrict__ ed_s, const float* __restrict__ C_s,
                const float* __restrict__ Cm_s, const int* __restrict__ src_s,
                const int* __restrict__ dst_s, const int* __restrict__ z,
                const bf16* __restrict__ nbrembbf, const bf16* __restrict__ wpp,
                const float* __restrict__ bpcv,
                const float* __restrict__ meanscv, const float* __restrict__ betascv,
                float* __restrict__ msg) {
    __shared__ bf16 mv[64][136];
    __shared__ bf16 est[64][136];
    __shared__ int ddst[64];
    int i0 = blockIdx.x * 64;
    int tid = threadIdx.x;
    int wave = tid >> 6, lane = tid & 63, quad = lane >> 4, lc = lane & 15;
    if (tid < 64) ddst[tid] = dst_s[i0 + tid];
    {   // stage nbr-emb rows for the block's 64 src atoms (coalesced)
        int row = tid >> 2, c0 = (tid & 3) * 32;
        int zz = z[src_s[i0 + row]];
        zz = zz < 0 ? 0 : (zz >= MAXZ_ ? MAXZ_ - 1 : zz);
        const bf16* ep = nbrembbf + (size_t)zz * HC + c0;
        #pragma unroll
        for (int j = 0; j < 4; j++)
            *(bf8v*)&est[row][c0 + j * 8] = *(const bf8v*)(ep + j * 8);
    }
    // attr A-fragments in registers
    int arow = i0 + wave * 16 + lc;
    float Ci = C_s[arow], edi = ed_s[arow];
    bf8v af[2];
    #pragma unroll
    for (int ks = 0; ks < 2; ks++) {
        #pragma unroll
        for (int j = 0; j < 8; j++) {
            int r = ks * 32 + quad * 8 + j;
            float v = 0.0f;
            if (r < RBF) { float u = edi - meanscv[r]; v = Ci * __expf(-betascv[r] * u * u); }
            af[ks][j] = f2s(v);
        }
    }
    __syncthreads();   // est/ddst staged before epilogue reads
    f4v zero = {0.f, 0.f, 0.f, 0.f};
    f4v acc[8];
    #pragma unroll
    for (int nt = 0; nt < 8; nt++) acc[nt] = zero;
    #pragma unroll
    for (int nt = 0; nt < 8; nt++)
        #pragma unroll
        for (int ks = 0; ks < 2; ks++) {
            bf8v b = *(const bf8v*)(wpp + ((nt * 2 + ks) * 64 + lane) * 8);
            acc[nt] = MFMA(af[ks], b, acc[nt]);
        }
    float Cr[4];
    #pragma unroll
    for (int r = 0; r < 4; r++) Cr[r] = Cm_s[i0 + wave * 16 + quad * 4 + r];
    #pragma unroll
    for (int nt = 0; nt < 8; nt++) {
        int n = nt * 16 + lc;
        float bb = bpcv[n];
        #pragma unroll
        for (int r = 0; r < 4; r++) {
            int row = wave * 16 + quad * 4 + r;
            float v = (acc[nt][r] + bb) * Cr[r] * b2f(est[row][n]);
            mv[row][n] = f2b(v);
        }
    }
    __syncthreads();
    seg_sum2(mv, ddst, msg, tid);
}

// ---------------- acomb prep: [emb[z[n]] | msg[n]] bf16 ----------------
template<int ISF>
__device__ void prep_body(const int* __restrict__ z, const void* __restrict__ emb,
                          const float* __restrict__ msg, bf16* __restrict__ acomb) {
    int n = blockIdx.x, j = threadIdx.x;
    int zz = z[n]; zz = zz < 0 ? 0 : (zz >= MAXZ_ ? MAXZ_ - 1 : zz);
    float v = (j < HC) ? LD<ISF>(emb, (size_t)zz * HC + j)
                       : msg[(size_t)n * HC + (j - HC)];
    acomb[(size_t)n * 256 + j] = f2b(v);
}
__global__ void prep_k(const int* z, const void* emb, const float* msg,
                       const int* flagp, bf16* acomb) {
    if (flagp[1]) prep_body<1>(z, emb, msg, acomb);
    else          prep_body<0>(z, emb, msg, acomb);
}

// ---------------- combine: x = acomb @ Wc + bc; also y0 = x @ cW1[0] -------
__global__ __launch_bounds__(256)
void combine_mfma_k(const bf16* __restrict__ acomb, const bf16* __restrict__ wcp,
                    const float* __restrict__ bccv, const bf16* __restrict__ cw1b,
                    float* __restrict__ x, bf16* __restrict__ xb,
                    bf16* __restrict__ ybf) {
    __shared__ bf16 srow[64][136];
    int tid = threadIdx.x;
    int wave = tid >> 6, lane = tid & 63, quad = lane >> 4, lc = lane & 15;
    int m0 = blockIdx.x * 64;
    bf8v azero = {0, 0, 0, 0, 0, 0, 0, 0};
    bf8v af[8];
    int arow = m0 + wave * 16 + lc;
    #pragma unroll
    for (int ks = 0; ks < 8; ks++) {
        if (arow < NATOMS)
            af[ks] = *(const bf8v*)(acomb + (size_t)arow * 256 + ks * 32 + quad * 8);
        else af[ks] = azero;
    }
    f4v zero = {0.f, 0.f, 0.f, 0.f};
    f4v acc[8];
    #pragma unroll
    for (int nt = 0; nt < 8; nt++) acc[nt] = zero;
    #pragma unroll
    for (int nt = 0; nt < 8; nt++)
        #pragma unroll
        for (int ks = 0; ks < 8; ks++) {
            bf8v b = *(const bf8v*)(wcp + ((nt * 8 + ks) * 64 + lane) * 8);
            acc[nt] = MFMA(af[ks], b, acc[nt]);
        }
    #pragma unroll
    for (int nt = 0; nt < 8; nt++) {
        int n = nt * 16 + lc;
        float bb = bccv[n];
        #pragma unroll
        for (int r = 0; r < 4; r++) {
            int row = m0 + wave * 16 + quad * 4 + r;
            float v = acc[nt][r] + bb;
            bf16 vb = f2b(v);
            srow[wave * 16 + quad * 4 + r][n] = vb;
            if (row < NATOMS) {
                x[(size_t)row * HC + n] = v;
                xb[(size_t)row * HC + n] = vb;
            }
        }
    }
    __syncthreads();
    // GEMM3: y0 = xnew @ cW1[0]
    bf8v a3[4];
    #pragma unroll
    for (int ks = 0; ks < 4; ks++)
        a3[ks] = *(const bf8v*)&srow[wave * 16 + lc][ks * 32 + quad * 8];
    f4v acc3[8];
    #pragma unroll
    for (int nt = 0; nt < 8; nt++) acc3[nt] = zero;
    #pragma unroll
    for (int nt = 0; nt < 8; nt++)
        #pragma unroll
        for (int ks = 0; ks < 4; ks++) {
            bf8v b = *(const bf8v*)(cw1b + ((nt * 4 + ks) * 64 + lane) * 8);
            acc3[nt] = MFMA(a3[ks], b, acc3[nt]);
        }
    #pragma unroll
    for (int nt = 0; nt < 8; nt++) {
        int n = nt * 16 + lc;
        #pragma unroll
        for (int r = 0; r < 4; r++) {
            int row = m0 + wave * 16 + quad * 4 + r;
            if (row < NATOMS) ybf[(size_t)row * HC + n] = f2b(acc3[nt][r]);
        }
    }
}

// ---------------- filter MLP + gather + product + fused sum ----------------
__global__ __launch_bounds__(256)
void filt_mfma_k(int l,
                 const float* __restrict__ ed_s, const float* __restrict__ C_s,
                 const int* __restrict__ src_s, const int* __restrict__ dst_s,
                 const bf16* __restrict__ ybf,
                 const bf16* __restrict__ w1p, const bf16* __restrict__ w2p,
                 const float* __restrict__ b1cv, const float* __restrict__ b2cv,
                 const float* __restrict__ meanscv, const float* __restrict__ betascv,
                 float* __restrict__ msum) {
    __shared__ bf16 hid[64][136];
    __shared__ bf16 ysrc[64][136];
    __shared__ int ddst[64];
    int i0 = blockIdx.x * 64;
    int tid = threadIdx.x;
    int wave = tid >> 6, lane = tid & 63, quad = lane >> 4, lc = lane & 15;
    if (tid < 64) ddst[tid] = dst_s[i0 + tid];
    {   // stage y[src] rows (coalesced 16B loads, 4 threads per row)
        int row = tid >> 2, c0 = (tid & 3) * 32;
        const bf16* yp = ybf + (size_t)src_s[i0 + row] * HC + c0;
        #pragma unroll
        for (int j = 0; j < 4; j++)
            *(bf8v*)&ysrc[row][c0 + j * 8] = *(const bf8v*)(yp + j * 8);
    }
    // attr A-fragments in registers
    int arow = i0 + wave * 16 + lc;
    float Ci = C_s[arow], edi = ed_s[arow];
    bf8v af[2];
    #pragma unroll
    for (int ks = 0; ks < 2; ks++) {
        #pragma unroll
        for (int j = 0; j < 8; j++) {
            int r = ks * 32 + quad * 8 + j;
            float v = 0.0f;
            if (r < RBF) { float u = edi - meanscv[r]; v = Ci * __expf(-betascv[r] * u * u); }
            af[ks][j] = f2s(v);
        }
    }
    // GEMM1: attr @ W1
    f4v zero = {0.f, 0.f, 0.f, 0.f};
    f4v acc[8];
    #pragma unroll
    for (int nt = 0; nt < 8; nt++) acc[nt] = zero;
    const bf16* w1b = w1p + (size_t)l * 8192;
    #pragma unroll
    for (int nt = 0; nt < 8; nt++)
        #pragma unroll
        for (int ks = 0; ks < 2; ks++) {
            bf8v b = *(const bf8v*)(w1b + ((nt * 2 + ks) * 64 + lane) * 8);
            acc[nt] = MFMA(af[ks], b, acc[nt]);
        }
    // bias + silu -> hid
    #pragma unroll
    for (int nt = 0; nt < 8; nt++) {
        int n = nt * 16 + lc;
        float bb = b1cv[l * HC + n];
        #pragma unroll
        for (int r = 0; r < 4; r++) {
            float v = acc[nt][r] + bb;
            v = v / (1.0f + __expf(-v));
            hid[wave * 16 + quad * 4 + r][n] = f2b(v);
        }
    }
    __syncthreads();   // hid + ysrc + ddst writes complete
    bf8v a2[4];
    #pragma unroll
    for (int ks = 0; ks < 4; ks++)
        a2[ks] = *(const bf8v*)&hid[wave * 16 + lc][ks * 32 + quad * 8];
    __syncthreads();   // all a2 reads done before hid overwritten
    f4v acc2[8];
    #pragma unroll
    for (int nt = 0; nt < 8; nt++) acc2[nt] = zero;
    const bf16* w2b = w2p + (size_t)l * 16384;
    #pragma unroll
    for (int nt = 0; nt < 8; nt++)
        #pragma unroll
        for (int ks = 0; ks < 4; ks++) {
            bf8v b = *(const bf8v*)(w2b + ((nt * 4 + ks) * 64 + lane) * 8);
            acc2[nt] = MFMA(a2[ks], b, acc2[nt]);
        }
    float Cr[4];
    #pragma unroll
    for (int r = 0; r < 4; r++) Cr[r] = C_s[i0 + wave * 16 + quad * 4 + r];
    #pragma unroll
    for (int nt = 0; nt < 8; nt++) {
        int n = nt * 16 + lc;
        float bb = b2cv[l * HC + n];
        #pragma unroll
        for (int r = 0; r < 4; r++) {
            int row = wave * 16 + quad * 4 + r;
            float wf = (acc2[nt][r] + bb) * Cr[r];
            float mv = wf * b2f(ysrc[row][n]);
            hid[row][n] = f2b(mv);
        }
    }
    __syncthreads();
    seg_sum2(hid, ddst, msum, tid);
}

// ---- node update: msum@cW2+cb2 -> silu -> @lW+lb -> x+=; y = xnew@cW1[l+1] -
__global__ __launch_bounds__(256)
void upd_mfma_k(const float* __restrict__ msum, int l,
                const bf16* __restrict__ cw2p, const float* __restrict__ cb2cv,
                const bf16* __restrict__ lwp, const float* __restrict__ lbcv,
                const bf16* __restrict__ cw1p, int do_y,
                float* __restrict__ x, bf16* __restrict__ xb,
                bf16* __restrict__ ybf) {
    __shared__ bf16 srow[64][136];
    int tid = threadIdx.x;
    int wave = tid >> 6, lane = tid & 63, quad = lane >> 4, lc = lane & 15;
    int m0 = blockIdx.x * 64;
    bf8v azero = {0, 0, 0, 0, 0, 0, 0, 0};
    bf8v af[4];
    int arow = m0 + wave * 16 + lc;
    #pragma unroll
    for (int ks = 0; ks < 4; ks++) {
        if (arow < NATOMS) {
            const float* p = msum + (size_t)arow * HC + ks * 32 + quad * 8;
            bf8v f;
            #pragma unroll
            for (int j = 0; j < 8; j++) f[j] = f2s(p[j]);
            af[ks] = f;
        } else af[ks] = azero;
    }
    f4v zero = {0.f, 0.f, 0.f, 0.f};
    f4v acc[8];
    #pragma unroll
    for (int nt = 0; nt < 8; nt++) acc[nt] = zero;
    const bf16* c2b = cw2p + (size_t)l * 16384;
    #pragma unroll
    for (int nt = 0; nt < 8; nt++)
        #pragma unroll
        for (int ks = 0; ks < 4; ks++) {
            bf8v b = *(const bf8v*)(c2b + ((nt * 4 + ks) * 64 + lane) * 8);
            acc[nt] = MFMA(af[ks], b, acc[nt]);
        }
    #pragma unroll
    for (int nt = 0; nt < 8; nt++) {
        int n = nt * 16 + lc;
        float bb = cb2cv[l * HC + n];
        #pragma unroll
        for (int r = 0; r < 4; r++) {
            float v = acc[nt][r] + bb;
            v = v / (1.0f + __expf(-v));
            srow[wave * 16 + quad * 4 + r][n] = f2b(v);
        }
    }
    __syncthreads();
    bf8v a2[4];
    #pragma unroll
    for (int ks = 0; ks < 4; ks++)
        a2[ks] = *(const bf8v*)&srow[wave * 16 + lc][ks * 32 + quad * 8];
    __syncthreads();   // a2 reads done before srow overwritten with xnew
    f4v acc2[8];
    #pragma unroll
    for (int nt = 0; nt < 8; nt++) acc2[nt] = zero;
    const bf16* lwb = lwp + (size_t)l * 16384;
    #pragma unroll
    for (int nt = 0; nt < 8; nt++)
        #pragma unroll
        for (int ks = 0; ks < 4; ks++) {
            bf8v b = *(const bf8v*)(lwb + ((nt * 4 + ks) * 64 + lane) * 8);
            acc2[nt] = MFMA(a2[ks], b, acc2[nt]);
        }
    #pragma unroll
    for (int nt = 0; nt < 8; nt++) {
        int n = nt * 16 + lc;
        float bb = lbcv[l * HC + n];
        #pragma unroll
        for (int r = 0; r < 4; r++) {
            int row = m0 + wave * 16 + quad * 4 + r;
            float nv = 0.0f;
            if (row < NATOMS) {
                size_t o = (size_t)row * HC + n;
                nv = x[o] + acc2[nt][r] + bb;
                x[o] = nv;
                xb[o] = f2b(nv);
            }
            srow[wave * 16 + quad * 4 + r][n] = f2b(nv);
        }
    }
    if (do_y) {
        __syncthreads();
        bf8v a3[4];
        #pragma unroll
        for (int ks = 0; ks < 4; ks++)
            a3[ks] = *(const bf8v*)&srow[wave * 16 + lc][ks * 32 + quad * 8];
        f4v acc3[8];
        #pragma unroll
        for (int nt = 0; nt < 8; nt++) acc3[nt] = zero;
        const bf16* c1b = cw1p + (size_t)(l + 1) * 16384;
        #pragma unroll
        for (int nt = 0; nt < 8; nt++)
            #pragma unroll
            for (int ks = 0; ks < 4; ks++) {
                bf8v b = *(const bf8v*)(c1b + ((nt * 4 + ks) * 64 + lane) * 8);
                acc3[nt] = MFMA(a3[ks], b, acc3[nt]);
            }
        #pragma unroll
        for (int nt = 0; nt < 8; nt++) {
            int n = nt * 16 + lc;
            #pragma unroll
            for (int r = 0; r < 4; r++) {
                int row = m0 + wave * 16 + quad * 4 + r;
                if (row < NATOMS) ybf[(size_t)row * HC + n] = f2b(acc3[nt][r]);
            }
        }
    }
}

__global__ void out_k(const float* __restrict__ x, void* out, const int* flagp) {
    int i = blockIdx.x * 256 + threadIdx.x;
    if (i >= NATOMS * HC) return;
    if (flagp[1]) ((float*)out)[i] = x[i];
    else          ((bf16*)out)[i] = f2b(x[i]);
}

// ---------------- launch ----------------
extern "C" void kernel_launch(void* const* d_in, const int* in_sizes, int n_in,
                              void* d_out, int out_size, void* d_ws, size_t ws_size,
                              hipStream_t stream) {
    const int*  z      = (const int*) d_in[0];
    const void* pos    = d_in[1];
    const int*  ei     = (const int*) d_in[3];
    const void* emb    = d_in[4];
    const void* nbremb = d_in[5];
    const void* Wp     = d_in[6];
    const void* bp     = d_in[7];
    const void* Wc     = d_in[8];
    const void* bc     = d_in[9];
    const void* means  = d_in[10];
    const void* betas  = d_in[11];
    const void* W1     = d_in[12];
    const void* b1     = d_in[13];
    const void* W2     = d_in[14];
    const void* b2     = d_in[15];
    const void* cW1    = d_in[16];
    const void* cW2    = d_in[17];
    const void* cb2    = d_in[18];
    const void* lW     = d_in[19];
    const void* lb     = d_in[20];

    char* p = (char*)d_ws;
    auto alloc = [&](size_t bytes) { char* r = p; p += (bytes + 255) / 256 * 256; return r; };
    int*   flag    = (int*)  alloc(256);
    int*   counts  = (int*)  alloc((size_t)NATOMS * 4);
    int*   rowptr  = (int*)  alloc((size_t)(NATOMS + 1) * 4);
    int*   cursor  = (int*)  alloc((size_t)NATOMS * 4);
    int*   perm    = (int*)  alloc((size_t)NEDGES * 4);
    int*   src_s   = (int*)  alloc((size_t)NEDGES * 4);
    int*   dst_s   = (int*)  alloc((size_t)NEDGES * 4);
    float* C_s     = (float*)alloc((size_t)NEDGES * 4);
    float* Cm_s    = (float*)alloc((size_t)NEDGES * 4);
    float* ed_s    = (float*)alloc((size_t)NEDGES * 4);
    float* x       = (float*)alloc((size_t)NATOMS * HC * 4);
    bf16*  xb      = (bf16*) alloc((size_t)NATOMS * HC * 2);
    bf16*  ybf     = (bf16*) alloc((size_t)NATOMS * HC * 2);
    float* msum    = (float*)alloc((size_t)NATOMS * HC * 4);
    float* msg     = (float*)alloc((size_t)NATOMS * HC * 4);
    bf16*  acomb   = (bf16*) alloc((size_t)NATOMS * 256 * 2);
    bf16*  wpp     = (bf16*) alloc((size_t)8192 * 2);
    bf16*  wcp     = (bf16*) alloc((size_t)32768 * 2);
    bf16*  w1p     = (bf16*) alloc((size_t)NLAY * 8192 * 2);
    bf16*  w2p     = (bf16*) alloc((size_t)NLAY * 16384 * 2);
    bf16*  cw1p    = (bf16*) alloc((size_t)NLAY * 16384 * 2);
    bf16*  cw2p    = (bf16*) alloc((size_t)NLAY * 16384 * 2);
    bf16*  lwp     = (bf16*) alloc((size_t)NLAY * 16384 * 2);
    bf16*  nbrembbf= (bf16*) alloc((size_t)MAXZ_ * HC * 2);
    float* bpcv    = (float*)alloc((size_t)HC * 4);
    float* bccv    = (float*)alloc((size_t)HC * 4);
    float* b1cv    = (float*)alloc((size_t)NLAY * HC * 4);
    float* b2cv    = (float*)alloc((size_t)NLAY * HC * 4);
    float* cb2cv   = (float*)alloc((size_t)NLAY * HC * 4);
    float* lbcv    = (float*)alloc((size_t)NLAY * HC * 4);
    float* meanscv = (float*)alloc((size_t)RBF * 4);
    float* betascv = (float*)alloc((size_t)RBF * 4);

    const int EG = (NEDGES + 255) / 256;
    const int NG = (NATOMS + 255) / 256;

    zero_k<<<1, 64, 0, stream>>>(flag, 2);
    zero_k<<<NG, 256, 0, stream>>>(counts, NATOMS);
    probe_k<<<(NATOMS * 3 + 255) / 256, 256, 0, stream>>>(pos, NATOMS * 3, flag);
    setflag_k<<<1, 64, 0, stream>>>(flag);

    hist_k<<<EG, 256, 0, stream>>>(ei + NEDGES, counts);
    scan_k<<<1, 1024, 0, stream>>>(counts, rowptr);
    copy_k<<<NG, 256, 0, stream>>>(rowptr, cursor, NATOMS);
    perm_k<<<EG, 256, 0, stream>>>(ei + NEDGES, cursor, perm);
    geom_k<<<EG, 256, 0, stream>>>(ei, pos, perm, flag, C_s, Cm_s, ed_s, src_s, dst_s);

    packB_k<<<4,  256, 0, stream>>>(Wp,  RBF, 2, 6400, 8192, 1, flag, wpp);
    packB_k<<<16, 256, 0, stream>>>(Wc,  256, 8, 32768, 32768, 1, flag, wcp);
    packB_k<<<24, 256, 0, stream>>>(W1,  RBF, 2, 6400, 8192, NLAY, flag, w1p);
    packB24_k<<<192, 256, 0, stream>>>(W2, cW1, cW2, lW, flag, w2p, cw1p, cw2p, lwp);
    cvts_k<<<14, 256, 0, stream>>>(means, betas, bp, bc, b1, b2, cb2, lb, flag,
                                   meanscv, betascv, bpcv, bccv, b1cv, b2cv, cb2cv, lbcv);
    cvtb_k<<<(MAXZ_ * HC + 255) / 256, 256, 0, stream>>>(nbremb, MAXZ_ * HC, flag, nbrembbf);

    hipMemsetAsync(msg, 0, (size_t)NATOMS * HC * 4, stream);
    nbr_mfma_k<<<EGRID, 256, 0, stream>>>(ed_s, C_s, Cm_s, src_s, dst_s, z, nbrembbf,
                                          wpp, bpcv, meanscv, betascv, msg);
    prep_k<<<NATOMS, 256, 0, stream>>>(z, emb, msg, flag, acomb);
    combine_mfma_k<<<YGRID, 256, 0, stream>>>(acomb, wcp, bccv, cw1p, x, xb, ybf);

    for (int l = 0; l < NLAY; l++) {
        hipMemsetAsync(msum, 0, (size_t)NATOMS * HC * 4, stream);
        filt_mfma_k<<<EGRID, 256, 0, stream>>>(l, ed_s, C_s, src_s, dst_s, ybf,
                                               w1p, w2p, b1cv, b2cv,
                                               meanscv, betascv, msum);
        upd_mfma_k<<<YGRID, 256, 0, stream>>>(msum, l, cw2p, cb2cv, lwp, lbcv,
                                              cw1p, (l < NLAY - 1) ? 1 : 0, x, xb, ybf);
    }
    out_k<<<(NATOMS * HC + 255) / 256, 256, 0, stream>>>(x, d_out, flag);
}

// Round 7
// 721.265 us; speedup vs baseline: 12.4878x; 1.1267x over previous
//
#include <hip/hip_runtime.h>
#include <hip/hip_bf16.h>

// TorchMD_GN_Ext R7:
//  - segmented sum via MFMA indicator-matmul (sorted edges -> ~2.2 segs/block;
//    slot[] by wave shuffle-prefix; mv stored transposed mvT[128][72] so
//    B-frags are single ds_read_b128; interior segs direct-store, boundary
//    segs atomicAdd; serial fallback for nseg>16)
//  - silu via v_rcp_f32 (__builtin_amdgcn_rcpf) instead of IEEE div
//  - mvT unions with hid LDS -> ~36.6KB, 4 blocks/CU preserved

#define NATOMS 10000
#define NEDGES 320000
#define HC 128
#define RBF 50
#define NLAY 6
#define MAXZ_ 100
#define EGRID (NEDGES / 64)         // 5000
#define YGRID ((NATOMS + 63) / 64)  // 157

typedef __hip_bfloat16 bf16;
typedef __attribute__((ext_vector_type(8))) short bf8v;
typedef __attribute__((ext_vector_type(4))) float f4v;

__device__ __forceinline__ float b2f(bf16 v) { return __bfloat162float(v); }
__device__ __forceinline__ bf16  f2b(float v) { return __float2bfloat16(v); }
__device__ __forceinline__ short f2s(float v) { bf16 h = f2b(v); return *(short*)&h; }
__device__ __forceinline__ float silu(float v) {
    return v * __builtin_amdgcn_rcpf(1.0f + __expf(-v));
}

template<int ISF>
__device__ __forceinline__ float LD(const void* p, size_t i) {
    if (ISF) return ((const float*)p)[i];
    return b2f(((const bf16*)p)[i]);
}

// ---------------- dtype probe ----------------
__global__ void probe_k(const void* pos, int nelem, int* flag) {
    int i = blockIdx.x * 256 + threadIdx.x;
    float v = 0.0f;
    if (i < nelem) {
        v = fabsf(b2f(((const bf16*)pos)[i]));
        if (v != v) v = 1e30f;
    }
    atomicMax(flag, __float_as_int(v));
}
__global__ void setflag_k(int* flag) {
    if (threadIdx.x == 0) flag[1] = (__int_as_float(flag[0]) > 1.0e4f) ? 1 : 0;
}

// ---------------- CSR build ----------------
__global__ void zero_k(int* p, int n) {
    int i = blockIdx.x * 256 + threadIdx.x;
    if (i < n) p[i] = 0;
}
__device__ __forceinline__ int clampN(int v) {
    return v < 0 ? 0 : (v >= NATOMS ? NATOMS - 1 : v);
}
__global__ void hist_k(const int* __restrict__ dst, int* __restrict__ counts) {
    int e = blockIdx.x * 256 + threadIdx.x;
    if (e < NEDGES) atomicAdd(&counts[clampN(dst[e])], 1);
}
__global__ void scan_k(const int* __restrict__ counts, int* __restrict__ rowptr) {
    __shared__ int wsum[16];
    __shared__ int carry_s;
    __shared__ int chunktot;
    int tid = threadIdx.x, lane = tid & 63, w = tid >> 6;
    if (tid == 0) { carry_s = 0; rowptr[0] = 0; }
    __syncthreads();
    for (int base = 0; base < NATOMS; base += 1024) {
        int i = base + tid;
        int s = (i < NATOMS) ? counts[i] : 0;
        #pragma unroll
        for (int off = 1; off < 64; off <<= 1) {
            int t = __shfl_up(s, off, 64);
            if (lane >= off) s += t;
        }
        if (lane == 63) wsum[w] = s;
        __syncthreads();
        if (w == 0 && lane < 16) {
            int t = wsum[lane];
            int si = t;
            #pragma unroll
            for (int off = 1; off < 16; off <<= 1) {
                int u = __shfl_up(si, off, 64);
                if (lane >= off) si += u;
            }
            wsum[lane] = si - t;
            if (lane == 15) chunktot = si;
        }
        __syncthreads();
        int carry = carry_s;
        if (i < NATOMS) rowptr[i + 1] = carry + wsum[w] + s;
        __syncthreads();
        if (tid == 0) carry_s += chunktot;
        __syncthreads();
    }
}
__global__ void copy_k(const int* __restrict__ a, int* __restrict__ b, int n) {
    int i = blockIdx.x * 256 + threadIdx.x;
    if (i < n) b[i] = a[i];
}
__global__ void perm_k(const int* __restrict__ dst, int* __restrict__ cursor,
                       int* __restrict__ perm) {
    int e = blockIdx.x * 256 + threadIdx.x;
    if (e < NEDGES) {
        int p = atomicAdd(&cursor[clampN(dst[e])], 1);
        perm[p] = e;
    }
}

// ---------------- geometry ----------------
template<int ISF>
__device__ void geom_body(const int* __restrict__ ei, const void* __restrict__ pos,
                          const int* __restrict__ perm,
                          float* __restrict__ C_s, float* __restrict__ Cm_s,
                          float* __restrict__ ed_s, int* __restrict__ src_s,
                          int* __restrict__ dst_s) {
    int i = blockIdx.x * 256 + threadIdx.x;
    if (i >= NEDGES) return;
    int e = perm[i];
    int s = clampN(ei[e]);
    int t = clampN(ei[NEDGES + e]);
    float dx = LD<ISF>(pos, (size_t)s * 3 + 0) - LD<ISF>(pos, (size_t)t * 3 + 0);
    float dy = LD<ISF>(pos, (size_t)s * 3 + 1) - LD<ISF>(pos, (size_t)t * 3 + 1);
    float dz = LD<ISF>(pos, (size_t)s * 3 + 2) - LD<ISF>(pos, (size_t)t * 3 + 2);
    float d = sqrtf(dx * dx + dy * dy + dz * dz + 1e-12f);
    if (d != d) d = 1e30f;
    float C = (d < 5.0f) ? 0.5f * (__cosf(d * 0.6283185307f) + 1.0f) : 0.0f;
    C_s[i] = C;
    Cm_s[i] = (s != t) ? C : 0.0f;
    ed_s[i] = __expf(-d);
    src_s[i] = s;
    dst_s[i] = t;
}
__global__ void geom_k(const int* ei, const void* pos, const int* perm, const int* flagp,
                       float* C_s, float* Cm_s, float* ed_s, int* src_s, int* dst_s) {
    if (flagp[1]) geom_body<1>(ei, pos, perm, C_s, Cm_s, ed_s, src_s, dst_s);
    else          geom_body<0>(ei, pos, perm, C_s, Cm_s, ed_s, src_s, dst_s);
}

// ---------------- weight pack / convert ----------------
template<int ISF>
__device__ void packB_body(const void* src, int K, int ksteps, size_t perLsrc,
                           size_t perLdst, int L, bf16* dst) {
    int t = blockIdx.x * 256 + threadIdx.x;
    int total = L * 8 * ksteps * 64;
    if (t >= total) return;
    int lane = t & 63;
    int t2 = t >> 6;
    int ks = t2 % ksteps;
    int t3 = t2 / ksteps;
    int nt = t3 & 7;
    int l  = t3 >> 3;
    int quad = lane >> 4, lc = lane & 15;
    int col = nt * 16 + lc;
    for (int j = 0; j < 8; j++) {
        int k = ks * 32 + quad * 8 + j;
        float v = (k < K) ? LD<ISF>(src, (size_t)l * perLsrc + (size_t)k * 128 + col) : 0.0f;
        dst[(size_t)l * perLdst + ((size_t)((nt * ksteps + ks) * 64 + lane)) * 8 + j] = f2b(v);
    }
}
__global__ void packB_k(const void* src, int K, int ksteps, size_t perLsrc,
                        size_t perLdst, int L, const int* flagp, bf16* dst) {
    if (flagp[1]) packB_body<1>(src, K, ksteps, perLsrc, perLdst, L, dst);
    else          packB_body<0>(src, K, ksteps, perLsrc, perLdst, L, dst);
}
template<int ISF>
__device__ void packB24_body(const void* w2, const void* cw1, const void* cw2,
                             const void* lw, bf16* w2p, bf16* cw1p, bf16* cw2p,
                             bf16* lwp) {
    int t = blockIdx.x * 256 + threadIdx.x;
    if (t >= 24 * 8 * 4 * 64) return;
    int lane = t & 63;
    int t2 = t >> 6;
    int ks = t2 & 3;
    int t3 = t2 >> 2;
    int nt = t3 & 7;
    int m  = t3 >> 3;
    int which = m / NLAY, li = m % NLAY;
    const void* src = which == 0 ? w2 : which == 1 ? cw1 : which == 2 ? cw2 : lw;
    bf16* dst = which == 0 ? w2p : which == 1 ? cw1p : which == 2 ? cw2p : lwp;
    int quad = lane >> 4, lc = lane & 15;
    int col = nt * 16 + lc;
    #pragma unroll
    for (int j = 0; j < 8; j++) {
        int k = ks * 32 + quad * 8 + j;
        float v = LD<ISF>(src, (size_t)li * 16384 + (size_t)k * 128 + col);
        dst[(size_t)li * 16384 + ((size_t)((nt * 4 + ks) * 64 + lane)) * 8 + j] = f2b(v);
    }
}
__global__ void packB24_k(const void* w2, const void* cw1, const void* cw2,
                          const void* lw, const int* flagp,
                          bf16* w2p, bf16* cw1p, bf16* cw2p, bf16* lwp) {
    if (flagp[1]) packB24_body<1>(w2, cw1, cw2, lw, w2p, cw1p, cw2p, lwp);
    else          packB24_body<0>(w2, cw1, cw2, lw, w2p, cw1p, cw2p, lwp);
}
template<int ISF>
__device__ void cvts_body(const void* means, const void* betas, const void* bp,
                          const void* bc, const void* b1, const void* b2,
                          const void* cb2, const void* lb,
                          float* meanscv, float* betascv, float* bpcv, float* bccv,
                          float* b1cv, float* b2cv, float* cb2cv, float* lbcv) {
    int i = blockIdx.x * 256 + threadIdx.x;
    if      (i < 50)   meanscv[i]        = LD<ISF>(means, i);
    else if (i < 100)  betascv[i - 50]   = LD<ISF>(betas, i - 50);
    else if (i < 228)  bpcv[i - 100]     = LD<ISF>(bp, i - 100);
    else if (i < 356)  bccv[i - 228]     = LD<ISF>(bc, i - 228);
    else if (i < 1124) b1cv[i - 356]     = LD<ISF>(b1, i - 356);
    else if (i < 1892) b2cv[i - 1124]    = LD<ISF>(b2, i - 1124);
    else if (i < 2660) cb2cv[i - 1892]   = LD<ISF>(cb2, i - 1892);
    else if (i < 3428) lbcv[i - 2660]    = LD<ISF>(lb, i - 2660);
}
__global__ void cvts_k(const void* means, const void* betas, const void* bp,
                       const void* bc, const void* b1, const void* b2,
                       const void* cb2, const void* lb, const int* flagp,
                       float* meanscv, float* betascv, float* bpcv, float* bccv,
                       float* b1cv, float* b2cv, float* cb2cv, float* lbcv) {
    if (flagp[1]) cvts_body<1>(means, betas, bp, bc, b1, b2, cb2, lb,
                               meanscv, betascv, bpcv, bccv, b1cv, b2cv, cb2cv, lbcv);
    else          cvts_body<0>(means, betas, bp, bc, b1, b2, cb2, lb,
                               meanscv, betascv, bpcv, bccv, b1cv, b2cv, cb2cv, lbcv);
}
template<int ISF>
__device__ void cvtb_body(const void* src, int n, bf16* dst) {
    int i = blockIdx.x * 256 + threadIdx.x;
    if (i < n) dst[i] = f2b(LD<ISF>(src, i));
}
__global__ void cvtb_k(const void* src, int n, const int* flagp, bf16* dst) {
    if (flagp[1]) cvtb_body<1>(src, n, dst);
    else          cvtb_body<0>(src, n, dst);
}

// ---------------- MFMA helpers ----------------
#define MFMA(a, b, c) __builtin_amdgcn_mfma_f32_16x16x32_bf16((a), (b), (c), 0, 0, 0)

// slot/distinct/nseg by wave 0 (tid<64): shuffle prefix over sorted dst
__device__ __forceinline__ void seg_prep(const int* __restrict__ dst_s, int i0, int tid,
                                         int* ddst, int* slot_s, int* distinct_s,
                                         int* nseg_s) {
    if (tid < 64) {
        int d = dst_s[i0 + tid];
        ddst[tid] = d;
        int dprev = __shfl_up(d, 1, 64);
        int flag = (tid == 0 || d != dprev) ? 1 : 0;
        int s = flag;
        #pragma unroll
        for (int off = 1; off < 64; off <<= 1) {
            int t = __shfl_up(s, off, 64);
            if (tid >= off) s += t;
        }
        slot_s[tid] = s - 1;
        if (flag) distinct_s[s - 1] = d;
        if (tid == 63) *nseg_s = s;
    }
}

// segmented column-sum via MFMA indicator-matmul (mvT transposed [128][72]).
// interior segments direct-store, boundary atomicAdd. Fallback if nseg>16.
__device__ __forceinline__ void seg_mfma(const bf16 (*mvT)[72], const int* ddst,
                                         const int* slot_s, const int* distinct_s,
                                         int nseg, float* __restrict__ out, int tid) {
    int wave = tid >> 6, lane = tid & 63, quad = lane >> 4, lc = lane & 15;
    if (nseg <= 16) {
        bf8v sa[2];
        #pragma unroll
        for (int ks = 0; ks < 2; ks++)
            #pragma unroll
            for (int j = 0; j < 8; j++) {
                int k = ks * 32 + quad * 8 + j;
                sa[ks][j] = (slot_s[k] == lc) ? (short)0x3F80 : (short)0;
            }
        f4v z4 = {0.f, 0.f, 0.f, 0.f};
        f4v sacc[2] = {z4, z4};
        #pragma unroll
        for (int nt = 0; nt < 2; nt++)
            #pragma unroll
            for (int ks = 0; ks < 2; ks++) {
                bf8v b = *(const bf8v*)&mvT[wave * 32 + nt * 16 + lc][ks * 32 + quad * 8];
                sacc[nt] = MFMA(sa[ks], b, sacc[nt]);
            }
        #pragma unroll
        for (int nt = 0; nt < 2; nt++)
            #pragma unroll
            for (int r = 0; r < 4; r++) {
                int sl = quad * 4 + r;
                if (sl < nseg) {
                    int atom = distinct_s[sl];
                    int n = wave * 32 + nt * 16 + lc;
                    float v = sacc[nt][r];
                    if (sl == 0 || sl == nseg - 1)
                        atomicAdd(&out[(size_t)atom * HC + n], v);
                    else
                        out[(size_t)atom * HC + n] = v;
                }
            }
    } else {  // rare fallback: serial per column (transposed reads)
        int col = tid & 127;
        int base = (tid >> 7) * 32;
        int cur = ddst[base];
        float s = 0.0f;
        bool first = true;
        for (int e = base; e < base + 32; e++) {
            int dn = ddst[e];
            if (dn != cur) {
                if (first) atomicAdd(&out[(size_t)cur * HC + col], s);
                else out[(size_t)cur * HC + col] = s;
                first = false; cur = dn; s = 0.0f;
            }
            s += b2f(mvT[col][e]);
        }
        atomicAdd(&out[(size_t)cur * HC + col], s);
    }
}

// ---------------- neighbor-embedding edge kernel ----------------
__global__ __launch_bounds__(256)
void nbr_mfma_k(const float* __restrict__ ed_s, const float* __restrict__ C_s,
                const float* __restrict__ Cm_s, const int* __restrict__ src_s,
                const int* __restrict__ dst_s, const int* __restrict__ z,
                const bf16* __restrict__ nbrembbf, const bf16* __restrict__ wpp,
                const float* __restrict__ bpcv,
                const float* __restrict__ meanscv, const float* __restrict__ betascv,
                float* __restrict__ msg) {
    __shared__ bf16 mvT[128][72];
    __shared__ bf16 est[64][136];
    __shared__ int ddst[64], slot_s[64], distinct_s[64];
    __shared__ int nseg_s;
    int i0 = blockIdx.x * 64;
    int tid = threadIdx.x;
    int wave = tid >> 6, lane = tid & 63, quad = lane >> 4, lc = lane & 15;
    seg_prep(dst_s, i0, tid, ddst, slot_s, distinct_s, &nseg_s);
    {   // stage nbr-emb rows (coalesced 16B loads, 4 threads per row)
        int row = tid >> 2, c0 = (tid & 3) * 32;
        int zz = z[src_s[i0 + row]];
        zz = zz < 0 ? 0 : (zz >= MAXZ_ ? MAXZ_ - 1 : zz);
        const bf16* ep = nbrembbf + (size_t)zz * HC + c0;
        #pragma unroll
        for (int j = 0; j < 4; j++)
            *(bf8v*)&est[row][c0 + j * 8] = *(const bf8v*)(ep + j * 8);
    }
    // attr A-fragments in registers
    int arow = i0 + wave * 16 + lc;
    float Ci = C_s[arow], edi = ed_s[arow];
    bf8v af[2];
    #pragma unroll
    for (int ks = 0; ks < 2; ks++) {
        #pragma unroll
        for (int j = 0; j < 8; j++) {
            int r = ks * 32 + quad * 8 + j;
            float v = 0.0f;
            if (r < RBF) { float u = edi - meanscv[r]; v = Ci * __expf(-betascv[r] * u * u); }
            af[ks][j] = f2s(v);
        }
    }
    f4v zero = {0.f, 0.f, 0.f, 0.f};
    f4v acc[8];
    #pragma unroll
    for (int nt = 0; nt < 8; nt++) acc[nt] = zero;
    #pragma unroll
    for (int nt = 0; nt < 8; nt++)
        #pragma unroll
        for (int ks = 0; ks < 2; ks++) {
            bf8v b = *(const bf8v*)(wpp + ((nt * 2 + ks) * 64 + lane) * 8);
            acc[nt] = MFMA(af[ks], b, acc[nt]);
        }
    float Cr[4];
    #pragma unroll
    for (int r = 0; r < 4; r++) Cr[r] = Cm_s[i0 + wave * 16 + quad * 4 + r];
    __syncthreads();   // est + seg_prep visible
    #pragma unroll
    for (int nt = 0; nt < 8; nt++) {
        int n = nt * 16 + lc;
        float bb = bpcv[n];
        #pragma unroll
        for (int r = 0; r < 4; r++) {
            int row = wave * 16 + quad * 4 + r;
            float v = (acc[nt][r] + bb) * Cr[r] * b2f(est[row][n]);
            mvT[n][row] = f2b(v);
        }
    }
    __syncthreads();   // mvT complete
    seg_mfma(mvT, ddst, slot_s, distinct_s, nseg_s, msg, tid);
}

// ---------------- acomb prep: [emb[z[n]] | msg[n]] bf16 ----------------
template<int ISF>
__device__ void prep_body(const int* __restrict__ z, const void* __restrict__ emb,
                          const float* __restrict__ msg, bf16* __restrict__ acomb) {
    int n = blockIdx.x, j = threadIdx.x;
    int zz = z[n]; zz = zz < 0 ? 0 : (zz >= MAXZ_ ? MAXZ_ - 1 : zz);
    float v = (j < HC) ? LD<ISF>(emb, (size_t)zz * HC + j)
                       : msg[(size_t)n * HC + (j - HC)];
    acomb[(size_t)n * 256 + j] = f2b(v);
}
__global__ void prep_k(const int* z, const void* emb, const float* msg,
                       const int* flagp, bf16* acomb) {
    if (flagp[1]) prep_body<1>(z, emb, msg, acomb);
    else          prep_body<0>(z, emb, msg, acomb);
}

// ---------------- combine: x = acomb @ Wc + bc; y0 = x @ cW1[0] ----------------
__global__ __launch_bounds__(256)
void combine_mfma_k(const bf16* __restrict__ acomb, const bf16* __restrict__ wcp,
                    const float* __restrict__ bccv, const bf16* __restrict__ cw1b,
                    float* __restrict__ x, bf16* __restrict__ xb,
                    bf16* __restrict__ ybf) {
    __shared__ bf16 srow[64][136];
    int tid = threadIdx.x;
    int wave = tid >> 6, lane = tid & 63, quad = lane >> 4, lc = lane & 15;
    int m0 = blockIdx.x * 64;
    bf8v azero = {0, 0, 0, 0, 0, 0, 0, 0};
    bf8v af[8];
    int arow = m0 + wave * 16 + lc;
    #pragma unroll
    for (int ks = 0; ks < 8; ks++) {
        if (arow < NATOMS)
            af[ks] = *(const bf8v*)(acomb + (size_t)arow * 256 + ks * 32 + quad * 8);
        else af[ks] = azero;
    }
    f4v zero = {0.f, 0.f, 0.f, 0.f};
    f4v acc[8];
    #pragma unroll
    for (int nt = 0; nt < 8; nt++) acc[nt] = zero;
    #pragma unroll
    for (int nt = 0; nt < 8; nt++)
        #pragma unroll
        for (int ks = 0; ks < 8; ks++) {
            bf8v b = *(const bf8v*)(wcp + ((nt * 8 + ks) * 64 + lane) * 8);
            acc[nt] = MFMA(af[ks], b, acc[nt]);
        }
    #pragma unroll
    for (int nt = 0; nt < 8; nt++) {
        int n = nt * 16 + lc;
        float bb = bccv[n];
        #pragma unroll
        for (int r = 0; r < 4; r++) {
            int row = m0 + wave * 16 + quad * 4 + r;
            float v = acc[nt][r] + bb;
            bf16 vb = f2b(v);
            srow[wave * 16 + quad * 4 + r][n] = vb;
            if (row < NATOMS) {
                x[(size_t)row * HC + n] = v;
                xb[(size_t)row * HC + n] = vb;
            }
        }
    }
    __syncthreads();
    bf8v a3[4];
    #pragma unroll
    for (int ks = 0; ks < 4; ks++)
        a3[ks] = *(const bf8v*)&srow[wave * 16 + lc][ks * 32 + quad * 8];
    f4v acc3[8];
    #pragma unroll
    for (int nt = 0; nt < 8; nt++) acc3[nt] = zero;
    #pragma unroll
    for (int nt = 0; nt < 8; nt++)
        #pragma unroll
        for (int ks = 0; ks < 4; ks++) {
            bf8v b = *(const bf8v*)(cw1b + ((nt * 4 + ks) * 64 + lane) * 8);
            acc3[nt] = MFMA(a3[ks], b, acc3[nt]);
        }
    #pragma unroll
    for (int nt = 0; nt < 8; nt++) {
        int n = nt * 16 + lc;
        #pragma unroll
        for (int r = 0; r < 4; r++) {
            int row = m0 + wave * 16 + quad * 4 + r;
            if (row < NATOMS) ybf[(size_t)row * HC + n] = f2b(acc3[nt][r]);
        }
    }
}

// ---------------- filter MLP + gather + product + MFMA seg-sum ----------------
__global__ __launch_bounds__(256)
void filt_mfma_k(int l,
                 const float* __restrict__ ed_s, const float* __restrict__ C_s,
                 const int* __restrict__ src_s, const int* __restrict__ dst_s,
                 const bf16* __restrict__ ybf,
                 const bf16* __restrict__ w1p, const bf16* __restrict__ w2p,
                 const float* __restrict__ b1cv, const float* __restrict__ b2cv,
                 const float* __restrict__ meanscv, const float* __restrict__ betascv,
                 float* __restrict__ msum) {
    __shared__ union {
        bf16 hid[64][136];
        bf16 mvT[128][72];
    } u;
    __shared__ bf16 ysrc[64][136];
    __shared__ int ddst[64], slot_s[64], distinct_s[64];
    __shared__ int nseg_s;
    int i0 = blockIdx.x * 64;
    int tid = threadIdx.x;
    int wave = tid >> 6, lane = tid & 63, quad = lane >> 4, lc = lane & 15;
    seg_prep(dst_s, i0, tid, ddst, slot_s, distinct_s, &nseg_s);
    {   // stage y[src] rows (coalesced 16B loads, 4 threads per row)
        int row = tid >> 2, c0 = (tid & 3) * 32;
        const bf16* yp = ybf + (size_t)src_s[i0 + row] * HC + c0;
        #pragma unroll
        for (int j = 0; j < 4; j++)
            *(bf8v*)&ysrc[row][c0 + j * 8] = *(const bf8v*)(yp + j * 8);
    }
    // attr A-fragments in registers
    int arow = i0 + wave * 16 + lc;
    float Ci = C_s[arow], edi = ed_s[arow];
    bf8v af[2];
    #pragma unroll
    for (int ks = 0; ks < 2; ks++) {
        #pragma unroll
        for (int j = 0; j < 8; j++) {
            int r = ks * 32 + quad * 8 + j;
            float v = 0.0f;
            if (r < RBF) { float u = edi - meanscv[r]; v = Ci * __expf(-betascv[r] * u * u); }
            af[ks][j] = f2s(v);
        }
    }
    // GEMM1: attr @ W1
    f4v zero = {0.f, 0.f, 0.f, 0.f};
    f4v acc[8];
    #pragma unroll
    for (int nt = 0; nt < 8; nt++) acc[nt] = zero;
    const bf16* w1b = w1p + (size_t)l * 8192;
    #pragma unroll
    for (int nt = 0; nt < 8; nt++)
        #pragma unroll
        for (int ks = 0; ks < 2; ks++) {
            bf8v b = *(const bf8v*)(w1b + ((nt * 2 + ks) * 64 + lane) * 8);
            acc[nt] = MFMA(af[ks], b, acc[nt]);
        }
    // bias + silu -> hid
    #pragma unroll
    for (int nt = 0; nt < 8; nt++) {
        int n = nt * 16 + lc;
        float bb = b1cv[l * HC + n];
        #pragma unroll
        for (int r = 0; r < 4; r++)
            u.hid[wave * 16 + quad * 4 + r][n] = f2b(silu(acc[nt][r] + bb));
    }
    __syncthreads();   // hid + ysrc + seg_prep complete
    bf8v a2[4];
    #pragma unroll
    for (int ks = 0; ks < 4; ks++)
        a2[ks] = *(const bf8v*)&u.hid[wave * 16 + lc][ks * 32 + quad * 8];
    __syncthreads();   // all a2 reads done before union reused as mvT
    f4v acc2[8];
    #pragma unroll
    for (int nt = 0; nt < 8; nt++) acc2[nt] = zero;
    const bf16* w2b = w2p + (size_t)l * 16384;
    #pragma unroll
    for (int nt = 0; nt < 8; nt++)
        #pragma unroll
        for (int ks = 0; ks < 4; ks++) {
            bf8v b = *(const bf8v*)(w2b + ((nt * 4 + ks) * 64 + lane) * 8);
            acc2[nt] = MFMA(a2[ks], b, acc2[nt]);
        }
    float Cr[4];
    #pragma unroll
    for (int r = 0; r < 4; r++) Cr[r] = C_s[i0 + wave * 16 + quad * 4 + r];
    #pragma unroll
    for (int nt = 0; nt < 8; nt++) {
        int n = nt * 16 + lc;
        float bb = b2cv[l * HC + n];
        #pragma unroll
        for (int r = 0; r < 4; r++) {
            int row = wave * 16 + quad * 4 + r;
            float wf = (acc2[nt][r] + bb) * Cr[r];
            u.mvT[n][row] = f2b(wf * b2f(ysrc[row][n]));
        }
    }
    __syncthreads();   // mvT complete
    seg_mfma(u.mvT, ddst, slot_s, distinct_s, nseg_s, msum, tid);
}

// ---- node update: msum@cW2+cb2 -> silu -> @lW+lb -> x+=; y = xnew@cW1[l+1] -
__global__ __launch_bounds__(256)
void upd_mfma_k(const float* __restrict__ msum, int l,
                const bf16* __restrict__ cw2p, const float* __restrict__ cb2cv,
                const bf16* __restrict__ lwp, const float* __restrict__ lbcv,
                const bf16* __restrict__ cw1p, int do_y,
                float* __restrict__ x, bf16* __restrict__ xb,
                bf16* __restrict__ ybf) {
    __shared__ bf16 srow[64][136];
    int tid = threadIdx.x;
    int wave = tid >> 6, lane = tid & 63, quad = lane >> 4, lc = lane & 15;
    int m0 = blockIdx.x * 64;
    bf8v azero = {0, 0, 0, 0, 0, 0, 0, 0};
    bf8v af[4];
    int arow = m0 + wave * 16 + lc;
    #pragma unroll
    for (int ks = 0; ks < 4; ks++) {
        if (arow < NATOMS) {
            const float* p = msum + (size_t)arow * HC + ks * 32 + quad * 8;
            bf8v f;
            #pragma unroll
            for (int j = 0; j < 8; j++) f[j] = f2s(p[j]);
            af[ks] = f;
        } else af[ks] = azero;
    }
    f4v zero = {0.f, 0.f, 0.f, 0.f};
    f4v acc[8];
    #pragma unroll
    for (int nt = 0; nt < 8; nt++) acc[nt] = zero;
    const bf16* c2b = cw2p + (size_t)l * 16384;
    #pragma unroll
    for (int nt = 0; nt < 8; nt++)
        #pragma unroll
        for (int ks = 0; ks < 4; ks++) {
            bf8v b = *(const bf8v*)(c2b + ((nt * 4 + ks) * 64 + lane) * 8);
            acc[nt] = MFMA(af[ks], b, acc[nt]);
        }
    #pragma unroll
    for (int nt = 0; nt < 8; nt++) {
        int n = nt * 16 + lc;
        float bb = cb2cv[l * HC + n];
        #pragma unroll
        for (int r = 0; r < 4; r++)
            srow[wave * 16 + quad * 4 + r][n] = f2b(silu(acc[nt][r] + bb));
    }
    __syncthreads();
    bf8v a2[4];
    #pragma unroll
    for (int ks = 0; ks < 4; ks++)
        a2[ks] = *(const bf8v*)&srow[wave * 16 + lc][ks * 32 + quad * 8];
    __syncthreads();
    f4v acc2[8];
    #pragma unroll
    for (int nt = 0; nt < 8; nt++) acc2[nt] = zero;
    const bf16* lwb = lwp + (size_t)l * 16384;
    #pragma unroll
    for (int nt = 0; nt < 8; nt++)
        #pragma unroll
        for (int ks = 0; ks < 4; ks++) {
            bf8v b = *(const bf8v*)(lwb + ((nt * 4 + ks) * 64 + lane) * 8);
            acc2[nt] = MFMA(a2[ks], b, acc2[nt]);
        }
    #pragma unroll
    for (int nt = 0; nt < 8; nt++) {
        int n = nt * 16 + lc;
        float bb = lbcv[l * HC + n];
        #pragma unroll
        for (int r = 0; r < 4; r++) {
            int row = m0 + wave * 16 + quad * 4 + r;
            float nv = 0.0f;
            if (row < NATOMS) {
                size_t o = (size_t)row * HC + n;
                nv = x[o] + acc2[nt][r] + bb;
                x[o] = nv;
                xb[o] = f2b(nv);
            }
            srow[wave * 16 + quad * 4 + r][n] = f2b(nv);
        }
    }
    if (do_y) {
        __syncthreads();
        bf8v a3[4];
        #pragma unroll
        for (int ks = 0; ks < 4; ks++)
            a3[ks] = *(const bf8v*)&srow[wave * 16 + lc][ks * 32 + quad * 8];
        f4v acc3[8];
        #pragma unroll
        for (int nt = 0; nt < 8; nt++) acc3[nt] = zero;
        const bf16* c1b = cw1p + (size_t)(l + 1) * 16384;
        #pragma unroll
        for (int nt = 0; nt < 8; nt++)
            #pragma unroll
            for (int ks = 0; ks < 4; ks++) {
                bf8v b = *(const bf8v*)(c1b + ((nt * 4 + ks) * 64 + lane) * 8);
                acc3[nt] = MFMA(a3[ks], b, acc3[nt]);
            }
        #pragma unroll
        for (int nt = 0; nt < 8; nt++) {
            int n = nt * 16 + lc;
            #pragma unroll
            for (int r = 0; r < 4; r++) {
                int row = m0 + wave * 16 + quad * 4 + r;
                if (row < NATOMS) ybf[(size_t)row * HC + n] = f2b(acc3[nt][r]);
            }
        }
    }
}

__global__ void out_k(const float* __restrict__ x, void* out, const int* flagp) {
    int i = blockIdx.x * 256 + threadIdx.x;
    if (i >= NATOMS * HC) return;
    if (flagp[1]) ((float*)out)[i] = x[i];
    else          ((bf16*)out)[i] = f2b(x[i]);
}

// ---------------- launch ----------------
extern "C" void kernel_launch(void* const* d_in, const int* in_sizes, int n_in,
                              void* d_out, int out_size, void* d_ws, size_t ws_size,
                              hipStream_t stream) {
    const int*  z      = (const int*) d_in[0];
    const void* pos    = d_in[1];
    const int*  ei     = (const int*) d_in[3];
    const void* emb    = d_in[4];
    const void* nbremb = d_in[5];
    const void* Wp     = d_in[6];
    const void* bp     = d_in[7];
    const void* Wc     = d_in[8];
    const void* bc     = d_in[9];
    const void* means  = d_in[10];
    const void* betas  = d_in[11];
    const void* W1     = d_in[12];
    const void* b1     = d_in[13];
    const void* W2     = d_in[14];
    const void* b2     = d_in[15];
    const void* cW1    = d_in[16];
    const void* cW2    = d_in[17];
    const void* cb2    = d_in[18];
    const void* lW     = d_in[19];
    const void* lb     = d_in[20];

    char* p = (char*)d_ws;
    auto alloc = [&](size_t bytes) { char* r = p; p += (bytes + 255) / 256 * 256; return r; };
    int*   flag    = (int*)  alloc(256);
    int*   counts  = (int*)  alloc((size_t)NATOMS * 4);
    int*   rowptr  = (int*)  alloc((size_t)(NATOMS + 1) * 4);
    int*   cursor  = (int*)  alloc((size_t)NATOMS * 4);
    int*   perm    = (int*)  alloc((size_t)NEDGES * 4);
    int*   src_s   = (int*)  alloc((size_t)NEDGES * 4);
    int*   dst_s   = (int*)  alloc((size_t)NEDGES * 4);
    float* C_s     = (float*)alloc((size_t)NEDGES * 4);
    float* Cm_s    = (float*)alloc((size_t)NEDGES * 4);
    float* ed_s    = (float*)alloc((size_t)NEDGES * 4);
    float* x       = (float*)alloc((size_t)NATOMS * HC * 4);
    bf16*  xb      = (bf16*) alloc((size_t)NATOMS * HC * 2);
    bf16*  ybf     = (bf16*) alloc((size_t)NATOMS * HC * 2);
    float* msum    = (float*)alloc((size_t)NATOMS * HC * 4);
    float* msg     = (float*)alloc((size_t)NATOMS * HC * 4);
    bf16*  acomb   = (bf16*) alloc((size_t)NATOMS * 256 * 2);
    bf16*  wpp     = (bf16*) alloc((size_t)8192 * 2);
    bf16*  wcp     = (bf16*) alloc((size_t)32768 * 2);
    bf16*  w1p     = (bf16*) alloc((size_t)NLAY * 8192 * 2);
    bf16*  w2p     = (bf16*) alloc((size_t)NLAY * 16384 * 2);
    bf16*  cw1p    = (bf16*) alloc((size_t)NLAY * 16384 * 2);
    bf16*  cw2p    = (bf16*) alloc((size_t)NLAY * 16384 * 2);
    bf16*  lwp     = (bf16*) alloc((size_t)NLAY * 16384 * 2);
    bf16*  nbrembbf= (bf16*) alloc((size_t)MAXZ_ * HC * 2);
    float* bpcv    = (float*)alloc((size_t)HC * 4);
    float* bccv    = (float*)alloc((size_t)HC * 4);
    float* b1cv    = (float*)alloc((size_t)NLAY * HC * 4);
    float* b2cv    = (float*)alloc((size_t)NLAY * HC * 4);
    float* cb2cv   = (float*)alloc((size_t)NLAY * HC * 4);
    float* lbcv    = (float*)alloc((size_t)NLAY * HC * 4);
    float* meanscv = (float*)alloc((size_t)RBF * 4);
    float* betascv = (float*)alloc((size_t)RBF * 4);

    const int EG = (NEDGES + 255) / 256;
    const int NG = (NATOMS + 255) / 256;

    zero_k<<<1, 64, 0, stream>>>(flag, 2);
    zero_k<<<NG, 256, 0, stream>>>(counts, NATOMS);
    probe_k<<<(NATOMS * 3 + 255) / 256, 256, 0, stream>>>(pos, NATOMS * 3, flag);
    setflag_k<<<1, 64, 0, stream>>>(flag);

    hist_k<<<EG, 256, 0, stream>>>(ei + NEDGES, counts);
    scan_k<<<1, 1024, 0, stream>>>(counts, rowptr);
    copy_k<<<NG, 256, 0, stream>>>(rowptr, cursor, NATOMS);
    perm_k<<<EG, 256, 0, stream>>>(ei + NEDGES, cursor, perm);
    geom_k<<<EG, 256, 0, stream>>>(ei, pos, perm, flag, C_s, Cm_s, ed_s, src_s, dst_s);

    packB_k<<<4,  256, 0, stream>>>(Wp,  RBF, 2, 6400, 8192, 1, flag, wpp);
    packB_k<<<16, 256, 0, stream>>>(Wc,  256, 8, 32768, 32768, 1, flag, wcp);
    packB_k<<<24, 256, 0, stream>>>(W1,  RBF, 2, 6400, 8192, NLAY, flag, w1p);
    packB24_k<<<192, 256, 0, stream>>>(W2, cW1, cW2, lW, flag, w2p, cw1p, cw2p, lwp);
    cvts_k<<<14, 256, 0, stream>>>(means, betas, bp, bc, b1, b2, cb2, lb, flag,
                                   meanscv, betascv, bpcv, bccv, b1cv, b2cv, cb2cv, lbcv);
    cvtb_k<<<(MAXZ_ * HC + 255) / 256, 256, 0, stream>>>(nbremb, MAXZ_ * HC, flag, nbrembbf);

    hipMemsetAsync(msg, 0, (size_t)NATOMS * HC * 4, stream);
    nbr_mfma_k<<<EGRID, 256, 0, stream>>>(ed_s, C_s, Cm_s, src_s, dst_s, z, nbrembbf,
                                          wpp, bpcv, meanscv, betascv, msg);
    prep_k<<<NATOMS, 256, 0, stream>>>(z, emb, msg, flag, acomb);
    combine_mfma_k<<<YGRID, 256, 0, stream>>>(acomb, wcp, bccv, cw1p, x, xb, ybf);

    for (int l = 0; l < NLAY; l++) {
        hipMemsetAsync(msum, 0, (size_t)NATOMS * HC * 4, stream);
        filt_mfma_k<<<EGRID, 256, 0, stream>>>(l, ed_s, C_s, src_s, dst_s, ybf,
                                               w1p, w2p, b1cv, b2cv,
                                               meanscv, betascv, msum);
        upd_mfma_k<<<YGRID, 256, 0, stream>>>(msum, l, cw2p, cb2cv, lwp, lbcv,
                                              cw1p, (l < NLAY - 1) ? 1 : 0, x, xb, ybf);
    }
    out_k<<<(NATOMS * HC + 255) / 256, 256, 0, stream>>>(x, d_out, flag);
}

// Round 8
// 718.539 us; speedup vs baseline: 12.5352x; 1.0038x over previous
//
#include <hip/hip_runtime.h>
#include <hip/hip_bf16.h>

// TorchMD_GN_Ext R8: filter-MLP TABULATION.
// Wf(edge) is a function of the scalar d only => precompute Tf[l][2048][128]
// (exact MLP at 2048 ed-knots via one MFMA kernel), then edge kernels do a
// 2-row lerp instead of the MLP (removes 48 MFMAs + 2 silu epilogues + all
// attr exps per block). Seg-sum stays MFMA indicator-matmul (R7).
// Lane map (row=tid&63, c0=(tid>>6)*32) => conflict-free mvT stores.

#define NATOMS 10000
#define NEDGES 320000
#define HC 128
#define RBF 50
#define NLAY 6
#define MAXZ_ 100
#define NK 2048
#define EGRID (NEDGES / 64)         // 5000
#define YGRID ((NATOMS + 63) / 64)  // 157

typedef __hip_bfloat16 bf16;
typedef __attribute__((ext_vector_type(8))) short bf8v;
typedef __attribute__((ext_vector_type(4))) float f4v;

__device__ __forceinline__ float b2f(bf16 v) { return __bfloat162float(v); }
__device__ __forceinline__ bf16  f2b(float v) { return __float2bfloat16(v); }
__device__ __forceinline__ short f2s(float v) { bf16 h = f2b(v); return *(short*)&h; }
__device__ __forceinline__ float silu(float v) {
    return v * __builtin_amdgcn_rcpf(1.0f + __expf(-v));
}

template<int ISF>
__device__ __forceinline__ float LD(const void* p, size_t i) {
    if (ISF) return ((const float*)p)[i];
    return b2f(((const bf16*)p)[i]);
}

// ---------------- dtype probe ----------------
__global__ void probe_k(const void* pos, int nelem, int* flag) {
    int i = blockIdx.x * 256 + threadIdx.x;
    float v = 0.0f;
    if (i < nelem) {
        v = fabsf(b2f(((const bf16*)pos)[i]));
        if (v != v) v = 1e30f;
    }
    atomicMax(flag, __float_as_int(v));
}
__global__ void setflag_k(int* flag) {
    if (threadIdx.x == 0) flag[1] = (__int_as_float(flag[0]) > 1.0e4f) ? 1 : 0;
}

// ---------------- CSR build ----------------
__global__ void zero_k(int* p, int n) {
    int i = blockIdx.x * 256 + threadIdx.x;
    if (i < n) p[i] = 0;
}
__device__ __forceinline__ int clampN(int v) {
    return v < 0 ? 0 : (v >= NATOMS ? NATOMS - 1 : v);
}
__global__ void hist_k(const int* __restrict__ dst, int* __restrict__ counts) {
    int e = blockIdx.x * 256 + threadIdx.x;
    if (e < NEDGES) atomicAdd(&counts[clampN(dst[e])], 1);
}
__global__ void scan_k(const int* __restrict__ counts, int* __restrict__ rowptr) {
    __shared__ int wsum[16];
    __shared__ int carry_s;
    __shared__ int chunktot;
    int tid = threadIdx.x, lane = tid & 63, w = tid >> 6;
    if (tid == 0) { carry_s = 0; rowptr[0] = 0; }
    __syncthreads();
    for (int base = 0; base < NATOMS; base += 1024) {
        int i = base + tid;
        int s = (i < NATOMS) ? counts[i] : 0;
        #pragma unroll
        for (int off = 1; off < 64; off <<= 1) {
            int t = __shfl_up(s, off, 64);
            if (lane >= off) s += t;
        }
        if (lane == 63) wsum[w] = s;
        __syncthreads();
        if (w == 0 && lane < 16) {
            int t = wsum[lane];
            int si = t;
            #pragma unroll
            for (int off = 1; off < 16; off <<= 1) {
                int u = __shfl_up(si, off, 64);
                if (lane >= off) si += u;
            }
            wsum[lane] = si - t;
            if (lane == 15) chunktot = si;
        }
        __syncthreads();
        int carry = carry_s;
        if (i < NATOMS) rowptr[i + 1] = carry + wsum[w] + s;
        __syncthreads();
        if (tid == 0) carry_s += chunktot;
        __syncthreads();
    }
}
__global__ void copy_k(const int* __restrict__ a, int* __restrict__ b, int n) {
    int i = blockIdx.x * 256 + threadIdx.x;
    if (i < n) b[i] = a[i];
}
__global__ void perm_k(const int* __restrict__ dst, int* __restrict__ cursor,
                       int* __restrict__ perm) {
    int e = blockIdx.x * 256 + threadIdx.x;
    if (e < NEDGES) {
        int p = atomicAdd(&cursor[clampN(dst[e])], 1);
        perm[p] = e;
    }
}

// ---------------- geometry ----------------
template<int ISF>
__device__ void geom_body(const int* __restrict__ ei, const void* __restrict__ pos,
                          const int* __restrict__ perm,
                          float* __restrict__ ed_s, int* __restrict__ src_s,
                          int* __restrict__ dst_s) {
    int i = blockIdx.x * 256 + threadIdx.x;
    if (i >= NEDGES) return;
    int e = perm[i];
    int s = clampN(ei[e]);
    int t = clampN(ei[NEDGES + e]);
    float dx = LD<ISF>(pos, (size_t)s * 3 + 0) - LD<ISF>(pos, (size_t)t * 3 + 0);
    float dy = LD<ISF>(pos, (size_t)s * 3 + 1) - LD<ISF>(pos, (size_t)t * 3 + 1);
    float dz = LD<ISF>(pos, (size_t)s * 3 + 2) - LD<ISF>(pos, (size_t)t * 3 + 2);
    float d = sqrtf(dx * dx + dy * dy + dz * dz + 1e-12f);
    if (d != d) d = 1e30f;
    ed_s[i] = __expf(-d);
    src_s[i] = s;
    dst_s[i] = t;
}
__global__ void geom_k(const int* ei, const void* pos, const int* perm, const int* flagp,
                       float* ed_s, int* src_s, int* dst_s) {
    if (flagp[1]) geom_body<1>(ei, pos, perm, ed_s, src_s, dst_s);
    else          geom_body<0>(ei, pos, perm, ed_s, src_s, dst_s);
}

// ---------------- weight pack / convert ----------------
template<int ISF>
__device__ void packB_body(const void* src, int K, int ksteps, size_t perLsrc,
                           size_t perLdst, int L, bf16* dst) {
    int t = blockIdx.x * 256 + threadIdx.x;
    int total = L * 8 * ksteps * 64;
    if (t >= total) return;
    int lane = t & 63;
    int t2 = t >> 6;
    int ks = t2 % ksteps;
    int t3 = t2 / ksteps;
    int nt = t3 & 7;
    int l  = t3 >> 3;
    int quad = lane >> 4, lc = lane & 15;
    int col = nt * 16 + lc;
    for (int j = 0; j < 8; j++) {
        int k = ks * 32 + quad * 8 + j;
        float v = (k < K) ? LD<ISF>(src, (size_t)l * perLsrc + (size_t)k * 128 + col) : 0.0f;
        dst[(size_t)l * perLdst + ((size_t)((nt * ksteps + ks) * 64 + lane)) * 8 + j] = f2b(v);
    }
}
__global__ void packB_k(const void* src, int K, int ksteps, size_t perLsrc,
                        size_t perLdst, int L, const int* flagp, bf16* dst) {
    if (flagp[1]) packB_body<1>(src, K, ksteps, perLsrc, perLdst, L, dst);
    else          packB_body<0>(src, K, ksteps, perLsrc, perLdst, L, dst);
}
template<int ISF>
__device__ void packB24_body(const void* w2, const void* cw1, const void* cw2,
                             const void* lw, bf16* w2p, bf16* cw1p, bf16* cw2p,
                             bf16* lwp) {
    int t = blockIdx.x * 256 + threadIdx.x;
    if (t >= 24 * 8 * 4 * 64) return;
    int lane = t & 63;
    int t2 = t >> 6;
    int ks = t2 & 3;
    int t3 = t2 >> 2;
    int nt = t3 & 7;
    int m  = t3 >> 3;
    int which = m / NLAY, li = m % NLAY;
    const void* src = which == 0 ? w2 : which == 1 ? cw1 : which == 2 ? cw2 : lw;
    bf16* dst = which == 0 ? w2p : which == 1 ? cw1p : which == 2 ? cw2p : lwp;
    int quad = lane >> 4, lc = lane & 15;
    int col = nt * 16 + lc;
    #pragma unroll
    for (int j = 0; j < 8; j++) {
        int k = ks * 32 + quad * 8 + j;
        float v = LD<ISF>(src, (size_t)li * 16384 + (size_t)k * 128 + col);
        dst[(size_t)li * 16384 + ((size_t)((nt * 4 + ks) * 64 + lane)) * 8 + j] = f2b(v);
    }
}
__global__ void packB24_k(const void* w2, const void* cw1, const void* cw2,
                          const void* lw, const int* flagp,
                          bf16* w2p, bf16* cw1p, bf16* cw2p, bf16* lwp) {
    if (flagp[1]) packB24_body<1>(w2, cw1, cw2, lw, w2p, cw1p, cw2p, lwp);
    else          packB24_body<0>(w2, cw1, cw2, lw, w2p, cw1p, cw2p, lwp);
}
template<int ISF>
__device__ void cvts_body(const void* means, const void* betas, const void* bp,
                          const void* bc, const void* b1, const void* b2,
                          const void* cb2, const void* lb,
                          float* meanscv, float* betascv, float* bpcv, float* bccv,
                          float* b1cv, float* b2cv, float* cb2cv, float* lbcv) {
    int i = blockIdx.x * 256 + threadIdx.x;
    if      (i < 50)   meanscv[i]        = LD<ISF>(means, i);
    else if (i < 100)  betascv[i - 50]   = LD<ISF>(betas, i - 50);
    else if (i < 228)  bpcv[i - 100]     = LD<ISF>(bp, i - 100);
    else if (i < 356)  bccv[i - 228]     = LD<ISF>(bc, i - 228);
    else if (i < 1124) b1cv[i - 356]     = LD<ISF>(b1, i - 356);
    else if (i < 1892) b2cv[i - 1124]    = LD<ISF>(b2, i - 1124);
    else if (i < 2660) cb2cv[i - 1892]   = LD<ISF>(cb2, i - 1892);
    else if (i < 3428) lbcv[i - 2660]    = LD<ISF>(lb, i - 2660);
}
__global__ void cvts_k(const void* means, const void* betas, const void* bp,
                       const void* bc, const void* b1, const void* b2,
                       const void* cb2, const void* lb, const int* flagp,
                       float* meanscv, float* betascv, float* bpcv, float* bccv,
                       float* b1cv, float* b2cv, float* cb2cv, float* lbcv) {
    if (flagp[1]) cvts_body<1>(means, betas, bp, bc, b1, b2, cb2, lb,
                               meanscv, betascv, bpcv, bccv, b1cv, b2cv, cb2cv, lbcv);
    else          cvts_body<0>(means, betas, bp, bc, b1, b2, cb2, lb,
                               meanscv, betascv, bpcv, bccv, b1cv, b2cv, cb2cv, lbcv);
}
template<int ISF>
__device__ void cvtb_body(const void* src, int n, bf16* dst) {
    int i = blockIdx.x * 256 + threadIdx.x;
    if (i < n) dst[i] = f2b(LD<ISF>(src, i));
}
__global__ void cvtb_k(const void* src, int n, const int* flagp, bf16* dst) {
    if (flagp[1]) cvtb_body<1>(src, n, dst);
    else          cvtb_body<0>(src, n, dst);
}

// ---------------- MFMA helpers ----------------
#define MFMA(a, b, c) __builtin_amdgcn_mfma_f32_16x16x32_bf16((a), (b), (c), 0, 0, 0)

__device__ __forceinline__ void seg_prep(const int* __restrict__ dst_s, int i0, int tid,
                                         int* ddst, int* slot_s, int* distinct_s,
                                         int* nseg_s) {
    if (tid < 64) {
        int d = dst_s[i0 + tid];
        ddst[tid] = d;
        int dprev = __shfl_up(d, 1, 64);
        int flag = (tid == 0 || d != dprev) ? 1 : 0;
        int s = flag;
        #pragma unroll
        for (int off = 1; off < 64; off <<= 1) {
            int t = __shfl_up(s, off, 64);
            if (tid >= off) s += t;
        }
        slot_s[tid] = s - 1;
        if (flag) distinct_s[s - 1] = d;
        if (tid == 63) *nseg_s = s;
    }
}

__device__ __forceinline__ void seg_mfma(const bf16 (*mvT)[72], const int* ddst,
                                         const int* slot_s, const int* distinct_s,
                                         int nseg, float* __restrict__ out, int tid) {
    int wave = tid >> 6, lane = tid & 63, quad = lane >> 4, lc = lane & 15;
    if (nseg <= 16) {
        bf8v sa[2];
        #pragma unroll
        for (int ks = 0; ks < 2; ks++)
            #pragma unroll
            for (int j = 0; j < 8; j++) {
                int k = ks * 32 + quad * 8 + j;
                sa[ks][j] = (slot_s[k] == lc) ? (short)0x3F80 : (short)0;
            }
        f4v z4 = {0.f, 0.f, 0.f, 0.f};
        f4v sacc[2] = {z4, z4};
        #pragma unroll
        for (int nt = 0; nt < 2; nt++)
            #pragma unroll
            for (int ks = 0; ks < 2; ks++) {
                bf8v b = *(const bf8v*)&mvT[wave * 32 + nt * 16 + lc][ks * 32 + quad * 8];
                sacc[nt] = MFMA(sa[ks], b, sacc[nt]);
            }
        #pragma unroll
        for (int nt = 0; nt < 2; nt++)
            #pragma unroll
            for (int r = 0; r < 4; r++) {
                int sl = quad * 4 + r;
                if (sl < nseg) {
                    int atom = distinct_s[sl];
                    int n = wave * 32 + nt * 16 + lc;
                    float v = sacc[nt][r];
                    if (sl == 0 || sl == nseg - 1)
                        atomicAdd(&out[(size_t)atom * HC + n], v);
                    else
                        out[(size_t)atom * HC + n] = v;
                }
            }
    } else {
        int col = tid & 127;
        int base = (tid >> 7) * 32;
        int cur = ddst[base];
        float s = 0.0f;
        bool first = true;
        for (int e = base; e < base + 32; e++) {
            int dn = ddst[e];
            if (dn != cur) {
                if (first) atomicAdd(&out[(size_t)cur * HC + col], s);
                else out[(size_t)cur * HC + col] = s;
                first = false; cur = dn; s = 0.0f;
            }
            s += b2f(mvT[col][e]);
        }
        atomicAdd(&out[(size_t)cur * HC + col], s);
    }
}

// ---------------- table build: exact MLP at NK ed-knots ----------------
// blockIdx: f = bx>>5 (0=nbr filter, 1..6 = layer), kb = bx&31 -> 64 knots.
__global__ __launch_bounds__(256)
void tabbuild_k(const bf16* __restrict__ wpp, const float* __restrict__ bpcv,
                const bf16* __restrict__ w1p, const float* __restrict__ b1cv,
                const bf16* __restrict__ w2p, const float* __restrict__ b2cv,
                const float* __restrict__ meanscv, const float* __restrict__ betascv,
                float* __restrict__ Tn, float* __restrict__ Tf) {
    __shared__ bf16 hid[64][136];
    __shared__ float csh[64], edsh[64];
    int f = blockIdx.x >> 5, kb = blockIdx.x & 31;
    int base = kb * 64;
    int tid = threadIdx.x;
    int wave = tid >> 6, lane = tid & 63, quad = lane >> 4, lc = lane & 15;
    if (tid < 64) {
        float ed = (float)(base + tid) * (1.0f / (NK - 1));
        float d = -logf(fmaxf(ed, 1e-30f));
        float C = (d < 5.0f) ? 0.5f * (__cosf(d * 0.6283185307f) + 1.0f) : 0.0f;
        csh[tid] = C; edsh[tid] = ed;
    }
    __syncthreads();
    // A-frags: attr at knot row
    float edi = edsh[wave * 16 + lc], Ci = csh[wave * 16 + lc];
    bf8v af[2];
    #pragma unroll
    for (int ks = 0; ks < 2; ks++) {
        #pragma unroll
        for (int j = 0; j < 8; j++) {
            int r = ks * 32 + quad * 8 + j;
            float v = 0.0f;
            if (r < RBF) { float u = edi - meanscv[r]; v = Ci * __expf(-betascv[r] * u * u); }
            af[ks][j] = f2s(v);
        }
    }
    f4v zero = {0.f, 0.f, 0.f, 0.f};
    f4v acc[8];
    #pragma unroll
    for (int nt = 0; nt < 8; nt++) acc[nt] = zero;
    const bf16* w1b = (f == 0) ? wpp : w1p + (size_t)(f - 1) * 8192;
    #pragma unroll
    for (int nt = 0; nt < 8; nt++)
        #pragma unroll
        for (int ks = 0; ks < 2; ks++) {
            bf8v b = *(const bf8v*)(w1b + ((nt * 2 + ks) * 64 + lane) * 8);
            acc[nt] = MFMA(af[ks], b, acc[nt]);
        }
    if (f == 0) {
        #pragma unroll
        for (int nt = 0; nt < 8; nt++) {
            int n = nt * 16 + lc;
            float bb = bpcv[n];
            #pragma unroll
            for (int r = 0; r < 4; r++) {
                int row = wave * 16 + quad * 4 + r;
                Tn[(size_t)(base + row) * HC + n] = (acc[nt][r] + bb) * csh[row];
            }
        }
        return;
    }
    int l = f - 1;
    #pragma unroll
    for (int nt = 0; nt < 8; nt++) {
        int n = nt * 16 + lc;
        float bb = b1cv[l * HC + n];
        #pragma unroll
        for (int r = 0; r < 4; r++)
            hid[wave * 16 + quad * 4 + r][n] = f2b(silu(acc[nt][r] + bb));
    }
    __syncthreads();
    bf8v a2[4];
    #pragma unroll
    for (int ks = 0; ks < 4; ks++)
        a2[ks] = *(const bf8v*)&hid[wave * 16 + lc][ks * 32 + quad * 8];
    f4v acc2[8];
    #pragma unroll
    for (int nt = 0; nt < 8; nt++) acc2[nt] = zero;
    const bf16* w2b = w2p + (size_t)l * 16384;
    #pragma unroll
    for (int nt = 0; nt < 8; nt++)
        #pragma unroll
        for (int ks = 0; ks < 4; ks++) {
            bf8v b = *(const bf8v*)(w2b + ((nt * 4 + ks) * 64 + lane) * 8);
            acc2[nt] = MFMA(a2[ks], b, acc2[nt]);
        }
    #pragma unroll
    for (int nt = 0; nt < 8; nt++) {
        int n = nt * 16 + lc;
        float bb = b2cv[l * HC + n];
        #pragma unroll
        for (int r = 0; r < 4; r++) {
            int row = wave * 16 + quad * 4 + r;
            Tf[((size_t)l * NK + base + row) * HC + n] = (acc2[nt][r] + bb) * csh[row];
        }
    }
}

// ---------------- neighbor-embedding edges: lerp(Tn)·mask·emb + seg-sum ----
__global__ __launch_bounds__(256)
void nbr_tab_k(const float* __restrict__ ed_s, const int* __restrict__ src_s,
               const int* __restrict__ dst_s, const int* __restrict__ z,
               const bf16* __restrict__ nbrembbf, const float* __restrict__ Tn,
               float* __restrict__ msg) {
    __shared__ bf16 mvT[128][72];
    __shared__ int ddst[64], slot_s[64], distinct_s[64];
    __shared__ int nseg_s;
    int i0 = blockIdx.x * 64;
    int tid = threadIdx.x;
    seg_prep(dst_s, i0, tid, ddst, slot_s, distinct_s, &nseg_s);
    int row = tid & 63, c0 = (tid >> 6) * 32;
    int e = i0 + row;
    int s = src_s[e];
    float msk = (s != dst_s[e]) ? 1.0f : 0.0f;
    float pos = fminf(fmaxf(ed_s[e] * (float)(NK - 1), 0.0f), (float)(NK - 1));
    int k = (int)pos; if (k > NK - 2) k = NK - 2;
    float frac = pos - (float)k;
    const float* t0 = Tn + (size_t)k * HC + c0;
    int zz = z[s]; zz = zz < 0 ? 0 : (zz >= MAXZ_ ? MAXZ_ - 1 : zz);
    const bf16* ep = nbrembbf + (size_t)zz * HC + c0;
    #pragma unroll
    for (int j = 0; j < 32; j++) {
        float v = t0[j] + frac * (t0[HC + j] - t0[j]);
        mvT[c0 + j][row] = f2b(v * msk * b2f(ep[j]));
    }
    __syncthreads();
    seg_mfma(mvT, ddst, slot_s, distinct_s, nseg_s, msg, tid);
}

// ---------------- acomb prep ----------------
template<int ISF>
__device__ void prep_body(const int* __restrict__ z, const void* __restrict__ emb,
                          const float* __restrict__ msg, bf16* __restrict__ acomb) {
    int n = blockIdx.x, j = threadIdx.x;
    int zz = z[n]; zz = zz < 0 ? 0 : (zz >= MAXZ_ ? MAXZ_ - 1 : zz);
    float v = (j < HC) ? LD<ISF>(emb, (size_t)zz * HC + j)
                       : msg[(size_t)n * HC + (j - HC)];
    acomb[(size_t)n * 256 + j] = f2b(v);
}
__global__ void prep_k(const int* z, const void* emb, const float* msg,
                       const int* flagp, bf16* acomb) {
    if (flagp[1]) prep_body<1>(z, emb, msg, acomb);
    else          prep_body<0>(z, emb, msg, acomb);
}

// ---------------- combine: x = acomb @ Wc + bc; y0 = x @ cW1[0] ------------
__global__ __launch_bounds__(256)
void combine_mfma_k(const bf16* __restrict__ acomb, const bf16* __restrict__ wcp,
                    const float* __restrict__ bccv, const bf16* __restrict__ cw1b,
                    float* __restrict__ x, bf16* __restrict__ xb,
                    bf16* __restrict__ ybf) {
    __shared__ bf16 srow[64][136];
    int tid = threadIdx.x;
    int wave = tid >> 6, lane = tid & 63, quad = lane >> 4, lc = lane & 15;
    int m0 = blockIdx.x * 64;
    bf8v azero = {0, 0, 0, 0, 0, 0, 0, 0};
    bf8v af[8];
    int arow = m0 + wave * 16 + lc;
    #pragma unroll
    for (int ks = 0; ks < 8; ks++) {
        if (arow < NATOMS)
            af[ks] = *(const bf8v*)(acomb + (size_t)arow * 256 + ks * 32 + quad * 8);
        else af[ks] = azero;
    }
    f4v zero = {0.f, 0.f, 0.f, 0.f};
    f4v acc[8];
    #pragma unroll
    for (int nt = 0; nt < 8; nt++) acc[nt] = zero;
    #pragma unroll
    for (int nt = 0; nt < 8; nt++)
        #pragma unroll
        for (int ks = 0; ks < 8; ks++) {
            bf8v b = *(const bf8v*)(wcp + ((nt * 8 + ks) * 64 + lane) * 8);
            acc[nt] = MFMA(af[ks], b, acc[nt]);
        }
    #pragma unroll
    for (int nt = 0; nt < 8; nt++) {
        int n = nt * 16 + lc;
        float bb = bccv[n];
        #pragma unroll
        for (int r = 0; r < 4; r++) {
            int row = m0 + wave * 16 + quad * 4 + r;
            float v = acc[nt][r] + bb;
            bf16 vb = f2b(v);
            srow[wave * 16 + quad * 4 + r][n] = vb;
            if (row < NATOMS) {
                x[(size_t)row * HC + n] = v;
                xb[(size_t)row * HC + n] = vb;
            }
        }
    }
    __syncthreads();
    bf8v a3[4];
    #pragma unroll
    for (int ks = 0; ks < 4; ks++)
        a3[ks] = *(const bf8v*)&srow[wave * 16 + lc][ks * 32 + quad * 8];
    f4v acc3[8];
    #pragma unroll
    for (int nt = 0; nt < 8; nt++) acc3[nt] = zero;
    #pragma unroll
    for (int nt = 0; nt < 8; nt++)
        #pragma unroll
        for (int ks = 0; ks < 4; ks++) {
            bf8v b = *(const bf8v*)(cw1b + ((nt * 4 + ks) * 64 + lane) * 8);
            acc3[nt] = MFMA(a3[ks], b, acc3[nt]);
        }
    #pragma unroll
    for (int nt = 0; nt < 8; nt++) {
        int n = nt * 16 + lc;
        #pragma unroll
        for (int r = 0; r < 4; r++) {
            int row = m0 + wave * 16 + quad * 4 + r;
            if (row < NATOMS) ybf[(size_t)row * HC + n] = f2b(acc3[nt][r]);
        }
    }
}

// ---------------- filter edges: lerp(Tf[l])·y[src] + MFMA seg-sum ----------
__global__ __launch_bounds__(256)
void filt_tab_k(int l, const float* __restrict__ ed_s, const int* __restrict__ src_s,
                const int* __restrict__ dst_s, const bf16* __restrict__ ybf,
                const float* __restrict__ Tf, float* __restrict__ msum) {
    __shared__ bf16 mvT[128][72];
    __shared__ int ddst[64], slot_s[64], distinct_s[64];
    __shared__ int nseg_s;
    int i0 = blockIdx.x * 64;
    int tid = threadIdx.x;
    seg_prep(dst_s, i0, tid, ddst, slot_s, distinct_s, &nseg_s);
    int row = tid & 63, c0 = (tid >> 6) * 32;
    int e = i0 + row;
    float pos = fminf(fmaxf(ed_s[e] * (float)(NK - 1), 0.0f), (float)(NK - 1));
    int k = (int)pos; if (k > NK - 2) k = NK - 2;
    float frac = pos - (float)k;
    const float* t0 = Tf + ((size_t)l * NK + k) * HC + c0;
    const bf16* yp = ybf + (size_t)src_s[e] * HC + c0;
    #pragma unroll
    for (int j = 0; j < 32; j++) {
        float v = t0[j] + frac * (t0[HC + j] - t0[j]);
        mvT[c0 + j][row] = f2b(v * b2f(yp[j]));
    }
    __syncthreads();
    seg_mfma(mvT, ddst, slot_s, distinct_s, nseg_s, msum, tid);
}

// ---- node update: msum@cW2+cb2 -> silu -> @lW+lb -> x+=; y = xnew@cW1[l+1] -
__global__ __launch_bounds__(256)
void upd_mfma_k(const float* __restrict__ msum, int l,
                const bf16* __restrict__ cw2p, const float* __restrict__ cb2cv,
                const bf16* __restrict__ lwp, const float* __restrict__ lbcv,
                const bf16* __restrict__ cw1p, int do_y,
                float* __restrict__ x, bf16* __restrict__ xb,
                bf16* __restrict__ ybf) {
    __shared__ bf16 srow[64][136];
    int tid = threadIdx.x;
    int wave = tid >> 6, lane = tid & 63, quad = lane >> 4, lc = lane & 15;
    int m0 = blockIdx.x * 64;
    bf8v azero = {0, 0, 0, 0, 0, 0, 0, 0};
    bf8v af[4];
    int arow = m0 + wave * 16 + lc;
    #pragma unroll
    for (int ks = 0; ks < 4; ks++) {
        if (arow < NATOMS) {
            const float* p = msum + (size_t)arow * HC + ks * 32 + quad * 8;
            bf8v f;
            #pragma unroll
            for (int j = 0; j < 8; j++) f[j] = f2s(p[j]);
            af[ks] = f;
        } else af[ks] = azero;
    }
    f4v zero = {0.f, 0.f, 0.f, 0.f};
    f4v acc[8];
    #pragma unroll
    for (int nt = 0; nt < 8; nt++) acc[nt] = zero;
    const bf16* c2b = cw2p + (size_t)l * 16384;
    #pragma unroll
    for (int nt = 0; nt < 8; nt++)
        #pragma unroll
        for (int ks = 0; ks < 4; ks++) {
            bf8v b = *(const bf8v*)(c2b + ((nt * 4 + ks) * 64 + lane) * 8);
            acc[nt] = MFMA(af[ks], b, acc[nt]);
        }
    #pragma unroll
    for (int nt = 0; nt < 8; nt++) {
        int n = nt * 16 + lc;
        float bb = cb2cv[l * HC + n];
        #pragma unroll
        for (int r = 0; r < 4; r++)
            srow[wave * 16 + quad * 4 + r][n] = f2b(silu(acc[nt][r] + bb));
    }
    __syncthreads();
    bf8v a2[4];
    #pragma unroll
    for (int ks = 0; ks < 4; ks++)
        a2[ks] = *(const bf8v*)&srow[wave * 16 + lc][ks * 32 + quad * 8];
    __syncthreads();
    f4v acc2[8];
    #pragma unroll
    for (int nt = 0; nt < 8; nt++) acc2[nt] = zero;
    const bf16* lwb = lwp + (size_t)l * 16384;
    #pragma unroll
    for (int nt = 0; nt < 8; nt++)
        #pragma unroll
        for (int ks = 0; ks < 4; ks++) {
            bf8v b = *(const bf8v*)(lwb + ((nt * 4 + ks) * 64 + lane) * 8);
            acc2[nt] = MFMA(a2[ks], b, acc2[nt]);
        }
    #pragma unroll
    for (int nt = 0; nt < 8; nt++) {
        int n = nt * 16 + lc;
        float bb = lbcv[l * HC + n];
        #pragma unroll
        for (int r = 0; r < 4; r++) {
            int row = m0 + wave * 16 + quad * 4 + r;
            float nv = 0.0f;
            if (row < NATOMS) {
                size_t o = (size_t)row * HC + n;
                nv = x[o] + acc2[nt][r] + bb;
                x[o] = nv;
                xb[o] = f2b(nv);
            }
            srow[wave * 16 + quad * 4 + r][n] = f2b(nv);
        }
    }
    if (do_y) {
        __syncthreads();
        bf8v a3[4];
        #pragma unroll
        for (int ks = 0; ks < 4; ks++)
            a3[ks] = *(const bf8v*)&srow[wave * 16 + lc][ks * 32 + quad * 8];
        f4v acc3[8];
        #pragma unroll
        for (int nt = 0; nt < 8; nt++) acc3[nt] = zero;
        const bf16* c1b = cw1p + (size_t)(l + 1) * 16384;
        #pragma unroll
        for (int nt = 0; nt < 8; nt++)
            #pragma unroll
            for (int ks = 0; ks < 4; ks++) {
                bf8v b = *(const bf8v*)(c1b + ((nt * 4 + ks) * 64 + lane) * 8);
                acc3[nt] = MFMA(a3[ks], b, acc3[nt]);
            }
        #pragma unroll
        for (int nt = 0; nt < 8; nt++) {
            int n = nt * 16 + lc;
            #pragma unroll
            for (int r = 0; r < 4; r++) {
                int row = m0 + wave * 16 + quad * 4 + r;
                if (row < NATOMS) ybf[(size_t)row * HC + n] = f2b(acc3[nt][r]);
            }
        }
    }
}

__global__ void out_k(const float* __restrict__ x, void* out, const int* flagp) {
    int i = blockIdx.x * 256 + threadIdx.x;
    if (i >= NATOMS * HC) return;
    if (flagp[1]) ((float*)out)[i] = x[i];
    else          ((bf16*)out)[i] = f2b(x[i]);
}

// ---------------- launch ----------------
extern "C" void kernel_launch(void* const* d_in, const int* in_sizes, int n_in,
                              void* d_out, int out_size, void* d_ws, size_t ws_size,
                              hipStream_t stream) {
    const int*  z      = (const int*) d_in[0];
    const void* pos    = d_in[1];
    const int*  ei     = (const int*) d_in[3];
    const void* emb    = d_in[4];
    const void* nbremb = d_in[5];
    const void* Wp     = d_in[6];
    const void* bp     = d_in[7];
    const void* Wc     = d_in[8];
    const void* bc     = d_in[9];
    const void* means  = d_in[10];
    const void* betas  = d_in[11];
    const void* W1     = d_in[12];
    const void* b1     = d_in[13];
    const void* W2     = d_in[14];
    const void* b2     = d_in[15];
    const void* cW1    = d_in[16];
    const void* cW2    = d_in[17];
    const void* cb2    = d_in[18];
    const void* lW     = d_in[19];
    const void* lb     = d_in[20];

    char* p = (char*)d_ws;
    auto alloc = [&](size_t bytes) { char* r = p; p += (bytes + 255) / 256 * 256; return r; };
    int*   flag    = (int*)  alloc(256);
    int*   counts  = (int*)  alloc((size_t)NATOMS * 4);
    int*   rowptr  = (int*)  alloc((size_t)(NATOMS + 1) * 4);
    int*   cursor  = (int*)  alloc((size_t)NATOMS * 4);
    int*   perm    = (int*)  alloc((size_t)NEDGES * 4);
    int*   src_s   = (int*)  alloc((size_t)NEDGES * 4);
    int*   dst_s   = (int*)  alloc((size_t)NEDGES * 4);
    float* ed_s    = (float*)alloc((size_t)NEDGES * 4);
    float* x       = (float*)alloc((size_t)NATOMS * HC * 4);
    bf16*  xb      = (bf16*) alloc((size_t)NATOMS * HC * 2);
    bf16*  ybf     = (bf16*) alloc((size_t)NATOMS * HC * 2);
    float* msum    = (float*)alloc((size_t)NATOMS * HC * 4);
    float* msg     = (float*)alloc((size_t)NATOMS * HC * 4);
    bf16*  acomb   = (bf16*) alloc((size_t)NATOMS * 256 * 2);
    float* Tn      = (float*)alloc((size_t)NK * HC * 4);            // 1.05 MB
    float* Tf      = (float*)alloc((size_t)NLAY * NK * HC * 4);     // 6.3 MB
    bf16*  wpp     = (bf16*) alloc((size_t)8192 * 2);
    bf16*  wcp     = (bf16*) alloc((size_t)32768 * 2);
    bf16*  w1p     = (bf16*) alloc((size_t)NLAY * 8192 * 2);
    bf16*  w2p     = (bf16*) alloc((size_t)NLAY * 16384 * 2);
    bf16*  cw1p    = (bf16*) alloc((size_t)NLAY * 16384 * 2);
    bf16*  cw2p    = (bf16*) alloc((size_t)NLAY * 16384 * 2);
    bf16*  lwp     = (bf16*) alloc((size_t)NLAY * 16384 * 2);
    bf16*  nbrembbf= (bf16*) alloc((size_t)MAXZ_ * HC * 2);
    float* bpcv    = (float*)alloc((size_t)HC * 4);
    float* bccv    = (float*)alloc((size_t)HC * 4);
    float* b1cv    = (float*)alloc((size_t)NLAY * HC * 4);
    float* b2cv    = (float*)alloc((size_t)NLAY * HC * 4);
    float* cb2cv   = (float*)alloc((size_t)NLAY * HC * 4);
    float* lbcv    = (float*)alloc((size_t)NLAY * HC * 4);
    float* meanscv = (float*)alloc((size_t)RBF * 4);
    float* betascv = (float*)alloc((size_t)RBF * 4);

    const int EG = (NEDGES + 255) / 256;
    const int NG = (NATOMS + 255) / 256;

    zero_k<<<1, 64, 0, stream>>>(flag, 2);
    zero_k<<<NG, 256, 0, stream>>>(counts, NATOMS);
    probe_k<<<(NATOMS * 3 + 255) / 256, 256, 0, stream>>>(pos, NATOMS * 3, flag);
    setflag_k<<<1, 64, 0, stream>>>(flag);

    hist_k<<<EG, 256, 0, stream>>>(ei + NEDGES, counts);
    scan_k<<<1, 1024, 0, stream>>>(counts, rowptr);
    copy_k<<<NG, 256, 0, stream>>>(rowptr, cursor, NATOMS);
    perm_k<<<EG, 256, 0, stream>>>(ei + NEDGES, cursor, perm);
    geom_k<<<EG, 256, 0, stream>>>(ei, pos, perm, flag, ed_s, src_s, dst_s);

    packB_k<<<4,  256, 0, stream>>>(Wp,  RBF, 2, 6400, 8192, 1, flag, wpp);
    packB_k<<<16, 256, 0, stream>>>(Wc,  256, 8, 32768, 32768, 1, flag, wcp);
    packB_k<<<24, 256, 0, stream>>>(W1,  RBF, 2, 6400, 8192, NLAY, flag, w1p);
    packB24_k<<<192, 256, 0, stream>>>(W2, cW1, cW2, lW, flag, w2p, cw1p, cw2p, lwp);
    cvts_k<<<14, 256, 0, stream>>>(means, betas, bp, bc, b1, b2, cb2, lb, flag,
                                   meanscv, betascv, bpcv, bccv, b1cv, b2cv, cb2cv, lbcv);
    cvtb_k<<<(MAXZ_ * HC + 255) / 256, 256, 0, stream>>>(nbremb, MAXZ_ * HC, flag, nbrembbf);

    tabbuild_k<<<7 * (NK / 64), 256, 0, stream>>>(wpp, bpcv, w1p, b1cv, w2p, b2cv,
                                                  meanscv, betascv, Tn, Tf);

    hipMemsetAsync(msg, 0, (size_t)NATOMS * HC * 4, stream);
    nbr_tab_k<<<EGRID, 256, 0, stream>>>(ed_s, src_s, dst_s, z, nbrembbf, Tn, msg);
    prep_k<<<NATOMS, 256, 0, stream>>>(z, emb, msg, flag, acomb);
    combine_mfma_k<<<YGRID, 256, 0, stream>>>(acomb, wcp, bccv, cw1p, x, xb, ybf);

    for (int l = 0; l < NLAY; l++) {
        hipMemsetAsync(msum, 0, (size_t)NATOMS * HC * 4, stream);
        filt_tab_k<<<EGRID, 256, 0, stream>>>(l, ed_s, src_s, dst_s, ybf, Tf, msum);
        upd_mfma_k<<<YGRID, 256, 0, stream>>>(msum, l, cw2p, cb2cv, lwp, lbcv,
                                              cw1p, (l < NLAY - 1) ? 1 : 0, x, xb, ybf);
    }
    out_k<<<(NATOMS * HC + 255) / 256, 256, 0, stream>>>(x, d_out, flag);
}

// Round 9
// 616.115 us; speedup vs baseline: 14.6191x; 1.1662x over previous
//
#include <hip/hip_runtime.h>
#include <hip/hip_bf16.h>

// TorchMD_GN_Ext R9: TA-gather reduction.
// R8 showed filt_tab is address-request-bound (20 scattered 16B reqs/thread,
// all counters idle). R9: (a) interleaved bf16 knot-pair table - one u32 holds
// (T[k][c],T[k+1][c]) so one 128B row serves the whole lerp (16->8 table reqs);
// (b) explicit 16B vector loads for y/emb; (c) msum zeroing folded into upd
// (data-dependent zero, drops 6 memsets); (d) prep folded into combine,
// cursor into scan. 40 -> 32 dispatches.

#define NATOMS 10000
#define NEDGES 320000
#define HC 128
#define RBF 50
#define NLAY 6
#define MAXZ_ 100
#define NK 2048
#define EGRID (NEDGES / 64)         // 5000
#define YGRID ((NATOMS + 63) / 64)  // 157

typedef __hip_bfloat16 bf16;
typedef __attribute__((ext_vector_type(8))) short bf8v;
typedef __attribute__((ext_vector_type(4))) float f4v;
typedef __attribute__((ext_vector_type(4))) unsigned int u4v;

__device__ __forceinline__ float b2f(bf16 v) { return __bfloat162float(v); }
__device__ __forceinline__ bf16  f2b(float v) { return __float2bfloat16(v); }
__device__ __forceinline__ short f2s(float v) { bf16 h = f2b(v); return *(short*)&h; }
__device__ __forceinline__ float s2f(unsigned short s) {
    return __int_as_float(((int)s) << 16);
}
__device__ __forceinline__ float silu(float v) {
    return v * __builtin_amdgcn_rcpf(1.0f + __expf(-v));
}

template<int ISF>
__device__ __forceinline__ float LD(const void* p, size_t i) {
    if (ISF) return ((const float*)p)[i];
    return b2f(((const bf16*)p)[i]);
}

// ---------------- dtype probe ----------------
__global__ void probe_k(const void* pos, int nelem, int* flag) {
    int i = blockIdx.x * 256 + threadIdx.x;
    float v = 0.0f;
    if (i < nelem) {
        v = fabsf(b2f(((const bf16*)pos)[i]));
        if (v != v) v = 1e30f;
    }
    atomicMax(flag, __float_as_int(v));
}
__global__ void setflag_k(int* flag) {
    if (threadIdx.x == 0) flag[1] = (__int_as_float(flag[0]) > 1.0e4f) ? 1 : 0;
}

// ---------------- CSR build ----------------
__global__ void zero2_k(int* flag, int* counts) {
    int i = blockIdx.x * 256 + threadIdx.x;
    if (i < 2) flag[i] = 0;
    if (i < NATOMS) counts[i] = 0;
}
__device__ __forceinline__ int clampN(int v) {
    return v < 0 ? 0 : (v >= NATOMS ? NATOMS - 1 : v);
}
__global__ void hist_k(const int* __restrict__ dst, int* __restrict__ counts) {
    int e = blockIdx.x * 256 + threadIdx.x;
    if (e < NEDGES) atomicAdd(&counts[clampN(dst[e])], 1);
}
// scan also emits cursor[i] = exclusive prefix (for perm_k)
__global__ void scan_k(const int* __restrict__ counts, int* __restrict__ rowptr,
                       int* __restrict__ cursor) {
    __shared__ int wsum[16];
    __shared__ int carry_s;
    __shared__ int chunktot;
    int tid = threadIdx.x, lane = tid & 63, w = tid >> 6;
    if (tid == 0) { carry_s = 0; rowptr[0] = 0; }
    __syncthreads();
    for (int base = 0; base < NATOMS; base += 1024) {
        int i = base + tid;
        int v = (i < NATOMS) ? counts[i] : 0;
        int s = v;
        #pragma unroll
        for (int off = 1; off < 64; off <<= 1) {
            int t = __shfl_up(s, off, 64);
            if (lane >= off) s += t;
        }
        if (lane == 63) wsum[w] = s;
        __syncthreads();
        if (w == 0 && lane < 16) {
            int t = wsum[lane];
            int si = t;
            #pragma unroll
            for (int off = 1; off < 16; off <<= 1) {
                int u = __shfl_up(si, off, 64);
                if (lane >= off) si += u;
            }
            wsum[lane] = si - t;
            if (lane == 15) chunktot = si;
        }
        __syncthreads();
        int carry = carry_s;
        if (i < NATOMS) {
            int inc = carry + wsum[w] + s;
            rowptr[i + 1] = inc;
            cursor[i] = inc - v;
        }
        __syncthreads();
        if (tid == 0) carry_s += chunktot;
        __syncthreads();
    }
}
__global__ void perm_k(const int* __restrict__ dst, int* __restrict__ cursor,
                       int* __restrict__ perm) {
    int e = blockIdx.x * 256 + threadIdx.x;
    if (e < NEDGES) {
        int p = atomicAdd(&cursor[clampN(dst[e])], 1);
        perm[p] = e;
    }
}

// ---------------- geometry ----------------
template<int ISF>
__device__ void geom_body(const int* __restrict__ ei, const void* __restrict__ pos,
                          const int* __restrict__ perm,
                          float* __restrict__ ed_s, int* __restrict__ src_s,
                          int* __restrict__ dst_s) {
    int i = blockIdx.x * 256 + threadIdx.x;
    if (i >= NEDGES) return;
    int e = perm[i];
    int s = clampN(ei[e]);
    int t = clampN(ei[NEDGES + e]);
    float dx = LD<ISF>(pos, (size_t)s * 3 + 0) - LD<ISF>(pos, (size_t)t * 3 + 0);
    float dy = LD<ISF>(pos, (size_t)s * 3 + 1) - LD<ISF>(pos, (size_t)t * 3 + 1);
    float dz = LD<ISF>(pos, (size_t)s * 3 + 2) - LD<ISF>(pos, (size_t)t * 3 + 2);
    float d = sqrtf(dx * dx + dy * dy + dz * dz + 1e-12f);
    if (d != d) d = 1e30f;
    ed_s[i] = __expf(-d);
    src_s[i] = s;
    dst_s[i] = t;
}
__global__ void geom_k(const int* ei, const void* pos, const int* perm, const int* flagp,
                       float* ed_s, int* src_s, int* dst_s) {
    if (flagp[1]) geom_body<1>(ei, pos, perm, ed_s, src_s, dst_s);
    else          geom_body<0>(ei, pos, perm, ed_s, src_s, dst_s);
}

// ---------------- weight pack / convert ----------------
template<int ISF>
__device__ void packB_body(const void* src, int K, int ksteps, size_t perLsrc,
                           size_t perLdst, int L, bf16* dst) {
    int t = blockIdx.x * 256 + threadIdx.x;
    int total = L * 8 * ksteps * 64;
    if (t >= total) return;
    int lane = t & 63;
    int t2 = t >> 6;
    int ks = t2 % ksteps;
    int t3 = t2 / ksteps;
    int nt = t3 & 7;
    int l  = t3 >> 3;
    int quad = lane >> 4, lc = lane & 15;
    int col = nt * 16 + lc;
    for (int j = 0; j < 8; j++) {
        int k = ks * 32 + quad * 8 + j;
        float v = (k < K) ? LD<ISF>(src, (size_t)l * perLsrc + (size_t)k * 128 + col) : 0.0f;
        dst[(size_t)l * perLdst + ((size_t)((nt * ksteps + ks) * 64 + lane)) * 8 + j] = f2b(v);
    }
}
__global__ void packB_k(const void* src, int K, int ksteps, size_t perLsrc,
                        size_t perLdst, int L, const int* flagp, bf16* dst) {
    if (flagp[1]) packB_body<1>(src, K, ksteps, perLsrc, perLdst, L, dst);
    else          packB_body<0>(src, K, ksteps, perLsrc, perLdst, L, dst);
}
template<int ISF>
__device__ void packB24_body(const void* w2, const void* cw1, const void* cw2,
                             const void* lw, bf16* w2p, bf16* cw1p, bf16* cw2p,
                             bf16* lwp) {
    int t = blockIdx.x * 256 + threadIdx.x;
    if (t >= 24 * 8 * 4 * 64) return;
    int lane = t & 63;
    int t2 = t >> 6;
    int ks = t2 & 3;
    int t3 = t2 >> 2;
    int nt = t3 & 7;
    int m  = t3 >> 3;
    int which = m / NLAY, li = m % NLAY;
    const void* src = which == 0 ? w2 : which == 1 ? cw1 : which == 2 ? cw2 : lw;
    bf16* dst = which == 0 ? w2p : which == 1 ? cw1p : which == 2 ? cw2p : lwp;
    int quad = lane >> 4, lc = lane & 15;
    int col = nt * 16 + lc;
    #pragma unroll
    for (int j = 0; j < 8; j++) {
        int k = ks * 32 + quad * 8 + j;
        float v = LD<ISF>(src, (size_t)li * 16384 + (size_t)k * 128 + col);
        dst[(size_t)li * 16384 + ((size_t)((nt * 4 + ks) * 64 + lane)) * 8 + j] = f2b(v);
    }
}
__global__ void packB24_k(const void* w2, const void* cw1, const void* cw2,
                          const void* lw, const int* flagp,
                          bf16* w2p, bf16* cw1p, bf16* cw2p, bf16* lwp) {
    if (flagp[1]) packB24_body<1>(w2, cw1, cw2, lw, w2p, cw1p, cw2p, lwp);
    else          packB24_body<0>(w2, cw1, cw2, lw, w2p, cw1p, cw2p, lwp);
}
template<int ISF>
__device__ void cvts_body(const void* means, const void* betas, const void* bp,
                          const void* bc, const void* b1, const void* b2,
                          const void* cb2, const void* lb,
                          float* meanscv, float* betascv, float* bpcv, float* bccv,
                          float* b1cv, float* b2cv, float* cb2cv, float* lbcv) {
    int i = blockIdx.x * 256 + threadIdx.x;
    if      (i < 50)   meanscv[i]        = LD<ISF>(means, i);
    else if (i < 100)  betascv[i - 50]   = LD<ISF>(betas, i - 50);
    else if (i < 228)  bpcv[i - 100]     = LD<ISF>(bp, i - 100);
    else if (i < 356)  bccv[i - 228]     = LD<ISF>(bc, i - 228);
    else if (i < 1124) b1cv[i - 356]     = LD<ISF>(b1, i - 356);
    else if (i < 1892) b2cv[i - 1124]    = LD<ISF>(b2, i - 1124);
    else if (i < 2660) cb2cv[i - 1892]   = LD<ISF>(cb2, i - 1892);
    else if (i < 3428) lbcv[i - 2660]    = LD<ISF>(lb, i - 2660);
}
__global__ void cvts_k(const void* means, const void* betas, const void* bp,
                       const void* bc, const void* b1, const void* b2,
                       const void* cb2, const void* lb, const int* flagp,
                       float* meanscv, float* betascv, float* bpcv, float* bccv,
                       float* b1cv, float* b2cv, float* cb2cv, float* lbcv) {
    if (flagp[1]) cvts_body<1>(means, betas, bp, bc, b1, b2, cb2, lb,
                               meanscv, betascv, bpcv, bccv, b1cv, b2cv, cb2cv, lbcv);
    else          cvts_body<0>(means, betas, bp, bc, b1, b2, cb2, lb,
                               meanscv, betascv, bpcv, bccv, b1cv, b2cv, cb2cv, lbcv);
}
template<int ISF>
__device__ void cvtb_body(const void* src, int n, bf16* dst) {
    int i = blockIdx.x * 256 + threadIdx.x;
    if (i < n) dst[i] = f2b(LD<ISF>(src, i));
}
__global__ void cvtb_k(const void* src, int n, const int* flagp, bf16* dst) {
    if (flagp[1]) cvtb_body<1>(src, n, dst);
    else          cvtb_body<0>(src, n, dst);
}

// ---------------- MFMA helpers ----------------
#define MFMA(a, b, c) __builtin_amdgcn_mfma_f32_16x16x32_bf16((a), (b), (c), 0, 0, 0)

__device__ __forceinline__ void seg_prep(const int* __restrict__ dst_s, int i0, int tid,
                                         int* ddst, int* slot_s, int* distinct_s,
                                         int* nseg_s) {
    if (tid < 64) {
        int d = dst_s[i0 + tid];
        ddst[tid] = d;
        int dprev = __shfl_up(d, 1, 64);
        int flag = (tid == 0 || d != dprev) ? 1 : 0;
        int s = flag;
        #pragma unroll
        for (int off = 1; off < 64; off <<= 1) {
            int t = __shfl_up(s, off, 64);
            if (tid >= off) s += t;
        }
        slot_s[tid] = s - 1;
        if (flag) distinct_s[s - 1] = d;
        if (tid == 63) *nseg_s = s;
    }
}

__device__ __forceinline__ void seg_mfma(const bf16 (*mvT)[72], const int* ddst,
                                         const int* slot_s, const int* distinct_s,
                                         int nseg, float* __restrict__ out, int tid) {
    int wave = tid >> 6, lane = tid & 63, quad = lane >> 4, lc = lane & 15;
    if (nseg <= 16) {
        bf8v sa[2];
        #pragma unroll
        for (int ks = 0; ks < 2; ks++)
            #pragma unroll
            for (int j = 0; j < 8; j++) {
                int k = ks * 32 + quad * 8 + j;
                sa[ks][j] = (slot_s[k] == lc) ? (short)0x3F80 : (short)0;
            }
        f4v z4 = {0.f, 0.f, 0.f, 0.f};
        f4v sacc[2] = {z4, z4};
        #pragma unroll
        for (int nt = 0; nt < 2; nt++)
            #pragma unroll
            for (int ks = 0; ks < 2; ks++) {
                bf8v b = *(const bf8v*)&mvT[wave * 32 + nt * 16 + lc][ks * 32 + quad * 8];
                sacc[nt] = MFMA(sa[ks], b, sacc[nt]);
            }
        #pragma unroll
        for (int nt = 0; nt < 2; nt++)
            #pragma unroll
            for (int r = 0; r < 4; r++) {
                int sl = quad * 4 + r;
                if (sl < nseg) {
                    int atom = distinct_s[sl];
                    int n = wave * 32 + nt * 16 + lc;
                    float v = sacc[nt][r];
                    if (sl == 0 || sl == nseg - 1)
                        atomicAdd(&out[(size_t)atom * HC + n], v);
                    else
                        out[(size_t)atom * HC + n] = v;
                }
            }
    } else {
        int col = tid & 127;
        int base = (tid >> 7) * 32;
        int cur = ddst[base];
        float s = 0.0f;
        bool first = true;
        for (int e = base; e < base + 32; e++) {
            int dn = ddst[e];
            if (dn != cur) {
                if (first) atomicAdd(&out[(size_t)cur * HC + col], s);
                else out[(size_t)cur * HC + col] = s;
                first = false; cur = dn; s = 0.0f;
            }
            s += b2f(mvT[col][e]);
        }
        atomicAdd(&out[(size_t)cur * HC + col], s);
    }
}

// ---------------- table build: exact MLP at NK ed-knots (fp32) ----------------
__global__ __launch_bounds__(256)
void tabbuild_k(const bf16* __restrict__ wpp, const float* __restrict__ bpcv,
                const bf16* __restrict__ w1p, const float* __restrict__ b1cv,
                const bf16* __restrict__ w2p, const float* __restrict__ b2cv,
                const float* __restrict__ meanscv, const float* __restrict__ betascv,
                float* __restrict__ Tn, float* __restrict__ Tf) {
    __shared__ bf16 hid[64][136];
    __shared__ float csh[64], edsh[64];
    int f = blockIdx.x >> 5, kb = blockIdx.x & 31;
    int base = kb * 64;
    int tid = threadIdx.x;
    int wave = tid >> 6, lane = tid & 63, quad = lane >> 4, lc = lane & 15;
    if (tid < 64) {
        float ed = (float)(base + tid) * (1.0f / (NK - 1));
        float d = -logf(fmaxf(ed, 1e-30f));
        float C = (d < 5.0f) ? 0.5f * (__cosf(d * 0.6283185307f) + 1.0f) : 0.0f;
        csh[tid] = C; edsh[tid] = ed;
    }
    __syncthreads();
    float edi = edsh[wave * 16 + lc], Ci = csh[wave * 16 + lc];
    bf8v af[2];
    #pragma unroll
    for (int ks = 0; ks < 2; ks++) {
        #pragma unroll
        for (int j = 0; j < 8; j++) {
            int r = ks * 32 + quad * 8 + j;
            float v = 0.0f;
            if (r < RBF) { float u = edi - meanscv[r]; v = Ci * __expf(-betascv[r] * u * u); }
            af[ks][j] = f2s(v);
        }
    }
    f4v zero = {0.f, 0.f, 0.f, 0.f};
    f4v acc[8];
    #pragma unroll
    for (int nt = 0; nt < 8; nt++) acc[nt] = zero;
    const bf16* w1b = (f == 0) ? wpp : w1p + (size_t)(f - 1) * 8192;
    #pragma unroll
    for (int nt = 0; nt < 8; nt++)
        #pragma unroll
        for (int ks = 0; ks < 2; ks++) {
            bf8v b = *(const bf8v*)(w1b + ((nt * 2 + ks) * 64 + lane) * 8);
            acc[nt] = MFMA(af[ks], b, acc[nt]);
        }
    if (f == 0) {
        #pragma unroll
        for (int nt = 0; nt < 8; nt++) {
            int n = nt * 16 + lc;
            float bb = bpcv[n];
            #pragma unroll
            for (int r = 0; r < 4; r++) {
                int row = wave * 16 + quad * 4 + r;
                Tn[(size_t)(base + row) * HC + n] = (acc[nt][r] + bb) * csh[row];
            }
        }
        return;
    }
    int l = f - 1;
    #pragma unroll
    for (int nt = 0; nt < 8; nt++) {
        int n = nt * 16 + lc;
        float bb = b1cv[l * HC + n];
        #pragma unroll
        for (int r = 0; r < 4; r++)
            hid[wave * 16 + quad * 4 + r][n] = f2b(silu(acc[nt][r] + bb));
    }
    __syncthreads();
    bf8v a2[4];
    #pragma unroll
    for (int ks = 0; ks < 4; ks++)
        a2[ks] = *(const bf8v*)&hid[wave * 16 + lc][ks * 32 + quad * 8];
    f4v acc2[8];
    #pragma unroll
    for (int nt = 0; nt < 8; nt++) acc2[nt] = zero;
    const bf16* w2b = w2p + (size_t)l * 16384;
    #pragma unroll
    for (int nt = 0; nt < 8; nt++)
        #pragma unroll
        for (int ks = 0; ks < 4; ks++) {
            bf8v b = *(const bf8v*)(w2b + ((nt * 4 + ks) * 64 + lane) * 8);
            acc2[nt] = MFMA(a2[ks], b, acc2[nt]);
        }
    #pragma unroll
    for (int nt = 0; nt < 8; nt++) {
        int n = nt * 16 + lc;
        float bb = b2cv[l * HC + n];
        #pragma unroll
        for (int r = 0; r < 4; r++) {
            int row = wave * 16 + quad * 4 + r;
            Tf[((size_t)l * NK + base + row) * HC + n] = (acc2[nt][r] + bb) * csh[row];
        }
    }
}

// pack fp32 tables into interleaved bf16 knot-pair u32 tables
__global__ void packtab_k(const float* __restrict__ Tn, const float* __restrict__ Tf,
                          unsigned int* __restrict__ Tni, unsigned int* __restrict__ Tfi) {
    int i = blockIdx.x * 256 + threadIdx.x;
    const int per = NK * HC;
    if (i >= (NLAY + 1) * per) return;
    int f = i / per, o = i - f * per;
    int kk = o / HC, c = o - kk * HC;
    const float* T = (f == 0) ? Tn : Tf + (size_t)(f - 1) * per;
    unsigned int* Ti = (f == 0) ? Tni : Tfi + (size_t)(f - 1) * per;
    int k1 = (kk < NK - 1) ? kk + 1 : kk;
    unsigned int lo = (unsigned short)f2s(T[(size_t)kk * HC + c]);
    unsigned int hi = (unsigned short)f2s(T[(size_t)k1 * HC + c]);
    Ti[(size_t)kk * HC + c] = lo | (hi << 16);
}

// ---------------- neighbor edges: lerp(Tni)·mask·emb + seg-sum ----------------
__global__ __launch_bounds__(256)
void nbr_tab_k(const float* __restrict__ ed_s, const int* __restrict__ src_s,
               const int* __restrict__ dst_s, const int* __restrict__ z,
               const bf16* __restrict__ nbrembbf, const unsigned int* __restrict__ Tni,
               float* __restrict__ msg) {
    __shared__ bf16 mvT[128][72];
    __shared__ int ddst[64], slot_s[64], distinct_s[64];
    __shared__ int nseg_s;
    int i0 = blockIdx.x * 64;
    int tid = threadIdx.x;
    seg_prep(dst_s, i0, tid, ddst, slot_s, distinct_s, &nseg_s);
    int row = tid & 63, c0 = (tid >> 6) * 32;
    int e = i0 + row;
    int s = src_s[e];
    float msk = (s != dst_s[e]) ? 1.0f : 0.0f;
    float pos = fminf(fmaxf(ed_s[e] * (float)(NK - 1), 0.0f), (float)(NK - 1));
    int k = (int)pos; if (k > NK - 2) k = NK - 2;
    float frac = pos - (float)k;
    const u4v* tp = (const u4v*)(Tni + (size_t)k * HC + c0);
    u4v tv[8];
    #pragma unroll
    for (int g = 0; g < 8; g++) tv[g] = tp[g];
    int zz = z[s]; zz = zz < 0 ? 0 : (zz >= MAXZ_ ? MAXZ_ - 1 : zz);
    const bf8v* ep = (const bf8v*)(nbrembbf + (size_t)zz * HC + c0);
    bf8v ev[4];
    #pragma unroll
    for (int g = 0; g < 4; g++) ev[g] = ep[g];
    #pragma unroll
    for (int g = 0; g < 8; g++)
        #pragma unroll
        for (int m = 0; m < 4; m++) {
            unsigned int u = tv[g][m];
            float lo = __int_as_float((int)(u << 16));
            float hi = __int_as_float((int)(u & 0xffff0000u));
            float v = lo + frac * (hi - lo);
            int j = g * 4 + m;
            float ef = s2f((unsigned short)ev[j >> 3][j & 7]);
            mvT[c0 + j][row] = f2b(v * msk * ef);
        }
    __syncthreads();
    seg_mfma(mvT, ddst, slot_s, distinct_s, nseg_s, msg, tid);
}

// ---------------- combine (prep fused): x=[emb[z]|msg]@Wc+bc; y0=x@cW1[0] ----
template<int ISF>
__device__ void combine_body(const int* __restrict__ z, const void* __restrict__ emb,
                             const float* __restrict__ msg, const bf16* __restrict__ wcp,
                             const float* __restrict__ bccv, const bf16* __restrict__ cw1b,
                             float* __restrict__ x, bf16* __restrict__ xb,
                             bf16* __restrict__ ybf) {
    __shared__ bf16 srow[64][136];
    int tid = threadIdx.x;
    int wave = tid >> 6, lane = tid & 63, quad = lane >> 4, lc = lane & 15;
    int m0 = blockIdx.x * 64;
    int arow = m0 + wave * 16 + lc;
    int rowc = arow < NATOMS ? arow : NATOMS - 1;
    int zz = z[rowc]; zz = zz < 0 ? 0 : (zz >= MAXZ_ ? MAXZ_ - 1 : zz);
    bf8v af[8];
    #pragma unroll
    for (int ks = 0; ks < 4; ks++)
        #pragma unroll
        for (int j = 0; j < 8; j++)
            af[ks][j] = f2s(LD<ISF>(emb, (size_t)zz * HC + ks * 32 + quad * 8 + j));
    #pragma unroll
    for (int ks = 4; ks < 8; ks++) {
        const float* mp = msg + (size_t)rowc * HC + (ks - 4) * 32 + quad * 8;
        #pragma unroll
        for (int j = 0; j < 8; j++) af[ks][j] = f2s(mp[j]);
    }
    f4v zero = {0.f, 0.f, 0.f, 0.f};
    f4v acc[8];
    #pragma unroll
    for (int nt = 0; nt < 8; nt++) acc[nt] = zero;
    #pragma unroll
    for (int nt = 0; nt < 8; nt++)
        #pragma unroll
        for (int ks = 0; ks < 8; ks++) {
            bf8v b = *(const bf8v*)(wcp + ((nt * 8 + ks) * 64 + lane) * 8);
            acc[nt] = MFMA(af[ks], b, acc[nt]);
        }
    #pragma unroll
    for (int nt = 0; nt < 8; nt++) {
        int n = nt * 16 + lc;
        float bb = bccv[n];
        #pragma unroll
        for (int r = 0; r < 4; r++) {
            int row = m0 + wave * 16 + quad * 4 + r;
            float v = acc[nt][r] + bb;
            bf16 vb = f2b(v);
            srow[wave * 16 + quad * 4 + r][n] = vb;
            if (row < NATOMS) {
                x[(size_t)row * HC + n] = v;
                xb[(size_t)row * HC + n] = vb;
            }
        }
    }
    __syncthreads();
    bf8v a3[4];
    #pragma unroll
    for (int ks = 0; ks < 4; ks++)
        a3[ks] = *(const bf8v*)&srow[wave * 16 + lc][ks * 32 + quad * 8];
    f4v acc3[8];
    #pragma unroll
    for (int nt = 0; nt < 8; nt++) acc3[nt] = zero;
    #pragma unroll
    for (int nt = 0; nt < 8; nt++)
        #pragma unroll
        for (int ks = 0; ks < 4; ks++) {
            bf8v b = *(const bf8v*)(cw1b + ((nt * 4 + ks) * 64 + lane) * 8);
            acc3[nt] = MFMA(a3[ks], b, acc3[nt]);
        }
    #pragma unroll
    for (int nt = 0; nt < 8; nt++) {
        int n = nt * 16 + lc;
        #pragma unroll
        for (int r = 0; r < 4; r++) {
            int row = m0 + wave * 16 + quad * 4 + r;
            if (row < NATOMS) ybf[(size_t)row * HC + n] = f2b(acc3[nt][r]);
        }
    }
}
__global__ __launch_bounds__(256)
void combine_k(const int* z, const void* emb, const float* msg, const bf16* wcp,
               const float* bccv, const bf16* cw1b, const int* flagp,
               float* x, bf16* xb, bf16* ybf) {
    if (flagp[1]) combine_body<1>(z, emb, msg, wcp, bccv, cw1b, x, xb, ybf);
    else          combine_body<0>(z, emb, msg, wcp, bccv, cw1b, x, xb, ybf);
}

// ---------------- filter edges: lerp(Tfi)·y[src] + MFMA seg-sum ----------------
__global__ __launch_bounds__(256)
void filt_tab_k(int l, const float* __restrict__ ed_s, const int* __restrict__ src_s,
                const int* __restrict__ dst_s, const bf16* __restrict__ ybf,
                const unsigned int* __restrict__ Tfi, float* __restrict__ msum) {
    __shared__ bf16 mvT[128][72];
    __shared__ int ddst[64], slot_s[64], distinct_s[64];
    __shared__ int nseg_s;
    int i0 = blockIdx.x * 64;
    int tid = threadIdx.x;
    seg_prep(dst_s, i0, tid, ddst, slot_s, distinct_s, &nseg_s);
    int row = tid & 63, c0 = (tid >> 6) * 32;
    int e = i0 + row;
    float pos = fminf(fmaxf(ed_s[e] * (float)(NK - 1), 0.0f), (float)(NK - 1));
    int k = (int)pos; if (k > NK - 2) k = NK - 2;
    float frac = pos - (float)k;
    const u4v* tp = (const u4v*)(Tfi + ((size_t)l * NK + k) * HC + c0);
    u4v tv[8];
    #pragma unroll
    for (int g = 0; g < 8; g++) tv[g] = tp[g];
    const bf8v* yp = (const bf8v*)(ybf + (size_t)src_s[e] * HC + c0);
    bf8v yv[4];
    #pragma unroll
    for (int g = 0; g < 4; g++) yv[g] = yp[g];
    #pragma unroll
    for (int g = 0; g < 8; g++)
        #pragma unroll
        for (int m = 0; m < 4; m++) {
            unsigned int u = tv[g][m];
            float lo = __int_as_float((int)(u << 16));
            float hi = __int_as_float((int)(u & 0xffff0000u));
            float v = lo + frac * (hi - lo);
            int j = g * 4 + m;
            float yf = s2f((unsigned short)yv[j >> 3][j & 7]);
            mvT[c0 + j][row] = f2b(v * yf);
        }
    __syncthreads();
    seg_mfma(mvT, ddst, slot_s, distinct_s, nseg_s, msum, tid);
}

// ---- node update: msum@cW2 -> silu -> @lW + residual; zero msum; y=x@cW1[l+1]
__global__ __launch_bounds__(256)
void upd_mfma_k(float* msum, int l,
                const bf16* __restrict__ cw2p, const float* __restrict__ cb2cv,
                const bf16* __restrict__ lwp, const float* __restrict__ lbcv,
                const bf16* __restrict__ cw1p, int do_y,
                float* __restrict__ x, bf16* __restrict__ xb,
                bf16* __restrict__ ybf) {
    __shared__ bf16 srow[64][136];
    int tid = threadIdx.x;
    int wave = tid >> 6, lane = tid & 63, quad = lane >> 4, lc = lane & 15;
    int m0 = blockIdx.x * 64;
    bf8v azero = {0, 0, 0, 0, 0, 0, 0, 0};
    bf8v af[4];
    int arow = m0 + wave * 16 + lc;
    #pragma unroll
    for (int ks = 0; ks < 4; ks++) {
        if (arow < NATOMS) {
            const float* p = msum + (size_t)arow * HC + ks * 32 + quad * 8;
            bf8v f;
            #pragma unroll
            for (int j = 0; j < 8; j++) f[j] = f2s(p[j]);
            af[ks] = f;
        } else af[ks] = azero;
    }
    f4v zero = {0.f, 0.f, 0.f, 0.f};
    f4v acc[8];
    #pragma unroll
    for (int nt = 0; nt < 8; nt++) acc[nt] = zero;
    const bf16* c2b = cw2p + (size_t)l * 16384;
    #pragma unroll
    for (int nt = 0; nt < 8; nt++)
        #pragma unroll
        for (int ks = 0; ks < 4; ks++) {
            bf8v b = *(const bf8v*)(c2b + ((nt * 4 + ks) * 64 + lane) * 8);
            acc[nt] = MFMA(af[ks], b, acc[nt]);
        }
    // zero msum for the next layer (replaces hipMemset). zdep is 0.0f but
    // data-depends on acc (which consumed af) so stores cannot pass the loads.
    float zdep = fminf(fabsf(acc[0][0]), 0.0f);
    if (arow < NATOMS) {
        f4v zv = {zdep, zdep, zdep, zdep};
        #pragma unroll
        for (int ks = 0; ks < 4; ks++) {
            *(f4v*)(msum + (size_t)arow * HC + ks * 32 + quad * 8) = zv;
            *(f4v*)(msum + (size_t)arow * HC + ks * 32 + quad * 8 + 4) = zv;
        }
    }
    #pragma unroll
    for (int nt = 0; nt < 8; nt++) {
        int n = nt * 16 + lc;
        float bb = cb2cv[l * HC + n];
        #pragma unroll
        for (int r = 0; r < 4; r++)
            srow[wave * 16 + quad * 4 + r][n] = f2b(silu(acc[nt][r] + bb));
    }
    __syncthreads();
    bf8v a2[4];
    #pragma unroll
    for (int ks = 0; ks < 4; ks++)
        a2[ks] = *(const bf8v*)&srow[wave * 16 + lc][ks * 32 + quad * 8];
    __syncthreads();
    f4v acc2[8];
    #pragma unroll
    for (int nt = 0; nt < 8; nt++) acc2[nt] = zero;
    const bf16* lwb = lwp + (size_t)l * 16384;
    #pragma unroll
    for (int nt = 0; nt < 8; nt++)
        #pragma unroll
        for (int ks = 0; ks < 4; ks++) {
            bf8v b = *(const bf8v*)(lwb + ((nt * 4 + ks) * 64 + lane) * 8);
            acc2[nt] = MFMA(a2[ks], b, acc2[nt]);
        }
    #pragma unroll
    for (int nt = 0; nt < 8; nt++) {
        int n = nt * 16 + lc;
        float bb = lbcv[l * HC + n];
        #pragma unroll
        for (int r = 0; r < 4; r++) {
            int row = m0 + wave * 16 + quad * 4 + r;
            float nv = 0.0f;
            if (row < NATOMS) {
                size_t o = (size_t)row * HC + n;
                nv = x[o] + acc2[nt][r] + bb;
                x[o] = nv;
                xb[o] = f2b(nv);
            }
            srow[wave * 16 + quad * 4 + r][n] = f2b(nv);
        }
    }
    if (do_y) {
        __syncthreads();
        bf8v a3[4];
        #pragma unroll
        for (int ks = 0; ks < 4; ks++)
            a3[ks] = *(const bf8v*)&srow[wave * 16 + lc][ks * 32 + quad * 8];
        f4v acc3[8];
        #pragma unroll
        for (int nt = 0; nt < 8; nt++) acc3[nt] = zero;
        const bf16* c1b = cw1p + (size_t)(l + 1) * 16384;
        #pragma unroll
        for (int nt = 0; nt < 8; nt++)
            #pragma unroll
            for (int ks = 0; ks < 4; ks++) {
                bf8v b = *(const bf8v*)(c1b + ((nt * 4 + ks) * 64 + lane) * 8);
                acc3[nt] = MFMA(a3[ks], b, acc3[nt]);
            }
        #pragma unroll
        for (int nt = 0; nt < 8; nt++) {
            int n = nt * 16 + lc;
            #pragma unroll
            for (int r = 0; r < 4; r++) {
                int row = m0 + wave * 16 + quad * 4 + r;
                if (row < NATOMS) ybf[(size_t)row * HC + n] = f2b(acc3[nt][r]);
            }
        }
    }
}

__global__ void out_k(const float* __restrict__ x, void* out, const int* flagp) {
    int i = blockIdx.x * 256 + threadIdx.x;
    if (i >= NATOMS * HC) return;
    if (flagp[1]) ((float*)out)[i] = x[i];
    else          ((bf16*)out)[i] = f2b(x[i]);
}

// ---------------- launch ----------------
extern "C" void kernel_launch(void* const* d_in, const int* in_sizes, int n_in,
                              void* d_out, int out_size, void* d_ws, size_t ws_size,
                              hipStream_t stream) {
    const int*  z      = (const int*) d_in[0];
    const void* pos    = d_in[1];
    const int*  ei     = (const int*) d_in[3];
    const void* emb    = d_in[4];
    const void* nbremb = d_in[5];
    const void* Wp     = d_in[6];
    const void* bp     = d_in[7];
    const void* Wc     = d_in[8];
    const void* bc     = d_in[9];
    const void* means  = d_in[10];
    const void* betas  = d_in[11];
    const void* W1     = d_in[12];
    const void* b1     = d_in[13];
    const void* W2     = d_in[14];
    const void* b2     = d_in[15];
    const void* cW1    = d_in[16];
    const void* cW2    = d_in[17];
    const void* cb2    = d_in[18];
    const void* lW     = d_in[19];
    const void* lb     = d_in[20];

    char* p = (char*)d_ws;
    auto alloc = [&](size_t bytes) { char* r = p; p += (bytes + 255) / 256 * 256; return r; };
    int*   flag    = (int*)  alloc(256);
    int*   counts  = (int*)  alloc((size_t)NATOMS * 4);
    int*   rowptr  = (int*)  alloc((size_t)(NATOMS + 1) * 4);
    int*   cursor  = (int*)  alloc((size_t)NATOMS * 4);
    int*   perm    = (int*)  alloc((size_t)NEDGES * 4);
    int*   src_s   = (int*)  alloc((size_t)NEDGES * 4);
    int*   dst_s   = (int*)  alloc((size_t)NEDGES * 4);
    float* ed_s    = (float*)alloc((size_t)NEDGES * 4);
    float* x       = (float*)alloc((size_t)NATOMS * HC * 4);
    bf16*  xb      = (bf16*) alloc((size_t)NATOMS * HC * 2);
    bf16*  ybf     = (bf16*) alloc((size_t)NATOMS * HC * 2);
    float* msum    = (float*)alloc((size_t)NATOMS * HC * 4);   // contiguous with msg
    float* msg     = (float*)alloc((size_t)NATOMS * HC * 4);
    float* Tn      = (float*)alloc((size_t)NK * HC * 4);
    float* Tf      = (float*)alloc((size_t)NLAY * NK * HC * 4);
    unsigned int* Tni = (unsigned int*)alloc((size_t)NK * HC * 4);
    unsigned int* Tfi = (unsigned int*)alloc((size_t)NLAY * NK * HC * 4);
    bf16*  wpp     = (bf16*) alloc((size_t)8192 * 2);
    bf16*  wcp     = (bf16*) alloc((size_t)32768 * 2);
    bf16*  w1p     = (bf16*) alloc((size_t)NLAY * 8192 * 2);
    bf16*  w2p     = (bf16*) alloc((size_t)NLAY * 16384 * 2);
    bf16*  cw1p    = (bf16*) alloc((size_t)NLAY * 16384 * 2);
    bf16*  cw2p    = (bf16*) alloc((size_t)NLAY * 16384 * 2);
    bf16*  lwp     = (bf16*) alloc((size_t)NLAY * 16384 * 2);
    bf16*  nbrembbf= (bf16*) alloc((size_t)MAXZ_ * HC * 2);
    float* bpcv    = (float*)alloc((size_t)HC * 4);
    float* bccv    = (float*)alloc((size_t)HC * 4);
    float* b1cv    = (float*)alloc((size_t)NLAY * HC * 4);
    float* b2cv    = (float*)alloc((size_t)NLAY * HC * 4);
    float* cb2cv   = (float*)alloc((size_t)NLAY * HC * 4);
    float* lbcv    = (float*)alloc((size_t)NLAY * HC * 4);
    float* meanscv = (float*)alloc((size_t)RBF * 4);
    float* betascv = (float*)alloc((size_t)RBF * 4);

    const int EG = (NEDGES + 255) / 256;
    const int NG = (NATOMS + 255) / 256;

    zero2_k<<<NG, 256, 0, stream>>>(flag, counts);
    probe_k<<<(NATOMS * 3 + 255) / 256, 256, 0, stream>>>(pos, NATOMS * 3, flag);
    setflag_k<<<1, 64, 0, stream>>>(flag);

    hist_k<<<EG, 256, 0, stream>>>(ei + NEDGES, counts);
    scan_k<<<1, 1024, 0, stream>>>(counts, rowptr, cursor);
    perm_k<<<EG, 256, 0, stream>>>(ei + NEDGES, cursor, perm);
    geom_k<<<EG, 256, 0, stream>>>(ei, pos, perm, flag, ed_s, src_s, dst_s);

    packB_k<<<4,  256, 0, stream>>>(Wp,  RBF, 2, 6400, 8192, 1, flag, wpp);
    packB_k<<<16, 256, 0, stream>>>(Wc,  256, 8, 32768, 32768, 1, flag, wcp);
    packB_k<<<24, 256, 0, stream>>>(W1,  RBF, 2, 6400, 8192, NLAY, flag, w1p);
    packB24_k<<<192, 256, 0, stream>>>(W2, cW1, cW2, lW, flag, w2p, cw1p, cw2p, lwp);
    cvts_k<<<14, 256, 0, stream>>>(means, betas, bp, bc, b1, b2, cb2, lb, flag,
                                   meanscv, betascv, bpcv, bccv, b1cv, b2cv, cb2cv, lbcv);
    cvtb_k<<<(MAXZ_ * HC + 255) / 256, 256, 0, stream>>>(nbremb, MAXZ_ * HC, flag, nbrembbf);

    tabbuild_k<<<7 * (NK / 64), 256, 0, stream>>>(wpp, bpcv, w1p, b1cv, w2p, b2cv,
                                                  meanscv, betascv, Tn, Tf);
    packtab_k<<<((NLAY + 1) * NK * HC + 255) / 256, 256, 0, stream>>>(Tn, Tf, Tni, Tfi);

    // one memset covers msum + msg (contiguous allocations)
    hipMemsetAsync(msum, 0, (size_t)2 * NATOMS * HC * 4, stream);
    nbr_tab_k<<<EGRID, 256, 0, stream>>>(ed_s, src_s, dst_s, z, nbrembbf, Tni, msg);
    combine_k<<<YGRID, 256, 0, stream>>>(z, emb, msg, wcp, bccv, cw1p, flag, x, xb, ybf);

    for (int l = 0; l < NLAY; l++) {
        filt_tab_k<<<EGRID, 256, 0, stream>>>(l, ed_s, src_s, dst_s, ybf, Tfi, msum);
        upd_mfma_k<<<YGRID, 256, 0, stream>>>(msum, l, cw2p, cb2cv, lwp, lbcv,
                                              cw1p, (l < NLAY - 1) ? 1 : 0, x, xb, ybf);
    }
    out_k<<<(NATOMS * HC + 255) / 256, 256, 0, stream>>>(x, d_out, flag);
}

// Round 10
// 548.222 us; speedup vs baseline: 16.4296x; 1.1238x over previous
//
#include <hip/hip_runtime.h>
#include <hip/hip_bf16.h>

// TorchMD_GN_Ext R10:
//  - nearest-knot bf16 table (NK=8192, err ~0.2% = bf16 noise floor): table
//    reqs 8->4 per thread, lerp math gone, tabbuild writes bf16 directly
//    (packtab kernel deleted). Per-layer table 2.1MB = per-XCD L2 resident.
//  - mega pack kernel (6 setup launches -> 1), memsets consolidated.
//  - 23 dispatches total. Harness ws-poison (43us fill) is outside our control.

#define NATOMS 10000
#define NEDGES 320000
#define HC 128
#define RBF 50
#define NLAY 6
#define MAXZ_ 100
#define NK 8192
#define EGRID (NEDGES / 64)         // 5000
#define YGRID ((NATOMS + 63) / 64)  // 157

typedef __hip_bfloat16 bf16;
typedef __attribute__((ext_vector_type(8))) short bf8v;
typedef __attribute__((ext_vector_type(4))) float f4v;

__device__ __forceinline__ float b2f(bf16 v) { return __bfloat162float(v); }
__device__ __forceinline__ bf16  f2b(float v) { return __float2bfloat16(v); }
__device__ __forceinline__ short f2s(float v) { bf16 h = f2b(v); return *(short*)&h; }
__device__ __forceinline__ float s2f(unsigned short s) {
    return __int_as_float(((int)s) << 16);
}
__device__ __forceinline__ float silu(float v) {
    return v * __builtin_amdgcn_rcpf(1.0f + __expf(-v));
}

template<int ISF>
__device__ __forceinline__ float LD(const void* p, size_t i) {
    if (ISF) return ((const float*)p)[i];
    return b2f(((const bf16*)p)[i]);
}

// ---------------- dtype probe ----------------
__global__ void probe_k(const void* pos, int nelem, int* flag) {
    int i = blockIdx.x * 256 + threadIdx.x;
    float v = 0.0f;
    if (i < nelem) {
        v = fabsf(b2f(((const bf16*)pos)[i]));
        if (v != v) v = 1e30f;
    }
    atomicMax(flag, __float_as_int(v));
}
__global__ void setflag_k(int* flag) {
    if (threadIdx.x == 0) flag[1] = (__int_as_float(flag[0]) > 1.0e4f) ? 1 : 0;
}

// ---------------- CSR build ----------------
__device__ __forceinline__ int clampN(int v) {
    return v < 0 ? 0 : (v >= NATOMS ? NATOMS - 1 : v);
}
__global__ void hist_k(const int* __restrict__ dst, int* __restrict__ counts) {
    int e = blockIdx.x * 256 + threadIdx.x;
    if (e < NEDGES) atomicAdd(&counts[clampN(dst[e])], 1);
}
__global__ void scan_k(const int* __restrict__ counts, int* __restrict__ rowptr,
                       int* __restrict__ cursor) {
    __shared__ int wsum[16];
    __shared__ int carry_s;
    __shared__ int chunktot;
    int tid = threadIdx.x, lane = tid & 63, w = tid >> 6;
    if (tid == 0) { carry_s = 0; rowptr[0] = 0; }
    __syncthreads();
    for (int base = 0; base < NATOMS; base += 1024) {
        int i = base + tid;
        int v = (i < NATOMS) ? counts[i] : 0;
        int s = v;
        #pragma unroll
        for (int off = 1; off < 64; off <<= 1) {
            int t = __shfl_up(s, off, 64);
            if (lane >= off) s += t;
        }
        if (lane == 63) wsum[w] = s;
        __syncthreads();
        if (w == 0 && lane < 16) {
            int t = wsum[lane];
            int si = t;
            #pragma unroll
            for (int off = 1; off < 16; off <<= 1) {
                int u = __shfl_up(si, off, 64);
                if (lane >= off) si += u;
            }
            wsum[lane] = si - t;
            if (lane == 15) chunktot = si;
        }
        __syncthreads();
        int carry = carry_s;
        if (i < NATOMS) {
            int inc = carry + wsum[w] + s;
            rowptr[i + 1] = inc;
            cursor[i] = inc - v;
        }
        __syncthreads();
        if (tid == 0) carry_s += chunktot;
        __syncthreads();
    }
}
__global__ void perm_k(const int* __restrict__ dst, int* __restrict__ cursor,
                       int* __restrict__ perm) {
    int e = blockIdx.x * 256 + threadIdx.x;
    if (e < NEDGES) {
        int p = atomicAdd(&cursor[clampN(dst[e])], 1);
        perm[p] = e;
    }
}

// ---------------- geometry ----------------
template<int ISF>
__device__ void geom_body(const int* __restrict__ ei, const void* __restrict__ pos,
                          const int* __restrict__ perm,
                          float* __restrict__ ed_s, int* __restrict__ src_s,
                          int* __restrict__ dst_s) {
    int i = blockIdx.x * 256 + threadIdx.x;
    if (i >= NEDGES) return;
    int e = perm[i];
    int s = clampN(ei[e]);
    int t = clampN(ei[NEDGES + e]);
    float dx = LD<ISF>(pos, (size_t)s * 3 + 0) - LD<ISF>(pos, (size_t)t * 3 + 0);
    float dy = LD<ISF>(pos, (size_t)s * 3 + 1) - LD<ISF>(pos, (size_t)t * 3 + 1);
    float dz = LD<ISF>(pos, (size_t)s * 3 + 2) - LD<ISF>(pos, (size_t)t * 3 + 2);
    float d = sqrtf(dx * dx + dy * dy + dz * dz + 1e-12f);
    if (d != d) d = 1e30f;
    ed_s[i] = __expf(-d);
    src_s[i] = s;
    dst_s[i] = t;
}
__global__ void geom_k(const int* ei, const void* pos, const int* perm, const int* flagp,
                       float* ed_s, int* src_s, int* dst_s) {
    if (flagp[1]) geom_body<1>(ei, pos, perm, ed_s, src_s, dst_s);
    else          geom_body<0>(ei, pos, perm, ed_s, src_s, dst_s);
}

// ---------------- mega pack/convert (one dispatch) ----------------
template<int ISF>
__device__ void packB_at(int t, const void* src, int K, int ksteps, size_t perLsrc,
                         size_t perLdst, int L, bf16* dst) {
    if (t >= L * 8 * ksteps * 64) return;
    int lane = t & 63;
    int t2 = t >> 6;
    int ks = t2 % ksteps;
    int t3 = t2 / ksteps;
    int nt = t3 & 7;
    int l  = t3 >> 3;
    int quad = lane >> 4, lc = lane & 15;
    int col = nt * 16 + lc;
    for (int j = 0; j < 8; j++) {
        int k = ks * 32 + quad * 8 + j;
        float v = (k < K) ? LD<ISF>(src, (size_t)l * perLsrc + (size_t)k * 128 + col) : 0.0f;
        dst[(size_t)l * perLdst + ((size_t)((nt * ksteps + ks) * 64 + lane)) * 8 + j] = f2b(v);
    }
}
template<int ISF>
__device__ void packB24_at(int t, const void* w2, const void* cw1, const void* cw2,
                           const void* lw, bf16* w2p, bf16* cw1p, bf16* cw2p, bf16* lwp) {
    if (t >= 24 * 8 * 4 * 64) return;
    int lane = t & 63;
    int t2 = t >> 6;
    int ks = t2 & 3;
    int t3 = t2 >> 2;
    int nt = t3 & 7;
    int m  = t3 >> 3;
    int which = m / NLAY, li = m % NLAY;
    const void* src = which == 0 ? w2 : which == 1 ? cw1 : which == 2 ? cw2 : lw;
    bf16* dst = which == 0 ? w2p : which == 1 ? cw1p : which == 2 ? cw2p : lwp;
    int quad = lane >> 4, lc = lane & 15;
    int col = nt * 16 + lc;
    #pragma unroll
    for (int j = 0; j < 8; j++) {
        int k = ks * 32 + quad * 8 + j;
        float v = LD<ISF>(src, (size_t)li * 16384 + (size_t)k * 128 + col);
        dst[(size_t)li * 16384 + ((size_t)((nt * 4 + ks) * 64 + lane)) * 8 + j] = f2b(v);
    }
}
template<int ISF>
__device__ void cvts_at(int i, const void* means, const void* betas, const void* bp,
                        const void* bc, const void* b1, const void* b2,
                        const void* cb2, const void* lb,
                        float* meanscv, float* betascv, float* bpcv, float* bccv,
                        float* b1cv, float* b2cv, float* cb2cv, float* lbcv) {
    if      (i < 50)   meanscv[i]        = LD<ISF>(means, i);
    else if (i < 100)  betascv[i - 50]   = LD<ISF>(betas, i - 50);
    else if (i < 228)  bpcv[i - 100]     = LD<ISF>(bp, i - 100);
    else if (i < 356)  bccv[i - 228]     = LD<ISF>(bc, i - 228);
    else if (i < 1124) b1cv[i - 356]     = LD<ISF>(b1, i - 356);
    else if (i < 1892) b2cv[i - 1124]    = LD<ISF>(b2, i - 1124);
    else if (i < 2660) cb2cv[i - 1892]   = LD<ISF>(cb2, i - 1892);
    else if (i < 3428) lbcv[i - 2660]    = LD<ISF>(lb, i - 2660);
}
template<int ISF>
__device__ void packall_body(const void* Wp, const void* Wc, const void* W1,
                             const void* W2, const void* cW1, const void* cW2,
                             const void* lW, const void* means, const void* betas,
                             const void* bp, const void* bc, const void* b1,
                             const void* b2, const void* cb2, const void* lb,
                             const void* nbremb,
                             bf16* wpp, bf16* wcp, bf16* w1p, bf16* w2p, bf16* cw1p,
                             bf16* cw2p, bf16* lwp, float* meanscv, float* betascv,
                             float* bpcv, float* bccv, float* b1cv, float* b2cv,
                             float* cb2cv, float* lbcv, bf16* nbrembbf) {
    int b = blockIdx.x, tid = threadIdx.x;
    if (b < 4)        packB_at<ISF>(b * 256 + tid, Wp, RBF, 2, 6400, 8192, 1, wpp);
    else if (b < 20)  packB_at<ISF>((b - 4) * 256 + tid, Wc, 256, 8, 32768, 32768, 1, wcp);
    else if (b < 44)  packB_at<ISF>((b - 20) * 256 + tid, W1, RBF, 2, 6400, 8192, NLAY, w1p);
    else if (b < 236) packB24_at<ISF>((b - 44) * 256 + tid, W2, cW1, cW2, lW,
                                      w2p, cw1p, cw2p, lwp);
    else if (b < 250) cvts_at<ISF>((b - 236) * 256 + tid, means, betas, bp, bc, b1, b2,
                                   cb2, lb, meanscv, betascv, bpcv, bccv,
                                   b1cv, b2cv, cb2cv, lbcv);
    else {
        int i = (b - 250) * 256 + tid;
        if (i < MAXZ_ * HC) nbrembbf[i] = f2b(LD<ISF>(nbremb, i));
    }
}
__global__ void packall_k(const void* Wp, const void* Wc, const void* W1,
                          const void* W2, const void* cW1, const void* cW2,
                          const void* lW, const void* means, const void* betas,
                          const void* bp, const void* bc, const void* b1,
                          const void* b2, const void* cb2, const void* lb,
                          const void* nbremb, const int* flagp,
                          bf16* wpp, bf16* wcp, bf16* w1p, bf16* w2p, bf16* cw1p,
                          bf16* cw2p, bf16* lwp, float* meanscv, float* betascv,
                          float* bpcv, float* bccv, float* b1cv, float* b2cv,
                          float* cb2cv, float* lbcv, bf16* nbrembbf) {
    if (flagp[1]) packall_body<1>(Wp, Wc, W1, W2, cW1, cW2, lW, means, betas, bp, bc,
                                  b1, b2, cb2, lb, nbremb, wpp, wcp, w1p, w2p, cw1p,
                                  cw2p, lwp, meanscv, betascv, bpcv, bccv, b1cv, b2cv,
                                  cb2cv, lbcv, nbrembbf);
    else          packall_body<0>(Wp, Wc, W1, W2, cW1, cW2, lW, means, betas, bp, bc,
                                  b1, b2, cb2, lb, nbremb, wpp, wcp, w1p, w2p, cw1p,
                                  cw2p, lwp, meanscv, betascv, bpcv, bccv, b1cv, b2cv,
                                  cb2cv, lbcv, nbrembbf);
}

// ---------------- MFMA helpers ----------------
#define MFMA(a, b, c) __builtin_amdgcn_mfma_f32_16x16x32_bf16((a), (b), (c), 0, 0, 0)

__device__ __forceinline__ void seg_prep(const int* __restrict__ dst_s, int i0, int tid,
                                         int* ddst, int* slot_s, int* distinct_s,
                                         int* nseg_s) {
    if (tid < 64) {
        int d = dst_s[i0 + tid];
        ddst[tid] = d;
        int dprev = __shfl_up(d, 1, 64);
        int flag = (tid == 0 || d != dprev) ? 1 : 0;
        int s = flag;
        #pragma unroll
        for (int off = 1; off < 64; off <<= 1) {
            int t = __shfl_up(s, off, 64);
            if (tid >= off) s += t;
        }
        slot_s[tid] = s - 1;
        if (flag) distinct_s[s - 1] = d;
        if (tid == 63) *nseg_s = s;
    }
}

__device__ __forceinline__ void seg_mfma(const bf16 (*mvT)[72], const int* ddst,
                                         const int* slot_s, const int* distinct_s,
                                         int nseg, float* __restrict__ out, int tid) {
    int wave = tid >> 6, lane = tid & 63, quad = lane >> 4, lc = lane & 15;
    if (nseg <= 16) {
        bf8v sa[2];
        #pragma unroll
        for (int ks = 0; ks < 2; ks++)
            #pragma unroll
            for (int j = 0; j < 8; j++) {
                int k = ks * 32 + quad * 8 + j;
                sa[ks][j] = (slot_s[k] == lc) ? (short)0x3F80 : (short)0;
            }
        f4v z4 = {0.f, 0.f, 0.f, 0.f};
        f4v sacc[2] = {z4, z4};
        #pragma unroll
        for (int nt = 0; nt < 2; nt++)
            #pragma unroll
            for (int ks = 0; ks < 2; ks++) {
                bf8v b = *(const bf8v*)&mvT[wave * 32 + nt * 16 + lc][ks * 32 + quad * 8];
                sacc[nt] = MFMA(sa[ks], b, sacc[nt]);
            }
        #pragma unroll
        for (int nt = 0; nt < 2; nt++)
            #pragma unroll
            for (int r = 0; r < 4; r++) {
                int sl = quad * 4 + r;
                if (sl < nseg) {
                    int atom = distinct_s[sl];
                    int n = wave * 32 + nt * 16 + lc;
                    float v = sacc[nt][r];
                    if (sl == 0 || sl == nseg - 1)
                        atomicAdd(&out[(size_t)atom * HC + n], v);
                    else
                        out[(size_t)atom * HC + n] = v;
                }
            }
    } else {
        int col = tid & 127;
        int base = (tid >> 7) * 32;
        int cur = ddst[base];
        float s = 0.0f;
        bool first = true;
        for (int e = base; e < base + 32; e++) {
            int dn = ddst[e];
            if (dn != cur) {
                if (first) atomicAdd(&out[(size_t)cur * HC + col], s);
                else out[(size_t)cur * HC + col] = s;
                first = false; cur = dn; s = 0.0f;
            }
            s += b2f(mvT[col][e]);
        }
        atomicAdd(&out[(size_t)cur * HC + col], s);
    }
}

// ---------------- table build: exact MLP at NK ed-knots, bf16 out ----------
// Tb layout: [f][NK][HC], f=0 neighbor filter, f=1..6 layer filters.
__global__ __launch_bounds__(256)
void tabbuild_k(const bf16* __restrict__ wpp, const float* __restrict__ bpcv,
                const bf16* __restrict__ w1p, const float* __restrict__ b1cv,
                const bf16* __restrict__ w2p, const float* __restrict__ b2cv,
                const float* __restrict__ meanscv, const float* __restrict__ betascv,
                bf16* __restrict__ Tb) {
    __shared__ bf16 hid[64][136];
    __shared__ float csh[64], edsh[64];
    int f = blockIdx.x >> 7, kb = blockIdx.x & 127;   // NK/64 = 128
    int base = kb * 64;
    int tid = threadIdx.x;
    int wave = tid >> 6, lane = tid & 63, quad = lane >> 4, lc = lane & 15;
    if (tid < 64) {
        float ed = (float)(base + tid) * (1.0f / (NK - 1));
        float d = -logf(fmaxf(ed, 1e-30f));
        float C = (d < 5.0f) ? 0.5f * (__cosf(d * 0.6283185307f) + 1.0f) : 0.0f;
        csh[tid] = C; edsh[tid] = ed;
    }
    __syncthreads();
    float edi = edsh[wave * 16 + lc], Ci = csh[wave * 16 + lc];
    bf8v af[2];
    #pragma unroll
    for (int ks = 0; ks < 2; ks++) {
        #pragma unroll
        for (int j = 0; j < 8; j++) {
            int r = ks * 32 + quad * 8 + j;
            float v = 0.0f;
            if (r < RBF) { float u = edi - meanscv[r]; v = Ci * __expf(-betascv[r] * u * u); }
            af[ks][j] = f2s(v);
        }
    }
    f4v zero = {0.f, 0.f, 0.f, 0.f};
    f4v acc[8];
    #pragma unroll
    for (int nt = 0; nt < 8; nt++) acc[nt] = zero;
    const bf16* w1b = (f == 0) ? wpp : w1p + (size_t)(f - 1) * 8192;
    #pragma unroll
    for (int nt = 0; nt < 8; nt++)
        #pragma unroll
        for (int ks = 0; ks < 2; ks++) {
            bf8v b = *(const bf8v*)(w1b + ((nt * 2 + ks) * 64 + lane) * 8);
            acc[nt] = MFMA(af[ks], b, acc[nt]);
        }
    if (f == 0) {
        #pragma unroll
        for (int nt = 0; nt < 8; nt++) {
            int n = nt * 16 + lc;
            float bb = bpcv[n];
            #pragma unroll
            for (int r = 0; r < 4; r++) {
                int row = wave * 16 + quad * 4 + r;
                Tb[(size_t)(base + row) * HC + n] = f2b((acc[nt][r] + bb) * csh[row]);
            }
        }
        return;
    }
    int l = f - 1;
    #pragma unroll
    for (int nt = 0; nt < 8; nt++) {
        int n = nt * 16 + lc;
        float bb = b1cv[l * HC + n];
        #pragma unroll
        for (int r = 0; r < 4; r++)
            hid[wave * 16 + quad * 4 + r][n] = f2b(silu(acc[nt][r] + bb));
    }
    __syncthreads();
    bf8v a2[4];
    #pragma unroll
    for (int ks = 0; ks < 4; ks++)
        a2[ks] = *(const bf8v*)&hid[wave * 16 + lc][ks * 32 + quad * 8];
    f4v acc2[8];
    #pragma unroll
    for (int nt = 0; nt < 8; nt++) acc2[nt] = zero;
    const bf16* w2b = w2p + (size_t)l * 16384;
    #pragma unroll
    for (int nt = 0; nt < 8; nt++)
        #pragma unroll
        for (int ks = 0; ks < 4; ks++) {
            bf8v b = *(const bf8v*)(w2b + ((nt * 4 + ks) * 64 + lane) * 8);
            acc2[nt] = MFMA(a2[ks], b, acc2[nt]);
        }
    #pragma unroll
    for (int nt = 0; nt < 8; nt++) {
        int n = nt * 16 + lc;
        float bb = b2cv[l * HC + n];
        #pragma unroll
        for (int r = 0; r < 4; r++) {
            int row = wave * 16 + quad * 4 + r;
            Tb[((size_t)f * NK + base + row) * HC + n] = f2b((acc2[nt][r] + bb) * csh[row]);
        }
    }
}

// ---------------- neighbor edges: T[k]·mask·emb + seg-sum ----------------
__global__ __launch_bounds__(256)
void nbr_tab_k(const float* __restrict__ ed_s, const int* __restrict__ src_s,
               const int* __restrict__ dst_s, const int* __restrict__ z,
               const bf16* __restrict__ nbrembbf, const bf16* __restrict__ Tb,
               float* __restrict__ msg) {
    __shared__ bf16 mvT[128][72];
    __shared__ int ddst[64], slot_s[64], distinct_s[64];
    __shared__ int nseg_s;
    int i0 = blockIdx.x * 64;
    int tid = threadIdx.x;
    seg_prep(dst_s, i0, tid, ddst, slot_s, distinct_s, &nseg_s);
    int row = tid & 63, c0 = (tid >> 6) * 32;
    int e = i0 + row;
    int s = src_s[e];
    float msk = (s != dst_s[e]) ? 1.0f : 0.0f;
    float pos = fminf(fmaxf(ed_s[e] * (float)(NK - 1) + 0.5f, 0.0f), (float)(NK - 1));
    int k = (int)pos;
    const bf8v* tp = (const bf8v*)(Tb + (size_t)k * HC + c0);
    bf8v tv[4];
    #pragma unroll
    for (int g = 0; g < 4; g++) tv[g] = tp[g];
    int zz = z[s]; zz = zz < 0 ? 0 : (zz >= MAXZ_ ? MAXZ_ - 1 : zz);
    const bf8v* ep = (const bf8v*)(nbrembbf + (size_t)zz * HC + c0);
    bf8v ev[4];
    #pragma unroll
    for (int g = 0; g < 4; g++) ev[g] = ep[g];
    #pragma unroll
    for (int g = 0; g < 4; g++)
        #pragma unroll
        for (int m = 0; m < 8; m++) {
            float v = s2f((unsigned short)tv[g][m]) * msk *
                      s2f((unsigned short)ev[g][m]);
            mvT[c0 + g * 8 + m][row] = f2b(v);
        }
    __syncthreads();
    seg_mfma(mvT, ddst, slot_s, distinct_s, nseg_s, msg, tid);
}

// ---------------- combine (prep fused): x=[emb[z]|msg]@Wc+bc; y0=x@cW1[0] ----
template<int ISF>
__device__ void combine_body(const int* __restrict__ z, const void* __restrict__ emb,
                             const float* __restrict__ msg, const bf16* __restrict__ wcp,
                             const float* __restrict__ bccv, const bf16* __restrict__ cw1b,
                             float* __restrict__ x, bf16* __restrict__ xb,
                             bf16* __restrict__ ybf) {
    __shared__ bf16 srow[64][136];
    int tid = threadIdx.x;
    int wave = tid >> 6, lane = tid & 63, quad = lane >> 4, lc = lane & 15;
    int m0 = blockIdx.x * 64;
    int arow = m0 + wave * 16 + lc;
    int rowc = arow < NATOMS ? arow : NATOMS - 1;
    int zz = z[rowc]; zz = zz < 0 ? 0 : (zz >= MAXZ_ ? MAXZ_ - 1 : zz);
    bf8v af[8];
    #pragma unroll
    for (int ks = 0; ks < 4; ks++)
        #pragma unroll
        for (int j = 0; j < 8; j++)
            af[ks][j] = f2s(LD<ISF>(emb, (size_t)zz * HC + ks * 32 + quad * 8 + j));
    #pragma unroll
    for (int ks = 4; ks < 8; ks++) {
        const float* mp = msg + (size_t)rowc * HC + (ks - 4) * 32 + quad * 8;
        #pragma unroll
        for (int j = 0; j < 8; j++) af[ks][j] = f2s(mp[j]);
    }
    f4v zero = {0.f, 0.f, 0.f, 0.f};
    f4v acc[8];
    #pragma unroll
    for (int nt = 0; nt < 8; nt++) acc[nt] = zero;
    #pragma unroll
    for (int nt = 0; nt < 8; nt++)
        #pragma unroll
        for (int ks = 0; ks < 8; ks++) {
            bf8v b = *(const bf8v*)(wcp + ((nt * 8 + ks) * 64 + lane) * 8);
            acc[nt] = MFMA(af[ks], b, acc[nt]);
        }
    #pragma unroll
    for (int nt = 0; nt < 8; nt++) {
        int n = nt * 16 + lc;
        float bb = bccv[n];
        #pragma unroll
        for (int r = 0; r < 4; r++) {
            int row = m0 + wave * 16 + quad * 4 + r;
            float v = acc[nt][r] + bb;
            bf16 vb = f2b(v);
            srow[wave * 16 + quad * 4 + r][n] = vb;
            if (row < NATOMS) {
                x[(size_t)row * HC + n] = v;
                xb[(size_t)row * HC + n] = vb;
            }
        }
    }
    __syncthreads();
    bf8v a3[4];
    #pragma unroll
    for (int ks = 0; ks < 4; ks++)
        a3[ks] = *(const bf8v*)&srow[wave * 16 + lc][ks * 32 + quad * 8];
    f4v acc3[8];
    #pragma unroll
    for (int nt = 0; nt < 8; nt++) acc3[nt] = zero;
    #pragma unroll
    for (int nt = 0; nt < 8; nt++)
        #pragma unroll
        for (int ks = 0; ks < 4; ks++) {
            bf8v b = *(const bf8v*)(cw1b + ((nt * 4 + ks) * 64 + lane) * 8);
            acc3[nt] = MFMA(a3[ks], b, acc3[nt]);
        }
    #pragma unroll
    for (int nt = 0; nt < 8; nt++) {
        int n = nt * 16 + lc;
        #pragma unroll
        for (int r = 0; r < 4; r++) {
            int row = m0 + wave * 16 + quad * 4 + r;
            if (row < NATOMS) ybf[(size_t)row * HC + n] = f2b(acc3[nt][r]);
        }
    }
}
__global__ __launch_bounds__(256)
void combine_k(const int* z, const void* emb, const float* msg, const bf16* wcp,
               const float* bccv, const bf16* cw1b, const int* flagp,
               float* x, bf16* xb, bf16* ybf) {
    if (flagp[1]) combine_body<1>(z, emb, msg, wcp, bccv, cw1b, x, xb, ybf);
    else          combine_body<0>(z, emb, msg, wcp, bccv, cw1b, x, xb, ybf);
}

// ---------------- filter edges: T[l+1][k]·y[src] + MFMA seg-sum ------------
__global__ __launch_bounds__(256)
void filt_tab_k(int l, const float* __restrict__ ed_s, const int* __restrict__ src_s,
                const int* __restrict__ dst_s, const bf16* __restrict__ ybf,
                const bf16* __restrict__ Tb, float* __restrict__ msum) {
    __shared__ bf16 mvT[128][72];
    __shared__ int ddst[64], slot_s[64], distinct_s[64];
    __shared__ int nseg_s;
    int i0 = blockIdx.x * 64;
    int tid = threadIdx.x;
    seg_prep(dst_s, i0, tid, ddst, slot_s, distinct_s, &nseg_s);
    int row = tid & 63, c0 = (tid >> 6) * 32;
    int e = i0 + row;
    float pos = fminf(fmaxf(ed_s[e] * (float)(NK - 1) + 0.5f, 0.0f), (float)(NK - 1));
    int k = (int)pos;
    const bf8v* tp = (const bf8v*)(Tb + ((size_t)(l + 1) * NK + k) * HC + c0);
    bf8v tv[4];
    #pragma unroll
    for (int g = 0; g < 4; g++) tv[g] = tp[g];
    const bf8v* yp = (const bf8v*)(ybf + (size_t)src_s[e] * HC + c0);
    bf8v yv[4];
    #pragma unroll
    for (int g = 0; g < 4; g++) yv[g] = yp[g];
    #pragma unroll
    for (int g = 0; g < 4; g++)
        #pragma unroll
        for (int m = 0; m < 8; m++) {
            float v = s2f((unsigned short)tv[g][m]) * s2f((unsigned short)yv[g][m]);
            mvT[c0 + g * 8 + m][row] = f2b(v);
        }
    __syncthreads();
    seg_mfma(mvT, ddst, slot_s, distinct_s, nseg_s, msum, tid);
}

// ---- node update: msum@cW2 -> silu -> @lW + residual; zero msum; y=x@cW1[l+1]
__global__ __launch_bounds__(256)
void upd_mfma_k(float* msum, int l,
                const bf16* __restrict__ cw2p, const float* __restrict__ cb2cv,
                const bf16* __restrict__ lwp, const float* __restrict__ lbcv,
                const bf16* __restrict__ cw1p, int do_y,
                float* __restrict__ x, bf16* __restrict__ xb,
                bf16* __restrict__ ybf) {
    __shared__ bf16 srow[64][136];
    int tid = threadIdx.x;
    int wave = tid >> 6, lane = tid & 63, quad = lane >> 4, lc = lane & 15;
    int m0 = blockIdx.x * 64;
    bf8v azero = {0, 0, 0, 0, 0, 0, 0, 0};
    bf8v af[4];
    int arow = m0 + wave * 16 + lc;
    #pragma unroll
    for (int ks = 0; ks < 4; ks++) {
        if (arow < NATOMS) {
            const float* p = msum + (size_t)arow * HC + ks * 32 + quad * 8;
            bf8v f;
            #pragma unroll
            for (int j = 0; j < 8; j++) f[j] = f2s(p[j]);
            af[ks] = f;
        } else af[ks] = azero;
    }
    f4v zero = {0.f, 0.f, 0.f, 0.f};
    f4v acc[8];
    #pragma unroll
    for (int nt = 0; nt < 8; nt++) acc[nt] = zero;
    const bf16* c2b = cw2p + (size_t)l * 16384;
    #pragma unroll
    for (int nt = 0; nt < 8; nt++)
        #pragma unroll
        for (int ks = 0; ks < 4; ks++) {
            bf8v b = *(const bf8v*)(c2b + ((nt * 4 + ks) * 64 + lane) * 8);
            acc[nt] = MFMA(af[ks], b, acc[nt]);
        }
    float zdep = fminf(fabsf(acc[0][0]), 0.0f);
    if (arow < NATOMS) {
        f4v zv = {zdep, zdep, zdep, zdep};
        #pragma unroll
        for (int ks = 0; ks < 4; ks++) {
            *(f4v*)(msum + (size_t)arow * HC + ks * 32 + quad * 8) = zv;
            *(f4v*)(msum + (size_t)arow * HC + ks * 32 + quad * 8 + 4) = zv;
        }
    }
    #pragma unroll
    for (int nt = 0; nt < 8; nt++) {
        int n = nt * 16 + lc;
        float bb = cb2cv[l * HC + n];
        #pragma unroll
        for (int r = 0; r < 4; r++)
            srow[wave * 16 + quad * 4 + r][n] = f2b(silu(acc[nt][r] + bb));
    }
    __syncthreads();
    bf8v a2[4];
    #pragma unroll
    for (int ks = 0; ks < 4; ks++)
        a2[ks] = *(const bf8v*)&srow[wave * 16 + lc][ks * 32 + quad * 8];
    __syncthreads();
    f4v acc2[8];
    #pragma unroll
    for (int nt = 0; nt < 8; nt++) acc2[nt] = zero;
    const bf16* lwb = lwp + (size_t)l * 16384;
    #pragma unroll
    for (int nt = 0; nt < 8; nt++)
        #pragma unroll
        for (int ks = 0; ks < 4; ks++) {
            bf8v b = *(const bf8v*)(lwb + ((nt * 4 + ks) * 64 + lane) * 8);
            acc2[nt] = MFMA(a2[ks], b, acc2[nt]);
        }
    #pragma unroll
    for (int nt = 0; nt < 8; nt++) {
        int n = nt * 16 + lc;
        float bb = lbcv[l * HC + n];
        #pragma unroll
        for (int r = 0; r < 4; r++) {
            int row = m0 + wave * 16 + quad * 4 + r;
            float nv = 0.0f;
            if (row < NATOMS) {
                size_t o = (size_t)row * HC + n;
                nv = x[o] + acc2[nt][r] + bb;
                x[o] = nv;
                xb[o] = f2b(nv);
            }
            srow[wave * 16 + quad * 4 + r][n] = f2b(nv);
        }
    }
    if (do_y) {
        __syncthreads();
        bf8v a3[4];
        #pragma unroll
        for (int ks = 0; ks < 4; ks++)
            a3[ks] = *(const bf8v*)&srow[wave * 16 + lc][ks * 32 + quad * 8];
        f4v acc3[8];
        #pragma unroll
        for (int nt = 0; nt < 8; nt++) acc3[nt] = zero;
        const bf16* c1b = cw1p + (size_t)(l + 1) * 16384;
        #pragma unroll
        for (int nt = 0; nt < 8; nt++)
            #pragma unroll
            for (int ks = 0; ks < 4; ks++) {
                bf8v b = *(const bf8v*)(c1b + ((nt * 4 + ks) * 64 + lane) * 8);
                acc3[nt] = MFMA(a3[ks], b, acc3[nt]);
            }
        #pragma unroll
        for (int nt = 0; nt < 8; nt++) {
            int n = nt * 16 + lc;
            #pragma unroll
            for (int r = 0; r < 4; r++) {
                int row = m0 + wave * 16 + quad * 4 + r;
                if (row < NATOMS) ybf[(size_t)row * HC + n] = f2b(acc3[nt][r]);
            }
        }
    }
}

__global__ void out_k(const float* __restrict__ x, void* out, const int* flagp) {
    int i = blockIdx.x * 256 + threadIdx.x;
    if (i >= NATOMS * HC) return;
    if (flagp[1]) ((float*)out)[i] = x[i];
    else          ((bf16*)out)[i] = f2b(x[i]);
}

// ---------------- launch ----------------
extern "C" void kernel_launch(void* const* d_in, const int* in_sizes, int n_in,
                              void* d_out, int out_size, void* d_ws, size_t ws_size,
                              hipStream_t stream) {
    const int*  z      = (const int*) d_in[0];
    const void* pos    = d_in[1];
    const int*  ei     = (const int*) d_in[3];
    const void* emb    = d_in[4];
    const void* nbremb = d_in[5];
    const void* Wp     = d_in[6];
    const void* bp     = d_in[7];
    const void* Wc     = d_in[8];
    const void* bc     = d_in[9];
    const void* means  = d_in[10];
    const void* betas  = d_in[11];
    const void* W1     = d_in[12];
    const void* b1     = d_in[13];
    const void* W2     = d_in[14];
    const void* b2     = d_in[15];
    const void* cW1    = d_in[16];
    const void* cW2    = d_in[17];
    const void* cb2    = d_in[18];
    const void* lW     = d_in[19];
    const void* lb     = d_in[20];

    char* p = (char*)d_ws;
    auto alloc = [&](size_t bytes) { char* r = p; p += (bytes + 255) / 256 * 256; return r; };
    int*   flag    = (int*)  alloc(256);                       // adjacent with counts
    int*   counts  = (int*)  alloc((size_t)NATOMS * 4);
    int*   rowptr  = (int*)  alloc((size_t)(NATOMS + 1) * 4);
    int*   cursor  = (int*)  alloc((size_t)NATOMS * 4);
    int*   perm    = (int*)  alloc((size_t)NEDGES * 4);
    int*   src_s   = (int*)  alloc((size_t)NEDGES * 4);
    int*   dst_s   = (int*)  alloc((size_t)NEDGES * 4);
    float* ed_s    = (float*)alloc((size_t)NEDGES * 4);
    float* x       = (float*)alloc((size_t)NATOMS * HC * 4);
    bf16*  xb      = (bf16*) alloc((size_t)NATOMS * HC * 2);
    bf16*  ybf     = (bf16*) alloc((size_t)NATOMS * HC * 2);
    float* msum    = (float*)alloc((size_t)NATOMS * HC * 4);   // adjacent with msg
    float* msg     = (float*)alloc((size_t)NATOMS * HC * 4);
    bf16*  Tb      = (bf16*) alloc((size_t)(NLAY + 1) * NK * HC * 2);  // 14.7 MB
    bf16*  wpp     = (bf16*) alloc((size_t)8192 * 2);
    bf16*  wcp     = (bf16*) alloc((size_t)32768 * 2);
    bf16*  w1p     = (bf16*) alloc((size_t)NLAY * 8192 * 2);
    bf16*  w2p     = (bf16*) alloc((size_t)NLAY * 16384 * 2);
    bf16*  cw1p    = (bf16*) alloc((size_t)NLAY * 16384 * 2);
    bf16*  cw2p    = (bf16*) alloc((size_t)NLAY * 16384 * 2);
    bf16*  lwp     = (bf16*) alloc((size_t)NLAY * 16384 * 2);
    bf16*  nbrembbf= (bf16*) alloc((size_t)MAXZ_ * HC * 2);
    float* bpcv    = (float*)alloc((size_t)HC * 4);
    float* bccv    = (float*)alloc((size_t)HC * 4);
    float* b1cv    = (float*)alloc((size_t)NLAY * HC * 4);
    float* b2cv    = (float*)alloc((size_t)NLAY * HC * 4);
    float* cb2cv   = (float*)alloc((size_t)NLAY * HC * 4);
    float* lbcv    = (float*)alloc((size_t)NLAY * HC * 4);
    float* meanscv = (float*)alloc((size_t)RBF * 4);
    float* betascv = (float*)alloc((size_t)RBF * 4);

    const int EG = (NEDGES + 255) / 256;

    // one memset zeroes flag (256B-aligned) + counts (adjacent)
    hipMemsetAsync(flag, 0, 256 + ((size_t)NATOMS * 4 + 255) / 256 * 256, stream);
    probe_k<<<(NATOMS * 3 + 255) / 256, 256, 0, stream>>>(pos, NATOMS * 3, flag);
    setflag_k<<<1, 64, 0, stream>>>(flag);

    hist_k<<<EG, 256, 0, stream>>>(ei + NEDGES, counts);
    scan_k<<<1, 1024, 0, stream>>>(counts, rowptr, cursor);
    perm_k<<<EG, 256, 0, stream>>>(ei + NEDGES, cursor, perm);
    geom_k<<<EG, 256, 0, stream>>>(ei, pos, perm, flag, ed_s, src_s, dst_s);

    packall_k<<<300, 256, 0, stream>>>(Wp, Wc, W1, W2, cW1, cW2, lW, means, betas,
                                       bp, bc, b1, b2, cb2, lb, nbremb, flag,
                                       wpp, wcp, w1p, w2p, cw1p, cw2p, lwp,
                                       meanscv, betascv, bpcv, bccv, b1cv, b2cv,
                                       cb2cv, lbcv, nbrembbf);
    tabbuild_k<<<7 * (NK / 64), 256, 0, stream>>>(wpp, bpcv, w1p, b1cv, w2p, b2cv,
                                                  meanscv, betascv, Tb);

    // one memset covers msum + msg (contiguous allocations)
    hipMemsetAsync(msum, 0, (size_t)2 * NATOMS * HC * 4, stream);
    nbr_tab_k<<<EGRID, 256, 0, stream>>>(ed_s, src_s, dst_s, z, nbrembbf, Tb, msg);
    combine_k<<<YGRID, 256, 0, stream>>>(z, emb, msg, wcp, bccv, cw1p, flag, x, xb, ybf);

    for (int l = 0; l < NLAY; l++) {
        filt_tab_k<<<EGRID, 256, 0, stream>>>(l, ed_s, src_s, dst_s, ybf, Tb, msum);
        upd_mfma_k<<<YGRID, 256, 0, stream>>>(msum, l, cw2p, cb2cv, lwp, lbcv,
                                              cw1p, (l < NLAY - 1) ? 1 : 0, x, xb, ybf);
    }
    out_k<<<(NATOMS * HC + 255) / 256, 256, 0, stream>>>(x, d_out, flag);
}

// Round 11
// 487.501 us; speedup vs baseline: 18.4760x; 1.1246x over previous
//
#include <hip/hip_runtime.h>
#include <hip/hip_bf16.h>

// TorchMD_GN_Ext R11: distribution-tail cuts.
//  - upd: 32 rows/block (grid 313, wave->(rowband,colhalf)): 2x CU coverage,
//    half the per-wave MFMA chain. out_k fused into last upd.
//  - launch merges: probe->hist, setflag->scan, perm+geom merged (perm array
//    eliminated; geometry written directly at sorted slot). 21 dispatches.
//  - filt/nbr unchanged (at TA-request floor: 8x16B gathers/thread).

#define NATOMS 10000
#define NEDGES 320000
#define HC 128
#define RBF 50
#define NLAY 6
#define MAXZ_ 100
#define NK 8192
#define EGRID (NEDGES / 64)         // 5000
#define YGRID ((NATOMS + 63) / 64)  // 157
#define UGRID ((NATOMS + 31) / 32)  // 313

typedef __hip_bfloat16 bf16;
typedef __attribute__((ext_vector_type(8))) short bf8v;
typedef __attribute__((ext_vector_type(4))) float f4v;

__device__ __forceinline__ float b2f(bf16 v) { return __bfloat162float(v); }
__device__ __forceinline__ bf16  f2b(float v) { return __float2bfloat16(v); }
__device__ __forceinline__ short f2s(float v) { bf16 h = f2b(v); return *(short*)&h; }
__device__ __forceinline__ float s2f(unsigned short s) {
    return __int_as_float(((int)s) << 16);
}
__device__ __forceinline__ float silu(float v) {
    return v * __builtin_amdgcn_rcpf(1.0f + __expf(-v));
}

template<int ISF>
__device__ __forceinline__ float LD(const void* p, size_t i) {
    if (ISF) return ((const float*)p)[i];
    return b2f(((const bf16*)p)[i]);
}

__device__ __forceinline__ int clampN(int v) {
    return v < 0 ? 0 : (v >= NATOMS ? NATOMS - 1 : v);
}

// ---------------- hist + dtype probe (merged) ----------------
__global__ void histprobe_k(const int* __restrict__ dst, const void* pos,
                            int* __restrict__ counts, int* flag) {
    int i = blockIdx.x * 256 + threadIdx.x;
    if (i < NEDGES) atomicAdd(&counts[clampN(dst[i])], 1);
    if (i < NATOMS * 3) {
        float v = fabsf(b2f(((const bf16*)pos)[i]));
        if (v != v) v = 1e30f;
        atomicMax(flag, __float_as_int(v));
    }
}

// ---------------- scan (+setflag) ----------------
__global__ void scan_k(const int* __restrict__ counts, int* __restrict__ rowptr,
                       int* __restrict__ cursor, int* flag) {
    __shared__ int wsum[16];
    __shared__ int carry_s;
    __shared__ int chunktot;
    int tid = threadIdx.x, lane = tid & 63, w = tid >> 6;
    if (tid == 0) {
        carry_s = 0; rowptr[0] = 0;
        flag[1] = (__int_as_float(flag[0]) > 1.0e4f) ? 1 : 0;
    }
    __syncthreads();
    for (int base = 0; base < NATOMS; base += 1024) {
        int i = base + tid;
        int v = (i < NATOMS) ? counts[i] : 0;
        int s = v;
        #pragma unroll
        for (int off = 1; off < 64; off <<= 1) {
            int t = __shfl_up(s, off, 64);
            if (lane >= off) s += t;
        }
        if (lane == 63) wsum[w] = s;
        __syncthreads();
        if (w == 0 && lane < 16) {
            int t = wsum[lane];
            int si = t;
            #pragma unroll
            for (int off = 1; off < 16; off <<= 1) {
                int u = __shfl_up(si, off, 64);
                if (lane >= off) si += u;
            }
            wsum[lane] = si - t;
            if (lane == 15) chunktot = si;
        }
        __syncthreads();
        int carry = carry_s;
        if (i < NATOMS) {
            int inc = carry + wsum[w] + s;
            rowptr[i + 1] = inc;
            cursor[i] = inc - v;
        }
        __syncthreads();
        if (tid == 0) carry_s += chunktot;
        __syncthreads();
    }
}

// ---------------- perm + geometry (merged; perm array eliminated) ----------
template<int ISF>
__device__ void permgeom_body(const int* __restrict__ ei, const void* __restrict__ pos,
                              int* __restrict__ cursor,
                              float* __restrict__ ed_s, int* __restrict__ src_s,
                              int* __restrict__ dst_s) {
    int e = blockIdx.x * 256 + threadIdx.x;
    if (e >= NEDGES) return;
    int s = clampN(ei[e]);
    int t = clampN(ei[NEDGES + e]);
    int p = atomicAdd(&cursor[t], 1);
    float dx = LD<ISF>(pos, (size_t)s * 3 + 0) - LD<ISF>(pos, (size_t)t * 3 + 0);
    float dy = LD<ISF>(pos, (size_t)s * 3 + 1) - LD<ISF>(pos, (size_t)t * 3 + 1);
    float dz = LD<ISF>(pos, (size_t)s * 3 + 2) - LD<ISF>(pos, (size_t)t * 3 + 2);
    float d = sqrtf(dx * dx + dy * dy + dz * dz + 1e-12f);
    if (d != d) d = 1e30f;
    ed_s[p] = __expf(-d);
    src_s[p] = s;
    dst_s[p] = t;
}
__global__ void permgeom_k(const int* ei, const void* pos, int* cursor, const int* flagp,
                           float* ed_s, int* src_s, int* dst_s) {
    if (flagp[1]) permgeom_body<1>(ei, pos, cursor, ed_s, src_s, dst_s);
    else          permgeom_body<0>(ei, pos, cursor, ed_s, src_s, dst_s);
}

// ---------------- mega pack/convert ----------------
template<int ISF>
__device__ void packB_at(int t, const void* src, int K, int ksteps, size_t perLsrc,
                         size_t perLdst, int L, bf16* dst) {
    if (t >= L * 8 * ksteps * 64) return;
    int lane = t & 63;
    int t2 = t >> 6;
    int ks = t2 % ksteps;
    int t3 = t2 / ksteps;
    int nt = t3 & 7;
    int l  = t3 >> 3;
    int quad = lane >> 4, lc = lane & 15;
    int col = nt * 16 + lc;
    for (int j = 0; j < 8; j++) {
        int k = ks * 32 + quad * 8 + j;
        float v = (k < K) ? LD<ISF>(src, (size_t)l * perLsrc + (size_t)k * 128 + col) : 0.0f;
        dst[(size_t)l * perLdst + ((size_t)((nt * ksteps + ks) * 64 + lane)) * 8 + j] = f2b(v);
    }
}
template<int ISF>
__device__ void packB24_at(int t, const void* w2, const void* cw1, const void* cw2,
                           const void* lw, bf16* w2p, bf16* cw1p, bf16* cw2p, bf16* lwp) {
    if (t >= 24 * 8 * 4 * 64) return;
    int lane = t & 63;
    int t2 = t >> 6;
    int ks = t2 & 3;
    int t3 = t2 >> 2;
    int nt = t3 & 7;
    int m  = t3 >> 3;
    int which = m / NLAY, li = m % NLAY;
    const void* src = which == 0 ? w2 : which == 1 ? cw1 : which == 2 ? cw2 : lw;
    bf16* dst = which == 0 ? w2p : which == 1 ? cw1p : which == 2 ? cw2p : lwp;
    int quad = lane >> 4, lc = lane & 15;
    int col = nt * 16 + lc;
    #pragma unroll
    for (int j = 0; j < 8; j++) {
        int k = ks * 32 + quad * 8 + j;
        float v = LD<ISF>(src, (size_t)li * 16384 + (size_t)k * 128 + col);
        dst[(size_t)li * 16384 + ((size_t)((nt * 4 + ks) * 64 + lane)) * 8 + j] = f2b(v);
    }
}
template<int ISF>
__device__ void cvts_at(int i, const void* means, const void* betas, const void* bp,
                        const void* bc, const void* b1, const void* b2,
                        const void* cb2, const void* lb,
                        float* meanscv, float* betascv, float* bpcv, float* bccv,
                        float* b1cv, float* b2cv, float* cb2cv, float* lbcv) {
    if      (i < 50)   meanscv[i]        = LD<ISF>(means, i);
    else if (i < 100)  betascv[i - 50]   = LD<ISF>(betas, i - 50);
    else if (i < 228)  bpcv[i - 100]     = LD<ISF>(bp, i - 100);
    else if (i < 356)  bccv[i - 228]     = LD<ISF>(bc, i - 228);
    else if (i < 1124) b1cv[i - 356]     = LD<ISF>(b1, i - 356);
    else if (i < 1892) b2cv[i - 1124]    = LD<ISF>(b2, i - 1124);
    else if (i < 2660) cb2cv[i - 1892]   = LD<ISF>(cb2, i - 1892);
    else if (i < 3428) lbcv[i - 2660]    = LD<ISF>(lb, i - 2660);
}
template<int ISF>
__device__ void packall_body(const void* Wp, const void* Wc, const void* W1,
                             const void* W2, const void* cW1, const void* cW2,
                             const void* lW, const void* means, const void* betas,
                             const void* bp, const void* bc, const void* b1,
                             const void* b2, const void* cb2, const void* lb,
                             const void* nbremb,
                             bf16* wpp, bf16* wcp, bf16* w1p, bf16* w2p, bf16* cw1p,
                             bf16* cw2p, bf16* lwp, float* meanscv, float* betascv,
                             float* bpcv, float* bccv, float* b1cv, float* b2cv,
                             float* cb2cv, float* lbcv, bf16* nbrembbf) {
    int b = blockIdx.x, tid = threadIdx.x;
    if (b < 4)        packB_at<ISF>(b * 256 + tid, Wp, RBF, 2, 6400, 8192, 1, wpp);
    else if (b < 20)  packB_at<ISF>((b - 4) * 256 + tid, Wc, 256, 8, 32768, 32768, 1, wcp);
    else if (b < 44)  packB_at<ISF>((b - 20) * 256 + tid, W1, RBF, 2, 6400, 8192, NLAY, w1p);
    else if (b < 236) packB24_at<ISF>((b - 44) * 256 + tid, W2, cW1, cW2, lW,
                                      w2p, cw1p, cw2p, lwp);
    else if (b < 250) cvts_at<ISF>((b - 236) * 256 + tid, means, betas, bp, bc, b1, b2,
                                   cb2, lb, meanscv, betascv, bpcv, bccv,
                                   b1cv, b2cv, cb2cv, lbcv);
    else {
        int i = (b - 250) * 256 + tid;
        if (i < MAXZ_ * HC) nbrembbf[i] = f2b(LD<ISF>(nbremb, i));
    }
}
__global__ void packall_k(const void* Wp, const void* Wc, const void* W1,
                          const void* W2, const void* cW1, const void* cW2,
                          const void* lW, const void* means, const void* betas,
                          const void* bp, const void* bc, const void* b1,
                          const void* b2, const void* cb2, const void* lb,
                          const void* nbremb, const int* flagp,
                          bf16* wpp, bf16* wcp, bf16* w1p, bf16* w2p, bf16* cw1p,
                          bf16* cw2p, bf16* lwp, float* meanscv, float* betascv,
                          float* bpcv, float* bccv, float* b1cv, float* b2cv,
                          float* cb2cv, float* lbcv, bf16* nbrembbf) {
    if (flagp[1]) packall_body<1>(Wp, Wc, W1, W2, cW1, cW2, lW, means, betas, bp, bc,
                                  b1, b2, cb2, lb, nbremb, wpp, wcp, w1p, w2p, cw1p,
                                  cw2p, lwp, meanscv, betascv, bpcv, bccv, b1cv, b2cv,
                                  cb2cv, lbcv, nbrembbf);
    else          packall_body<0>(Wp, Wc, W1, W2, cW1, cW2, lW, means, betas, bp, bc,
                                  b1, b2, cb2, lb, nbremb, wpp, wcp, w1p, w2p, cw1p,
                                  cw2p, lwp, meanscv, betascv, bpcv, bccv, b1cv, b2cv,
                                  cb2cv, lbcv, nbrembbf);
}

// ---------------- MFMA helpers ----------------
#define MFMA(a, b, c) __builtin_amdgcn_mfma_f32_16x16x32_bf16((a), (b), (c), 0, 0, 0)

__device__ __forceinline__ void seg_prep(const int* __restrict__ dst_s, int i0, int tid,
                                         int* ddst, int* slot_s, int* distinct_s,
                                         int* nseg_s) {
    if (tid < 64) {
        int d = dst_s[i0 + tid];
        ddst[tid] = d;
        int dprev = __shfl_up(d, 1, 64);
        int flag = (tid == 0 || d != dprev) ? 1 : 0;
        int s = flag;
        #pragma unroll
        for (int off = 1; off < 64; off <<= 1) {
            int t = __shfl_up(s, off, 64);
            if (tid >= off) s += t;
        }
        slot_s[tid] = s - 1;
        if (flag) distinct_s[s - 1] = d;
        if (tid == 63) *nseg_s = s;
    }
}

__device__ __forceinline__ void seg_mfma(const bf16 (*mvT)[72], const int* ddst,
                                         const int* slot_s, const int* distinct_s,
                                         int nseg, float* __restrict__ out, int tid) {
    int wave = tid >> 6, lane = tid & 63, quad = lane >> 4, lc = lane & 15;
    if (nseg <= 16) {
        bf8v sa[2];
        #pragma unroll
        for (int ks = 0; ks < 2; ks++)
            #pragma unroll
            for (int j = 0; j < 8; j++) {
                int k = ks * 32 + quad * 8 + j;
                sa[ks][j] = (slot_s[k] == lc) ? (short)0x3F80 : (short)0;
            }
        f4v z4 = {0.f, 0.f, 0.f, 0.f};
        f4v sacc[2] = {z4, z4};
        #pragma unroll
        for (int nt = 0; nt < 2; nt++)
            #pragma unroll
            for (int ks = 0; ks < 2; ks++) {
                bf8v b = *(const bf8v*)&mvT[wave * 32 + nt * 16 + lc][ks * 32 + quad * 8];
                sacc[nt] = MFMA(sa[ks], b, sacc[nt]);
            }
        #pragma unroll
        for (int nt = 0; nt < 2; nt++)
            #pragma unroll
            for (int r = 0; r < 4; r++) {
                int sl = quad * 4 + r;
                if (sl < nseg) {
                    int atom = distinct_s[sl];
                    int n = wave * 32 + nt * 16 + lc;
                    float v = sacc[nt][r];
                    if (sl == 0 || sl == nseg - 1)
                        atomicAdd(&out[(size_t)atom * HC + n], v);
                    else
                        out[(size_t)atom * HC + n] = v;
                }
            }
    } else {
        int col = tid & 127;
        int base = (tid >> 7) * 32;
        int cur = ddst[base];
        float s = 0.0f;
        bool first = true;
        for (int e = base; e < base + 32; e++) {
            int dn = ddst[e];
            if (dn != cur) {
                if (first) atomicAdd(&out[(size_t)cur * HC + col], s);
                else out[(size_t)cur * HC + col] = s;
                first = false; cur = dn; s = 0.0f;
            }
            s += b2f(mvT[col][e]);
        }
        atomicAdd(&out[(size_t)cur * HC + col], s);
    }
}

// ---------------- table build ----------------
__global__ __launch_bounds__(256)
void tabbuild_k(const bf16* __restrict__ wpp, const float* __restrict__ bpcv,
                const bf16* __restrict__ w1p, const float* __restrict__ b1cv,
                const bf16* __restrict__ w2p, const float* __restrict__ b2cv,
                const float* __restrict__ meanscv, const float* __restrict__ betascv,
                bf16* __restrict__ Tb) {
    __shared__ bf16 hid[64][136];
    __shared__ float csh[64], edsh[64];
    int f = blockIdx.x >> 7, kb = blockIdx.x & 127;
    int base = kb * 64;
    int tid = threadIdx.x;
    int wave = tid >> 6, lane = tid & 63, quad = lane >> 4, lc = lane & 15;
    if (tid < 64) {
        float ed = (float)(base + tid) * (1.0f / (NK - 1));
        float d = -logf(fmaxf(ed, 1e-30f));
        float C = (d < 5.0f) ? 0.5f * (__cosf(d * 0.6283185307f) + 1.0f) : 0.0f;
        csh[tid] = C; edsh[tid] = ed;
    }
    __syncthreads();
    float edi = edsh[wave * 16 + lc], Ci = csh[wave * 16 + lc];
    bf8v af[2];
    #pragma unroll
    for (int ks = 0; ks < 2; ks++) {
        #pragma unroll
        for (int j = 0; j < 8; j++) {
            int r = ks * 32 + quad * 8 + j;
            float v = 0.0f;
            if (r < RBF) { float u = edi - meanscv[r]; v = Ci * __expf(-betascv[r] * u * u); }
            af[ks][j] = f2s(v);
        }
    }
    f4v zero = {0.f, 0.f, 0.f, 0.f};
    f4v acc[8];
    #pragma unroll
    for (int nt = 0; nt < 8; nt++) acc[nt] = zero;
    const bf16* w1b = (f == 0) ? wpp : w1p + (size_t)(f - 1) * 8192;
    #pragma unroll
    for (int nt = 0; nt < 8; nt++)
        #pragma unroll
        for (int ks = 0; ks < 2; ks++) {
            bf8v b = *(const bf8v*)(w1b + ((nt * 2 + ks) * 64 + lane) * 8);
            acc[nt] = MFMA(af[ks], b, acc[nt]);
        }
    if (f == 0) {
        #pragma unroll
        for (int nt = 0; nt < 8; nt++) {
            int n = nt * 16 + lc;
            float bb = bpcv[n];
            #pragma unroll
            for (int r = 0; r < 4; r++) {
                int row = wave * 16 + quad * 4 + r;
                Tb[(size_t)(base + row) * HC + n] = f2b((acc[nt][r] + bb) * csh[row]);
            }
        }
        return;
    }
    int l = f - 1;
    #pragma unroll
    for (int nt = 0; nt < 8; nt++) {
        int n = nt * 16 + lc;
        float bb = b1cv[l * HC + n];
        #pragma unroll
        for (int r = 0; r < 4; r++)
            hid[wave * 16 + quad * 4 + r][n] = f2b(silu(acc[nt][r] + bb));
    }
    __syncthreads();
    bf8v a2[4];
    #pragma unroll
    for (int ks = 0; ks < 4; ks++)
        a2[ks] = *(const bf8v*)&hid[wave * 16 + lc][ks * 32 + quad * 8];
    f4v acc2[8];
    #pragma unroll
    for (int nt = 0; nt < 8; nt++) acc2[nt] = zero;
    const bf16* w2b = w2p + (size_t)l * 16384;
    #pragma unroll
    for (int nt = 0; nt < 8; nt++)
        #pragma unroll
        for (int ks = 0; ks < 4; ks++) {
            bf8v b = *(const bf8v*)(w2b + ((nt * 4 + ks) * 64 + lane) * 8);
            acc2[nt] = MFMA(a2[ks], b, acc2[nt]);
        }
    #pragma unroll
    for (int nt = 0; nt < 8; nt++) {
        int n = nt * 16 + lc;
        float bb = b2cv[l * HC + n];
        #pragma unroll
        for (int r = 0; r < 4; r++) {
            int row = wave * 16 + quad * 4 + r;
            Tb[((size_t)f * NK + base + row) * HC + n] = f2b((acc2[nt][r] + bb) * csh[row]);
        }
    }
}

// ---------------- neighbor edges ----------------
__global__ __launch_bounds__(256)
void nbr_tab_k(const float* __restrict__ ed_s, const int* __restrict__ src_s,
               const int* __restrict__ dst_s, const int* __restrict__ z,
               const bf16* __restrict__ nbrembbf, const bf16* __restrict__ Tb,
               float* __restrict__ msg) {
    __shared__ bf16 mvT[128][72];
    __shared__ int ddst[64], slot_s[64], distinct_s[64];
    __shared__ int nseg_s;
    int i0 = blockIdx.x * 64;
    int tid = threadIdx.x;
    seg_prep(dst_s, i0, tid, ddst, slot_s, distinct_s, &nseg_s);
    int row = tid & 63, c0 = (tid >> 6) * 32;
    int e = i0 + row;
    int s = src_s[e];
    float msk = (s != dst_s[e]) ? 1.0f : 0.0f;
    float pos = fminf(fmaxf(ed_s[e] * (float)(NK - 1) + 0.5f, 0.0f), (float)(NK - 1));
    int k = (int)pos;
    const bf8v* tp = (const bf8v*)(Tb + (size_t)k * HC + c0);
    bf8v tv[4];
    #pragma unroll
    for (int g = 0; g < 4; g++) tv[g] = tp[g];
    int zz = z[s]; zz = zz < 0 ? 0 : (zz >= MAXZ_ ? MAXZ_ - 1 : zz);
    const bf8v* ep = (const bf8v*)(nbrembbf + (size_t)zz * HC + c0);
    bf8v ev[4];
    #pragma unroll
    for (int g = 0; g < 4; g++) ev[g] = ep[g];
    #pragma unroll
    for (int g = 0; g < 4; g++)
        #pragma unroll
        for (int m = 0; m < 8; m++) {
            float v = s2f((unsigned short)tv[g][m]) * msk *
                      s2f((unsigned short)ev[g][m]);
            mvT[c0 + g * 8 + m][row] = f2b(v);
        }
    __syncthreads();
    seg_mfma(mvT, ddst, slot_s, distinct_s, nseg_s, msg, tid);
}

// ---------------- combine (prep fused) ----------------
template<int ISF>
__device__ void combine_body(const int* __restrict__ z, const void* __restrict__ emb,
                             const float* __restrict__ msg, const bf16* __restrict__ wcp,
                             const float* __restrict__ bccv, const bf16* __restrict__ cw1b,
                             float* __restrict__ x, bf16* __restrict__ xb,
                             bf16* __restrict__ ybf) {
    __shared__ bf16 srow[64][136];
    int tid = threadIdx.x;
    int wave = tid >> 6, lane = tid & 63, quad = lane >> 4, lc = lane & 15;
    int m0 = blockIdx.x * 64;
    int arow = m0 + wave * 16 + lc;
    int rowc = arow < NATOMS ? arow : NATOMS - 1;
    int zz = z[rowc]; zz = zz < 0 ? 0 : (zz >= MAXZ_ ? MAXZ_ - 1 : zz);
    bf8v af[8];
    #pragma unroll
    for (int ks = 0; ks < 4; ks++)
        #pragma unroll
        for (int j = 0; j < 8; j++)
            af[ks][j] = f2s(LD<ISF>(emb, (size_t)zz * HC + ks * 32 + quad * 8 + j));
    #pragma unroll
    for (int ks = 4; ks < 8; ks++) {
        const float* mp = msg + (size_t)rowc * HC + (ks - 4) * 32 + quad * 8;
        #pragma unroll
        for (int j = 0; j < 8; j++) af[ks][j] = f2s(mp[j]);
    }
    f4v zero = {0.f, 0.f, 0.f, 0.f};
    f4v acc[8];
    #pragma unroll
    for (int nt = 0; nt < 8; nt++) acc[nt] = zero;
    #pragma unroll
    for (int nt = 0; nt < 8; nt++)
        #pragma unroll
        for (int ks = 0; ks < 8; ks++) {
            bf8v b = *(const bf8v*)(wcp + ((nt * 8 + ks) * 64 + lane) * 8);
            acc[nt] = MFMA(af[ks], b, acc[nt]);
        }
    #pragma unroll
    for (int nt = 0; nt < 8; nt++) {
        int n = nt * 16 + lc;
        float bb = bccv[n];
        #pragma unroll
        for (int r = 0; r < 4; r++) {
            int row = m0 + wave * 16 + quad * 4 + r;
            float v = acc[nt][r] + bb;
            bf16 vb = f2b(v);
            srow[wave * 16 + quad * 4 + r][n] = vb;
            if (row < NATOMS) {
                x[(size_t)row * HC + n] = v;
                xb[(size_t)row * HC + n] = vb;
            }
        }
    }
    __syncthreads();
    bf8v a3[4];
    #pragma unroll
    for (int ks = 0; ks < 4; ks++)
        a3[ks] = *(const bf8v*)&srow[wave * 16 + lc][ks * 32 + quad * 8];
    f4v acc3[8];
    #pragma unroll
    for (int nt = 0; nt < 8; nt++) acc3[nt] = zero;
    #pragma unroll
    for (int nt = 0; nt < 8; nt++)
        #pragma unroll
        for (int ks = 0; ks < 4; ks++) {
            bf8v b = *(const bf8v*)(cw1b + ((nt * 4 + ks) * 64 + lane) * 8);
            acc3[nt] = MFMA(a3[ks], b, acc3[nt]);
        }
    #pragma unroll
    for (int nt = 0; nt < 8; nt++) {
        int n = nt * 16 + lc;
        #pragma unroll
        for (int r = 0; r < 4; r++) {
            int row = m0 + wave * 16 + quad * 4 + r;
            if (row < NATOMS) ybf[(size_t)row * HC + n] = f2b(acc3[nt][r]);
        }
    }
}
__global__ __launch_bounds__(256)
void combine_k(const int* z, const void* emb, const float* msg, const bf16* wcp,
               const float* bccv, const bf16* cw1b, const int* flagp,
               float* x, bf16* xb, bf16* ybf) {
    if (flagp[1]) combine_body<1>(z, emb, msg, wcp, bccv, cw1b, x, xb, ybf);
    else          combine_body<0>(z, emb, msg, wcp, bccv, cw1b, x, xb, ybf);
}

// ---------------- filter edges ----------------
__global__ __launch_bounds__(256)
void filt_tab_k(int l, const float* __restrict__ ed_s, const int* __restrict__ src_s,
                const int* __restrict__ dst_s, const bf16* __restrict__ ybf,
                const bf16* __restrict__ Tb, float* __restrict__ msum) {
    __shared__ bf16 mvT[128][72];
    __shared__ int ddst[64], slot_s[64], distinct_s[64];
    __shared__ int nseg_s;
    int i0 = blockIdx.x * 64;
    int tid = threadIdx.x;
    seg_prep(dst_s, i0, tid, ddst, slot_s, distinct_s, &nseg_s);
    int row = tid & 63, c0 = (tid >> 6) * 32;
    int e = i0 + row;
    float pos = fminf(fmaxf(ed_s[e] * (float)(NK - 1) + 0.5f, 0.0f), (float)(NK - 1));
    int k = (int)pos;
    const bf8v* tp = (const bf8v*)(Tb + ((size_t)(l + 1) * NK + k) * HC + c0);
    bf8v tv[4];
    #pragma unroll
    for (int g = 0; g < 4; g++) tv[g] = tp[g];
    const bf8v* yp = (const bf8v*)(ybf + (size_t)src_s[e] * HC + c0);
    bf8v yv[4];
    #pragma unroll
    for (int g = 0; g < 4; g++) yv[g] = yp[g];
    #pragma unroll
    for (int g = 0; g < 4; g++)
        #pragma unroll
        for (int m = 0; m < 8; m++) {
            float v = s2f((unsigned short)tv[g][m]) * s2f((unsigned short)yv[g][m]);
            mvT[c0 + g * 8 + m][row] = f2b(v);
        }
    __syncthreads();
    seg_mfma(mvT, ddst, slot_s, distinct_s, nseg_s, msum, tid);
}

// ---- node update, 32 rows/block: wave -> (rowband rb, colhalf ch) ----------
// GEMM1 msum@cW2 -> silu -> GEMM2 @lW + residual; zero msum; y=x@cW1[l+1];
// last layer writes d_out directly (out_k fused).
__global__ __launch_bounds__(256)
void upd_mfma_k(float* msum, int l,
                const bf16* __restrict__ cw2p, const float* __restrict__ cb2cv,
                const bf16* __restrict__ lwp, const float* __restrict__ lbcv,
                const bf16* __restrict__ cw1p, int do_y, int last,
                float* __restrict__ x, bf16* __restrict__ xb,
                bf16* __restrict__ ybf, void* out, const int* flagp) {
    __shared__ bf16 srow[32][136];
    int tid = threadIdx.x;
    int wave = tid >> 6, lane = tid & 63, quad = lane >> 4, lc = lane & 15;
    int rb = wave >> 1, ch = wave & 1;
    int m0 = blockIdx.x * 32 + rb * 16;
    bf8v azero = {0, 0, 0, 0, 0, 0, 0, 0};
    bf8v af[4];
    int arow = m0 + lc;
    #pragma unroll
    for (int ks = 0; ks < 4; ks++) {
        if (arow < NATOMS) {
            const float* p = msum + (size_t)arow * HC + ks * 32 + quad * 8;
            bf8v f;
            #pragma unroll
            for (int j = 0; j < 8; j++) f[j] = f2s(p[j]);
            af[ks] = f;
        } else af[ks] = azero;
    }
    f4v zero = {0.f, 0.f, 0.f, 0.f};
    f4v acc[4];
    #pragma unroll
    for (int nt = 0; nt < 4; nt++) acc[nt] = zero;
    const bf16* c2b = cw2p + (size_t)l * 16384;
    #pragma unroll
    for (int nt = 0; nt < 4; nt++)
        #pragma unroll
        for (int ks = 0; ks < 4; ks++) {
            bf8v b = *(const bf8v*)(c2b + (((ch * 4 + nt) * 4 + ks) * 64 + lane) * 8);
            acc[nt] = MFMA(af[ks], b, acc[nt]);
        }
    #pragma unroll
    for (int nt = 0; nt < 4; nt++) {
        int n = ch * 64 + nt * 16 + lc;
        float bb = cb2cv[l * HC + n];
        #pragma unroll
        for (int r = 0; r < 4; r++)
            srow[rb * 16 + quad * 4 + r][n] = f2b(silu(acc[nt][r] + bb));
    }
    __syncthreads();   // all af loads + srow writes complete
    // zero msum for next layer (ch==0 waves only; safe: all loads are done)
    if (ch == 0 && arow < NATOMS) {
        float zdep = fminf(fabsf(acc[0][0]), 0.0f);   // = 0, data-dep on loads
        f4v zv = {zdep, zdep, zdep, zdep};
        #pragma unroll
        for (int ks = 0; ks < 4; ks++) {
            *(f4v*)(msum + (size_t)arow * HC + ks * 32 + quad * 8) = zv;
            *(f4v*)(msum + (size_t)arow * HC + ks * 32 + quad * 8 + 4) = zv;
        }
    }
    bf8v a2[4];
    #pragma unroll
    for (int ks = 0; ks < 4; ks++)
        a2[ks] = *(const bf8v*)&srow[rb * 16 + lc][ks * 32 + quad * 8];
    __syncthreads();   // a2 reads done before srow overwritten with xnew
    f4v acc2[4];
    #pragma unroll
    for (int nt = 0; nt < 4; nt++) acc2[nt] = zero;
    const bf16* lwb = lwp + (size_t)l * 16384;
    #pragma unroll
    for (int nt = 0; nt < 4; nt++)
        #pragma unroll
        for (int ks = 0; ks < 4; ks++) {
            bf8v b = *(const bf8v*)(lwb + (((ch * 4 + nt) * 4 + ks) * 64 + lane) * 8);
            acc2[nt] = MFMA(a2[ks], b, acc2[nt]);
        }
    int isf = flagp[1];
    #pragma unroll
    for (int nt = 0; nt < 4; nt++) {
        int n = ch * 64 + nt * 16 + lc;
        float bb = lbcv[l * HC + n];
        #pragma unroll
        for (int r = 0; r < 4; r++) {
            int row = m0 + quad * 4 + r;
            float nv = 0.0f;
            if (row < NATOMS) {
                size_t o = (size_t)row * HC + n;
                nv = x[o] + acc2[nt][r] + bb;
                if (!last) {
                    x[o] = nv;
                    xb[o] = f2b(nv);
                } else {
                    if (isf) ((float*)out)[o] = nv;
                    else     ((bf16*)out)[o] = f2b(nv);
                }
            }
            srow[rb * 16 + quad * 4 + r][n] = f2b(nv);
        }
    }
    if (do_y) {
        __syncthreads();
        bf8v a3[4];
        #pragma unroll
        for (int ks = 0; ks < 4; ks++)
            a3[ks] = *(const bf8v*)&srow[rb * 16 + lc][ks * 32 + quad * 8];
        f4v acc3[4];
        #pragma unroll
        for (int nt = 0; nt < 4; nt++) acc3[nt] = zero;
        const bf16* c1b = cw1p + (size_t)(l + 1) * 16384;
        #pragma unroll
        for (int nt = 0; nt < 4; nt++)
            #pragma unroll
            for (int ks = 0; ks < 4; ks++) {
                bf8v b = *(const bf8v*)(c1b + (((ch * 4 + nt) * 4 + ks) * 64 + lane) * 8);
                acc3[nt] = MFMA(a3[ks], b, acc3[nt]);
            }
        #pragma unroll
        for (int nt = 0; nt < 4; nt++) {
            int n = ch * 64 + nt * 16 + lc;
            #pragma unroll
            for (int r = 0; r < 4; r++) {
                int row = m0 + quad * 4 + r;
                if (row < NATOMS) ybf[(size_t)row * HC + n] = f2b(acc3[nt][r]);
            }
        }
    }
}

// ---------------- launch ----------------
extern "C" void kernel_launch(void* const* d_in, const int* in_sizes, int n_in,
                              void* d_out, int out_size, void* d_ws, size_t ws_size,
                              hipStream_t stream) {
    const int*  z      = (const int*) d_in[0];
    const void* pos    = d_in[1];
    const int*  ei     = (const int*) d_in[3];
    const void* emb    = d_in[4];
    const void* nbremb = d_in[5];
    const void* Wp     = d_in[6];
    const void* bp     = d_in[7];
    const void* Wc     = d_in[8];
    const void* bc     = d_in[9];
    const void* means  = d_in[10];
    const void* betas  = d_in[11];
    const void* W1     = d_in[12];
    const void* b1     = d_in[13];
    const void* W2     = d_in[14];
    const void* b2     = d_in[15];
    const void* cW1    = d_in[16];
    const void* cW2    = d_in[17];
    const void* cb2    = d_in[18];
    const void* lW     = d_in[19];
    const void* lb     = d_in[20];

    char* p = (char*)d_ws;
    auto alloc = [&](size_t bytes) { char* r = p; p += (bytes + 255) / 256 * 256; return r; };
    int*   flag    = (int*)  alloc(256);                       // adjacent with counts
    int*   counts  = (int*)  alloc((size_t)NATOMS * 4);
    int*   rowptr  = (int*)  alloc((size_t)(NATOMS + 1) * 4);
    int*   cursor  = (int*)  alloc((size_t)NATOMS * 4);
    int*   src_s   = (int*)  alloc((size_t)NEDGES * 4);
    int*   dst_s   = (int*)  alloc((size_t)NEDGES * 4);
    float* ed_s    = (float*)alloc((size_t)NEDGES * 4);
    float* x       = (float*)alloc((size_t)NATOMS * HC * 4);
    bf16*  xb      = (bf16*) alloc((size_t)NATOMS * HC * 2);
    bf16*  ybf     = (bf16*) alloc((size_t)NATOMS * HC * 2);
    float* msum    = (float*)alloc((size_t)NATOMS * HC * 4);   // adjacent with msg
    float* msg     = (float*)alloc((size_t)NATOMS * HC * 4);
    bf16*  Tb      = (bf16*) alloc((size_t)(NLAY + 1) * NK * HC * 2);  // 14.7 MB
    bf16*  wpp     = (bf16*) alloc((size_t)8192 * 2);
    bf16*  wcp     = (bf16*) alloc((size_t)32768 * 2);
    bf16*  w1p     = (bf16*) alloc((size_t)NLAY * 8192 * 2);
    bf16*  w2p     = (bf16*) alloc((size_t)NLAY * 16384 * 2);
    bf16*  cw1p    = (bf16*) alloc((size_t)NLAY * 16384 * 2);
    bf16*  cw2p    = (bf16*) alloc((size_t)NLAY * 16384 * 2);
    bf16*  lwp     = (bf16*) alloc((size_t)NLAY * 16384 * 2);
    bf16*  nbrembbf= (bf16*) alloc((size_t)MAXZ_ * HC * 2);
    float* bpcv    = (float*)alloc((size_t)HC * 4);
    float* bccv    = (float*)alloc((size_t)HC * 4);
    float* b1cv    = (float*)alloc((size_t)NLAY * HC * 4);
    float* b2cv    = (float*)alloc((size_t)NLAY * HC * 4);
    float* cb2cv   = (float*)alloc((size_t)NLAY * HC * 4);
    float* lbcv    = (float*)alloc((size_t)NLAY * HC * 4);
    float* meanscv = (float*)alloc((size_t)RBF * 4);
    float* betascv = (float*)alloc((size_t)RBF * 4);

    const int EG = (NEDGES + 255) / 256;

    hipMemsetAsync(flag, 0, 256 + ((size_t)NATOMS * 4 + 255) / 256 * 256, stream);
    histprobe_k<<<EG, 256, 0, stream>>>(ei + NEDGES, pos, counts, flag);
    scan_k<<<1, 1024, 0, stream>>>(counts, rowptr, cursor, flag);
    permgeom_k<<<EG, 256, 0, stream>>>(ei, pos, cursor, flag, ed_s, src_s, dst_s);

    packall_k<<<300, 256, 0, stream>>>(Wp, Wc, W1, W2, cW1, cW2, lW, means, betas,
                                       bp, bc, b1, b2, cb2, lb, nbremb, flag,
                                       wpp, wcp, w1p, w2p, cw1p, cw2p, lwp,
                                       meanscv, betascv, bpcv, bccv, b1cv, b2cv,
                                       cb2cv, lbcv, nbrembbf);
    tabbuild_k<<<7 * (NK / 64), 256, 0, stream>>>(wpp, bpcv, w1p, b1cv, w2p, b2cv,
                                                  meanscv, betascv, Tb);

    hipMemsetAsync(msum, 0, (size_t)2 * NATOMS * HC * 4, stream);
    nbr_tab_k<<<EGRID, 256, 0, stream>>>(ed_s, src_s, dst_s, z, nbrembbf, Tb, msg);
    combine_k<<<YGRID, 256, 0, stream>>>(z, emb, msg, wcp, bccv, cw1p, flag, x, xb, ybf);

    for (int l = 0; l < NLAY; l++) {
        filt_tab_k<<<EGRID, 256, 0, stream>>>(l, ed_s, src_s, dst_s, ybf, Tb, msum);
        int lastl = (l == NLAY - 1) ? 1 : 0;
        upd_mfma_k<<<UGRID, 256, 0, stream>>>(msum, l, cw2p, cb2cv, lwp, lbcv,
                                              cw1p, lastl ? 0 : 1, lastl,
                                              x, xb, ybf, d_out, flag);
    }
}

// Round 12
// 368.102 us; speedup vs baseline: 24.4689x; 1.3244x over previous
//
#include <hip/hip_runtime.h>
#include <hip/hip_bf16.h>

// TorchMD_GN_Ext R12: ACTIVE-EDGE COMPACTION.
// C(d)=0 for d>=5 makes ~71% of edges contribute exactly zero (pos=randn*3,
// P(d<5)=F_chi3(5/4.243)~0.29). CSR build now keeps only active edges;
// pad slots get {dst=N-1, src=0, ed=0} (ed=0 -> table row 0 -> zero product,
// pads always the last segment -> atomicAdd of 0). Edge kernels early-exit
// blocks past Eact=rowptr[N]; grid stays worst-case-correct (exact even if
// all edges active). Everything else unchanged from R11.

#define NATOMS 10000
#define NEDGES 320000
#define HC 128
#define RBF 50
#define NLAY 6
#define MAXZ_ 100
#define NK 8192
#define EGRID (NEDGES / 64)         // 5000 (worst case; blocks early-exit)
#define YGRID ((NATOMS + 63) / 64)  // 157
#define UGRID ((NATOMS + 31) / 32)  // 313

typedef __hip_bfloat16 bf16;
typedef __attribute__((ext_vector_type(8))) short bf8v;
typedef __attribute__((ext_vector_type(4))) float f4v;

__device__ __forceinline__ float b2f(bf16 v) { return __bfloat162float(v); }
__device__ __forceinline__ bf16  f2b(float v) { return __float2bfloat16(v); }
__device__ __forceinline__ short f2s(float v) { bf16 h = f2b(v); return *(short*)&h; }
__device__ __forceinline__ float s2f(unsigned short s) {
    return __int_as_float(((int)s) << 16);
}
__device__ __forceinline__ float silu(float v) {
    return v * __builtin_amdgcn_rcpf(1.0f + __expf(-v));
}

template<int ISF>
__device__ __forceinline__ float LD(const void* p, size_t i) {
    if (ISF) return ((const float*)p)[i];
    return b2f(((const bf16*)p)[i]);
}

__device__ __forceinline__ int clampN(int v) {
    return v < 0 ? 0 : (v >= NATOMS ? NATOMS - 1 : v);
}

// edge distance (shared by hist + permgeom; identical ops => identical result)
template<int ISF>
__device__ __forceinline__ float edge_d(const int* __restrict__ ei,
                                        const void* __restrict__ pos, int e,
                                        int* sOut, int* tOut) {
    int s = clampN(ei[e]);
    int t = clampN(ei[NEDGES + e]);
    *sOut = s; *tOut = t;
    float dx = LD<ISF>(pos, (size_t)s * 3 + 0) - LD<ISF>(pos, (size_t)t * 3 + 0);
    float dy = LD<ISF>(pos, (size_t)s * 3 + 1) - LD<ISF>(pos, (size_t)t * 3 + 1);
    float dz = LD<ISF>(pos, (size_t)s * 3 + 2) - LD<ISF>(pos, (size_t)t * 3 + 2);
    float d = sqrtf(dx * dx + dy * dy + dz * dz + 1e-12f);
    if (d != d) d = 1e30f;
    return d;
}

// ---------------- dtype probe ----------------
__global__ void probe_k(const void* pos, int* flag) {
    int i = blockIdx.x * 256 + threadIdx.x;
    float v = 0.0f;
    if (i < NATOMS * 3) {
        v = fabsf(b2f(((const bf16*)pos)[i]));
        if (v != v) v = 1e30f;
    }
    atomicMax(flag, __float_as_int(v));
}
__global__ void setflag_k(int* flag) {
    if (threadIdx.x == 0) flag[1] = (__int_as_float(flag[0]) > 1.0e4f) ? 1 : 0;
}

// ---------------- histogram of ACTIVE (d<5) edges ----------------
template<int ISF>
__device__ void histd_body(const int* __restrict__ ei, const void* __restrict__ pos,
                           int* __restrict__ counts) {
    int e = blockIdx.x * 256 + threadIdx.x;
    if (e >= NEDGES) return;
    int s, t;
    float d = edge_d<ISF>(ei, pos, e, &s, &t);
    if (d < 5.0f) atomicAdd(&counts[t], 1);
}
__global__ void histd_k(const int* ei, const void* pos, const int* flagp,
                        int* counts) {
    if (flagp[1]) histd_body<1>(ei, pos, counts);
    else          histd_body<0>(ei, pos, counts);
}

// ---------------- scan ----------------
__global__ void scan_k(const int* __restrict__ counts, int* __restrict__ rowptr,
                       int* __restrict__ cursor) {
    __shared__ int wsum[16];
    __shared__ int carry_s;
    __shared__ int chunktot;
    int tid = threadIdx.x, lane = tid & 63, w = tid >> 6;
    if (tid == 0) { carry_s = 0; rowptr[0] = 0; }
    __syncthreads();
    for (int base = 0; base < NATOMS; base += 1024) {
        int i = base + tid;
        int v = (i < NATOMS) ? counts[i] : 0;
        int s = v;
        #pragma unroll
        for (int off = 1; off < 64; off <<= 1) {
            int t = __shfl_up(s, off, 64);
            if (lane >= off) s += t;
        }
        if (lane == 63) wsum[w] = s;
        __syncthreads();
        if (w == 0 && lane < 16) {
            int t = wsum[lane];
            int si = t;
            #pragma unroll
            for (int off = 1; off < 16; off <<= 1) {
                int u = __shfl_up(si, off, 64);
                if (lane >= off) si += u;
            }
            wsum[lane] = si - t;
            if (lane == 15) chunktot = si;
        }
        __syncthreads();
        int carry = carry_s;
        if (i < NATOMS) {
            int inc = carry + wsum[w] + s;
            rowptr[i + 1] = inc;
            cursor[i] = inc - v;
        }
        __syncthreads();
        if (tid == 0) carry_s += chunktot;
        __syncthreads();
    }
}

// ---------------- perm + geometry (active edges only) ----------------
template<int ISF>
__device__ void permgeom_body(const int* __restrict__ ei, const void* __restrict__ pos,
                              int* __restrict__ cursor,
                              float* __restrict__ ed_s, int* __restrict__ src_s,
                              int* __restrict__ dst_s) {
    int e = blockIdx.x * 256 + threadIdx.x;
    if (e >= NEDGES) return;
    int s, t;
    float d = edge_d<ISF>(ei, pos, e, &s, &t);
    if (d >= 5.0f) return;                  // dead edge: contributes exactly 0
    int p = atomicAdd(&cursor[t], 1);
    ed_s[p] = __expf(-d);
    src_s[p] = s;
    dst_s[p] = t;
}
__global__ void permgeom_k(const int* ei, const void* pos, int* cursor, const int* flagp,
                           float* ed_s, int* src_s, int* dst_s) {
    if (flagp[1]) permgeom_body<1>(ei, pos, cursor, ed_s, src_s, dst_s);
    else          permgeom_body<0>(ei, pos, cursor, ed_s, src_s, dst_s);
}

// ---------------- pad dead slots [Eact, E) ----------------
__global__ void pad_k(const int* __restrict__ rowptr, float* __restrict__ ed_s,
                      int* __restrict__ src_s, int* __restrict__ dst_s) {
    int i = blockIdx.x * 256 + threadIdx.x;
    if (i >= NEDGES) return;
    int Eact = rowptr[NATOMS];
    if (i >= Eact) {
        ed_s[i] = 0.0f;          // k=0 -> d=inf -> C=0 -> zero table row
        src_s[i] = 0;
        dst_s[i] = NATOMS - 1;   // pads always tail segment -> atomicAdd of 0
    }
}

// ---------------- mega pack/convert ----------------
template<int ISF>
__device__ void packB_at(int t, const void* src, int K, int ksteps, size_t perLsrc,
                         size_t perLdst, int L, bf16* dst) {
    if (t >= L * 8 * ksteps * 64) return;
    int lane = t & 63;
    int t2 = t >> 6;
    int ks = t2 % ksteps;
    int t3 = t2 / ksteps;
    int nt = t3 & 7;
    int l  = t3 >> 3;
    int quad = lane >> 4, lc = lane & 15;
    int col = nt * 16 + lc;
    for (int j = 0; j < 8; j++) {
        int k = ks * 32 + quad * 8 + j;
        float v = (k < K) ? LD<ISF>(src, (size_t)l * perLsrc + (size_t)k * 128 + col) : 0.0f;
        dst[(size_t)l * perLdst + ((size_t)((nt * ksteps + ks) * 64 + lane)) * 8 + j] = f2b(v);
    }
}
template<int ISF>
__device__ void packB24_at(int t, const void* w2, const void* cw1, const void* cw2,
                           const void* lw, bf16* w2p, bf16* cw1p, bf16* cw2p, bf16* lwp) {
    if (t >= 24 * 8 * 4 * 64) return;
    int lane = t & 63;
    int t2 = t >> 6;
    int ks = t2 & 3;
    int t3 = t2 >> 2;
    int nt = t3 & 7;
    int m  = t3 >> 3;
    int which = m / NLAY, li = m % NLAY;
    const void* src = which == 0 ? w2 : which == 1 ? cw1 : which == 2 ? cw2 : lw;
    bf16* dst = which == 0 ? w2p : which == 1 ? cw1p : which == 2 ? cw2p : lwp;
    int quad = lane >> 4, lc = lane & 15;
    int col = nt * 16 + lc;
    #pragma unroll
    for (int j = 0; j < 8; j++) {
        int k = ks * 32 + quad * 8 + j;
        float v = LD<ISF>(src, (size_t)li * 16384 + (size_t)k * 128 + col);
        dst[(size_t)li * 16384 + ((size_t)((nt * 4 + ks) * 64 + lane)) * 8 + j] = f2b(v);
    }
}
template<int ISF>
__device__ void cvts_at(int i, const void* means, const void* betas, const void* bp,
                        const void* bc, const void* b1, const void* b2,
                        const void* cb2, const void* lb,
                        float* meanscv, float* betascv, float* bpcv, float* bccv,
                        float* b1cv, float* b2cv, float* cb2cv, float* lbcv) {
    if      (i < 50)   meanscv[i]        = LD<ISF>(means, i);
    else if (i < 100)  betascv[i - 50]   = LD<ISF>(betas, i - 50);
    else if (i < 228)  bpcv[i - 100]     = LD<ISF>(bp, i - 100);
    else if (i < 356)  bccv[i - 228]     = LD<ISF>(bc, i - 228);
    else if (i < 1124) b1cv[i - 356]     = LD<ISF>(b1, i - 356);
    else if (i < 1892) b2cv[i - 1124]    = LD<ISF>(b2, i - 1124);
    else if (i < 2660) cb2cv[i - 1892]   = LD<ISF>(cb2, i - 1892);
    else if (i < 3428) lbcv[i - 2660]    = LD<ISF>(lb, i - 2660);
}
template<int ISF>
__device__ void packall_body(const void* Wp, const void* Wc, const void* W1,
                             const void* W2, const void* cW1, const void* cW2,
                             const void* lW, const void* means, const void* betas,
                             const void* bp, const void* bc, const void* b1,
                             const void* b2, const void* cb2, const void* lb,
                             const void* nbremb,
                             bf16* wpp, bf16* wcp, bf16* w1p, bf16* w2p, bf16* cw1p,
                             bf16* cw2p, bf16* lwp, float* meanscv, float* betascv,
                             float* bpcv, float* bccv, float* b1cv, float* b2cv,
                             float* cb2cv, float* lbcv, bf16* nbrembbf) {
    int b = blockIdx.x, tid = threadIdx.x;
    if (b < 4)        packB_at<ISF>(b * 256 + tid, Wp, RBF, 2, 6400, 8192, 1, wpp);
    else if (b < 20)  packB_at<ISF>((b - 4) * 256 + tid, Wc, 256, 8, 32768, 32768, 1, wcp);
    else if (b < 44)  packB_at<ISF>((b - 20) * 256 + tid, W1, RBF, 2, 6400, 8192, NLAY, w1p);
    else if (b < 236) packB24_at<ISF>((b - 44) * 256 + tid, W2, cW1, cW2, lW,
                                      w2p, cw1p, cw2p, lwp);
    else if (b < 250) cvts_at<ISF>((b - 236) * 256 + tid, means, betas, bp, bc, b1, b2,
                                   cb2, lb, meanscv, betascv, bpcv, bccv,
                                   b1cv, b2cv, cb2cv, lbcv);
    else {
        int i = (b - 250) * 256 + tid;
        if (i < MAXZ_ * HC) nbrembbf[i] = f2b(LD<ISF>(nbremb, i));
    }
}
__global__ void packall_k(const void* Wp, const void* Wc, const void* W1,
                          const void* W2, const void* cW1, const void* cW2,
                          const void* lW, const void* means, const void* betas,
                          const void* bp, const void* bc, const void* b1,
                          const void* b2, const void* cb2, const void* lb,
                          const void* nbremb, const int* flagp,
                          bf16* wpp, bf16* wcp, bf16* w1p, bf16* w2p, bf16* cw1p,
                          bf16* cw2p, bf16* lwp, float* meanscv, float* betascv,
                          float* bpcv, float* bccv, float* b1cv, float* b2cv,
                          float* cb2cv, float* lbcv, bf16* nbrembbf) {
    if (flagp[1]) packall_body<1>(Wp, Wc, W1, W2, cW1, cW2, lW, means, betas, bp, bc,
                                  b1, b2, cb2, lb, nbremb, wpp, wcp, w1p, w2p, cw1p,
                                  cw2p, lwp, meanscv, betascv, bpcv, bccv, b1cv, b2cv,
                                  cb2cv, lbcv, nbrembbf);
    else          packall_body<0>(Wp, Wc, W1, W2, cW1, cW2, lW, means, betas, bp, bc,
                                  b1, b2, cb2, lb, nbremb, wpp, wcp, w1p, w2p, cw1p,
                                  cw2p, lwp, meanscv, betascv, bpcv, bccv, b1cv, b2cv,
                                  cb2cv, lbcv, nbrembbf);
}

// ---------------- MFMA helpers ----------------
#define MFMA(a, b, c) __builtin_amdgcn_mfma_f32_16x16x32_bf16((a), (b), (c), 0, 0, 0)

__device__ __forceinline__ void seg_prep(const int* __restrict__ dst_s, int i0, int tid,
                                         int* ddst, int* slot_s, int* distinct_s,
                                         int* nseg_s) {
    if (tid < 64) {
        int d = dst_s[i0 + tid];
        ddst[tid] = d;
        int dprev = __shfl_up(d, 1, 64);
        int flag = (tid == 0 || d != dprev) ? 1 : 0;
        int s = flag;
        #pragma unroll
        for (int off = 1; off < 64; off <<= 1) {
            int t = __shfl_up(s, off, 64);
            if (tid >= off) s += t;
        }
        slot_s[tid] = s - 1;
        if (flag) distinct_s[s - 1] = d;
        if (tid == 63) *nseg_s = s;
    }
}

__device__ __forceinline__ void seg_mfma(const bf16 (*mvT)[72], const int* ddst,
                                         const int* slot_s, const int* distinct_s,
                                         int nseg, float* __restrict__ out, int tid) {
    int wave = tid >> 6, lane = tid & 63, quad = lane >> 4, lc = lane & 15;
    if (nseg <= 16) {
        bf8v sa[2];
        #pragma unroll
        for (int ks = 0; ks < 2; ks++)
            #pragma unroll
            for (int j = 0; j < 8; j++) {
                int k = ks * 32 + quad * 8 + j;
                sa[ks][j] = (slot_s[k] == lc) ? (short)0x3F80 : (short)0;
            }
        f4v z4 = {0.f, 0.f, 0.f, 0.f};
        f4v sacc[2] = {z4, z4};
        #pragma unroll
        for (int nt = 0; nt < 2; nt++)
            #pragma unroll
            for (int ks = 0; ks < 2; ks++) {
                bf8v b = *(const bf8v*)&mvT[wave * 32 + nt * 16 + lc][ks * 32 + quad * 8];
                sacc[nt] = MFMA(sa[ks], b, sacc[nt]);
            }
        #pragma unroll
        for (int nt = 0; nt < 2; nt++)
            #pragma unroll
            for (int r = 0; r < 4; r++) {
                int sl = quad * 4 + r;
                if (sl < nseg) {
                    int atom = distinct_s[sl];
                    int n = wave * 32 + nt * 16 + lc;
                    float v = sacc[nt][r];
                    if (sl == 0 || sl == nseg - 1)
                        atomicAdd(&out[(size_t)atom * HC + n], v);
                    else
                        out[(size_t)atom * HC + n] = v;
                }
            }
    } else {
        int col = tid & 127;
        int base = (tid >> 7) * 32;
        int cur = ddst[base];
        float s = 0.0f;
        bool first = true;
        for (int e = base; e < base + 32; e++) {
            int dn = ddst[e];
            if (dn != cur) {
                if (first) atomicAdd(&out[(size_t)cur * HC + col], s);
                else out[(size_t)cur * HC + col] = s;
                first = false; cur = dn; s = 0.0f;
            }
            s += b2f(mvT[col][e]);
        }
        atomicAdd(&out[(size_t)cur * HC + col], s);
    }
}

// ---------------- table build ----------------
__global__ __launch_bounds__(256)
void tabbuild_k(const bf16* __restrict__ wpp, const float* __restrict__ bpcv,
                const bf16* __restrict__ w1p, const float* __restrict__ b1cv,
                const bf16* __restrict__ w2p, const float* __restrict__ b2cv,
                const float* __restrict__ meanscv, const float* __restrict__ betascv,
                bf16* __restrict__ Tb) {
    __shared__ bf16 hid[64][136];
    __shared__ float csh[64], edsh[64];
    int f = blockIdx.x >> 7, kb = blockIdx.x & 127;
    int base = kb * 64;
    int tid = threadIdx.x;
    int wave = tid >> 6, lane = tid & 63, quad = lane >> 4, lc = lane & 15;
    if (tid < 64) {
        float ed = (float)(base + tid) * (1.0f / (NK - 1));
        float d = -logf(fmaxf(ed, 1e-30f));
        float C = (d < 5.0f) ? 0.5f * (__cosf(d * 0.6283185307f) + 1.0f) : 0.0f;
        csh[tid] = C; edsh[tid] = ed;
    }
    __syncthreads();
    float edi = edsh[wave * 16 + lc], Ci = csh[wave * 16 + lc];
    bf8v af[2];
    #pragma unroll
    for (int ks = 0; ks < 2; ks++) {
        #pragma unroll
        for (int j = 0; j < 8; j++) {
            int r = ks * 32 + quad * 8 + j;
            float v = 0.0f;
            if (r < RBF) { float u = edi - meanscv[r]; v = Ci * __expf(-betascv[r] * u * u); }
            af[ks][j] = f2s(v);
        }
    }
    f4v zero = {0.f, 0.f, 0.f, 0.f};
    f4v acc[8];
    #pragma unroll
    for (int nt = 0; nt < 8; nt++) acc[nt] = zero;
    const bf16* w1b = (f == 0) ? wpp : w1p + (size_t)(f - 1) * 8192;
    #pragma unroll
    for (int nt = 0; nt < 8; nt++)
        #pragma unroll
        for (int ks = 0; ks < 2; ks++) {
            bf8v b = *(const bf8v*)(w1b + ((nt * 2 + ks) * 64 + lane) * 8);
            acc[nt] = MFMA(af[ks], b, acc[nt]);
        }
    if (f == 0) {
        #pragma unroll
        for (int nt = 0; nt < 8; nt++) {
            int n = nt * 16 + lc;
            float bb = bpcv[n];
            #pragma unroll
            for (int r = 0; r < 4; r++) {
                int row = wave * 16 + quad * 4 + r;
                Tb[(size_t)(base + row) * HC + n] = f2b((acc[nt][r] + bb) * csh[row]);
            }
        }
        return;
    }
    int l = f - 1;
    #pragma unroll
    for (int nt = 0; nt < 8; nt++) {
        int n = nt * 16 + lc;
        float bb = b1cv[l * HC + n];
        #pragma unroll
        for (int r = 0; r < 4; r++)
            hid[wave * 16 + quad * 4 + r][n] = f2b(silu(acc[nt][r] + bb));
    }
    __syncthreads();
    bf8v a2[4];
    #pragma unroll
    for (int ks = 0; ks < 4; ks++)
        a2[ks] = *(const bf8v*)&hid[wave * 16 + lc][ks * 32 + quad * 8];
    f4v acc2[8];
    #pragma unroll
    for (int nt = 0; nt < 8; nt++) acc2[nt] = zero;
    const bf16* w2b = w2p + (size_t)l * 16384;
    #pragma unroll
    for (int nt = 0; nt < 8; nt++)
        #pragma unroll
        for (int ks = 0; ks < 4; ks++) {
            bf8v b = *(const bf8v*)(w2b + ((nt * 4 + ks) * 64 + lane) * 8);
            acc2[nt] = MFMA(a2[ks], b, acc2[nt]);
        }
    #pragma unroll
    for (int nt = 0; nt < 8; nt++) {
        int n = nt * 16 + lc;
        float bb = b2cv[l * HC + n];
        #pragma unroll
        for (int r = 0; r < 4; r++) {
            int row = wave * 16 + quad * 4 + r;
            Tb[((size_t)f * NK + base + row) * HC + n] = f2b((acc2[nt][r] + bb) * csh[row]);
        }
    }
}

// ---------------- neighbor edges ----------------
__global__ __launch_bounds__(256)
void nbr_tab_k(const int* __restrict__ rowptr,
               const float* __restrict__ ed_s, const int* __restrict__ src_s,
               const int* __restrict__ dst_s, const int* __restrict__ z,
               const bf16* __restrict__ nbrembbf, const bf16* __restrict__ Tb,
               float* __restrict__ msg) {
    __shared__ bf16 mvT[128][72];
    __shared__ int ddst[64], slot_s[64], distinct_s[64];
    __shared__ int nseg_s;
    int i0 = blockIdx.x * 64;
    if (i0 >= rowptr[NATOMS]) return;    // block fully past active edges
    int tid = threadIdx.x;
    seg_prep(dst_s, i0, tid, ddst, slot_s, distinct_s, &nseg_s);
    int row = tid & 63, c0 = (tid >> 6) * 32;
    int e = i0 + row;
    int s = src_s[e];
    float msk = (s != dst_s[e]) ? 1.0f : 0.0f;
    float pos = fminf(fmaxf(ed_s[e] * (float)(NK - 1) + 0.5f, 0.0f), (float)(NK - 1));
    int k = (int)pos;
    const bf8v* tp = (const bf8v*)(Tb + (size_t)k * HC + c0);
    bf8v tv[4];
    #pragma unroll
    for (int g = 0; g < 4; g++) tv[g] = tp[g];
    int zz = z[s]; zz = zz < 0 ? 0 : (zz >= MAXZ_ ? MAXZ_ - 1 : zz);
    const bf8v* ep = (const bf8v*)(nbrembbf + (size_t)zz * HC + c0);
    bf8v ev[4];
    #pragma unroll
    for (int g = 0; g < 4; g++) ev[g] = ep[g];
    #pragma unroll
    for (int g = 0; g < 4; g++)
        #pragma unroll
        for (int m = 0; m < 8; m++) {
            float v = s2f((unsigned short)tv[g][m]) * msk *
                      s2f((unsigned short)ev[g][m]);
            mvT[c0 + g * 8 + m][row] = f2b(v);
        }
    __syncthreads();
    seg_mfma(mvT, ddst, slot_s, distinct_s, nseg_s, msg, tid);
}

// ---------------- combine (prep fused) ----------------
template<int ISF>
__device__ void combine_body(const int* __restrict__ z, const void* __restrict__ emb,
                             const float* __restrict__ msg, const bf16* __restrict__ wcp,
                             const float* __restrict__ bccv, const bf16* __restrict__ cw1b,
                             float* __restrict__ x, bf16* __restrict__ xb,
                             bf16* __restrict__ ybf) {
    __shared__ bf16 srow[64][136];
    int tid = threadIdx.x;
    int wave = tid >> 6, lane = tid & 63, quad = lane >> 4, lc = lane & 15;
    int m0 = blockIdx.x * 64;
    int arow = m0 + wave * 16 + lc;
    int rowc = arow < NATOMS ? arow : NATOMS - 1;
    int zz = z[rowc]; zz = zz < 0 ? 0 : (zz >= MAXZ_ ? MAXZ_ - 1 : zz);
    bf8v af[8];
    #pragma unroll
    for (int ks = 0; ks < 4; ks++)
        #pragma unroll
        for (int j = 0; j < 8; j++)
            af[ks][j] = f2s(LD<ISF>(emb, (size_t)zz * HC + ks * 32 + quad * 8 + j));
    #pragma unroll
    for (int ks = 4; ks < 8; ks++) {
        const float* mp = msg + (size_t)rowc * HC + (ks - 4) * 32 + quad * 8;
        #pragma unroll
        for (int j = 0; j < 8; j++) af[ks][j] = f2s(mp[j]);
    }
    f4v zero = {0.f, 0.f, 0.f, 0.f};
    f4v acc[8];
    #pragma unroll
    for (int nt = 0; nt < 8; nt++) acc[nt] = zero;
    #pragma unroll
    for (int nt = 0; nt < 8; nt++)
        #pragma unroll
        for (int ks = 0; ks < 8; ks++) {
            bf8v b = *(const bf8v*)(wcp + ((nt * 8 + ks) * 64 + lane) * 8);
            acc[nt] = MFMA(af[ks], b, acc[nt]);
        }
    #pragma unroll
    for (int nt = 0; nt < 8; nt++) {
        int n = nt * 16 + lc;
        float bb = bccv[n];
        #pragma unroll
        for (int r = 0; r < 4; r++) {
            int row = m0 + wave * 16 + quad * 4 + r;
            float v = acc[nt][r] + bb;
            bf16 vb = f2b(v);
            srow[wave * 16 + quad * 4 + r][n] = vb;
            if (row < NATOMS) {
                x[(size_t)row * HC + n] = v;
                xb[(size_t)row * HC + n] = vb;
            }
        }
    }
    __syncthreads();
    bf8v a3[4];
    #pragma unroll
    for (int ks = 0; ks < 4; ks++)
        a3[ks] = *(const bf8v*)&srow[wave * 16 + lc][ks * 32 + quad * 8];
    f4v acc3[8];
    #pragma unroll
    for (int nt = 0; nt < 8; nt++) acc3[nt] = zero;
    #pragma unroll
    for (int nt = 0; nt < 8; nt++)
        #pragma unroll
        for (int ks = 0; ks < 4; ks++) {
            bf8v b = *(const bf8v*)(cw1b + ((nt * 4 + ks) * 64 + lane) * 8);
            acc3[nt] = MFMA(a3[ks], b, acc3[nt]);
        }
    #pragma unroll
    for (int nt = 0; nt < 8; nt++) {
        int n = nt * 16 + lc;
        #pragma unroll
        for (int r = 0; r < 4; r++) {
            int row = m0 + wave * 16 + quad * 4 + r;
            if (row < NATOMS) ybf[(size_t)row * HC + n] = f2b(acc3[nt][r]);
        }
    }
}
__global__ __launch_bounds__(256)
void combine_k(const int* z, const void* emb, const float* msg, const bf16* wcp,
               const float* bccv, const bf16* cw1b, const int* flagp,
               float* x, bf16* xb, bf16* ybf) {
    if (flagp[1]) combine_body<1>(z, emb, msg, wcp, bccv, cw1b, x, xb, ybf);
    else          combine_body<0>(z, emb, msg, wcp, bccv, cw1b, x, xb, ybf);
}

// ---------------- filter edges ----------------
__global__ __launch_bounds__(256)
void filt_tab_k(int l, const int* __restrict__ rowptr,
                const float* __restrict__ ed_s, const int* __restrict__ src_s,
                const int* __restrict__ dst_s, const bf16* __restrict__ ybf,
                const bf16* __restrict__ Tb, float* __restrict__ msum) {
    __shared__ bf16 mvT[128][72];
    __shared__ int ddst[64], slot_s[64], distinct_s[64];
    __shared__ int nseg_s;
    int i0 = blockIdx.x * 64;
    if (i0 >= rowptr[NATOMS]) return;    // block fully past active edges
    int tid = threadIdx.x;
    seg_prep(dst_s, i0, tid, ddst, slot_s, distinct_s, &nseg_s);
    int row = tid & 63, c0 = (tid >> 6) * 32;
    int e = i0 + row;
    float pos = fminf(fmaxf(ed_s[e] * (float)(NK - 1) + 0.5f, 0.0f), (float)(NK - 1));
    int k = (int)pos;
    const bf8v* tp = (const bf8v*)(Tb + ((size_t)(l + 1) * NK + k) * HC + c0);
    bf8v tv[4];
    #pragma unroll
    for (int g = 0; g < 4; g++) tv[g] = tp[g];
    const bf8v* yp = (const bf8v*)(ybf + (size_t)src_s[e] * HC + c0);
    bf8v yv[4];
    #pragma unroll
    for (int g = 0; g < 4; g++) yv[g] = yp[g];
    #pragma unroll
    for (int g = 0; g < 4; g++)
        #pragma unroll
        for (int m = 0; m < 8; m++) {
            float v = s2f((unsigned short)tv[g][m]) * s2f((unsigned short)yv[g][m]);
            mvT[c0 + g * 8 + m][row] = f2b(v);
        }
    __syncthreads();
    seg_mfma(mvT, ddst, slot_s, distinct_s, nseg_s, msum, tid);
}

// ---- node update, 32 rows/block ----
__global__ __launch_bounds__(256)
void upd_mfma_k(float* msum, int l,
                const bf16* __restrict__ cw2p, const float* __restrict__ cb2cv,
                const bf16* __restrict__ lwp, const float* __restrict__ lbcv,
                const bf16* __restrict__ cw1p, int do_y, int last,
                float* __restrict__ x, bf16* __restrict__ xb,
                bf16* __restrict__ ybf, void* out, const int* flagp) {
    __shared__ bf16 srow[32][136];
    int tid = threadIdx.x;
    int wave = tid >> 6, lane = tid & 63, quad = lane >> 4, lc = lane & 15;
    int rb = wave >> 1, ch = wave & 1;
    int m0 = blockIdx.x * 32 + rb * 16;
    bf8v azero = {0, 0, 0, 0, 0, 0, 0, 0};
    bf8v af[4];
    int arow = m0 + lc;
    #pragma unroll
    for (int ks = 0; ks < 4; ks++) {
        if (arow < NATOMS) {
            const float* p = msum + (size_t)arow * HC + ks * 32 + quad * 8;
            bf8v f;
            #pragma unroll
            for (int j = 0; j < 8; j++) f[j] = f2s(p[j]);
            af[ks] = f;
        } else af[ks] = azero;
    }
    f4v zero = {0.f, 0.f, 0.f, 0.f};
    f4v acc[4];
    #pragma unroll
    for (int nt = 0; nt < 4; nt++) acc[nt] = zero;
    const bf16* c2b = cw2p + (size_t)l * 16384;
    #pragma unroll
    for (int nt = 0; nt < 4; nt++)
        #pragma unroll
        for (int ks = 0; ks < 4; ks++) {
            bf8v b = *(const bf8v*)(c2b + (((ch * 4 + nt) * 4 + ks) * 64 + lane) * 8);
            acc[nt] = MFMA(af[ks], b, acc[nt]);
        }
    #pragma unroll
    for (int nt = 0; nt < 4; nt++) {
        int n = ch * 64 + nt * 16 + lc;
        float bb = cb2cv[l * HC + n];
        #pragma unroll
        for (int r = 0; r < 4; r++)
            srow[rb * 16 + quad * 4 + r][n] = f2b(silu(acc[nt][r] + bb));
    }
    __syncthreads();
    if (ch == 0 && arow < NATOMS) {
        float zdep = fminf(fabsf(acc[0][0]), 0.0f);
        f4v zv = {zdep, zdep, zdep, zdep};
        #pragma unroll
        for (int ks = 0; ks < 4; ks++) {
            *(f4v*)(msum + (size_t)arow * HC + ks * 32 + quad * 8) = zv;
            *(f4v*)(msum + (size_t)arow * HC + ks * 32 + quad * 8 + 4) = zv;
        }
    }
    bf8v a2[4];
    #pragma unroll
    for (int ks = 0; ks < 4; ks++)
        a2[ks] = *(const bf8v*)&srow[rb * 16 + lc][ks * 32 + quad * 8];
    __syncthreads();
    f4v acc2[4];
    #pragma unroll
    for (int nt = 0; nt < 4; nt++) acc2[nt] = zero;
    const bf16* lwb = lwp + (size_t)l * 16384;
    #pragma unroll
    for (int nt = 0; nt < 4; nt++)
        #pragma unroll
        for (int ks = 0; ks < 4; ks++) {
            bf8v b = *(const bf8v*)(lwb + (((ch * 4 + nt) * 4 + ks) * 64 + lane) * 8);
            acc2[nt] = MFMA(a2[ks], b, acc2[nt]);
        }
    int isf = flagp[1];
    #pragma unroll
    for (int nt = 0; nt < 4; nt++) {
        int n = ch * 64 + nt * 16 + lc;
        float bb = lbcv[l * HC + n];
        #pragma unroll
        for (int r = 0; r < 4; r++) {
            int row = m0 + quad * 4 + r;
            float nv = 0.0f;
            if (row < NATOMS) {
                size_t o = (size_t)row * HC + n;
                nv = x[o] + acc2[nt][r] + bb;
                if (!last) {
                    x[o] = nv;
                    xb[o] = f2b(nv);
                } else {
                    if (isf) ((float*)out)[o] = nv;
                    else     ((bf16*)out)[o] = f2b(nv);
                }
            }
            srow[rb * 16 + quad * 4 + r][n] = f2b(nv);
        }
    }
    if (do_y) {
        __syncthreads();
        bf8v a3[4];
        #pragma unroll
        for (int ks = 0; ks < 4; ks++)
            a3[ks] = *(const bf8v*)&srow[rb * 16 + lc][ks * 32 + quad * 8];
        f4v acc3[4];
        #pragma unroll
        for (int nt = 0; nt < 4; nt++) acc3[nt] = zero;
        const bf16* c1b = cw1p + (size_t)(l + 1) * 16384;
        #pragma unroll
        for (int nt = 0; nt < 4; nt++)
            #pragma unroll
            for (int ks = 0; ks < 4; ks++) {
                bf8v b = *(const bf8v*)(c1b + (((ch * 4 + nt) * 4 + ks) * 64 + lane) * 8);
                acc3[nt] = MFMA(a3[ks], b, acc3[nt]);
            }
        #pragma unroll
        for (int nt = 0; nt < 4; nt++) {
            int n = ch * 64 + nt * 16 + lc;
            #pragma unroll
            for (int r = 0; r < 4; r++) {
                int row = m0 + quad * 4 + r;
                if (row < NATOMS) ybf[(size_t)row * HC + n] = f2b(acc3[nt][r]);
            }
        }
    }
}

// ---------------- launch ----------------
extern "C" void kernel_launch(void* const* d_in, const int* in_sizes, int n_in,
                              void* d_out, int out_size, void* d_ws, size_t ws_size,
                              hipStream_t stream) {
    const int*  z      = (const int*) d_in[0];
    const void* pos    = d_in[1];
    const int*  ei     = (const int*) d_in[3];
    const void* emb    = d_in[4];
    const void* nbremb = d_in[5];
    const void* Wp     = d_in[6];
    const void* bp     = d_in[7];
    const void* Wc     = d_in[8];
    const void* bc     = d_in[9];
    const void* means  = d_in[10];
    const void* betas  = d_in[11];
    const void* W1     = d_in[12];
    const void* b1     = d_in[13];
    const void* W2     = d_in[14];
    const void* b2     = d_in[15];
    const void* cW1    = d_in[16];
    const void* cW2    = d_in[17];
    const void* cb2    = d_in[18];
    const void* lW     = d_in[19];
    const void* lb     = d_in[20];

    char* p = (char*)d_ws;
    auto alloc = [&](size_t bytes) { char* r = p; p += (bytes + 255) / 256 * 256; return r; };
    int*   flag    = (int*)  alloc(256);                       // adjacent with counts
    int*   counts  = (int*)  alloc((size_t)NATOMS * 4);
    int*   rowptr  = (int*)  alloc((size_t)(NATOMS + 1) * 4);
    int*   cursor  = (int*)  alloc((size_t)NATOMS * 4);
    int*   src_s   = (int*)  alloc((size_t)NEDGES * 4);
    int*   dst_s   = (int*)  alloc((size_t)NEDGES * 4);
    float* ed_s    = (float*)alloc((size_t)NEDGES * 4);
    float* x       = (float*)alloc((size_t)NATOMS * HC * 4);
    bf16*  xb      = (bf16*) alloc((size_t)NATOMS * HC * 2);
    bf16*  ybf     = (bf16*) alloc((size_t)NATOMS * HC * 2);
    float* msum    = (float*)alloc((size_t)NATOMS * HC * 4);   // adjacent with msg
    float* msg     = (float*)alloc((size_t)NATOMS * HC * 4);
    bf16*  Tb      = (bf16*) alloc((size_t)(NLAY + 1) * NK * HC * 2);  // 14.7 MB
    bf16*  wpp     = (bf16*) alloc((size_t)8192 * 2);
    bf16*  wcp     = (bf16*) alloc((size_t)32768 * 2);
    bf16*  w1p     = (bf16*) alloc((size_t)NLAY * 8192 * 2);
    bf16*  w2p     = (bf16*) alloc((size_t)NLAY * 16384 * 2);
    bf16*  cw1p    = (bf16*) alloc((size_t)NLAY * 16384 * 2);
    bf16*  cw2p    = (bf16*) alloc((size_t)NLAY * 16384 * 2);
    bf16*  lwp     = (bf16*) alloc((size_t)NLAY * 16384 * 2);
    bf16*  nbrembbf= (bf16*) alloc((size_t)MAXZ_ * HC * 2);
    float* bpcv    = (float*)alloc((size_t)HC * 4);
    float* bccv    = (float*)alloc((size_t)HC * 4);
    float* b1cv    = (float*)alloc((size_t)NLAY * HC * 4);
    float* b2cv    = (float*)alloc((size_t)NLAY * HC * 4);
    float* cb2cv   = (float*)alloc((size_t)NLAY * HC * 4);
    float* lbcv    = (float*)alloc((size_t)NLAY * HC * 4);
    float* meanscv = (float*)alloc((size_t)RBF * 4);
    float* betascv = (float*)alloc((size_t)RBF * 4);

    const int EG = (NEDGES + 255) / 256;

    hipMemsetAsync(flag, 0, 256 + ((size_t)NATOMS * 4 + 255) / 256 * 256, stream);
    probe_k<<<(NATOMS * 3 + 255) / 256, 256, 0, stream>>>(pos, flag);
    setflag_k<<<1, 64, 0, stream>>>(flag);
    histd_k<<<EG, 256, 0, stream>>>(ei, pos, flag, counts);
    scan_k<<<1, 1024, 0, stream>>>(counts, rowptr, cursor);
    permgeom_k<<<EG, 256, 0, stream>>>(ei, pos, cursor, flag, ed_s, src_s, dst_s);
    pad_k<<<EG, 256, 0, stream>>>(rowptr, ed_s, src_s, dst_s);

    packall_k<<<300, 256, 0, stream>>>(Wp, Wc, W1, W2, cW1, cW2, lW, means, betas,
                                       bp, bc, b1, b2, cb2, lb, nbremb, flag,
                                       wpp, wcp, w1p, w2p, cw1p, cw2p, lwp,
                                       meanscv, betascv, bpcv, bccv, b1cv, b2cv,
                                       cb2cv, lbcv, nbrembbf);
    tabbuild_k<<<7 * (NK / 64), 256, 0, stream>>>(wpp, bpcv, w1p, b1cv, w2p, b2cv,
                                                  meanscv, betascv, Tb);

    hipMemsetAsync(msum, 0, (size_t)2 * NATOMS * HC * 4, stream);
    nbr_tab_k<<<EGRID, 256, 0, stream>>>(rowptr, ed_s, src_s, dst_s, z, nbrembbf, Tb, msg);
    combine_k<<<YGRID, 256, 0, stream>>>(z, emb, msg, wcp, bccv, cw1p, flag, x, xb, ybf);

    for (int l = 0; l < NLAY; l++) {
        filt_tab_k<<<EGRID, 256, 0, stream>>>(l, rowptr, ed_s, src_s, dst_s, ybf, Tb, msum);
        int lastl = (l == NLAY - 1) ? 1 : 0;
        upd_mfma_k<<<UGRID, 256, 0, stream>>>(msum, l, cw2p, cb2cv, lwp, lbcv,
                                              cw1p, lastl ? 0 : 1, lastl,
                                              x, xb, ybf, d_out, flag);
    }
}

// Round 13
// 360.455 us; speedup vs baseline: 24.9880x; 1.0212x over previous
//
#include <hip/hip_runtime.h>
#include <hip/hip_bf16.h>

// TorchMD_GN_Ext R13: setup-chain consolidation on R12.
//  - setflag_k deleted (consumers compare flag[0] bits directly)
//  - pad_k deleted (histd pre-fills pad defaults for all E slots; permgeom
//    overwrites the active prefix)
//  - single memset (flag|counts|msum|msg contiguous)
//  21 dispatches. Edge kernels unchanged (TA-request floor on ~93k active edges).

#define NATOMS 10000
#define NEDGES 320000
#define HC 128
#define RBF 50
#define NLAY 6
#define MAXZ_ 100
#define NK 8192
#define EGRID (NEDGES / 64)         // worst case; blocks early-exit past Eact
#define YGRID ((NATOMS + 63) / 64)  // 157
#define UGRID ((NATOMS + 31) / 32)  // 313

typedef __hip_bfloat16 bf16;
typedef __attribute__((ext_vector_type(8))) short bf8v;
typedef __attribute__((ext_vector_type(4))) float f4v;

__device__ __forceinline__ float b2f(bf16 v) { return __bfloat162float(v); }
__device__ __forceinline__ bf16  f2b(float v) { return __float2bfloat16(v); }
__device__ __forceinline__ short f2s(float v) { bf16 h = f2b(v); return *(short*)&h; }
__device__ __forceinline__ float s2f(unsigned short s) {
    return __int_as_float(((int)s) << 16);
}
__device__ __forceinline__ float silu(float v) {
    return v * __builtin_amdgcn_rcpf(1.0f + __expf(-v));
}
__device__ __forceinline__ int isf_of(const int* flagp) {
    return (__int_as_float(flagp[0]) > 1.0e4f) ? 1 : 0;
}

template<int ISF>
__device__ __forceinline__ float LD(const void* p, size_t i) {
    if (ISF) return ((const float*)p)[i];
    return b2f(((const bf16*)p)[i]);
}

__device__ __forceinline__ int clampN(int v) {
    return v < 0 ? 0 : (v >= NATOMS ? NATOMS - 1 : v);
}

// edge distance (identical ops in histd + permgeom => identical results)
template<int ISF>
__device__ __forceinline__ float edge_d(const int* __restrict__ ei,
                                        const void* __restrict__ pos, int e,
                                        int* sOut, int* tOut) {
    int s = clampN(ei[e]);
    int t = clampN(ei[NEDGES + e]);
    *sOut = s; *tOut = t;
    float dx = LD<ISF>(pos, (size_t)s * 3 + 0) - LD<ISF>(pos, (size_t)t * 3 + 0);
    float dy = LD<ISF>(pos, (size_t)s * 3 + 1) - LD<ISF>(pos, (size_t)t * 3 + 1);
    float dz = LD<ISF>(pos, (size_t)s * 3 + 2) - LD<ISF>(pos, (size_t)t * 3 + 2);
    float d = sqrtf(dx * dx + dy * dy + dz * dz + 1e-12f);
    if (d != d) d = 1e30f;
    return d;
}

// ---------------- dtype probe ----------------
__global__ void probe_k(const void* pos, int* flag) {
    int i = blockIdx.x * 256 + threadIdx.x;
    float v = 0.0f;
    if (i < NATOMS * 3) {
        v = fabsf(b2f(((const bf16*)pos)[i]));
        if (v != v) v = 1e30f;
    }
    atomicMax(flag, __float_as_int(v));
}

// ------- histogram of ACTIVE (d<5) edges + pad-default prefill -------
template<int ISF>
__device__ void histd_body(const int* __restrict__ ei, const void* __restrict__ pos,
                           int* __restrict__ counts, float* __restrict__ ed_s,
                           int* __restrict__ src_s, int* __restrict__ dst_s) {
    int e = blockIdx.x * 256 + threadIdx.x;
    if (e >= NEDGES) return;
    // pad defaults for every slot; permgeom overwrites the active prefix.
    ed_s[e] = 0.0f;          // table row 0 -> C=0 -> zero contribution
    src_s[e] = 0;
    dst_s[e] = NATOMS - 1;   // pads form the tail segment -> atomicAdd of 0
    int s, t;
    float d = edge_d<ISF>(ei, pos, e, &s, &t);
    if (d < 5.0f) atomicAdd(&counts[t], 1);
}
__global__ void histd_k(const int* ei, const void* pos, const int* flagp,
                        int* counts, float* ed_s, int* src_s, int* dst_s) {
    if (isf_of(flagp)) histd_body<1>(ei, pos, counts, ed_s, src_s, dst_s);
    else               histd_body<0>(ei, pos, counts, ed_s, src_s, dst_s);
}

// ---------------- scan ----------------
__global__ void scan_k(const int* __restrict__ counts, int* __restrict__ rowptr,
                       int* __restrict__ cursor) {
    __shared__ int wsum[16];
    __shared__ int carry_s;
    __shared__ int chunktot;
    int tid = threadIdx.x, lane = tid & 63, w = tid >> 6;
    if (tid == 0) { carry_s = 0; rowptr[0] = 0; }
    __syncthreads();
    for (int base = 0; base < NATOMS; base += 1024) {
        int i = base + tid;
        int v = (i < NATOMS) ? counts[i] : 0;
        int s = v;
        #pragma unroll
        for (int off = 1; off < 64; off <<= 1) {
            int t = __shfl_up(s, off, 64);
            if (lane >= off) s += t;
        }
        if (lane == 63) wsum[w] = s;
        __syncthreads();
        if (w == 0 && lane < 16) {
            int t = wsum[lane];
            int si = t;
            #pragma unroll
            for (int off = 1; off < 16; off <<= 1) {
                int u = __shfl_up(si, off, 64);
                if (lane >= off) si += u;
            }
            wsum[lane] = si - t;
            if (lane == 15) chunktot = si;
        }
        __syncthreads();
        int carry = carry_s;
        if (i < NATOMS) {
            int inc = carry + wsum[w] + s;
            rowptr[i + 1] = inc;
            cursor[i] = inc - v;
        }
        __syncthreads();
        if (tid == 0) carry_s += chunktot;
        __syncthreads();
    }
}

// ---------------- perm + geometry (active edges only) ----------------
template<int ISF>
__device__ void permgeom_body(const int* __restrict__ ei, const void* __restrict__ pos,
                              int* __restrict__ cursor,
                              float* __restrict__ ed_s, int* __restrict__ src_s,
                              int* __restrict__ dst_s) {
    int e = blockIdx.x * 256 + threadIdx.x;
    if (e >= NEDGES) return;
    int s, t;
    float d = edge_d<ISF>(ei, pos, e, &s, &t);
    if (d >= 5.0f) return;                  // dead edge: exactly 0 contribution
    int p = atomicAdd(&cursor[t], 1);
    ed_s[p] = __expf(-d);
    src_s[p] = s;
    dst_s[p] = t;
}
__global__ void permgeom_k(const int* ei, const void* pos, int* cursor, const int* flagp,
                           float* ed_s, int* src_s, int* dst_s) {
    if (isf_of(flagp)) permgeom_body<1>(ei, pos, cursor, ed_s, src_s, dst_s);
    else               permgeom_body<0>(ei, pos, cursor, ed_s, src_s, dst_s);
}

// ---------------- mega pack/convert ----------------
template<int ISF>
__device__ void packB_at(int t, const void* src, int K, int ksteps, size_t perLsrc,
                         size_t perLdst, int L, bf16* dst) {
    if (t >= L * 8 * ksteps * 64) return;
    int lane = t & 63;
    int t2 = t >> 6;
    int ks = t2 % ksteps;
    int t3 = t2 / ksteps;
    int nt = t3 & 7;
    int l  = t3 >> 3;
    int quad = lane >> 4, lc = lane & 15;
    int col = nt * 16 + lc;
    for (int j = 0; j < 8; j++) {
        int k = ks * 32 + quad * 8 + j;
        float v = (k < K) ? LD<ISF>(src, (size_t)l * perLsrc + (size_t)k * 128 + col) : 0.0f;
        dst[(size_t)l * perLdst + ((size_t)((nt * ksteps + ks) * 64 + lane)) * 8 + j] = f2b(v);
    }
}
template<int ISF>
__device__ void packB24_at(int t, const void* w2, const void* cw1, const void* cw2,
                           const void* lw, bf16* w2p, bf16* cw1p, bf16* cw2p, bf16* lwp) {
    if (t >= 24 * 8 * 4 * 64) return;
    int lane = t & 63;
    int t2 = t >> 6;
    int ks = t2 & 3;
    int t3 = t2 >> 2;
    int nt = t3 & 7;
    int m  = t3 >> 3;
    int which = m / NLAY, li = m % NLAY;
    const void* src = which == 0 ? w2 : which == 1 ? cw1 : which == 2 ? cw2 : lw;
    bf16* dst = which == 0 ? w2p : which == 1 ? cw1p : which == 2 ? cw2p : lwp;
    int quad = lane >> 4, lc = lane & 15;
    int col = nt * 16 + lc;
    #pragma unroll
    for (int j = 0; j < 8; j++) {
        int k = ks * 32 + quad * 8 + j;
        float v = LD<ISF>(src, (size_t)li * 16384 + (size_t)k * 128 + col);
        dst[(size_t)li * 16384 + ((size_t)((nt * 4 + ks) * 64 + lane)) * 8 + j] = f2b(v);
    }
}
template<int ISF>
__device__ void cvts_at(int i, const void* means, const void* betas, const void* bp,
                        const void* bc, const void* b1, const void* b2,
                        const void* cb2, const void* lb,
                        float* meanscv, float* betascv, float* bpcv, float* bccv,
                        float* b1cv, float* b2cv, float* cb2cv, float* lbcv) {
    if      (i < 50)   meanscv[i]        = LD<ISF>(means, i);
    else if (i < 100)  betascv[i - 50]   = LD<ISF>(betas, i - 50);
    else if (i < 228)  bpcv[i - 100]     = LD<ISF>(bp, i - 100);
    else if (i < 356)  bccv[i - 228]     = LD<ISF>(bc, i - 228);
    else if (i < 1124) b1cv[i - 356]     = LD<ISF>(b1, i - 356);
    else if (i < 1892) b2cv[i - 1124]    = LD<ISF>(b2, i - 1124);
    else if (i < 2660) cb2cv[i - 1892]   = LD<ISF>(cb2, i - 1892);
    else if (i < 3428) lbcv[i - 2660]    = LD<ISF>(lb, i - 2660);
}
template<int ISF>
__device__ void packall_body(const void* Wp, const void* Wc, const void* W1,
                             const void* W2, const void* cW1, const void* cW2,
                             const void* lW, const void* means, const void* betas,
                             const void* bp, const void* bc, const void* b1,
                             const void* b2, const void* cb2, const void* lb,
                             const void* nbremb,
                             bf16* wpp, bf16* wcp, bf16* w1p, bf16* w2p, bf16* cw1p,
                             bf16* cw2p, bf16* lwp, float* meanscv, float* betascv,
                             float* bpcv, float* bccv, float* b1cv, float* b2cv,
                             float* cb2cv, float* lbcv, bf16* nbrembbf) {
    int b = blockIdx.x, tid = threadIdx.x;
    if (b < 4)        packB_at<ISF>(b * 256 + tid, Wp, RBF, 2, 6400, 8192, 1, wpp);
    else if (b < 20)  packB_at<ISF>((b - 4) * 256 + tid, Wc, 256, 8, 32768, 32768, 1, wcp);
    else if (b < 44)  packB_at<ISF>((b - 20) * 256 + tid, W1, RBF, 2, 6400, 8192, NLAY, w1p);
    else if (b < 236) packB24_at<ISF>((b - 44) * 256 + tid, W2, cW1, cW2, lW,
                                      w2p, cw1p, cw2p, lwp);
    else if (b < 250) cvts_at<ISF>((b - 236) * 256 + tid, means, betas, bp, bc, b1, b2,
                                   cb2, lb, meanscv, betascv, bpcv, bccv,
                                   b1cv, b2cv, cb2cv, lbcv);
    else {
        int i = (b - 250) * 256 + tid;
        if (i < MAXZ_ * HC) nbrembbf[i] = f2b(LD<ISF>(nbremb, i));
    }
}
__global__ void packall_k(const void* Wp, const void* Wc, const void* W1,
                          const void* W2, const void* cW1, const void* cW2,
                          const void* lW, const void* means, const void* betas,
                          const void* bp, const void* bc, const void* b1,
                          const void* b2, const void* cb2, const void* lb,
                          const void* nbremb, const int* flagp,
                          bf16* wpp, bf16* wcp, bf16* w1p, bf16* w2p, bf16* cw1p,
                          bf16* cw2p, bf16* lwp, float* meanscv, float* betascv,
                          float* bpcv, float* bccv, float* b1cv, float* b2cv,
                          float* cb2cv, float* lbcv, bf16* nbrembbf) {
    if (isf_of(flagp)) packall_body<1>(Wp, Wc, W1, W2, cW1, cW2, lW, means, betas,
                                       bp, bc, b1, b2, cb2, lb, nbremb, wpp, wcp,
                                       w1p, w2p, cw1p, cw2p, lwp, meanscv, betascv,
                                       bpcv, bccv, b1cv, b2cv, cb2cv, lbcv, nbrembbf);
    else               packall_body<0>(Wp, Wc, W1, W2, cW1, cW2, lW, means, betas,
                                       bp, bc, b1, b2, cb2, lb, nbremb, wpp, wcp,
                                       w1p, w2p, cw1p, cw2p, lwp, meanscv, betascv,
                                       bpcv, bccv, b1cv, b2cv, cb2cv, lbcv, nbrembbf);
}

// ---------------- MFMA helpers ----------------
#define MFMA(a, b, c) __builtin_amdgcn_mfma_f32_16x16x32_bf16((a), (b), (c), 0, 0, 0)

__device__ __forceinline__ void seg_prep(const int* __restrict__ dst_s, int i0, int tid,
                                         int* ddst, int* slot_s, int* distinct_s,
                                         int* nseg_s) {
    if (tid < 64) {
        int d = dst_s[i0 + tid];
        ddst[tid] = d;
        int dprev = __shfl_up(d, 1, 64);
        int flag = (tid == 0 || d != dprev) ? 1 : 0;
        int s = flag;
        #pragma unroll
        for (int off = 1; off < 64; off <<= 1) {
            int t = __shfl_up(s, off, 64);
            if (tid >= off) s += t;
        }
        slot_s[tid] = s - 1;
        if (flag) distinct_s[s - 1] = d;
        if (tid == 63) *nseg_s = s;
    }
}

__device__ __forceinline__ void seg_mfma(const bf16 (*mvT)[72], const int* ddst,
                                         const int* slot_s, const int* distinct_s,
                                         int nseg, float* __restrict__ out, int tid) {
    int wave = tid >> 6, lane = tid & 63, quad = lane >> 4, lc = lane & 15;
    if (nseg <= 16) {
        bf8v sa[2];
        #pragma unroll
        for (int ks = 0; ks < 2; ks++)
            #pragma unroll
            for (int j = 0; j < 8; j++) {
                int k = ks * 32 + quad * 8 + j;
                sa[ks][j] = (slot_s[k] == lc) ? (short)0x3F80 : (short)0;
            }
        f4v z4 = {0.f, 0.f, 0.f, 0.f};
        f4v sacc[2] = {z4, z4};
        #pragma unroll
        for (int nt = 0; nt < 2; nt++)
            #pragma unroll
            for (int ks = 0; ks < 2; ks++) {
                bf8v b = *(const bf8v*)&mvT[wave * 32 + nt * 16 + lc][ks * 32 + quad * 8];
                sacc[nt] = MFMA(sa[ks], b, sacc[nt]);
            }
        #pragma unroll
        for (int nt = 0; nt < 2; nt++)
            #pragma unroll
            for (int r = 0; r < 4; r++) {
                int sl = quad * 4 + r;
                if (sl < nseg) {
                    int atom = distinct_s[sl];
                    int n = wave * 32 + nt * 16 + lc;
                    float v = sacc[nt][r];
                    if (sl == 0 || sl == nseg - 1)
                        atomicAdd(&out[(size_t)atom * HC + n], v);
                    else
                        out[(size_t)atom * HC + n] = v;
                }
            }
    } else {
        int col = tid & 127;
        int base = (tid >> 7) * 32;
        int cur = ddst[base];
        float s = 0.0f;
        bool first = true;
        for (int e = base; e < base + 32; e++) {
            int dn = ddst[e];
            if (dn != cur) {
                if (first) atomicAdd(&out[(size_t)cur * HC + col], s);
                else out[(size_t)cur * HC + col] = s;
                first = false; cur = dn; s = 0.0f;
            }
            s += b2f(mvT[col][e]);
        }
        atomicAdd(&out[(size_t)cur * HC + col], s);
    }
}

// ---------------- table build ----------------
__global__ __launch_bounds__(256)
void tabbuild_k(const bf16* __restrict__ wpp, const float* __restrict__ bpcv,
                const bf16* __restrict__ w1p, const float* __restrict__ b1cv,
                const bf16* __restrict__ w2p, const float* __restrict__ b2cv,
                const float* __restrict__ meanscv, const float* __restrict__ betascv,
                bf16* __restrict__ Tb) {
    __shared__ bf16 hid[64][136];
    __shared__ float csh[64], edsh[64];
    int f = blockIdx.x >> 7, kb = blockIdx.x & 127;
    int base = kb * 64;
    int tid = threadIdx.x;
    int wave = tid >> 6, lane = tid & 63, quad = lane >> 4, lc = lane & 15;
    if (tid < 64) {
        float ed = (float)(base + tid) * (1.0f / (NK - 1));
        float d = -logf(fmaxf(ed, 1e-30f));
        float C = (d < 5.0f) ? 0.5f * (__cosf(d * 0.6283185307f) + 1.0f) : 0.0f;
        csh[tid] = C; edsh[tid] = ed;
    }
    __syncthreads();
    float edi = edsh[wave * 16 + lc], Ci = csh[wave * 16 + lc];
    bf8v af[2];
    #pragma unroll
    for (int ks = 0; ks < 2; ks++) {
        #pragma unroll
        for (int j = 0; j < 8; j++) {
            int r = ks * 32 + quad * 8 + j;
            float v = 0.0f;
            if (r < RBF) { float u = edi - meanscv[r]; v = Ci * __expf(-betascv[r] * u * u); }
            af[ks][j] = f2s(v);
        }
    }
    f4v zero = {0.f, 0.f, 0.f, 0.f};
    f4v acc[8];
    #pragma unroll
    for (int nt = 0; nt < 8; nt++) acc[nt] = zero;
    const bf16* w1b = (f == 0) ? wpp : w1p + (size_t)(f - 1) * 8192;
    #pragma unroll
    for (int nt = 0; nt < 8; nt++)
        #pragma unroll
        for (int ks = 0; ks < 2; ks++) {
            bf8v b = *(const bf8v*)(w1b + ((nt * 2 + ks) * 64 + lane) * 8);
            acc[nt] = MFMA(af[ks], b, acc[nt]);
        }
    if (f == 0) {
        #pragma unroll
        for (int nt = 0; nt < 8; nt++) {
            int n = nt * 16 + lc;
            float bb = bpcv[n];
            #pragma unroll
            for (int r = 0; r < 4; r++) {
                int row = wave * 16 + quad * 4 + r;
                Tb[(size_t)(base + row) * HC + n] = f2b((acc[nt][r] + bb) * csh[row]);
            }
        }
        return;
    }
    int l = f - 1;
    #pragma unroll
    for (int nt = 0; nt < 8; nt++) {
        int n = nt * 16 + lc;
        float bb = b1cv[l * HC + n];
        #pragma unroll
        for (int r = 0; r < 4; r++)
            hid[wave * 16 + quad * 4 + r][n] = f2b(silu(acc[nt][r] + bb));
    }
    __syncthreads();
    bf8v a2[4];
    #pragma unroll
    for (int ks = 0; ks < 4; ks++)
        a2[ks] = *(const bf8v*)&hid[wave * 16 + lc][ks * 32 + quad * 8];
    f4v acc2[8];
    #pragma unroll
    for (int nt = 0; nt < 8; nt++) acc2[nt] = zero;
    const bf16* w2b = w2p + (size_t)l * 16384;
    #pragma unroll
    for (int nt = 0; nt < 8; nt++)
        #pragma unroll
        for (int ks = 0; ks < 4; ks++) {
            bf8v b = *(const bf8v*)(w2b + ((nt * 4 + ks) * 64 + lane) * 8);
            acc2[nt] = MFMA(a2[ks], b, acc2[nt]);
        }
    #pragma unroll
    for (int nt = 0; nt < 8; nt++) {
        int n = nt * 16 + lc;
        float bb = b2cv[l * HC + n];
        #pragma unroll
        for (int r = 0; r < 4; r++) {
            int row = wave * 16 + quad * 4 + r;
            Tb[((size_t)f * NK + base + row) * HC + n] = f2b((acc2[nt][r] + bb) * csh[row]);
        }
    }
}

// ---------------- neighbor edges ----------------
__global__ __launch_bounds__(256)
void nbr_tab_k(const int* __restrict__ rowptr,
               const float* __restrict__ ed_s, const int* __restrict__ src_s,
               const int* __restrict__ dst_s, const int* __restrict__ z,
               const bf16* __restrict__ nbrembbf, const bf16* __restrict__ Tb,
               float* __restrict__ msg) {
    __shared__ bf16 mvT[128][72];
    __shared__ int ddst[64], slot_s[64], distinct_s[64];
    __shared__ int nseg_s;
    int i0 = blockIdx.x * 64;
    if (i0 >= rowptr[NATOMS]) return;
    int tid = threadIdx.x;
    seg_prep(dst_s, i0, tid, ddst, slot_s, distinct_s, &nseg_s);
    int row = tid & 63, c0 = (tid >> 6) * 32;
    int e = i0 + row;
    int s = src_s[e];
    float msk = (s != dst_s[e]) ? 1.0f : 0.0f;
    float pos = fminf(fmaxf(ed_s[e] * (float)(NK - 1) + 0.5f, 0.0f), (float)(NK - 1));
    int k = (int)pos;
    const bf8v* tp = (const bf8v*)(Tb + (size_t)k * HC + c0);
    bf8v tv[4];
    #pragma unroll
    for (int g = 0; g < 4; g++) tv[g] = tp[g];
    int zz = z[s]; zz = zz < 0 ? 0 : (zz >= MAXZ_ ? MAXZ_ - 1 : zz);
    const bf8v* ep = (const bf8v*)(nbrembbf + (size_t)zz * HC + c0);
    bf8v ev[4];
    #pragma unroll
    for (int g = 0; g < 4; g++) ev[g] = ep[g];
    #pragma unroll
    for (int g = 0; g < 4; g++)
        #pragma unroll
        for (int m = 0; m < 8; m++) {
            float v = s2f((unsigned short)tv[g][m]) * msk *
                      s2f((unsigned short)ev[g][m]);
            mvT[c0 + g * 8 + m][row] = f2b(v);
        }
    __syncthreads();
    seg_mfma(mvT, ddst, slot_s, distinct_s, nseg_s, msg, tid);
}

// ---------------- combine (prep fused) ----------------
template<int ISF>
__device__ void combine_body(const int* __restrict__ z, const void* __restrict__ emb,
                             const float* __restrict__ msg, const bf16* __restrict__ wcp,
                             const float* __restrict__ bccv, const bf16* __restrict__ cw1b,
                             float* __restrict__ x, bf16* __restrict__ xb,
                             bf16* __restrict__ ybf) {
    __shared__ bf16 srow[64][136];
    int tid = threadIdx.x;
    int wave = tid >> 6, lane = tid & 63, quad = lane >> 4, lc = lane & 15;
    int m0 = blockIdx.x * 64;
    int arow = m0 + wave * 16 + lc;
    int rowc = arow < NATOMS ? arow : NATOMS - 1;
    int zz = z[rowc]; zz = zz < 0 ? 0 : (zz >= MAXZ_ ? MAXZ_ - 1 : zz);
    bf8v af[8];
    #pragma unroll
    for (int ks = 0; ks < 4; ks++)
        #pragma unroll
        for (int j = 0; j < 8; j++)
            af[ks][j] = f2s(LD<ISF>(emb, (size_t)zz * HC + ks * 32 + quad * 8 + j));
    #pragma unroll
    for (int ks = 4; ks < 8; ks++) {
        const float* mp = msg + (size_t)rowc * HC + (ks - 4) * 32 + quad * 8;
        #pragma unroll
        for (int j = 0; j < 8; j++) af[ks][j] = f2s(mp[j]);
    }
    f4v zero = {0.f, 0.f, 0.f, 0.f};
    f4v acc[8];
    #pragma unroll
    for (int nt = 0; nt < 8; nt++) acc[nt] = zero;
    #pragma unroll
    for (int nt = 0; nt < 8; nt++)
        #pragma unroll
        for (int ks = 0; ks < 8; ks++) {
            bf8v b = *(const bf8v*)(wcp + ((nt * 8 + ks) * 64 + lane) * 8);
            acc[nt] = MFMA(af[ks], b, acc[nt]);
        }
    #pragma unroll
    for (int nt = 0; nt < 8; nt++) {
        int n = nt * 16 + lc;
        float bb = bccv[n];
        #pragma unroll
        for (int r = 0; r < 4; r++) {
            int row = m0 + wave * 16 + quad * 4 + r;
            float v = acc[nt][r] + bb;
            bf16 vb = f2b(v);
            srow[wave * 16 + quad * 4 + r][n] = vb;
            if (row < NATOMS) {
                x[(size_t)row * HC + n] = v;
                xb[(size_t)row * HC + n] = vb;
            }
        }
    }
    __syncthreads();
    bf8v a3[4];
    #pragma unroll
    for (int ks = 0; ks < 4; ks++)
        a3[ks] = *(const bf8v*)&srow[wave * 16 + lc][ks * 32 + quad * 8];
    f4v acc3[8];
    #pragma unroll
    for (int nt = 0; nt < 8; nt++) acc3[nt] = zero;
    #pragma unroll
    for (int nt = 0; nt < 8; nt++)
        #pragma unroll
        for (int ks = 0; ks < 4; ks++) {
            bf8v b = *(const bf8v*)(cw1b + ((nt * 4 + ks) * 64 + lane) * 8);
            acc3[nt] = MFMA(a3[ks], b, acc3[nt]);
        }
    #pragma unroll
    for (int nt = 0; nt < 8; nt++) {
        int n = nt * 16 + lc;
        #pragma unroll
        for (int r = 0; r < 4; r++) {
            int row = m0 + wave * 16 + quad * 4 + r;
            if (row < NATOMS) ybf[(size_t)row * HC + n] = f2b(acc3[nt][r]);
        }
    }
}
__global__ __launch_bounds__(256)
void combine_k(const int* z, const void* emb, const float* msg, const bf16* wcp,
               const float* bccv, const bf16* cw1b, const int* flagp,
               float* x, bf16* xb, bf16* ybf) {
    if (isf_of(flagp)) combine_body<1>(z, emb, msg, wcp, bccv, cw1b, x, xb, ybf);
    else               combine_body<0>(z, emb, msg, wcp, bccv, cw1b, x, xb, ybf);
}

// ---------------- filter edges ----------------
__global__ __launch_bounds__(256)
void filt_tab_k(int l, const int* __restrict__ rowptr,
                const float* __restrict__ ed_s, const int* __restrict__ src_s,
                const int* __restrict__ dst_s, const bf16* __restrict__ ybf,
                const bf16* __restrict__ Tb, float* __restrict__ msum) {
    __shared__ bf16 mvT[128][72];
    __shared__ int ddst[64], slot_s[64], distinct_s[64];
    __shared__ int nseg_s;
    int i0 = blockIdx.x * 64;
    if (i0 >= rowptr[NATOMS]) return;
    int tid = threadIdx.x;
    seg_prep(dst_s, i0, tid, ddst, slot_s, distinct_s, &nseg_s);
    int row = tid & 63, c0 = (tid >> 6) * 32;
    int e = i0 + row;
    float pos = fminf(fmaxf(ed_s[e] * (float)(NK - 1) + 0.5f, 0.0f), (float)(NK - 1));
    int k = (int)pos;
    const bf8v* tp = (const bf8v*)(Tb + ((size_t)(l + 1) * NK + k) * HC + c0);
    bf8v tv[4];
    #pragma unroll
    for (int g = 0; g < 4; g++) tv[g] = tp[g];
    const bf8v* yp = (const bf8v*)(ybf + (size_t)src_s[e] * HC + c0);
    bf8v yv[4];
    #pragma unroll
    for (int g = 0; g < 4; g++) yv[g] = yp[g];
    #pragma unroll
    for (int g = 0; g < 4; g++)
        #pragma unroll
        for (int m = 0; m < 8; m++) {
            float v = s2f((unsigned short)tv[g][m]) * s2f((unsigned short)yv[g][m]);
            mvT[c0 + g * 8 + m][row] = f2b(v);
        }
    __syncthreads();
    seg_mfma(mvT, ddst, slot_s, distinct_s, nseg_s, msum, tid);
}

// ---- node update, 32 rows/block ----
__global__ __launch_bounds__(256)
void upd_mfma_k(float* msum, int l,
                const bf16* __restrict__ cw2p, const float* __restrict__ cb2cv,
                const bf16* __restrict__ lwp, const float* __restrict__ lbcv,
                const bf16* __restrict__ cw1p, int do_y, int last,
                float* __restrict__ x, bf16* __restrict__ xb,
                bf16* __restrict__ ybf, void* out, const int* flagp) {
    __shared__ bf16 srow[32][136];
    int tid = threadIdx.x;
    int wave = tid >> 6, lane = tid & 63, quad = lane >> 4, lc = lane & 15;
    int rb = wave >> 1, ch = wave & 1;
    int m0 = blockIdx.x * 32 + rb * 16;
    bf8v azero = {0, 0, 0, 0, 0, 0, 0, 0};
    bf8v af[4];
    int arow = m0 + lc;
    #pragma unroll
    for (int ks = 0; ks < 4; ks++) {
        if (arow < NATOMS) {
            const float* p = msum + (size_t)arow * HC + ks * 32 + quad * 8;
            bf8v f;
            #pragma unroll
            for (int j = 0; j < 8; j++) f[j] = f2s(p[j]);
            af[ks] = f;
        } else af[ks] = azero;
    }
    f4v zero = {0.f, 0.f, 0.f, 0.f};
    f4v acc[4];
    #pragma unroll
    for (int nt = 0; nt < 4; nt++) acc[nt] = zero;
    const bf16* c2b = cw2p + (size_t)l * 16384;
    #pragma unroll
    for (int nt = 0; nt < 4; nt++)
        #pragma unroll
        for (int ks = 0; ks < 4; ks++) {
            bf8v b = *(const bf8v*)(c2b + (((ch * 4 + nt) * 4 + ks) * 64 + lane) * 8);
            acc[nt] = MFMA(af[ks], b, acc[nt]);
        }
    #pragma unroll
    for (int nt = 0; nt < 4; nt++) {
        int n = ch * 64 + nt * 16 + lc;
        float bb = cb2cv[l * HC + n];
        #pragma unroll
        for (int r = 0; r < 4; r++)
            srow[rb * 16 + quad * 4 + r][n] = f2b(silu(acc[nt][r] + bb));
    }
    __syncthreads();
    if (ch == 0 && arow < NATOMS) {
        float zdep = fminf(fabsf(acc[0][0]), 0.0f);
        f4v zv = {zdep, zdep, zdep, zdep};
        #pragma unroll
        for (int ks = 0; ks < 4; ks++) {
            *(f4v*)(msum + (size_t)arow * HC + ks * 32 + quad * 8) = zv;
            *(f4v*)(msum + (size_t)arow * HC + ks * 32 + quad * 8 + 4) = zv;
        }
    }
    bf8v a2[4];
    #pragma unroll
    for (int ks = 0; ks < 4; ks++)
        a2[ks] = *(const bf8v*)&srow[rb * 16 + lc][ks * 32 + quad * 8];
    __syncthreads();
    f4v acc2[4];
    #pragma unroll
    for (int nt = 0; nt < 4; nt++) acc2[nt] = zero;
    const bf16* lwb = lwp + (size_t)l * 16384;
    #pragma unroll
    for (int nt = 0; nt < 4; nt++)
        #pragma unroll
        for (int ks = 0; ks < 4; ks++) {
            bf8v b = *(const bf8v*)(lwb + (((ch * 4 + nt) * 4 + ks) * 64 + lane) * 8);
            acc2[nt] = MFMA(a2[ks], b, acc2[nt]);
        }
    int isf = isf_of(flagp);
    #pragma unroll
    for (int nt = 0; nt < 4; nt++) {
        int n = ch * 64 + nt * 16 + lc;
        float bb = lbcv[l * HC + n];
        #pragma unroll
        for (int r = 0; r < 4; r++) {
            int row = m0 + quad * 4 + r;
            float nv = 0.0f;
            if (row < NATOMS) {
                size_t o = (size_t)row * HC + n;
                nv = x[o] + acc2[nt][r] + bb;
                if (!last) {
                    x[o] = nv;
                    xb[o] = f2b(nv);
                } else {
                    if (isf) ((float*)out)[o] = nv;
                    else     ((bf16*)out)[o] = f2b(nv);
                }
            }
            srow[rb * 16 + quad * 4 + r][n] = f2b(nv);
        }
    }
    if (do_y) {
        __syncthreads();
        bf8v a3[4];
        #pragma unroll
        for (int ks = 0; ks < 4; ks++)
            a3[ks] = *(const bf8v*)&srow[rb * 16 + lc][ks * 32 + quad * 8];
        f4v acc3[4];
        #pragma unroll
        for (int nt = 0; nt < 4; nt++) acc3[nt] = zero;
        const bf16* c1b = cw1p + (size_t)(l + 1) * 16384;
        #pragma unroll
        for (int nt = 0; nt < 4; nt++)
            #pragma unroll
            for (int ks = 0; ks < 4; ks++) {
                bf8v b = *(const bf8v*)(c1b + (((ch * 4 + nt) * 4 + ks) * 64 + lane) * 8);
                acc3[nt] = MFMA(a3[ks], b, acc3[nt]);
            }
        #pragma unroll
        for (int nt = 0; nt < 4; nt++) {
            int n = ch * 64 + nt * 16 + lc;
            #pragma unroll
            for (int r = 0; r < 4; r++) {
                int row = m0 + quad * 4 + r;
                if (row < NATOMS) ybf[(size_t)row * HC + n] = f2b(acc3[nt][r]);
            }
        }
    }
}

// ---------------- launch ----------------
extern "C" void kernel_launch(void* const* d_in, const int* in_sizes, int n_in,
                              void* d_out, int out_size, void* d_ws, size_t ws_size,
                              hipStream_t stream) {
    const int*  z      = (const int*) d_in[0];
    const void* pos    = d_in[1];
    const int*  ei     = (const int*) d_in[3];
    const void* emb    = d_in[4];
    const void* nbremb = d_in[5];
    const void* Wp     = d_in[6];
    const void* bp     = d_in[7];
    const void* Wc     = d_in[8];
    const void* bc     = d_in[9];
    const void* means  = d_in[10];
    const void* betas  = d_in[11];
    const void* W1     = d_in[12];
    const void* b1     = d_in[13];
    const void* W2     = d_in[14];
    const void* b2     = d_in[15];
    const void* cW1    = d_in[16];
    const void* cW2    = d_in[17];
    const void* cb2    = d_in[18];
    const void* lW     = d_in[19];
    const void* lb     = d_in[20];

    char* p = (char*)d_ws;
    auto alloc = [&](size_t bytes) { char* r = p; p += (bytes + 255) / 256 * 256; return r; };
    // flag | counts | msum | msg CONTIGUOUS -> one memset zeroes all four
    int*   flag    = (int*)  alloc(256);
    int*   counts  = (int*)  alloc((size_t)NATOMS * 4);
    float* msum    = (float*)alloc((size_t)NATOMS * HC * 4);
    float* msg     = (float*)alloc((size_t)NATOMS * HC * 4);
    int*   rowptr  = (int*)  alloc((size_t)(NATOMS + 1) * 4);
    int*   cursor  = (int*)  alloc((size_t)NATOMS * 4);
    int*   src_s   = (int*)  alloc((size_t)NEDGES * 4);
    int*   dst_s   = (int*)  alloc((size_t)NEDGES * 4);
    float* ed_s    = (float*)alloc((size_t)NEDGES * 4);
    float* x       = (float*)alloc((size_t)NATOMS * HC * 4);
    bf16*  xb      = (bf16*) alloc((size_t)NATOMS * HC * 2);
    bf16*  ybf     = (bf16*) alloc((size_t)NATOMS * HC * 2);
    bf16*  Tb      = (bf16*) alloc((size_t)(NLAY + 1) * NK * HC * 2);  // 14.7 MB
    bf16*  wpp     = (bf16*) alloc((size_t)8192 * 2);
    bf16*  wcp     = (bf16*) alloc((size_t)32768 * 2);
    bf16*  w1p     = (bf16*) alloc((size_t)NLAY * 8192 * 2);
    bf16*  w2p     = (bf16*) alloc((size_t)NLAY * 16384 * 2);
    bf16*  cw1p    = (bf16*) alloc((size_t)NLAY * 16384 * 2);
    bf16*  cw2p    = (bf16*) alloc((size_t)NLAY * 16384 * 2);
    bf16*  lwp     = (bf16*) alloc((size_t)NLAY * 16384 * 2);
    bf16*  nbrembbf= (bf16*) alloc((size_t)MAXZ_ * HC * 2);
    float* bpcv    = (float*)alloc((size_t)HC * 4);
    float* bccv    = (float*)alloc((size_t)HC * 4);
    float* b1cv    = (float*)alloc((size_t)NLAY * HC * 4);
    float* b2cv    = (float*)alloc((size_t)NLAY * HC * 4);
    float* cb2cv   = (float*)alloc((size_t)NLAY * HC * 4);
    float* lbcv    = (float*)alloc((size_t)NLAY * HC * 4);
    float* meanscv = (float*)alloc((size_t)RBF * 4);
    float* betascv = (float*)alloc((size_t)RBF * 4);

    const int EG = (NEDGES + 255) / 256;

    // one memset: flag (256B) + counts (padded) + msum + msg
    size_t zbytes = 256 + ((size_t)NATOMS * 4 + 255) / 256 * 256
                  + (size_t)2 * NATOMS * HC * 4;
    hipMemsetAsync(flag, 0, zbytes, stream);
    probe_k<<<(NATOMS * 3 + 255) / 256, 256, 0, stream>>>(pos, flag);
    histd_k<<<EG, 256, 0, stream>>>(ei, pos, flag, counts, ed_s, src_s, dst_s);
    scan_k<<<1, 1024, 0, stream>>>(counts, rowptr, cursor);
    permgeom_k<<<EG, 256, 0, stream>>>(ei, pos, cursor, flag, ed_s, src_s, dst_s);

    packall_k<<<300, 256, 0, stream>>>(Wp, Wc, W1, W2, cW1, cW2, lW, means, betas,
                                       bp, bc, b1, b2, cb2, lb, nbremb, flag,
                                       wpp, wcp, w1p, w2p, cw1p, cw2p, lwp,
                                       meanscv, betascv, bpcv, bccv, b1cv, b2cv,
                                       cb2cv, lbcv, nbrembbf);
    tabbuild_k<<<7 * (NK / 64), 256, 0, stream>>>(wpp, bpcv, w1p, b1cv, w2p, b2cv,
                                                  meanscv, betascv, Tb);

    nbr_tab_k<<<EGRID, 256, 0, stream>>>(rowptr, ed_s, src_s, dst_s, z, nbrembbf, Tb, msg);
    combine_k<<<YGRID, 256, 0, stream>>>(z, emb, msg, wcp, bccv, cw1p, flag, x, xb, ybf);

    for (int l = 0; l < NLAY; l++) {
        filt_tab_k<<<EGRID, 256, 0, stream>>>(l, rowptr, ed_s, src_s, dst_s, ybf, Tb, msum);
        int lastl = (l == NLAY - 1) ? 1 : 0;
        upd_mfma_k<<<UGRID, 256, 0, stream>>>(msum, l, cw2p, cb2cv, lwp, lbcv,
                                              cw1p, lastl ? 0 : 1, lastl,
                                              x, xb, ybf, d_out, flag);
    }
}